// Round 1
// baseline (4352.062 us; speedup 1.0000x reference)
//
#include <hip/hip_runtime.h>

#define NN 50000      // nodes
#define NE 625000     // edges
#define DD 128        // hidden dim
#define HH 8          // heads
#define DHH 16        // head dim
#define NL 4          // layers
#define FIN 64        // in channels
#define NG 64         // graphs
#define LN_EPS 1e-5f

// ---------- helpers ----------
__device__ __forceinline__ unsigned fenc(float f) {
  unsigned u = __float_as_uint(f);
  return (u & 0x80000000u) ? ~u : (u | 0x80000000u);   // monotonic float->uint
}
__device__ __forceinline__ float fdec(unsigned u) {
  return __uint_as_float((u & 0x80000000u) ? (u & 0x7FFFFFFFu) : ~u);
}
__device__ __forceinline__ void fma4(float4& a, float s, float4 w) {
  a.x = fmaf(s, w.x, a.x); a.y = fmaf(s, w.y, a.y);
  a.z = fmaf(s, w.z, a.z); a.w = fmaf(s, w.w, a.w);
}

// LayerNorm 16 nodes -> LDS tile [16][128]; block = 256 threads (16 lanes/node)
__device__ __forceinline__ void ln_tile(const float* __restrict__ h, int nb,
                                        const float* __restrict__ sc,
                                        const float* __restrict__ bi,
                                        float xn[16][DD]) {
  int tid = threadIdx.x;
  int r = tid >> 4, l16 = tid & 15;
  const float* hp = h + (size_t)(nb + r) * DD + l16 * 8;
  float4 a0 = *(const float4*)hp;
  float4 a1 = *(const float4*)(hp + 4);
  float sum = a0.x + a0.y + a0.z + a0.w + a1.x + a1.y + a1.z + a1.w;
  float sq  = a0.x*a0.x + a0.y*a0.y + a0.z*a0.z + a0.w*a0.w
            + a1.x*a1.x + a1.y*a1.y + a1.z*a1.z + a1.w*a1.w;
#pragma unroll
  for (int off = 8; off >= 1; off >>= 1) {
    sum += __shfl_xor(sum, off, 64);
    sq  += __shfl_xor(sq,  off, 64);
  }
  float mu   = sum * (1.0f / DD);
  float var  = sq * (1.0f / DD) - mu * mu;
  float rstd = rsqrtf(var + LN_EPS);
  int d0 = l16 * 8;
  float4 s0 = *(const float4*)(sc + d0), s1 = *(const float4*)(sc + d0 + 4);
  float4 b0 = *(const float4*)(bi + d0), b1 = *(const float4*)(bi + d0 + 4);
  float4 o0, o1;
  o0.x = (a0.x - mu) * rstd * s0.x + b0.x;
  o0.y = (a0.y - mu) * rstd * s0.y + b0.y;
  o0.z = (a0.z - mu) * rstd * s0.z + b0.z;
  o0.w = (a0.w - mu) * rstd * s0.w + b0.w;
  o1.x = (a1.x - mu) * rstd * s1.x + b1.x;
  o1.y = (a1.y - mu) * rstd * s1.y + b1.y;
  o1.z = (a1.z - mu) * rstd * s1.z + b1.z;
  o1.w = (a1.w - mu) * rstd * s1.w + b1.w;
  *(float4*)&xn[r][d0]     = o0;
  *(float4*)&xn[r][d0 + 4] = o1;
}

// [16,128] @ [128,128] + bias ; MODE 0: store, 1: accumulate into out (residual)
template <int MODE>
__device__ __forceinline__ void gemm16(const float xn[16][DD], const float* __restrict__ W,
                                       const float* __restrict__ bias, float* __restrict__ out,
                                       int nb) {
  int tid = threadIdx.x;
  int c4 = (tid & 31) * 4;       // 4 consecutive output cols
  int r0 = (tid >> 5) * 2;       // 2 rows
  float4 acc0 = *(const float4*)(bias + c4);
  float4 acc1 = acc0;
  for (int kk = 0; kk < DD; kk += 4) {
    float4 x0 = *(const float4*)&xn[r0][kk];
    float4 x1 = *(const float4*)&xn[r0 + 1][kk];
    const float* wp = W + (size_t)kk * DD + c4;
    float4 w0 = *(const float4*)wp;
    float4 w1 = *(const float4*)(wp + DD);
    float4 w2 = *(const float4*)(wp + 2 * DD);
    float4 w3 = *(const float4*)(wp + 3 * DD);
    fma4(acc0, x0.x, w0); fma4(acc0, x0.y, w1); fma4(acc0, x0.z, w2); fma4(acc0, x0.w, w3);
    fma4(acc1, x1.x, w0); fma4(acc1, x1.y, w1); fma4(acc1, x1.z, w2); fma4(acc1, x1.w, w3);
  }
  float* o0 = out + (size_t)(nb + r0) * DD + c4;
  float* o1 = o0 + DD;
  if (MODE == 0) {
    *(float4*)o0 = acc0; *(float4*)o1 = acc1;
  } else {
    float4 h0 = *(const float4*)o0, h1 = *(const float4*)o1;
    h0.x += acc0.x; h0.y += acc0.y; h0.z += acc0.z; h0.w += acc0.w;
    h1.x += acc1.x; h1.y += acc1.y; h1.z += acc1.z; h1.w += acc1.w;
    *(float4*)o0 = h0; *(float4*)o1 = h1;
  }
}

// ---------- kernels ----------
// h = x @ node_W + node_b ; 8 nodes/block
__global__ __launch_bounds__(256) void k_node_proj(const float* __restrict__ x,
                                                   const float* __restrict__ W,
                                                   const float* __restrict__ b,
                                                   float* __restrict__ h) {
  __shared__ float xt[8][FIN];
  int tid = threadIdx.x;
  int nb = blockIdx.x * 8;
  {
    int idx = tid * 2;
    *(float2*)&xt[idx >> 6][idx & 63] = *(const float2*)(x + (size_t)nb * FIN + idx);
  }
  __syncthreads();
  int c4 = (tid & 31) * 4;
  int r  = tid >> 5;
  float4 acc = *(const float4*)(b + c4);
  for (int k = 0; k < FIN; k += 4) {
    float4 xk = *(const float4*)&xt[r][k];
    const float* wp = W + (size_t)k * DD + c4;
    fma4(acc, xk.x, *(const float4*)wp);
    fma4(acc, xk.y, *(const float4*)(wp + DD));
    fma4(acc, xk.z, *(const float4*)(wp + 2 * DD));
    fma4(acc, xk.w, *(const float4*)(wp + 3 * DD));
  }
  *(float4*)(h + (size_t)(nb + r) * DD + c4) = acc;
}

// per edge: sim (dot), dist (norm), atomicMax of sim over tgt. 32 lanes/edge.
__global__ __launch_bounds__(256) void k_edge1(const int* __restrict__ src, const int* __restrict__ tgt,
                                               const float* __restrict__ h, float* __restrict__ sim,
                                               float* __restrict__ dist, unsigned* __restrict__ m_enc) {
  int tid = threadIdx.x;
  int wave = (blockIdx.x * 256 + tid) >> 6;
  int lane = tid & 63;
  int e = wave * 2 + (lane >> 5);
  int j = lane & 31;
  int s = src[e], t = tgt[e];
  float4 a = *(const float4*)(h + (size_t)s * DD + j * 4);
  float4 b = *(const float4*)(h + (size_t)t * DD + j * 4);
  float dot = a.x*b.x + a.y*b.y + a.z*b.z + a.w*b.w;
  float dx = a.x-b.x, dy = a.y-b.y, dz = a.z-b.z, dw = a.w-b.w;
  float sq = dx*dx + dy*dy + dz*dz + dw*dw;
#pragma unroll
  for (int off = 16; off >= 1; off >>= 1) {
    dot += __shfl_xor(dot, off, 64);
    sq  += __shfl_xor(sq,  off, 64);
  }
  if (j == 0) {
    sim[e]  = dot;                  // BETA == 1.0
    dist[e] = sqrtf(sq);
    atomicMax(m_enc + t, fenc(dot));
  }
}

// denom & alpha*dist numerator per tgt
__global__ void k_edge2(const int* __restrict__ tgt, const float* __restrict__ sim,
                        const float* __restrict__ dist, const unsigned* __restrict__ m_enc,
                        float* __restrict__ den, float* __restrict__ nd) {
  int e = blockIdx.x * 256 + threadIdx.x;
  if (e >= NE) return;
  int t = tgt[e];
  float ev = expf(sim[e] - fdec(m_enc[t]));
  atomicAdd(den + t, ev);
  atomicAdd(nd + t, ev * dist[e]);
}

__global__ void k_aggv(const float* __restrict__ den, const float* __restrict__ nd,
                       float* __restrict__ aggv) {
  int n = blockIdx.x * 256 + threadIdx.x;
  if (n >= NN) return;
  float d = den[n];
  aggv[n] = d > 0.f ? nd[n] / d : 0.f;
}

__global__ __launch_bounds__(256) void k_ln_qkv(const float* __restrict__ h,
    const float* __restrict__ n1s_l, const float* __restrict__ n1b_l,
    const float* __restrict__ qW_l, const float* __restrict__ qb_l,
    const float* __restrict__ kW_l, const float* __restrict__ kb_l,
    const float* __restrict__ vW_l, const float* __restrict__ vb_l,
    float* __restrict__ q, float* __restrict__ k, float* __restrict__ v) {
  __shared__ float xn[16][DD];
  int nb = blockIdx.x * 16;
  ln_tile(h, nb, n1s_l, n1b_l, xn);
  __syncthreads();
  gemm16<0>(xn, qW_l, qb_l, q, nb);
  gemm16<0>(xn, kW_l, kb_l, k, nb);
  gemm16<0>(xn, vW_l, vb_l, v, nb);
}

// per (edge, head): qk score + curvature bias; atomicMax over tgt
__global__ __launch_bounds__(256) void k_scores(const int* __restrict__ src, const int* __restrict__ tgt,
    const float* __restrict__ q, const float* __restrict__ k,
    const float* __restrict__ dist, const float* __restrict__ aggv,
    const float* __restrict__ Ml, const float* __restrict__ basel,
    const float* __restrict__ cW1, const float* __restrict__ cb1,
    float* __restrict__ escore, unsigned* __restrict__ sm_enc) {
  __shared__ float lc1[DD], lcb[DD], lM[DD * HH];
  int tid = threadIdx.x;
  for (int i = tid; i < DD; i += 256) { lc1[i] = cW1[i]; lcb[i] = cb1[i]; }
  for (int i = tid; i < DD * HH; i += 256) lM[i] = Ml[i];
  __syncthreads();
  int gi = blockIdx.x * 256 + tid;
  if (gi >= NE * HH) return;
  int e = gi >> 3, hh = gi & 7;
  int s = src[e], t = tgt[e];
  float dd = dist[e];
  float curv = 1.0f - aggv[t] / fmaxf(dd, 1e-6f);
  float acc = basel[hh];
#pragma unroll 4
  for (int d = 0; d < DD; d++) {
    float r = fmaxf(fmaf(curv, lc1[d], lcb[d]), 0.0f);
    acc = fmaf(r, lM[d * HH + hh], acc);
  }
  const float4* qp = (const float4*)(q + (size_t)s * DD + hh * DHH);
  const float4* kp = (const float4*)(k + (size_t)t * DD + hh * DHH);
  float dot = 0.f;
#pragma unroll
  for (int i = 0; i < 4; i++) {
    float4 a = qp[i], b = kp[i];
    dot += a.x*b.x + a.y*b.y + a.z*b.z + a.w*b.w;
  }
  float sc = dot * 0.25f + acc;   // 1/sqrt(16)
  escore[gi] = sc;
  atomicMax(sm_enc + (size_t)t * HH + hh, fenc(sc));
}

__global__ void k_probs(const int* __restrict__ tgt, const unsigned* __restrict__ sm_enc,
                        float* __restrict__ escore, float* __restrict__ sden) {
  int gi = blockIdx.x * 256 + threadIdx.x;
  if (gi >= NE * HH) return;
  int e = gi >> 3, hh = gi & 7;
  int t = tgt[e];
  float p = expf(escore[gi] - fdec(sm_enc[(size_t)t * HH + hh]));
  escore[gi] = p;
  atomicAdd(sden + (size_t)t * HH + hh, p);
}

__global__ void k_sdinv(float* __restrict__ sden) {
  int i = blockIdx.x * 256 + threadIdx.x;
  if (i >= NN * HH) return;
  float x = sden[i];
  sden[i] = x > 0.f ? 1.0f / x : 0.f;
}

// CSR-gather message aggregation: one wave per src node, 2 dims/lane
__global__ __launch_bounds__(256) void k_agg(const int* __restrict__ tgt,
    const int* __restrict__ rowstart, const int* __restrict__ eids,
    const float* __restrict__ escore, const float* __restrict__ sdinv,
    const float* __restrict__ v, float* __restrict__ aggm) {
  int wave = (blockIdx.x * 256 + threadIdx.x) >> 6;
  int lane = threadIdx.x & 63;
  int rs = rowstart[wave], re = rowstart[wave + 1];
  int hh = lane >> 3;
  int d = lane * 2;
  float a0 = 0.f, a1 = 0.f;
  for (int i = rs; i < re; i++) {
    int e = eids[i];
    int t = tgt[e];
    float prob = escore[e * HH + hh] * sdinv[t * HH + hh];
    float2 vv = *(const float2*)(v + (size_t)t * DD + d);
    a0 = fmaf(prob, vv.x, a0);
    a1 = fmaf(prob, vv.y, a1);
  }
  float2 o; o.x = a0; o.y = a1;
  *(float2*)(aggm + (size_t)wave * DD + d) = o;
}

__global__ __launch_bounds__(256) void k_update_o(const float* __restrict__ aggm,
    const float* __restrict__ oW_l, const float* __restrict__ ob_l, float* __restrict__ h) {
  __shared__ float xt[16][DD];
  int tid = threadIdx.x;
  int nb = blockIdx.x * 16;
  for (int i = tid * 4; i < 16 * DD; i += 1024)
    *(float4*)&xt[i >> 7][i & 127] = *(const float4*)(aggm + (size_t)nb * DD + i);
  __syncthreads();
  gemm16<1>(xt, oW_l, ob_l, h, nb);
}

// fused FFN: h += relu(LN2(h)@f1W+f1b)@f2W+f2b, chunked over the 512 dim
__global__ __launch_bounds__(256) void k_ffn(const float* __restrict__ n2s_l, const float* __restrict__ n2b_l,
    const float* __restrict__ f1W_l, const float* __restrict__ f1b_l,
    const float* __restrict__ f2W_l, const float* __restrict__ f2b_l,
    float* __restrict__ h) {
  __shared__ float xn[16][DD];
  __shared__ float tt[16][DD];
  int nb = blockIdx.x * 16;
  ln_tile(h, nb, n2s_l, n2b_l, xn);
  __syncthreads();
  int tid = threadIdx.x;
  int c4 = (tid & 31) * 4;
  int r0 = (tid >> 5) * 2;
  float4 accO0 = *(const float4*)(f2b_l + c4);
  float4 accO1 = accO0;
  for (int ch = 0; ch < 4; ch++) {
    float4 aT0 = *(const float4*)(f1b_l + ch * DD + c4);
    float4 aT1 = aT0;
    for (int kk = 0; kk < DD; kk += 4) {
      float4 x0 = *(const float4*)&xn[r0][kk];
      float4 x1 = *(const float4*)&xn[r0 + 1][kk];
      const float* wp = f1W_l + (size_t)kk * 512 + ch * DD + c4;
      float4 w0 = *(const float4*)wp;
      float4 w1 = *(const float4*)(wp + 512);
      float4 w2 = *(const float4*)(wp + 1024);
      float4 w3 = *(const float4*)(wp + 1536);
      fma4(aT0, x0.x, w0); fma4(aT0, x0.y, w1); fma4(aT0, x0.z, w2); fma4(aT0, x0.w, w3);
      fma4(aT1, x1.x, w0); fma4(aT1, x1.y, w1); fma4(aT1, x1.z, w2); fma4(aT1, x1.w, w3);
    }
    aT0.x = fmaxf(aT0.x, 0.f); aT0.y = fmaxf(aT0.y, 0.f);
    aT0.z = fmaxf(aT0.z, 0.f); aT0.w = fmaxf(aT0.w, 0.f);
    aT1.x = fmaxf(aT1.x, 0.f); aT1.y = fmaxf(aT1.y, 0.f);
    aT1.z = fmaxf(aT1.z, 0.f); aT1.w = fmaxf(aT1.w, 0.f);
    __syncthreads();
    *(float4*)&tt[r0][c4]     = aT0;
    *(float4*)&tt[r0 + 1][c4] = aT1;
    __syncthreads();
    for (int kk = 0; kk < DD; kk += 4) {
      float4 t0 = *(const float4*)&tt[r0][kk];
      float4 t1 = *(const float4*)&tt[r0 + 1][kk];
      const float* wp = f2W_l + (size_t)(ch * DD + kk) * DD + c4;
      float4 w0 = *(const float4*)wp;
      float4 w1 = *(const float4*)(wp + DD);
      float4 w2 = *(const float4*)(wp + 2 * DD);
      float4 w3 = *(const float4*)(wp + 3 * DD);
      fma4(accO0, t0.x, w0); fma4(accO0, t0.y, w1); fma4(accO0, t0.z, w2); fma4(accO0, t0.w, w3);
      fma4(accO1, t1.x, w0); fma4(accO1, t1.y, w1); fma4(accO1, t1.z, w2); fma4(accO1, t1.w, w3);
    }
  }
  float* hp0 = h + (size_t)(nb + r0) * DD + c4;
  float* hp1 = hp0 + DD;
  float4 h0 = *(const float4*)hp0, h1 = *(const float4*)hp1;
  h0.x += accO0.x; h0.y += accO0.y; h0.z += accO0.z; h0.w += accO0.w;
  h1.x += accO1.x; h1.y += accO1.y; h1.z += accO1.z; h1.w += accO1.w;
  *(float4*)hp0 = h0;
  *(float4*)hp1 = h1;
}

// ---------- once-per-call setup kernels ----------
__global__ void k_hist(const int* __restrict__ src, int* __restrict__ cnt) {
  int e = blockIdx.x * 256 + threadIdx.x;
  if (e < NE) atomicAdd(cnt + src[e], 1);
}

__global__ __launch_bounds__(1024) void k_scan(const int* __restrict__ cnt, int* __restrict__ rowstart) {
  __shared__ int ps[1024];
  int t = threadIdx.x;
  const int CH = 49;                 // 1024*49 = 50176 >= NN
  int base = t * CH;
  int s = 0;
  for (int i = 0; i < CH; i++) {
    int idx = base + i;
    if (idx < NN) s += cnt[idx];
  }
  ps[t] = s;
  __syncthreads();
  for (int off = 1; off < 1024; off <<= 1) {
    int vv = (t >= off) ? ps[t - off] : 0;
    __syncthreads();
    ps[t] += vv;
    __syncthreads();
  }
  int run = ps[t] - s;               // exclusive prefix
  for (int i = 0; i < CH; i++) {
    int idx = base + i;
    if (idx < NN) { rowstart[idx] = run; run += cnt[idx]; }
  }
  if (t == 1023) rowstart[NN] = ps[1023];
}

__global__ void k_fill(const int* __restrict__ src, const int* __restrict__ rowstart,
                       int* __restrict__ cur, int* __restrict__ eids) {
  int e = blockIdx.x * 256 + threadIdx.x;
  if (e >= NE) return;
  int s = src[e];
  int p = atomicAdd(cur + s, 1);
  eids[rowstart[s] + p] = e;
}

// M_l = cW2 @ bW_l  [128,8];  base_l = cb2 @ bW_l + bb_l  [8]
__global__ void k_mbias(const float* __restrict__ cW2, const float* __restrict__ cb2,
                        const float* __restrict__ bW, const float* __restrict__ bb,
                        float* __restrict__ M, float* __restrict__ base) {
  int l = blockIdx.x;
  int tid = threadIdx.x;
  const float* bWl = bW + (size_t)l * DD * HH;
  for (int idx = tid; idx < DD * HH; idx += 256) {
    int d = idx >> 3, hh = idx & 7;
    float acc = 0.f;
    for (int j = 0; j < DD; j++) acc = fmaf(cW2[d * DD + j], bWl[j * HH + hh], acc);
    M[(size_t)l * DD * HH + idx] = acc;
  }
  if (tid < HH) {
    float acc = bb[l * HH + tid];
    for (int j = 0; j < DD; j++) acc = fmaf(cb2[j], bWl[j * HH + tid], acc);
    base[l * HH + tid] = acc;
  }
}

__global__ void k_bounds(const int* __restrict__ batch, int* __restrict__ gstart, int* __restrict__ gend) {
  int n = blockIdx.x * 256 + threadIdx.x;
  if (n >= NN) return;
  int b = batch[n];
  if (n == 0 || batch[n - 1] != b) gstart[b] = n;
  if (n == NN - 1 || batch[n + 1] != b) gend[b] = n + 1;
}

__global__ __launch_bounds__(256) void k_pool(const float* __restrict__ h, const int* __restrict__ gstart,
                                              const int* __restrict__ gend, float* __restrict__ gpool) {
  __shared__ float red[256];
  int g = blockIdx.x;
  int s0 = gstart[g], e0 = gend[g];
  int tid = threadIdx.x;
  int d = tid & 127, half = tid >> 7;
  float sum = 0.f;
  for (int n = s0 + half; n < e0; n += 2) sum += h[(size_t)n * DD + d];
  red[tid] = sum;
  __syncthreads();
  if (half == 0) {
    float tot = red[tid] + red[tid + 128];
    int c = e0 - s0;
    gpool[g * DD + d] = tot / (float)max(c, 1);
  }
}

__global__ __launch_bounds__(256) void k_head(const float* __restrict__ gpool,
    const float* __restrict__ W1, const float* __restrict__ b1,
    const float* __restrict__ W2, const float* __restrict__ b2, float* __restrict__ out) {
  __shared__ float mid[NG * 64];
  int tid = threadIdx.x;
  for (int idx = tid; idx < NG * 64; idx += 256) {
    int g = idx >> 6, j = idx & 63;
    float acc = b1[j];
    for (int d = 0; d < DD; d++) acc = fmaf(gpool[g * DD + d], W1[d * 64 + j], acc);
    mid[idx] = fmaxf(acc, 0.f);
  }
  __syncthreads();
  if (tid < NG) {
    float acc = b2[0];
    for (int j = 0; j < 64; j++) acc = fmaf(mid[tid * 64 + j], W2[j], acc);
    out[tid] = acc;
  }
}

// ---------- launch ----------
extern "C" void kernel_launch(void* const* d_in, const int* in_sizes, int n_in,
                              void* d_out, int out_size, void* d_ws, size_t ws_size,
                              hipStream_t stream) {
  const float* x      = (const float*)d_in[0];
  const int*   ei     = (const int*)d_in[1];
  const int*   batch  = (const int*)d_in[2];
  const float* node_W = (const float*)d_in[3];
  const float* node_b = (const float*)d_in[4];
  const float* cW1    = (const float*)d_in[5];
  const float* cb1    = (const float*)d_in[6];
  const float* cW2    = (const float*)d_in[7];
  const float* cb2    = (const float*)d_in[8];
  const float* qW     = (const float*)d_in[9];
  const float* qb     = (const float*)d_in[10];
  const float* kW     = (const float*)d_in[11];
  const float* kb     = (const float*)d_in[12];
  const float* vW     = (const float*)d_in[13];
  const float* vb     = (const float*)d_in[14];
  const float* oW     = (const float*)d_in[15];
  const float* ob     = (const float*)d_in[16];
  const float* bW     = (const float*)d_in[17];
  const float* bb     = (const float*)d_in[18];
  const float* f1W    = (const float*)d_in[19];
  const float* f1b    = (const float*)d_in[20];
  const float* f2W    = (const float*)d_in[21];
  const float* f2b    = (const float*)d_in[22];
  const float* n1s    = (const float*)d_in[23];
  const float* n1b    = (const float*)d_in[24];
  const float* n2s    = (const float*)d_in[25];
  const float* n2b    = (const float*)d_in[26];
  const float* outW1  = (const float*)d_in[27];
  const float* outb1  = (const float*)d_in[28];
  const float* outW2  = (const float*)d_in[29];
  const float* outb2  = (const float*)d_in[30];

  const int* src = ei;
  const int* tgt = ei + NE;

  char* wp = (char*)d_ws;
  auto alloc = [&](size_t elems) { void* p = (void*)wp; wp += elems * 4; return p; };
  float*    h       = (float*)alloc((size_t)NN * DD);
  float*    q       = (float*)alloc((size_t)NN * DD);
  float*    kk      = (float*)alloc((size_t)NN * DD);
  float*    v       = (float*)alloc((size_t)NN * DD);
  float*    aggm    = (float*)alloc((size_t)NN * DD);
  float*    sim     = (float*)alloc(NE);
  float*    dist    = (float*)alloc(NE);
  float*    escore  = (float*)alloc((size_t)NE * HH);
  char*     zbase   = wp;                         // zeroed once per layer:
  unsigned* m_enc   = (unsigned*)alloc(NN);
  float*    den     = (float*)alloc(NN);
  float*    nd      = (float*)alloc(NN);
  unsigned* sm_enc  = (unsigned*)alloc((size_t)NN * HH);
  float*    sden    = (float*)alloc((size_t)NN * HH);
  size_t    zbytes  = (size_t)(wp - zbase);
  float*    aggv    = (float*)alloc(NN);
  float*    Mb      = (float*)alloc(NL * DD * HH);
  float*    basel   = (float*)alloc(NL * HH);
  int*      rowstart= (int*)alloc(NN + 1);
  int*      eids    = (int*)alloc(NE);
  int*      cnt     = (int*)alloc(NN);
  int*      cur     = (int*)alloc(NN);
  int*      gstart  = (int*)alloc(NG);
  int*      gend    = (int*)alloc(NG);
  float*    gpool   = (float*)alloc(NG * DD);
  (void)in_sizes; (void)n_in; (void)out_size; (void)ws_size;

  // once-per-call setup
  hipMemsetAsync(cnt, 0, NN * 4, stream);
  hipMemsetAsync(cur, 0, NN * 4, stream);
  hipMemsetAsync(gstart, 0, NG * 4 * 2, stream);   // gstart + gend are adjacent
  k_hist<<<(NE + 255) / 256, 256, 0, stream>>>(src, cnt);
  k_scan<<<1, 1024, 0, stream>>>(cnt, rowstart);
  k_fill<<<(NE + 255) / 256, 256, 0, stream>>>(src, rowstart, cur, eids);
  k_mbias<<<NL, 256, 0, stream>>>(cW2, cb2, bW, bb, Mb, basel);
  k_bounds<<<(NN + 255) / 256, 256, 0, stream>>>(batch, gstart, gend);
  k_node_proj<<<NN / 8, 256, 0, stream>>>(x, node_W, node_b, h);

  for (int l = 0; l < NL; l++) {
    hipMemsetAsync(zbase, 0, zbytes, stream);
    k_edge1<<<NE / 8, 256, 0, stream>>>(src, tgt, h, sim, dist, m_enc);
    k_edge2<<<(NE + 255) / 256, 256, 0, stream>>>(tgt, sim, dist, m_enc, den, nd);
    k_aggv<<<(NN + 255) / 256, 256, 0, stream>>>(den, nd, aggv);
    k_ln_qkv<<<NN / 16, 256, 0, stream>>>(h, n1s + l * DD, n1b + l * DD,
        qW + (size_t)l * DD * DD, qb + l * DD,
        kW + (size_t)l * DD * DD, kb + l * DD,
        vW + (size_t)l * DD * DD, vb + l * DD, q, kk, v);
    k_scores<<<(NE * HH + 255) / 256, 256, 0, stream>>>(src, tgt, q, kk, dist, aggv,
        Mb + (size_t)l * DD * HH, basel + l * HH, cW1, cb1, escore, sm_enc);
    k_probs<<<(NE * HH + 255) / 256, 256, 0, stream>>>(tgt, sm_enc, escore, sden);
    k_sdinv<<<(NN * HH + 255) / 256, 256, 0, stream>>>(sden);
    k_agg<<<NN / 4, 256, 0, stream>>>(tgt, rowstart, eids, escore, sden, v, aggm);
    k_update_o<<<NN / 16, 256, 0, stream>>>(aggm, oW + (size_t)l * DD * DD, ob + l * DD, h);
    k_ffn<<<NN / 16, 256, 0, stream>>>(n2s + l * DD, n2b + l * DD,
        f1W + (size_t)l * DD * 4 * DD, f1b + (size_t)l * 4 * DD,
        f2W + (size_t)l * 4 * DD * DD, f2b + l * DD, h);
  }
  k_pool<<<NG, 256, 0, stream>>>(h, gstart, gend, gpool);
  k_head<<<1, 256, 0, stream>>>(gpool, outW1, outb1, outW2, outb2, (float*)d_out);
}

// Round 2
// 2701.401 us; speedup vs baseline: 1.6110x; 1.6110x over previous
//
#include <hip/hip_runtime.h>

#define NN 50000      // nodes
#define NE 625000     // edges
#define DD 128        // hidden dim
#define HH 8          // heads
#define DHH 16        // head dim
#define NL 4          // layers
#define FIN 64        // in channels
#define NG 64         // graphs
#define LN_EPS 1e-5f

typedef __bf16 bf16x8_t __attribute__((ext_vector_type(8)));
typedef unsigned short ushort8_t __attribute__((ext_vector_type(8)));
typedef float f32x4_t __attribute__((ext_vector_type(4)));
union BF8 { ushort8_t u; bf16x8_t b; };

// ---------- helpers ----------
__device__ __forceinline__ unsigned fenc(float f) {
  unsigned u = __float_as_uint(f);
  return (u & 0x80000000u) ? ~u : (u | 0x80000000u);   // monotonic float->uint
}
__device__ __forceinline__ float fdec(unsigned u) {
  return __uint_as_float((u & 0x80000000u) ? (u & 0x7FFFFFFFu) : ~u);
}
__device__ __forceinline__ void fma4(float4& a, float s, float4 w) {
  a.x = fmaf(s, w.x, a.x); a.y = fmaf(s, w.y, a.y);
  a.z = fmaf(s, w.z, a.z); a.w = fmaf(s, w.w, a.w);
}
__device__ __forceinline__ unsigned short f2bf(float f) {   // RNE f32->bf16
  unsigned u = __float_as_uint(f);
  unsigned r = ((u >> 16) & 1u) + 0x7FFFu;
  return (unsigned short)((u + r) >> 16);
}

// LayerNorm 16 nodes -> swizzled bf16 LDS tile [16][128]; block = 256 threads.
// byte offset = (row*256 + col*2) ^ ((row&7)<<4)  -> conflict-free ds_read_b128
__device__ __forceinline__ void ln_tile_bf(const float* __restrict__ h, int nb,
                                           const float* __restrict__ sc,
                                           const float* __restrict__ bi,
                                           ushort* xbf) {
  int tid = threadIdx.x;
  int r = tid >> 4, l16 = tid & 15;
  const float* hp = h + (size_t)(nb + r) * DD + l16 * 8;
  float4 a0 = *(const float4*)hp;
  float4 a1 = *(const float4*)(hp + 4);
  float sum = a0.x + a0.y + a0.z + a0.w + a1.x + a1.y + a1.z + a1.w;
  float sq  = a0.x*a0.x + a0.y*a0.y + a0.z*a0.z + a0.w*a0.w
            + a1.x*a1.x + a1.y*a1.y + a1.z*a1.z + a1.w*a1.w;
#pragma unroll
  for (int off = 8; off >= 1; off >>= 1) {
    sum += __shfl_xor(sum, off, 64);
    sq  += __shfl_xor(sq,  off, 64);
  }
  float mu   = sum * (1.0f / DD);
  float var  = sq * (1.0f / DD) - mu * mu;
  float rstd = rsqrtf(var + LN_EPS);
  int d0 = l16 * 8;
  float4 s0 = *(const float4*)(sc + d0), s1 = *(const float4*)(sc + d0 + 4);
  float4 b0 = *(const float4*)(bi + d0), b1 = *(const float4*)(bi + d0 + 4);
  ushort8_t u;
  u[0] = f2bf((a0.x - mu) * rstd * s0.x + b0.x);
  u[1] = f2bf((a0.y - mu) * rstd * s0.y + b0.y);
  u[2] = f2bf((a0.z - mu) * rstd * s0.z + b0.z);
  u[3] = f2bf((a0.w - mu) * rstd * s0.w + b0.w);
  u[4] = f2bf((a1.x - mu) * rstd * s1.x + b1.x);
  u[5] = f2bf((a1.y - mu) * rstd * s1.y + b1.y);
  u[6] = f2bf((a1.z - mu) * rstd * s1.z + b1.z);
  u[7] = f2bf((a1.w - mu) * rstd * s1.w + b1.w);
  int off = (r * 256 + l16 * 16) ^ ((r & 7) << 4);
  *(ushort8_t*)((char*)xbf + off) = u;
}

// ---------- kernels ----------
// h = x @ node_W + node_b ; 8 nodes/block (fp32 VALU — minor cost)
__global__ __launch_bounds__(256) void k_node_proj(const float* __restrict__ x,
                                                   const float* __restrict__ W,
                                                   const float* __restrict__ b,
                                                   float* __restrict__ h) {
  __shared__ float xt[8][FIN];
  int tid = threadIdx.x;
  int nb = blockIdx.x * 8;
  {
    int idx = tid * 2;
    *(float2*)&xt[idx >> 6][idx & 63] = *(const float2*)(x + (size_t)nb * FIN + idx);
  }
  __syncthreads();
  int c4 = (tid & 31) * 4;
  int r  = tid >> 5;
  float4 acc = *(const float4*)(b + c4);
  for (int k = 0; k < FIN; k += 4) {
    float4 xk = *(const float4*)&xt[r][k];
    const float* wp = W + (size_t)k * DD + c4;
    fma4(acc, xk.x, *(const float4*)wp);
    fma4(acc, xk.y, *(const float4*)(wp + DD));
    fma4(acc, xk.z, *(const float4*)(wp + 2 * DD));
    fma4(acc, xk.w, *(const float4*)(wp + 3 * DD));
  }
  *(float4*)(h + (size_t)(nb + r) * DD + c4) = acc;
}

// per edge: sim (dot), dist (norm), atomicMax of sim over tgt. 32 lanes/edge.
__global__ __launch_bounds__(256) void k_edge1(const int* __restrict__ src, const int* __restrict__ tgt,
                                               const float* __restrict__ h, float* __restrict__ sim,
                                               float* __restrict__ dist, unsigned* __restrict__ m_enc) {
  int tid = threadIdx.x;
  int wave = (blockIdx.x * 256 + tid) >> 6;
  int lane = tid & 63;
  int e = wave * 2 + (lane >> 5);
  int j = lane & 31;
  int s = src[e], t = tgt[e];
  float4 a = *(const float4*)(h + (size_t)s * DD + j * 4);
  float4 b = *(const float4*)(h + (size_t)t * DD + j * 4);
  float dot = a.x*b.x + a.y*b.y + a.z*b.z + a.w*b.w;
  float dx = a.x-b.x, dy = a.y-b.y, dz = a.z-b.z, dw = a.w-b.w;
  float sq = dx*dx + dy*dy + dz*dz + dw*dw;
#pragma unroll
  for (int off = 16; off >= 1; off >>= 1) {
    dot += __shfl_xor(dot, off, 64);
    sq  += __shfl_xor(sq,  off, 64);
  }
  if (j == 0) {
    sim[e]  = dot;                  // BETA == 1.0
    dist[e] = sqrtf(sq);
    atomicMax(m_enc + t, fenc(dot));
  }
}

// denom & alpha*dist numerator per tgt
__global__ void k_edge2(const int* __restrict__ tgt, const float* __restrict__ sim,
                        const float* __restrict__ dist, const unsigned* __restrict__ m_enc,
                        float* __restrict__ den, float* __restrict__ nd) {
  int e = blockIdx.x * 256 + threadIdx.x;
  if (e >= NE) return;
  int t = tgt[e];
  float ev = expf(sim[e] - fdec(m_enc[t]));
  atomicAdd(den + t, ev);
  atomicAdd(nd + t, ev * dist[e]);
}

__global__ void k_aggv(const float* __restrict__ den, const float* __restrict__ nd,
                       float* __restrict__ aggv) {
  int n = blockIdx.x * 256 + threadIdx.x;
  if (n >= NN) return;
  float d = den[n];
  aggv[n] = d > 0.f ? nd[n] / d : 0.f;
}

// LN1 + QKV projection via MFMA. 16 rows/block, 4 waves, 24 col-tiles (q|k|v).
__global__ __launch_bounds__(256) void k_ln_qkv(const float* __restrict__ h,
    const float* __restrict__ n1s_l, const float* __restrict__ n1b_l,
    const ushort* __restrict__ qkvT_l,
    const float* __restrict__ qb_l, const float* __restrict__ kb_l, const float* __restrict__ vb_l,
    float* __restrict__ q, float* __restrict__ kk, float* __restrict__ v) {
  __shared__ __align__(16) ushort xbf[16 * DD];
  int nb = blockIdx.x * 16;
  ln_tile_bf(h, nb, n1s_l, n1b_l, xbf);
  __syncthreads();
  int lane = threadIdx.x & 63;
  int w = threadIdx.x >> 6;
  int g = lane >> 4, c = lane & 15;
  int xr = (c & 7) << 4;
  BF8 a[4];
  char* xb = (char*)xbf;
#pragma unroll
  for (int kt = 0; kt < 4; kt++)
    a[kt].u = *(ushort8_t*)(xb + ((c * 256 + kt * 64 + g * 16) ^ xr));
#pragma unroll
  for (int ti = 0; ti < 6; ti++) {
    int t = w * 6 + ti;
    int m = t >> 3;                  // 0=q 1=k 2=v
    int colb = (t & 7) * 16;
    const float* bias = (m == 0 ? qb_l : (m == 1 ? kb_l : vb_l));
    float bv = bias[colb + c];
    f32x4_t acc = {bv, bv, bv, bv};
    const ushort* wp = qkvT_l + (size_t)(m * DD + colb + c) * DD + g * 8;
#pragma unroll
    for (int kt = 0; kt < 4; kt++) {
      BF8 b; b.u = *(const ushort8_t*)(wp + kt * 32);
      acc = __builtin_amdgcn_mfma_f32_16x16x32_bf16(a[kt].b, b.b, acc, 0, 0, 0);
    }
    float* out = (m == 0 ? q : (m == 1 ? kk : v));
#pragma unroll
    for (int j = 0; j < 4; j++)
      out[(size_t)(nb + g * 4 + j) * DD + colb + c] = acc[j];
  }
}

// per (edge, head): qk score + curvature bias; atomicMax over tgt
__global__ __launch_bounds__(256) void k_scores(const int* __restrict__ src, const int* __restrict__ tgt,
    const float* __restrict__ q, const float* __restrict__ k,
    const float* __restrict__ dist, const float* __restrict__ aggv,
    const float* __restrict__ Ml, const float* __restrict__ basel,
    const float* __restrict__ cW1, const float* __restrict__ cb1,
    float* __restrict__ escore, unsigned* __restrict__ sm_enc) {
  __shared__ float lc1[DD], lcb[DD], lM[DD * HH];
  int tid = threadIdx.x;
  for (int i = tid; i < DD; i += 256) { lc1[i] = cW1[i]; lcb[i] = cb1[i]; }
  for (int i = tid; i < DD * HH; i += 256) lM[i] = Ml[i];
  __syncthreads();
  int gi = blockIdx.x * 256 + tid;
  if (gi >= NE * HH) return;
  int e = gi >> 3, hh = gi & 7;
  int s = src[e], t = tgt[e];
  float dd = dist[e];
  float curv = 1.0f - aggv[t] / fmaxf(dd, 1e-6f);
  float acc = basel[hh];
#pragma unroll 4
  for (int d = 0; d < DD; d++) {
    float r = fmaxf(fmaf(curv, lc1[d], lcb[d]), 0.0f);
    acc = fmaf(r, lM[d * HH + hh], acc);
  }
  const float4* qp = (const float4*)(q + (size_t)s * DD + hh * DHH);
  const float4* kp = (const float4*)(k + (size_t)t * DD + hh * DHH);
  float dot = 0.f;
#pragma unroll
  for (int i = 0; i < 4; i++) {
    float4 a = qp[i], b = kp[i];
    dot += a.x*b.x + a.y*b.y + a.z*b.z + a.w*b.w;
  }
  float sc = dot * 0.25f + acc;   // 1/sqrt(16)
  escore[gi] = sc;
  atomicMax(sm_enc + (size_t)t * HH + hh, fenc(sc));
}

__global__ void k_probs(const int* __restrict__ tgt, const unsigned* __restrict__ sm_enc,
                        float* __restrict__ escore, float* __restrict__ sden) {
  int gi = blockIdx.x * 256 + threadIdx.x;
  if (gi >= NE * HH) return;
  int e = gi >> 3, hh = gi & 7;
  int t = tgt[e];
  float p = expf(escore[gi] - fdec(sm_enc[(size_t)t * HH + hh]));
  escore[gi] = p;
  atomicAdd(sden + (size_t)t * HH + hh, p);
}

__global__ void k_sdinv(float* __restrict__ sden) {
  int i = blockIdx.x * 256 + threadIdx.x;
  if (i >= NN * HH) return;
  float x = sden[i];
  sden[i] = x > 0.f ? 1.0f / x : 0.f;
}

// CSR-gather message aggregation: one wave per src node, 2 dims/lane -> bf16 out
__global__ __launch_bounds__(256) void k_agg(const int* __restrict__ tgt,
    const int* __restrict__ rowstart, const int* __restrict__ eids,
    const float* __restrict__ escore, const float* __restrict__ sdinv,
    const float* __restrict__ v, ushort* __restrict__ aggmb) {
  int wave = (blockIdx.x * 256 + threadIdx.x) >> 6;
  int lane = threadIdx.x & 63;
  int rs = rowstart[wave], re = rowstart[wave + 1];
  int hh = lane >> 3;
  int d = lane * 2;
  float a0 = 0.f, a1 = 0.f;
  for (int i = rs; i < re; i++) {
    int e = eids[i];
    int t = tgt[e];
    float prob = escore[e * HH + hh] * sdinv[t * HH + hh];
    float2 vv = *(const float2*)(v + (size_t)t * DD + d);
    a0 = fmaf(prob, vv.x, a0);
    a1 = fmaf(prob, vv.y, a1);
  }
  ushort2 o; o.x = f2bf(a0); o.y = f2bf(a1);
  *(ushort2*)(aggmb + (size_t)wave * DD + d) = o;
}

// h += aggm @ oW + ob via MFMA; A-frags straight from global bf16, no LDS.
__global__ __launch_bounds__(256) void k_update_o(const ushort* __restrict__ aggmb,
    const ushort* __restrict__ oT_l, const float* __restrict__ ob_l, float* __restrict__ h) {
  int nb = blockIdx.x * 16;
  int lane = threadIdx.x & 63, w = threadIdx.x >> 6;
  int g = lane >> 4, c = lane & 15;
  BF8 a[4];
  const ushort* ap = aggmb + (size_t)(nb + c) * DD + g * 8;
#pragma unroll
  for (int kt = 0; kt < 4; kt++) a[kt].u = *(const ushort8_t*)(ap + kt * 32);
#pragma unroll
  for (int ti = 0; ti < 2; ti++) {
    int colb = (w * 2 + ti) * 16;
    float bv = ob_l[colb + c];
    f32x4_t acc = {bv, bv, bv, bv};
    const ushort* wp = oT_l + (size_t)(colb + c) * DD + g * 8;
#pragma unroll
    for (int kt = 0; kt < 4; kt++) {
      BF8 b; b.u = *(const ushort8_t*)(wp + kt * 32);
      acc = __builtin_amdgcn_mfma_f32_16x16x32_bf16(a[kt].b, b.b, acc, 0, 0, 0);
    }
#pragma unroll
    for (int j = 0; j < 4; j++) {
      size_t o = (size_t)(nb + g * 4 + j) * DD + colb + c;
      h[o] += acc[j];
    }
  }
}

// fused FFN via MFMA: h += relu(LN2(h)@f1W+f1b)@f2W+f2b
__global__ __launch_bounds__(256) void k_ffn(const float* __restrict__ n2s_l, const float* __restrict__ n2b_l,
    const ushort* __restrict__ f1T_l, const float* __restrict__ f1b_l,
    const ushort* __restrict__ f2T_l, const float* __restrict__ f2b_l,
    float* __restrict__ h) {
  __shared__ __align__(16) ushort xbf[16 * DD];
  __shared__ __align__(16) ushort tbf[16 * 512];
  int nb = blockIdx.x * 16;
  ln_tile_bf(h, nb, n2s_l, n2b_l, xbf);
  __syncthreads();
  int lane = threadIdx.x & 63, w = threadIdx.x >> 6;
  int g = lane >> 4, c = lane & 15;
  int xr = (c & 7) << 4;
  BF8 a[4];
  char* xb = (char*)xbf;
#pragma unroll
  for (int kt = 0; kt < 4; kt++)
    a[kt].u = *(ushort8_t*)(xb + ((c * 256 + kt * 64 + g * 16) ^ xr));
  // GEMM1: [16,128]@[128,512], wave w owns col-tiles w*8 .. w*8+7
  char* tb = (char*)tbf;
#pragma unroll
  for (int ti = 0; ti < 8; ti++) {
    int colb = (w * 8 + ti) * 16;
    float bv = f1b_l[colb + c];
    f32x4_t acc = {bv, bv, bv, bv};
    const ushort* wp = f1T_l + (size_t)(colb + c) * DD + g * 8;
#pragma unroll
    for (int kt = 0; kt < 4; kt++) {
      BF8 b; b.u = *(const ushort8_t*)(wp + kt * 32);
      acc = __builtin_amdgcn_mfma_f32_16x16x32_bf16(a[kt].b, b.b, acc, 0, 0, 0);
    }
#pragma unroll
    for (int j = 0; j < 4; j++) {
      int row = g * 4 + j;
      int off = (row * 1024 + (colb + c) * 2) ^ ((row & 7) << 4);
      *(ushort*)(tb + off) = f2bf(fmaxf(acc[j], 0.f));
    }
  }
  __syncthreads();
  // GEMM2: [16,512]@[512,128], wave w owns col-tiles 2w, 2w+1
  {
    int colb0 = w * 32, colb1 = w * 32 + 16;
    float bv0 = f2b_l[colb0 + c], bv1 = f2b_l[colb1 + c];
    f32x4_t acc0 = {bv0, bv0, bv0, bv0};
    f32x4_t acc1 = {bv1, bv1, bv1, bv1};
    const ushort* wp0 = f2T_l + (size_t)(colb0 + c) * 512 + g * 8;
    const ushort* wp1 = wp0 + (size_t)16 * 512;
#pragma unroll
    for (int kt = 0; kt < 16; kt++) {
      BF8 a2; a2.u = *(ushort8_t*)(tb + ((c * 1024 + kt * 64 + g * 16) ^ xr));
      BF8 b0; b0.u = *(const ushort8_t*)(wp0 + kt * 32);
      BF8 b1; b1.u = *(const ushort8_t*)(wp1 + kt * 32);
      acc0 = __builtin_amdgcn_mfma_f32_16x16x32_bf16(a2.b, b0.b, acc0, 0, 0, 0);
      acc1 = __builtin_amdgcn_mfma_f32_16x16x32_bf16(a2.b, b1.b, acc1, 0, 0, 0);
    }
#pragma unroll
    for (int j = 0; j < 4; j++) {
      size_t o = (size_t)(nb + g * 4 + j) * DD;
      h[o + colb0 + c] += acc0[j];
      h[o + colb1 + c] += acc1[j];
    }
  }
}

// ---------- once-per-call setup kernels ----------
// transpose fp32 [K][C] -> bf16 [C][K], nm stacked matrices, dst stride per matrix
template <int K, int C>
__global__ void k_wt(const float* __restrict__ W, ushort* __restrict__ WT, int nm, int dstride) {
  int idx = blockIdx.x * 256 + threadIdx.x;
  if (idx >= K * C * nm) return;
  int mi = idx / (K * C), rem = idx - mi * (K * C);
  int cc = rem / K, kk2 = rem - cc * K;
  WT[(size_t)mi * dstride + cc * K + kk2] = f2bf(W[(size_t)mi * K * C + (size_t)kk2 * C + cc]);
}

__global__ void k_hist(const int* __restrict__ src, int* __restrict__ cnt) {
  int e = blockIdx.x * 256 + threadIdx.x;
  if (e < NE) atomicAdd(cnt + src[e], 1);
}

__global__ __launch_bounds__(1024) void k_scan(const int* __restrict__ cnt, int* __restrict__ rowstart) {
  __shared__ int ps[1024];
  int t = threadIdx.x;
  const int CH = 49;                 // 1024*49 = 50176 >= NN
  int base = t * CH;
  int s = 0;
  for (int i = 0; i < CH; i++) {
    int idx = base + i;
    if (idx < NN) s += cnt[idx];
  }
  ps[t] = s;
  __syncthreads();
  for (int off = 1; off < 1024; off <<= 1) {
    int vv = (t >= off) ? ps[t - off] : 0;
    __syncthreads();
    ps[t] += vv;
    __syncthreads();
  }
  int run = ps[t] - s;               // exclusive prefix
  for (int i = 0; i < CH; i++) {
    int idx = base + i;
    if (idx < NN) { rowstart[idx] = run; run += cnt[idx]; }
  }
  if (t == 1023) rowstart[NN] = ps[1023];
}

__global__ void k_fill(const int* __restrict__ src, const int* __restrict__ rowstart,
                       int* __restrict__ cur, int* __restrict__ eids) {
  int e = blockIdx.x * 256 + threadIdx.x;
  if (e >= NE) return;
  int s = src[e];
  int p = atomicAdd(cur + s, 1);
  eids[rowstart[s] + p] = e;
}

// M_l = cW2 @ bW_l  [128,8];  base_l = cb2 @ bW_l + bb_l  [8]
__global__ void k_mbias(const float* __restrict__ cW2, const float* __restrict__ cb2,
                        const float* __restrict__ bW, const float* __restrict__ bb,
                        float* __restrict__ M, float* __restrict__ base) {
  int l = blockIdx.x;
  int tid = threadIdx.x;
  const float* bWl = bW + (size_t)l * DD * HH;
  for (int idx = tid; idx < DD * HH; idx += 256) {
    int d = idx >> 3, hh = idx & 7;
    float acc = 0.f;
    for (int j = 0; j < DD; j++) acc = fmaf(cW2[d * DD + j], bWl[j * HH + hh], acc);
    M[(size_t)l * DD * HH + idx] = acc;
  }
  if (tid < HH) {
    float acc = bb[l * HH + tid];
    for (int j = 0; j < DD; j++) acc = fmaf(cb2[j], bWl[j * HH + tid], acc);
    base[l * HH + tid] = acc;
  }
}

__global__ void k_bounds(const int* __restrict__ batch, int* __restrict__ gstart, int* __restrict__ gend) {
  int n = blockIdx.x * 256 + threadIdx.x;
  if (n >= NN) return;
  int b = batch[n];
  if (n == 0 || batch[n - 1] != b) gstart[b] = n;
  if (n == NN - 1 || batch[n + 1] != b) gend[b] = n + 1;
}

__global__ __launch_bounds__(256) void k_pool(const float* __restrict__ h, const int* __restrict__ gstart,
                                              const int* __restrict__ gend, float* __restrict__ gpool) {
  __shared__ float red[256];
  int g = blockIdx.x;
  int s0 = gstart[g], e0 = gend[g];
  int tid = threadIdx.x;
  int d = tid & 127, half = tid >> 7;
  float sum = 0.f;
  for (int n = s0 + half; n < e0; n += 2) sum += h[(size_t)n * DD + d];
  red[tid] = sum;
  __syncthreads();
  if (half == 0) {
    float tot = red[tid] + red[tid + 128];
    int c = e0 - s0;
    gpool[g * DD + d] = tot / (float)max(c, 1);
  }
}

__global__ __launch_bounds__(256) void k_head(const float* __restrict__ gpool,
    const float* __restrict__ W1, const float* __restrict__ b1,
    const float* __restrict__ W2, const float* __restrict__ b2, float* __restrict__ out) {
  __shared__ float mid[NG * 64];
  int tid = threadIdx.x;
  for (int idx = tid; idx < NG * 64; idx += 256) {
    int g = idx >> 6, j = idx & 63;
    float acc = b1[j];
    for (int d = 0; d < DD; d++) acc = fmaf(gpool[g * DD + d], W1[d * 64 + j], acc);
    mid[idx] = fmaxf(acc, 0.f);
  }
  __syncthreads();
  if (tid < NG) {
    float acc = b2[0];
    for (int j = 0; j < 64; j++) acc = fmaf(mid[tid * 64 + j], W2[j], acc);
    out[tid] = acc;
  }
}

// ---------- launch ----------
extern "C" void kernel_launch(void* const* d_in, const int* in_sizes, int n_in,
                              void* d_out, int out_size, void* d_ws, size_t ws_size,
                              hipStream_t stream) {
  const float* x      = (const float*)d_in[0];
  const int*   ei     = (const int*)d_in[1];
  const int*   batch  = (const int*)d_in[2];
  const float* node_W = (const float*)d_in[3];
  const float* node_b = (const float*)d_in[4];
  const float* cW1    = (const float*)d_in[5];
  const float* cb1    = (const float*)d_in[6];
  const float* cW2    = (const float*)d_in[7];
  const float* cb2    = (const float*)d_in[8];
  const float* qW     = (const float*)d_in[9];
  const float* qb     = (const float*)d_in[10];
  const float* kW     = (const float*)d_in[11];
  const float* kb     = (const float*)d_in[12];
  const float* vW     = (const float*)d_in[13];
  const float* vb     = (const float*)d_in[14];
  const float* oW     = (const float*)d_in[15];
  const float* ob     = (const float*)d_in[16];
  const float* bW     = (const float*)d_in[17];
  const float* bb     = (const float*)d_in[18];
  const float* f1W    = (const float*)d_in[19];
  const float* f1b    = (const float*)d_in[20];
  const float* f2W    = (const float*)d_in[21];
  const float* f2b    = (const float*)d_in[22];
  const float* n1s    = (const float*)d_in[23];
  const float* n1b    = (const float*)d_in[24];
  const float* n2s    = (const float*)d_in[25];
  const float* n2b    = (const float*)d_in[26];
  const float* outW1  = (const float*)d_in[27];
  const float* outb1  = (const float*)d_in[28];
  const float* outW2  = (const float*)d_in[29];
  const float* outb2  = (const float*)d_in[30];

  const int* src = ei;
  const int* tgt = ei + NE;

  char* wp = (char*)d_ws;
  auto alloc = [&](size_t bytes) { void* p = (void*)wp; wp += (bytes + 255) & ~(size_t)255; return p; };
  float*    h       = (float*)alloc((size_t)NN * DD * 4);
  float*    q       = (float*)alloc((size_t)NN * DD * 4);
  float*    kk      = (float*)alloc((size_t)NN * DD * 4);
  float*    v       = (float*)alloc((size_t)NN * DD * 4);
  ushort*   aggmb   = (ushort*)alloc((size_t)NN * DD * 2);
  float*    sim     = (float*)alloc((size_t)NE * 4);
  float*    dist    = (float*)alloc((size_t)NE * 4);
  float*    escore  = (float*)alloc((size_t)NE * HH * 4);
  char*     zbase   = wp;                         // zeroed once per layer:
  unsigned* m_enc   = (unsigned*)alloc((size_t)NN * 4);
  float*    den     = (float*)alloc((size_t)NN * 4);
  float*    nd      = (float*)alloc((size_t)NN * 4);
  unsigned* sm_enc  = (unsigned*)alloc((size_t)NN * HH * 4);
  float*    sden    = (float*)alloc((size_t)NN * HH * 4);
  size_t    zbytes  = (size_t)(wp - zbase);
  float*    aggv    = (float*)alloc((size_t)NN * 4);
  float*    Mb      = (float*)alloc((size_t)NL * DD * HH * 4);
  float*    basel   = (float*)alloc((size_t)NL * HH * 4);
  int*      rowstart= (int*)alloc((size_t)(NN + 1) * 4);
  int*      eids    = (int*)alloc((size_t)NE * 4);
  int*      cnt     = (int*)alloc((size_t)NN * 4);
  int*      cur     = (int*)alloc((size_t)NN * 4);
  int*      gstart  = (int*)alloc((size_t)NG * 4);
  int*      gend    = (int*)alloc((size_t)NG * 4);
  float*    gpool   = (float*)alloc((size_t)NG * DD * 4);
  ushort*   qkvT    = (ushort*)alloc((size_t)NL * 3 * DD * DD * 2);
  ushort*   oT      = (ushort*)alloc((size_t)NL * DD * DD * 2);
  ushort*   f1T     = (ushort*)alloc((size_t)NL * DD * 512 * 2);
  ushort*   f2T     = (ushort*)alloc((size_t)NL * 512 * DD * 2);
  (void)in_sizes; (void)n_in; (void)out_size; (void)ws_size;

  // once-per-call setup
  hipMemsetAsync(cnt, 0, NN * 4, stream);
  hipMemsetAsync(cur, 0, NN * 4, stream);
  hipMemsetAsync(gstart, 0, NG * 4, stream);
  hipMemsetAsync(gend, 0, NG * 4, stream);
  k_hist<<<(NE + 255) / 256, 256, 0, stream>>>(src, cnt);
  k_scan<<<1, 1024, 0, stream>>>(cnt, rowstart);
  k_fill<<<(NE + 255) / 256, 256, 0, stream>>>(src, rowstart, cur, eids);
  k_mbias<<<NL, 256, 0, stream>>>(cW2, cb2, bW, bb, Mb, basel);
  k_bounds<<<(NN + 255) / 256, 256, 0, stream>>>(batch, gstart, gend);
  // bf16-transposed weights
  k_wt<DD, DD><<<(NL * DD * DD + 255) / 256, 256, 0, stream>>>(qW, qkvT,              NL, 3 * DD * DD);
  k_wt<DD, DD><<<(NL * DD * DD + 255) / 256, 256, 0, stream>>>(kW, qkvT + DD * DD,    NL, 3 * DD * DD);
  k_wt<DD, DD><<<(NL * DD * DD + 255) / 256, 256, 0, stream>>>(vW, qkvT + 2 * DD * DD, NL, 3 * DD * DD);
  k_wt<DD, DD><<<(NL * DD * DD + 255) / 256, 256, 0, stream>>>(oW, oT, NL, DD * DD);
  k_wt<DD, 512><<<(NL * DD * 512 + 255) / 256, 256, 0, stream>>>(f1W, f1T, NL, DD * 512);
  k_wt<512, DD><<<(NL * DD * 512 + 255) / 256, 256, 0, stream>>>(f2W, f2T, NL, DD * 512);
  k_node_proj<<<NN / 8, 256, 0, stream>>>(x, node_W, node_b, h);

  for (int l = 0; l < NL; l++) {
    hipMemsetAsync(zbase, 0, zbytes, stream);
    k_edge1<<<NE / 8, 256, 0, stream>>>(src, tgt, h, sim, dist, m_enc);
    k_edge2<<<(NE + 255) / 256, 256, 0, stream>>>(tgt, sim, dist, m_enc, den, nd);
    k_aggv<<<(NN + 255) / 256, 256, 0, stream>>>(den, nd, aggv);
    k_ln_qkv<<<NN / 16, 256, 0, stream>>>(h, n1s + l * DD, n1b + l * DD,
        qkvT + (size_t)l * 3 * DD * DD,
        qb + l * DD, kb + l * DD, vb + l * DD, q, kk, v);
    k_scores<<<(NE * HH + 255) / 256, 256, 0, stream>>>(src, tgt, q, kk, dist, aggv,
        Mb + (size_t)l * DD * HH, basel + l * HH, cW1, cb1, escore, sm_enc);
    k_probs<<<(NE * HH + 255) / 256, 256, 0, stream>>>(tgt, sm_enc, escore, sden);
    k_sdinv<<<(NN * HH + 255) / 256, 256, 0, stream>>>(sden);
    k_agg<<<NN / 4, 256, 0, stream>>>(tgt, rowstart, eids, escore, sden, v, aggmb);
    k_update_o<<<NN / 16, 256, 0, stream>>>(aggmb, oT + (size_t)l * DD * DD, ob + l * DD, h);
    k_ffn<<<NN / 16, 256, 0, stream>>>(n2s + l * DD, n2b + l * DD,
        f1T + (size_t)l * DD * 512, f1b + (size_t)l * 4 * DD,
        f2T + (size_t)l * 512 * DD, f2b + l * DD, h);
  }
  k_pool<<<NG, 256, 0, stream>>>(h, gstart, gend, gpool);
  k_head<<<1, 256, 0, stream>>>(gpool, outW1, outb1, outW2, outb2, (float*)d_out);
}

// Round 3
// 2330.892 us; speedup vs baseline: 1.8671x; 1.1590x over previous
//
#include <hip/hip_runtime.h>

#define NN 50000      // nodes
#define NE 625000     // edges
#define DD 128        // hidden dim
#define HH 8          // heads
#define DHH 16        // head dim
#define NL 4          // layers
#define FIN 64        // in channels
#define NG 64         // graphs
#define LN_EPS 1e-5f
#define NSEG 129      // PWL segments = 128 breakpoints + 1

typedef __bf16 bf16x8_t __attribute__((ext_vector_type(8)));
typedef unsigned short ushort8_t __attribute__((ext_vector_type(8)));
typedef float f32x4_t __attribute__((ext_vector_type(4)));
union BF8 { ushort8_t u; bf16x8_t b; };

// ---------- helpers ----------
__device__ __forceinline__ unsigned fenc(float f) {
  unsigned u = __float_as_uint(f);
  return (u & 0x80000000u) ? ~u : (u | 0x80000000u);   // monotonic float->uint
}
__device__ __forceinline__ float fdec(unsigned u) {
  return __uint_as_float((u & 0x80000000u) ? (u & 0x7FFFFFFFu) : ~u);
}
__device__ __forceinline__ void fma4(float4& a, float s, float4 w) {
  a.x = fmaf(s, w.x, a.x); a.y = fmaf(s, w.y, a.y);
  a.z = fmaf(s, w.z, a.z); a.w = fmaf(s, w.w, a.w);
}
__device__ __forceinline__ unsigned short f2bf(float f) {   // RNE f32->bf16
  unsigned u = __float_as_uint(f);
  unsigned r = ((u >> 16) & 1u) + 0x7FFFu;
  return (unsigned short)((u + r) >> 16);
}
__device__ __forceinline__ float bf2f(unsigned short u) {
  return __uint_as_float((unsigned)u << 16);
}

// LayerNorm 16 nodes -> swizzled bf16 LDS tile [16][128]; block = 256 threads.
// byte offset = (row*256 + col*2) ^ ((row&7)<<4)  -> conflict-free ds_read_b128
__device__ __forceinline__ void ln_tile_bf(const float* __restrict__ h, int nb,
                                           const float* __restrict__ sc,
                                           const float* __restrict__ bi,
                                           ushort* xbf) {
  int tid = threadIdx.x;
  int r = tid >> 4, l16 = tid & 15;
  const float* hp = h + (size_t)(nb + r) * DD + l16 * 8;
  float4 a0 = *(const float4*)hp;
  float4 a1 = *(const float4*)(hp + 4);
  float sum = a0.x + a0.y + a0.z + a0.w + a1.x + a1.y + a1.z + a1.w;
  float sq  = a0.x*a0.x + a0.y*a0.y + a0.z*a0.z + a0.w*a0.w
            + a1.x*a1.x + a1.y*a1.y + a1.z*a1.z + a1.w*a1.w;
#pragma unroll
  for (int off = 8; off >= 1; off >>= 1) {
    sum += __shfl_xor(sum, off, 64);
    sq  += __shfl_xor(sq,  off, 64);
  }
  float mu   = sum * (1.0f / DD);
  float var  = sq * (1.0f / DD) - mu * mu;
  float rstd = rsqrtf(var + LN_EPS);
  int d0 = l16 * 8;
  float4 s0 = *(const float4*)(sc + d0), s1 = *(const float4*)(sc + d0 + 4);
  float4 b0 = *(const float4*)(bi + d0), b1 = *(const float4*)(bi + d0 + 4);
  ushort8_t u;
  u[0] = f2bf((a0.x - mu) * rstd * s0.x + b0.x);
  u[1] = f2bf((a0.y - mu) * rstd * s0.y + b0.y);
  u[2] = f2bf((a0.z - mu) * rstd * s0.z + b0.z);
  u[3] = f2bf((a0.w - mu) * rstd * s0.w + b0.w);
  u[4] = f2bf((a1.x - mu) * rstd * s1.x + b1.x);
  u[5] = f2bf((a1.y - mu) * rstd * s1.y + b1.y);
  u[6] = f2bf((a1.z - mu) * rstd * s1.z + b1.z);
  u[7] = f2bf((a1.w - mu) * rstd * s1.w + b1.w);
  int off = (r * 256 + l16 * 16) ^ ((r & 7) << 4);
  *(ushort8_t*)((char*)xbf + off) = u;
}

// ---------- kernels ----------
// h = x @ node_W + node_b ; 8 nodes/block (fp32 VALU — minor cost)
__global__ __launch_bounds__(256) void k_node_proj(const float* __restrict__ x,
                                                   const float* __restrict__ W,
                                                   const float* __restrict__ b,
                                                   float* __restrict__ h) {
  __shared__ float xt[8][FIN];
  int tid = threadIdx.x;
  int nb = blockIdx.x * 8;
  {
    int idx = tid * 2;
    *(float2*)&xt[idx >> 6][idx & 63] = *(const float2*)(x + (size_t)nb * FIN + idx);
  }
  __syncthreads();
  int c4 = (tid & 31) * 4;
  int r  = tid >> 5;
  float4 acc = *(const float4*)(b + c4);
  for (int k = 0; k < FIN; k += 4) {
    float4 xk = *(const float4*)&xt[r][k];
    const float* wp = W + (size_t)k * DD + c4;
    fma4(acc, xk.x, *(const float4*)wp);
    fma4(acc, xk.y, *(const float4*)(wp + DD));
    fma4(acc, xk.z, *(const float4*)(wp + 2 * DD));
    fma4(acc, xk.w, *(const float4*)(wp + 3 * DD));
  }
  *(float4*)(h + (size_t)(nb + r) * DD + c4) = acc;
}

// per sorted edge: sim (dot), dist (norm), atomicMax of sim over tgt. 32 lanes/edge.
__global__ __launch_bounds__(256) void k_edge1(const int* __restrict__ src_s, const int* __restrict__ tgt_s,
                                               const float* __restrict__ h, float* __restrict__ sim,
                                               float* __restrict__ dist, unsigned* __restrict__ m_enc) {
  int tid = threadIdx.x;
  int wave = (blockIdx.x * 256 + tid) >> 6;
  int lane = tid & 63;
  int i = wave * 2 + (lane >> 5);
  int j = lane & 31;
  int s = src_s[i], t = tgt_s[i];
  float4 a = *(const float4*)(h + (size_t)s * DD + j * 4);
  float4 b = *(const float4*)(h + (size_t)t * DD + j * 4);
  float dot = a.x*b.x + a.y*b.y + a.z*b.z + a.w*b.w;
  float dx = a.x-b.x, dy = a.y-b.y, dz = a.z-b.z, dw = a.w-b.w;
  float sq = dx*dx + dy*dy + dz*dz + dw*dw;
#pragma unroll
  for (int off = 16; off >= 1; off >>= 1) {
    dot += __shfl_xor(dot, off, 64);
    sq  += __shfl_xor(sq,  off, 64);
  }
  if (j == 0) {
    sim[i]  = dot;                  // BETA == 1.0
    dist[i] = sqrtf(sq);
    atomicMax(m_enc + t, fenc(dot));
  }
}

// denom & alpha*dist numerator per tgt
__global__ void k_edge2(const int* __restrict__ tgt_s, const float* __restrict__ sim,
                        const float* __restrict__ dist, const unsigned* __restrict__ m_enc,
                        float* __restrict__ den, float* __restrict__ nd) {
  int i = blockIdx.x * 256 + threadIdx.x;
  if (i >= NE) return;
  int t = tgt_s[i];
  float ev = expf(sim[i] - fdec(m_enc[t]));
  atomicAdd(den + t, ev);
  atomicAdd(nd + t, ev * dist[i]);
}

__global__ void k_aggv(const float* __restrict__ den, const float* __restrict__ nd,
                       float* __restrict__ aggv) {
  int n = blockIdx.x * 256 + threadIdx.x;
  if (n >= NN) return;
  float d = den[n];
  aggv[n] = d > 0.f ? nd[n] / d : 0.f;
}

// per edge: curvature + PWL segment index (binary search over 128 sorted breakpoints)
__global__ __launch_bounds__(256) void k_curv(const int* __restrict__ tgt_s,
    const float* __restrict__ dist, const float* __restrict__ aggv,
    const float* __restrict__ bp_l, float* __restrict__ curvf, ushort* __restrict__ sege) {
  __shared__ float bp[DD];
  int tid = threadIdx.x;
  if (tid < DD) bp[tid] = bp_l[tid];
  __syncthreads();
  int i = blockIdx.x * 256 + tid;
  if (i >= NE) return;
  int t = tgt_s[i];
  float curv = 1.0f - aggv[t] / fmaxf(dist[i], 1e-6f);
  int lo = 0, hi = DD;
  while (lo < hi) { int mid = (lo + hi) >> 1; if (bp[mid] < curv) lo = mid + 1; else hi = mid; }
  curvf[i] = curv;
  sege[i] = (ushort)lo;     // segment in [0,128]
}

// LN1 + QKV projection via MFMA -> bf16 q/k/v. 16 rows/block, 4 waves.
__global__ __launch_bounds__(256) void k_ln_qkv(const float* __restrict__ h,
    const float* __restrict__ n1s_l, const float* __restrict__ n1b_l,
    const ushort* __restrict__ qkvT_l,
    const float* __restrict__ qb_l, const float* __restrict__ kb_l, const float* __restrict__ vb_l,
    ushort* __restrict__ q, ushort* __restrict__ kk, ushort* __restrict__ v) {
  __shared__ __align__(16) ushort xbf[16 * DD];
  int nb = blockIdx.x * 16;
  ln_tile_bf(h, nb, n1s_l, n1b_l, xbf);
  __syncthreads();
  int lane = threadIdx.x & 63;
  int w = threadIdx.x >> 6;
  int g = lane >> 4, c = lane & 15;
  int xr = (c & 7) << 4;
  BF8 a[4];
  char* xb = (char*)xbf;
#pragma unroll
  for (int kt = 0; kt < 4; kt++)
    a[kt].u = *(ushort8_t*)(xb + ((c * 256 + kt * 64 + g * 16) ^ xr));
#pragma unroll
  for (int ti = 0; ti < 6; ti++) {
    int t = w * 6 + ti;
    int m = t >> 3;                  // 0=q 1=k 2=v
    int colb = (t & 7) * 16;
    const float* bias = (m == 0 ? qb_l : (m == 1 ? kb_l : vb_l));
    float bv = bias[colb + c];
    f32x4_t acc = {bv, bv, bv, bv};
    const ushort* wp = qkvT_l + (size_t)(m * DD + colb + c) * DD + g * 8;
#pragma unroll
    for (int kt = 0; kt < 4; kt++) {
      BF8 b; b.u = *(const ushort8_t*)(wp + kt * 32);
      acc = __builtin_amdgcn_mfma_f32_16x16x32_bf16(a[kt].b, b.b, acc, 0, 0, 0);
    }
    ushort* out = (m == 0 ? q : (m == 1 ? kk : v));
#pragma unroll
    for (int j = 0; j < 4; j++)
      out[(size_t)(nb + g * 4 + j) * DD + colb + c] = f2bf(acc[j]);
  }
}

// per (edge, head): qk dot (bf16) + PWL bias; atomicMax over tgt
__global__ __launch_bounds__(256) void k_scores(const int* __restrict__ src_s, const int* __restrict__ tgt_s,
    const ushort* __restrict__ q, const ushort* __restrict__ k,
    const float* __restrict__ curvf, const ushort* __restrict__ sege,
    const float* __restrict__ slope_l, const float* __restrict__ inter_l,
    float* __restrict__ escore, unsigned* __restrict__ sm_enc) {
  __shared__ float lsl[NSEG * HH], lin[NSEG * HH];
  int tid = threadIdx.x;
  for (int idx = tid; idx < NSEG * HH; idx += 256) { lsl[idx] = slope_l[idx]; lin[idx] = inter_l[idx]; }
  __syncthreads();
  int gi = blockIdx.x * 256 + tid;
  if (gi >= NE * HH) return;
  int i = gi >> 3, hh = gi & 7;
  int s = src_s[i], t = tgt_s[i];
  int seg = sege[i];
  float bias = fmaf(lsl[seg * HH + hh], curvf[i], lin[seg * HH + hh]);
  const ushort8_t* qp = (const ushort8_t*)(q + (size_t)s * DD + hh * DHH);
  const ushort8_t* kp = (const ushort8_t*)(k + (size_t)t * DD + hh * DHH);
  float dot = 0.f;
#pragma unroll
  for (int ii = 0; ii < 2; ii++) {
    ushort8_t a = qp[ii], b = kp[ii];
#pragma unroll
    for (int jj = 0; jj < 8; jj++) dot = fmaf(bf2f(a[jj]), bf2f(b[jj]), dot);
  }
  float sc = dot * 0.25f + bias;   // 1/sqrt(16)
  escore[gi] = sc;
  atomicMax(sm_enc + (size_t)t * HH + hh, fenc(sc));
}

__global__ void k_probs(const int* __restrict__ tgt_s, const unsigned* __restrict__ sm_enc,
                        float* __restrict__ escore, float* __restrict__ sden) {
  int gi = blockIdx.x * 256 + threadIdx.x;
  if (gi >= NE * HH) return;
  int i = gi >> 3, hh = gi & 7;
  int t = tgt_s[i];
  float p = expf(escore[gi] - fdec(sm_enc[(size_t)t * HH + hh]));
  escore[gi] = p;
  atomicAdd(sden + (size_t)t * HH + hh, p);
}

__global__ void k_sdinv(float* __restrict__ sden) {
  int i = blockIdx.x * 256 + threadIdx.x;
  if (i >= NN * HH) return;
  float x = sden[i];
  sden[i] = x > 0.f ? 1.0f / x : 0.f;
}

// CSR-gather message aggregation: one wave per src node, 2 dims/lane -> bf16 out
__global__ __launch_bounds__(256) void k_agg(const int* __restrict__ tgt_s,
    const int* __restrict__ rowstart,
    const float* __restrict__ escore, const float* __restrict__ sdinv,
    const ushort* __restrict__ v, ushort* __restrict__ aggmb) {
  int wave = (blockIdx.x * 256 + threadIdx.x) >> 6;
  int lane = threadIdx.x & 63;
  int rs = rowstart[wave], re = rowstart[wave + 1];
  int hh = lane >> 3;
  int d = lane * 2;
  float a0 = 0.f, a1 = 0.f;
  for (int i = rs; i < re; i++) {
    int t = tgt_s[i];
    float prob = escore[i * HH + hh] * sdinv[t * HH + hh];
    ushort2 vv = *(const ushort2*)(v + (size_t)t * DD + d);
    a0 = fmaf(prob, bf2f(vv.x), a0);
    a1 = fmaf(prob, bf2f(vv.y), a1);
  }
  ushort2 o; o.x = f2bf(a0); o.y = f2bf(a1);
  *(ushort2*)(aggmb + (size_t)wave * DD + d) = o;
}

// h += aggm @ oW + ob via MFMA; A-frags straight from global bf16, no LDS.
__global__ __launch_bounds__(256) void k_update_o(const ushort* __restrict__ aggmb,
    const ushort* __restrict__ oT_l, const float* __restrict__ ob_l, float* __restrict__ h) {
  int nb = blockIdx.x * 16;
  int lane = threadIdx.x & 63, w = threadIdx.x >> 6;
  int g = lane >> 4, c = lane & 15;
  BF8 a[4];
  const ushort* ap = aggmb + (size_t)(nb + c) * DD + g * 8;
#pragma unroll
  for (int kt = 0; kt < 4; kt++) a[kt].u = *(const ushort8_t*)(ap + kt * 32);
#pragma unroll
  for (int ti = 0; ti < 2; ti++) {
    int colb = (w * 2 + ti) * 16;
    float bv = ob_l[colb + c];
    f32x4_t acc = {bv, bv, bv, bv};
    const ushort* wp = oT_l + (size_t)(colb + c) * DD + g * 8;
#pragma unroll
    for (int kt = 0; kt < 4; kt++) {
      BF8 b; b.u = *(const ushort8_t*)(wp + kt * 32);
      acc = __builtin_amdgcn_mfma_f32_16x16x32_bf16(a[kt].b, b.b, acc, 0, 0, 0);
    }
#pragma unroll
    for (int j = 0; j < 4; j++) {
      size_t o = (size_t)(nb + g * 4 + j) * DD + colb + c;
      h[o] += acc[j];
    }
  }
}

// fused FFN via MFMA: h += relu(LN2(h)@f1W+f1b)@f2W+f2b
__global__ __launch_bounds__(256) void k_ffn(const float* __restrict__ n2s_l, const float* __restrict__ n2b_l,
    const ushort* __restrict__ f1T_l, const float* __restrict__ f1b_l,
    const ushort* __restrict__ f2T_l, const float* __restrict__ f2b_l,
    float* __restrict__ h) {
  __shared__ __align__(16) ushort xbf[16 * DD];
  __shared__ __align__(16) ushort tbf[16 * 512];
  int nb = blockIdx.x * 16;
  ln_tile_bf(h, nb, n2s_l, n2b_l, xbf);
  __syncthreads();
  int lane = threadIdx.x & 63, w = threadIdx.x >> 6;
  int g = lane >> 4, c = lane & 15;
  int xr = (c & 7) << 4;
  BF8 a[4];
  char* xb = (char*)xbf;
#pragma unroll
  for (int kt = 0; kt < 4; kt++)
    a[kt].u = *(ushort8_t*)(xb + ((c * 256 + kt * 64 + g * 16) ^ xr));
  // GEMM1: [16,128]@[128,512], wave w owns col-tiles w*8 .. w*8+7
  char* tb = (char*)tbf;
#pragma unroll
  for (int ti = 0; ti < 8; ti++) {
    int colb = (w * 8 + ti) * 16;
    float bv = f1b_l[colb + c];
    f32x4_t acc = {bv, bv, bv, bv};
    const ushort* wp = f1T_l + (size_t)(colb + c) * DD + g * 8;
#pragma unroll
    for (int kt = 0; kt < 4; kt++) {
      BF8 b; b.u = *(const ushort8_t*)(wp + kt * 32);
      acc = __builtin_amdgcn_mfma_f32_16x16x32_bf16(a[kt].b, b.b, acc, 0, 0, 0);
    }
#pragma unroll
    for (int j = 0; j < 4; j++) {
      int row = g * 4 + j;
      int off = (row * 1024 + (colb + c) * 2) ^ ((row & 7) << 4);
      *(ushort*)(tb + off) = f2bf(fmaxf(acc[j], 0.f));
    }
  }
  __syncthreads();
  // GEMM2: [16,512]@[512,128], wave w owns col-tiles 2w, 2w+1
  {
    int colb0 = w * 32, colb1 = w * 32 + 16;
    float bv0 = f2b_l[colb0 + c], bv1 = f2b_l[colb1 + c];
    f32x4_t acc0 = {bv0, bv0, bv0, bv0};
    f32x4_t acc1 = {bv1, bv1, bv1, bv1};
    const ushort* wp0 = f2T_l + (size_t)(colb0 + c) * 512 + g * 8;
    const ushort* wp1 = wp0 + (size_t)16 * 512;
#pragma unroll
    for (int kt = 0; kt < 16; kt++) {
      BF8 a2; a2.u = *(ushort8_t*)(tb + ((c * 1024 + kt * 64 + g * 16) ^ xr));
      BF8 b0; b0.u = *(const ushort8_t*)(wp0 + kt * 32);
      BF8 b1; b1.u = *(const ushort8_t*)(wp1 + kt * 32);
      acc0 = __builtin_amdgcn_mfma_f32_16x16x32_bf16(a2.b, b0.b, acc0, 0, 0, 0);
      acc1 = __builtin_amdgcn_mfma_f32_16x16x32_bf16(a2.b, b1.b, acc1, 0, 0, 0);
    }
#pragma unroll
    for (int j = 0; j < 4; j++) {
      size_t o = (size_t)(nb + g * 4 + j) * DD;
      h[o + colb0 + c] += acc0[j];
      h[o + colb1 + c] += acc1[j];
    }
  }
}

// ---------- once-per-call setup kernels ----------
// transpose fp32 [K][C] -> bf16 [C][K], nm stacked matrices, dst stride per matrix
template <int K, int C>
__global__ void k_wt(const float* __restrict__ W, ushort* __restrict__ WT, int nm, int dstride) {
  int idx = blockIdx.x * 256 + threadIdx.x;
  if (idx >= K * C * nm) return;
  int mi = idx / (K * C), rem = idx - mi * (K * C);
  int cc = rem / K, kk2 = rem - cc * K;
  WT[(size_t)mi * dstride + cc * K + kk2] = f2bf(W[(size_t)mi * K * C + (size_t)kk2 * C + cc]);
}

__global__ void k_hist(const int* __restrict__ src, int* __restrict__ cnt) {
  int e = blockIdx.x * 256 + threadIdx.x;
  if (e < NE) atomicAdd(cnt + src[e], 1);
}

__global__ __launch_bounds__(1024) void k_scan(const int* __restrict__ cnt, int* __restrict__ rowstart) {
  __shared__ int ps[1024];
  int t = threadIdx.x;
  const int CH = 49;                 // 1024*49 = 50176 >= NN
  int base = t * CH;
  int s = 0;
  for (int i = 0; i < CH; i++) {
    int idx = base + i;
    if (idx < NN) s += cnt[idx];
  }
  ps[t] = s;
  __syncthreads();
  for (int off = 1; off < 1024; off <<= 1) {
    int vv = (t >= off) ? ps[t - off] : 0;
    __syncthreads();
    ps[t] += vv;
    __syncthreads();
  }
  int run = ps[t] - s;               // exclusive prefix
  for (int i = 0; i < CH; i++) {
    int idx = base + i;
    if (idx < NN) { rowstart[idx] = run; run += cnt[idx]; }
  }
  if (t == 1023) rowstart[NN] = ps[1023];
}

// scatter edges into src-sorted order (all per-edge arrays use sorted index)
__global__ void k_fill(const int* __restrict__ src, const int* __restrict__ tgt,
                       const int* __restrict__ rowstart,
                       int* __restrict__ cur, int* __restrict__ src_s, int* __restrict__ tgt_s) {
  int e = blockIdx.x * 256 + threadIdx.x;
  if (e >= NE) return;
  int s = src[e];
  int p = atomicAdd(cur + s, 1);
  int pos = rowstart[s] + p;
  src_s[pos] = s;
  tgt_s[pos] = tgt[e];
}

// M_l = cW2 @ bW_l  [128,8];  base_l = cb2 @ bW_l + bb_l  [8]
__global__ void k_mbias(const float* __restrict__ cW2, const float* __restrict__ cb2,
                        const float* __restrict__ bW, const float* __restrict__ bb,
                        float* __restrict__ M, float* __restrict__ base) {
  int l = blockIdx.x;
  int tid = threadIdx.x;
  const float* bWl = bW + (size_t)l * DD * HH;
  for (int idx = tid; idx < DD * HH; idx += 256) {
    int d = idx >> 3, hh = idx & 7;
    float acc = 0.f;
    for (int j = 0; j < DD; j++) acc = fmaf(cW2[d * DD + j], bWl[j * HH + hh], acc);
    M[(size_t)l * DD * HH + idx] = acc;
  }
  if (tid < HH) {
    float acc = bb[l * HH + tid];
    for (int j = 0; j < DD; j++) acc = fmaf(cb2[j], bWl[j * HH + tid], acc);
    base[l * HH + tid] = acc;
  }
}

// PWL table: bias_h(curv) = relu(curv*cW1+cb1) @ M_l + base_l is piecewise-linear
// in scalar curv with 128 breakpoints x_d = -cb1[d]/cW1[d]. Precompute sorted
// breakpoints + per-segment (slope,intercept) per head. Exact (reassociation only).
__global__ __launch_bounds__(256) void k_pwl(const float* __restrict__ cW1, const float* __restrict__ cb1,
    const float* __restrict__ Mb, const float* __restrict__ basel,
    float* __restrict__ bpg, float* __restrict__ slopeg, float* __restrict__ interg) {
  int l = blockIdx.x;
  __shared__ float c1[DD], cb[DD], x[DD], bp[DD];
  __shared__ int pos[DD];
  int tid = threadIdx.x;
  if (tid < DD) { c1[tid] = cW1[tid]; cb[tid] = cb1[tid]; }
  __syncthreads();
  if (tid < DD)
    x[tid] = (c1[tid] == 0.f) ? __builtin_inff() : (-cb[tid] / c1[tid]);
  __syncthreads();
  if (tid < DD) {
    float xv = x[tid]; int p = 0;
    for (int j = 0; j < DD; j++) {
      float xj = x[j];
      if (xj < xv || (xj == xv && j < tid)) p++;
    }
    pos[tid] = p;
    bp[p] = xv;
  }
  __syncthreads();
  if (tid < DD) bpg[l * DD + tid] = bp[tid];
  const float* M = Mb + (size_t)l * DD * HH;
  for (int idx = tid; idx < NSEG * HH; idx += 256) {
    int s = idx >> 3, hh = idx & 7;
    float sl = 0.f, in = 0.f;
    for (int d = 0; d < DD; d++) {
      bool act;
      if (c1[d] == 0.f)      act = (cb[d] > 0.f);
      else if (c1[d] > 0.f)  act = (pos[d] < s);
      else                   act = (pos[d] >= s);
      if (act) {
        float m = M[d * HH + hh];
        sl = fmaf(c1[d], m, sl);
        in = fmaf(cb[d], m, in);
      }
    }
    slopeg[(size_t)l * NSEG * HH + idx] = sl;
    interg[(size_t)l * NSEG * HH + idx] = in + basel[l * HH + hh];
  }
}

__global__ void k_bounds(const int* __restrict__ batch, int* __restrict__ gstart, int* __restrict__ gend) {
  int n = blockIdx.x * 256 + threadIdx.x;
  if (n >= NN) return;
  int b = batch[n];
  if (n == 0 || batch[n - 1] != b) gstart[b] = n;
  if (n == NN - 1 || batch[n + 1] != b) gend[b] = n + 1;
}

__global__ __launch_bounds__(256) void k_pool(const float* __restrict__ h, const int* __restrict__ gstart,
                                              const int* __restrict__ gend, float* __restrict__ gpool) {
  __shared__ float red[256];
  int g = blockIdx.x;
  int s0 = gstart[g], e0 = gend[g];
  int tid = threadIdx.x;
  int d = tid & 127, half = tid >> 7;
  float sum = 0.f;
  for (int n = s0 + half; n < e0; n += 2) sum += h[(size_t)n * DD + d];
  red[tid] = sum;
  __syncthreads();
  if (half == 0) {
    float tot = red[tid] + red[tid + 128];
    int c = e0 - s0;
    gpool[g * DD + d] = tot / (float)max(c, 1);
  }
}

__global__ __launch_bounds__(256) void k_head(const float* __restrict__ gpool,
    const float* __restrict__ W1, const float* __restrict__ b1,
    const float* __restrict__ W2, const float* __restrict__ b2, float* __restrict__ out) {
  __shared__ float mid[NG * 64];
  int tid = threadIdx.x;
  for (int idx = tid; idx < NG * 64; idx += 256) {
    int g = idx >> 6, j = idx & 63;
    float acc = b1[j];
    for (int d = 0; d < DD; d++) acc = fmaf(gpool[g * DD + d], W1[d * 64 + j], acc);
    mid[idx] = fmaxf(acc, 0.f);
  }
  __syncthreads();
  if (tid < NG) {
    float acc = b2[0];
    for (int j = 0; j < 64; j++) acc = fmaf(mid[tid * 64 + j], W2[j], acc);
    out[tid] = acc;
  }
}

// ---------- launch ----------
extern "C" void kernel_launch(void* const* d_in, const int* in_sizes, int n_in,
                              void* d_out, int out_size, void* d_ws, size_t ws_size,
                              hipStream_t stream) {
  const float* x      = (const float*)d_in[0];
  const int*   ei     = (const int*)d_in[1];
  const int*   batch  = (const int*)d_in[2];
  const float* node_W = (const float*)d_in[3];
  const float* node_b = (const float*)d_in[4];
  const float* cW1    = (const float*)d_in[5];
  const float* cb1    = (const float*)d_in[6];
  const float* cW2    = (const float*)d_in[7];
  const float* cb2    = (const float*)d_in[8];
  const float* qW     = (const float*)d_in[9];
  const float* qb     = (const float*)d_in[10];
  const float* kW     = (const float*)d_in[11];
  const float* kb     = (const float*)d_in[12];
  const float* vW     = (const float*)d_in[13];
  const float* vb     = (const float*)d_in[14];
  const float* oW     = (const float*)d_in[15];
  const float* ob     = (const float*)d_in[16];
  const float* bW     = (const float*)d_in[17];
  const float* bb     = (const float*)d_in[18];
  const float* f1W    = (const float*)d_in[19];
  const float* f1b    = (const float*)d_in[20];
  const float* f2W    = (const float*)d_in[21];
  const float* f2b    = (const float*)d_in[22];
  const float* n1s    = (const float*)d_in[23];
  const float* n1b    = (const float*)d_in[24];
  const float* n2s    = (const float*)d_in[25];
  const float* n2b    = (const float*)d_in[26];
  const float* outW1  = (const float*)d_in[27];
  const float* outb1  = (const float*)d_in[28];
  const float* outW2  = (const float*)d_in[29];
  const float* outb2  = (const float*)d_in[30];

  const int* src = ei;
  const int* tgt = ei + NE;

  char* wp = (char*)d_ws;
  auto alloc = [&](size_t bytes) { void* p = (void*)wp; wp += (bytes + 255) & ~(size_t)255; return p; };
  float*    h       = (float*)alloc((size_t)NN * DD * 4);
  ushort*   q       = (ushort*)alloc((size_t)NN * DD * 2);
  ushort*   kk      = (ushort*)alloc((size_t)NN * DD * 2);
  ushort*   v       = (ushort*)alloc((size_t)NN * DD * 2);
  ushort*   aggmb   = (ushort*)alloc((size_t)NN * DD * 2);
  float*    sim     = (float*)alloc((size_t)NE * 4);
  float*    dist    = (float*)alloc((size_t)NE * 4);
  float*    escore  = (float*)alloc((size_t)NE * HH * 4);
  float*    curvf   = (float*)alloc((size_t)NE * 4);
  ushort*   sege    = (ushort*)alloc((size_t)NE * 2);
  char*     zbase   = wp;                         // zeroed once per layer:
  unsigned* m_enc   = (unsigned*)alloc((size_t)NN * 4);
  float*    den     = (float*)alloc((size_t)NN * 4);
  float*    nd      = (float*)alloc((size_t)NN * 4);
  unsigned* sm_enc  = (unsigned*)alloc((size_t)NN * HH * 4);
  float*    sden    = (float*)alloc((size_t)NN * HH * 4);
  size_t    zbytes  = (size_t)(wp - zbase);
  float*    aggv    = (float*)alloc((size_t)NN * 4);
  float*    Mb      = (float*)alloc((size_t)NL * DD * HH * 4);
  float*    basel   = (float*)alloc((size_t)NL * HH * 4);
  float*    bpg     = (float*)alloc((size_t)NL * DD * 4);
  float*    slopeg  = (float*)alloc((size_t)NL * NSEG * HH * 4);
  float*    interg  = (float*)alloc((size_t)NL * NSEG * HH * 4);
  int*      rowstart= (int*)alloc((size_t)(NN + 1) * 4);
  int*      src_s   = (int*)alloc((size_t)NE * 4);
  int*      tgt_s   = (int*)alloc((size_t)NE * 4);
  int*      cnt     = (int*)alloc((size_t)NN * 4);
  int*      cur     = (int*)alloc((size_t)NN * 4);
  int*      gstart  = (int*)alloc((size_t)NG * 4);
  int*      gend    = (int*)alloc((size_t)NG * 4);
  float*    gpool   = (float*)alloc((size_t)NG * DD * 4);
  ushort*   qkvT    = (ushort*)alloc((size_t)NL * 3 * DD * DD * 2);
  ushort*   oT      = (ushort*)alloc((size_t)NL * DD * DD * 2);
  ushort*   f1T     = (ushort*)alloc((size_t)NL * DD * 512 * 2);
  ushort*   f2T     = (ushort*)alloc((size_t)NL * 512 * DD * 2);
  (void)in_sizes; (void)n_in; (void)out_size; (void)ws_size;

  // once-per-call setup
  hipMemsetAsync(cnt, 0, NN * 4, stream);
  hipMemsetAsync(cur, 0, NN * 4, stream);
  hipMemsetAsync(gstart, 0, NG * 4, stream);
  hipMemsetAsync(gend, 0, NG * 4, stream);
  k_hist<<<(NE + 255) / 256, 256, 0, stream>>>(src, cnt);
  k_scan<<<1, 1024, 0, stream>>>(cnt, rowstart);
  k_fill<<<(NE + 255) / 256, 256, 0, stream>>>(src, tgt, rowstart, cur, src_s, tgt_s);
  k_mbias<<<NL, 256, 0, stream>>>(cW2, cb2, bW, bb, Mb, basel);
  k_pwl<<<NL, 256, 0, stream>>>(cW1, cb1, Mb, basel, bpg, slopeg, interg);
  k_bounds<<<(NN + 255) / 256, 256, 0, stream>>>(batch, gstart, gend);
  // bf16-transposed weights
  k_wt<DD, DD><<<(NL * DD * DD + 255) / 256, 256, 0, stream>>>(qW, qkvT,               NL, 3 * DD * DD);
  k_wt<DD, DD><<<(NL * DD * DD + 255) / 256, 256, 0, stream>>>(kW, qkvT + DD * DD,     NL, 3 * DD * DD);
  k_wt<DD, DD><<<(NL * DD * DD + 255) / 256, 256, 0, stream>>>(vW, qkvT + 2 * DD * DD, NL, 3 * DD * DD);
  k_wt<DD, DD><<<(NL * DD * DD + 255) / 256, 256, 0, stream>>>(oW, oT, NL, DD * DD);
  k_wt<DD, 512><<<(NL * DD * 512 + 255) / 256, 256, 0, stream>>>(f1W, f1T, NL, DD * 512);
  k_wt<512, DD><<<(NL * DD * 512 + 255) / 256, 256, 0, stream>>>(f2W, f2T, NL, DD * 512);
  k_node_proj<<<NN / 8, 256, 0, stream>>>(x, node_W, node_b, h);

  for (int l = 0; l < NL; l++) {
    hipMemsetAsync(zbase, 0, zbytes, stream);
    k_edge1<<<NE / 8, 256, 0, stream>>>(src_s, tgt_s, h, sim, dist, m_enc);
    k_edge2<<<(NE + 255) / 256, 256, 0, stream>>>(tgt_s, sim, dist, m_enc, den, nd);
    k_aggv<<<(NN + 255) / 256, 256, 0, stream>>>(den, nd, aggv);
    k_curv<<<(NE + 255) / 256, 256, 0, stream>>>(tgt_s, dist, aggv, bpg + l * DD, curvf, sege);
    k_ln_qkv<<<NN / 16, 256, 0, stream>>>(h, n1s + l * DD, n1b + l * DD,
        qkvT + (size_t)l * 3 * DD * DD,
        qb + l * DD, kb + l * DD, vb + l * DD, q, kk, v);
    k_scores<<<(NE * HH + 255) / 256, 256, 0, stream>>>(src_s, tgt_s, q, kk,
        curvf, sege, slopeg + (size_t)l * NSEG * HH, interg + (size_t)l * NSEG * HH,
        escore, sm_enc);
    k_probs<<<(NE * HH + 255) / 256, 256, 0, stream>>>(tgt_s, sm_enc, escore, sden);
    k_sdinv<<<(NN * HH + 255) / 256, 256, 0, stream>>>(sden);
    k_agg<<<NN / 4, 256, 0, stream>>>(tgt_s, rowstart, escore, sden, v, aggmb);
    k_update_o<<<NN / 16, 256, 0, stream>>>(aggmb, oT + (size_t)l * DD * DD, ob + l * DD, h);
    k_ffn<<<NN / 16, 256, 0, stream>>>(n2s + l * DD, n2b + l * DD,
        f1T + (size_t)l * DD * 512, f1b + (size_t)l * 4 * DD,
        f2T + (size_t)l * 512 * DD, f2b + l * DD, h);
  }
  k_pool<<<NG, 256, 0, stream>>>(h, gstart, gend, gpool);
  k_head<<<1, 256, 0, stream>>>(gpool, outW1, outb1, outW2, outb2, (float*)d_out);
}

// Round 4
// 2063.837 us; speedup vs baseline: 2.1087x; 1.1294x over previous
//
#include <hip/hip_runtime.h>

#define NN 50000      // nodes
#define NE 625000     // edges
#define DD 128        // hidden dim
#define HH 8          // heads
#define DHH 16        // head dim
#define NL 4          // layers
#define FIN 64        // in channels
#define NG 64         // graphs
#define LN_EPS 1e-5f
#define NSEG 129      // PWL segments = 128 breakpoints + 1
#define NT32 1563     // ceil(NN/32)

typedef __bf16 bf16x8_t __attribute__((ext_vector_type(8)));
typedef unsigned short ushort8_t __attribute__((ext_vector_type(8)));
typedef float f32x4_t __attribute__((ext_vector_type(4)));
union BF8 { ushort8_t u; bf16x8_t b; };

// ---------- helpers ----------
__device__ __forceinline__ unsigned fenc(float f) {
  unsigned u = __float_as_uint(f);
  return (u & 0x80000000u) ? ~u : (u | 0x80000000u);   // monotonic float->uint
}
__device__ __forceinline__ float fdec(unsigned u) {
  return __uint_as_float((u & 0x80000000u) ? (u & 0x7FFFFFFFu) : ~u);
}
__device__ __forceinline__ void fma4(float4& a, float s, float4 w) {
  a.x = fmaf(s, w.x, a.x); a.y = fmaf(s, w.y, a.y);
  a.z = fmaf(s, w.z, a.z); a.w = fmaf(s, w.w, a.w);
}
__device__ __forceinline__ unsigned short f2bf(float f) {   // RNE f32->bf16
  unsigned u = __float_as_uint(f);
  unsigned r = ((u >> 16) & 1u) + 0x7FFFu;
  return (unsigned short)((u + r) >> 16);
}
__device__ __forceinline__ float bf2f(unsigned short u) {
  return __uint_as_float((unsigned)u << 16);
}

// LayerNorm 32 nodes -> swizzled bf16 LDS tile [32][128]; block = 512 threads.
// byte offset = (row*256 + col*2) ^ ((row&7)<<4)  -> low-conflict ds_read_b128
__device__ __forceinline__ void ln_tile_bf32(const float* __restrict__ h, int nb,
                                             const float* __restrict__ sc,
                                             const float* __restrict__ bi,
                                             ushort* xbf) {
  int tid = threadIdx.x;
  int r = tid >> 4, l16 = tid & 15;
  int nr = nb + r; if (nr >= NN) nr = NN - 1;   // clamp: tail rows unused
  const float* hp = h + (size_t)nr * DD + l16 * 8;
  float4 a0 = *(const float4*)hp;
  float4 a1 = *(const float4*)(hp + 4);
  float sum = a0.x + a0.y + a0.z + a0.w + a1.x + a1.y + a1.z + a1.w;
  float sq  = a0.x*a0.x + a0.y*a0.y + a0.z*a0.z + a0.w*a0.w
            + a1.x*a1.x + a1.y*a1.y + a1.z*a1.z + a1.w*a1.w;
#pragma unroll
  for (int off = 8; off >= 1; off >>= 1) {
    sum += __shfl_xor(sum, off, 64);
    sq  += __shfl_xor(sq,  off, 64);
  }
  float mu   = sum * (1.0f / DD);
  float var  = sq * (1.0f / DD) - mu * mu;
  float rstd = rsqrtf(var + LN_EPS);
  int d0 = l16 * 8;
  float4 s0 = *(const float4*)(sc + d0), s1 = *(const float4*)(sc + d0 + 4);
  float4 b0 = *(const float4*)(bi + d0), b1 = *(const float4*)(bi + d0 + 4);
  ushort8_t u;
  u[0] = f2bf((a0.x - mu) * rstd * s0.x + b0.x);
  u[1] = f2bf((a0.y - mu) * rstd * s0.y + b0.y);
  u[2] = f2bf((a0.z - mu) * rstd * s0.z + b0.z);
  u[3] = f2bf((a0.w - mu) * rstd * s0.w + b0.w);
  u[4] = f2bf((a1.x - mu) * rstd * s1.x + b1.x);
  u[5] = f2bf((a1.y - mu) * rstd * s1.y + b1.y);
  u[6] = f2bf((a1.z - mu) * rstd * s1.z + b1.z);
  u[7] = f2bf((a1.w - mu) * rstd * s1.w + b1.w);
  int off = (r * 256 + l16 * 16) ^ ((r & 7) << 4);
  *(ushort8_t*)((char*)xbf + off) = u;
}

// ---------- kernels ----------
// h = x @ node_W + node_b ; 8 nodes/block (fp32 VALU — minor cost)
__global__ __launch_bounds__(256) void k_node_proj(const float* __restrict__ x,
                                                   const float* __restrict__ W,
                                                   const float* __restrict__ b,
                                                   float* __restrict__ h) {
  __shared__ float xt[8][FIN];
  int tid = threadIdx.x;
  int nb = blockIdx.x * 8;
  {
    int idx = tid * 2;
    *(float2*)&xt[idx >> 6][idx & 63] = *(const float2*)(x + (size_t)nb * FIN + idx);
  }
  __syncthreads();
  int c4 = (tid & 31) * 4;
  int r  = tid >> 5;
  float4 acc = *(const float4*)(b + c4);
  for (int k = 0; k < FIN; k += 4) {
    float4 xk = *(const float4*)&xt[r][k];
    const float* wp = W + (size_t)k * DD + c4;
    fma4(acc, xk.x, *(const float4*)wp);
    fma4(acc, xk.y, *(const float4*)(wp + DD));
    fma4(acc, xk.z, *(const float4*)(wp + 2 * DD));
    fma4(acc, xk.w, *(const float4*)(wp + 3 * DD));
  }
  *(float4*)(h + (size_t)(nb + r) * DD + c4) = acc;
}

// per sorted edge: sim (dot), dist (norm), atomicMax of sim over tgt. 32 lanes/edge.
__global__ __launch_bounds__(256) void k_edge1(const int* __restrict__ src_s, const int* __restrict__ tgt_s,
                                               const float* __restrict__ h, float* __restrict__ sim,
                                               float* __restrict__ dist, unsigned* __restrict__ m_enc) {
  int tid = threadIdx.x;
  int wave = (blockIdx.x * 256 + tid) >> 6;
  int lane = tid & 63;
  int i = wave * 2 + (lane >> 5);
  int j = lane & 31;
  int s = src_s[i], t = tgt_s[i];
  float4 a = *(const float4*)(h + (size_t)s * DD + j * 4);
  float4 b = *(const float4*)(h + (size_t)t * DD + j * 4);
  float dot = a.x*b.x + a.y*b.y + a.z*b.z + a.w*b.w;
  float dx = a.x-b.x, dy = a.y-b.y, dz = a.z-b.z, dw = a.w-b.w;
  float sq = dx*dx + dy*dy + dz*dz + dw*dw;
#pragma unroll
  for (int off = 16; off >= 1; off >>= 1) {
    dot += __shfl_xor(dot, off, 64);
    sq  += __shfl_xor(sq,  off, 64);
  }
  if (j == 0) {
    sim[i]  = dot;                  // BETA == 1.0
    dist[i] = sqrtf(sq);
    atomicMax(m_enc + t, fenc(dot));
  }
}

// denom & alpha*dist numerator per tgt
__global__ void k_edge2(const int* __restrict__ tgt_s, const float* __restrict__ sim,
                        const float* __restrict__ dist, const unsigned* __restrict__ m_enc,
                        float* __restrict__ den, float* __restrict__ nd) {
  int i = blockIdx.x * 256 + threadIdx.x;
  if (i >= NE) return;
  int t = tgt_s[i];
  float ev = expf(sim[i] - fdec(m_enc[t]));
  atomicAdd(den + t, ev);
  atomicAdd(nd + t, ev * dist[i]);
}

__global__ void k_aggv(const float* __restrict__ den, const float* __restrict__ nd,
                       float* __restrict__ aggv) {
  int n = blockIdx.x * 256 + threadIdx.x;
  if (n >= NN) return;
  float d = den[n];
  aggv[n] = d > 0.f ? nd[n] / d : 0.f;
}

// per edge: curvature + PWL segment index (binary search over 128 sorted breakpoints)
__global__ __launch_bounds__(256) void k_curv(const int* __restrict__ tgt_s,
    const float* __restrict__ dist, const float* __restrict__ aggv,
    const float* __restrict__ bp_l, float* __restrict__ curvf, ushort* __restrict__ sege) {
  __shared__ float bp[DD];
  int tid = threadIdx.x;
  if (tid < DD) bp[tid] = bp_l[tid];
  __syncthreads();
  int i = blockIdx.x * 256 + tid;
  if (i >= NE) return;
  int t = tgt_s[i];
  float curv = 1.0f - aggv[t] / fmaxf(dist[i], 1e-6f);
  int lo = 0, hi = DD;
  while (lo < hi) { int mid = (lo + hi) >> 1; if (bp[mid] < curv) lo = mid + 1; else hi = mid; }
  curvf[i] = curv;
  sege[i] = (ushort)lo;     // segment in [0,128]
}

// LN1 + QKV projection via swapped-operand MFMA -> bf16 q/k/v. 32 rows/block, 8 waves.
__global__ __launch_bounds__(512) void k_ln_qkv(const float* __restrict__ h,
    const float* __restrict__ n1s_l, const float* __restrict__ n1b_l,
    const ushort* __restrict__ qkvT_l,
    const float* __restrict__ qb_l, const float* __restrict__ kb_l, const float* __restrict__ vb_l,
    ushort* __restrict__ q, ushort* __restrict__ kk, ushort* __restrict__ v) {
  __shared__ __align__(16) ushort xbf[32 * DD];
  int nb = blockIdx.x * 32;
  ln_tile_bf32(h, nb, n1s_l, n1b_l, xbf);
  __syncthreads();
  int lane = threadIdx.x & 63;
  int w = threadIdx.x >> 6;
  int g = lane >> 4, c = lane & 15;
  int xr = (c & 7) << 4;
  char* xb = (char*)xbf;
  BF8 a[2][4];
#pragma unroll
  for (int nt = 0; nt < 2; nt++)
#pragma unroll
    for (int kt = 0; kt < 4; kt++)
      a[nt][kt].u = *(ushort8_t*)(xb + (((nt * 16 + c) * 256 + kt * 64 + g * 16) ^ xr));
#pragma unroll
  for (int ti = 0; ti < 3; ti++) {
    int t = w * 3 + ti;                // 0..23
    int m = t >> 3;                    // 0=q 1=k 2=v
    int colb = (t & 7) * 16;
    const float* bias = (m == 0 ? qb_l : (m == 1 ? kb_l : vb_l));
    float4 bv = *(const float4*)(bias + colb + g * 4);
    f32x4_t acc0 = {bv.x, bv.y, bv.z, bv.w};
    f32x4_t acc1 = acc0;
    const ushort* wp = qkvT_l + (size_t)(m * DD + colb + c) * DD + g * 8;
#pragma unroll
    for (int kt = 0; kt < 4; kt++) {
      BF8 b; b.u = *(const ushort8_t*)(wp + kt * 32);
      acc0 = __builtin_amdgcn_mfma_f32_16x16x32_bf16(b.b, a[0][kt].b, acc0, 0, 0, 0);
      acc1 = __builtin_amdgcn_mfma_f32_16x16x32_bf16(b.b, a[1][kt].b, acc1, 0, 0, 0);
    }
    ushort* out = (m == 0 ? q : (m == 1 ? kk : v));
    int n0 = nb + c;
    if (n0 < NN) {
      ushort4 o; o.x = f2bf(acc0[0]); o.y = f2bf(acc0[1]); o.z = f2bf(acc0[2]); o.w = f2bf(acc0[3]);
      *(ushort4*)(out + (size_t)n0 * DD + colb + g * 4) = o;
    }
    int n1 = nb + 16 + c;
    if (n1 < NN) {
      ushort4 o; o.x = f2bf(acc1[0]); o.y = f2bf(acc1[1]); o.z = f2bf(acc1[2]); o.w = f2bf(acc1[3]);
      *(ushort4*)(out + (size_t)n1 * DD + colb + g * 4) = o;
    }
  }
}

// per (edge, head): qk dot (bf16) + PWL bias; atomicMax over tgt
__global__ __launch_bounds__(256) void k_scores(const int* __restrict__ src_s, const int* __restrict__ tgt_s,
    const ushort* __restrict__ q, const ushort* __restrict__ k,
    const float* __restrict__ curvf, const ushort* __restrict__ sege,
    const float* __restrict__ slope_l, const float* __restrict__ inter_l,
    float* __restrict__ escore, unsigned* __restrict__ sm_enc) {
  __shared__ float lsl[NSEG * HH], lin[NSEG * HH];
  int tid = threadIdx.x;
  for (int idx = tid; idx < NSEG * HH; idx += 256) { lsl[idx] = slope_l[idx]; lin[idx] = inter_l[idx]; }
  __syncthreads();
  int gi = blockIdx.x * 256 + tid;
  if (gi >= NE * HH) return;
  int i = gi >> 3, hh = gi & 7;
  int s = src_s[i], t = tgt_s[i];
  int seg = sege[i];
  float bias = fmaf(lsl[seg * HH + hh], curvf[i], lin[seg * HH + hh]);
  const ushort8_t* qp = (const ushort8_t*)(q + (size_t)s * DD + hh * DHH);
  const ushort8_t* kp = (const ushort8_t*)(k + (size_t)t * DD + hh * DHH);
  float dot = 0.f;
#pragma unroll
  for (int ii = 0; ii < 2; ii++) {
    ushort8_t a = qp[ii], b = kp[ii];
#pragma unroll
    for (int jj = 0; jj < 8; jj++) dot = fmaf(bf2f(a[jj]), bf2f(b[jj]), dot);
  }
  float sc = dot * 0.25f + bias;   // 1/sqrt(16)
  escore[gi] = sc;
  atomicMax(sm_enc + (size_t)t * HH + hh, fenc(sc));
}

__global__ void k_probs(const int* __restrict__ tgt_s, const unsigned* __restrict__ sm_enc,
                        float* __restrict__ escore, float* __restrict__ sden) {
  int gi = blockIdx.x * 256 + threadIdx.x;
  if (gi >= NE * HH) return;
  int i = gi >> 3, hh = gi & 7;
  int t = tgt_s[i];
  float p = expf(escore[gi] - fdec(sm_enc[(size_t)t * HH + hh]));
  escore[gi] = p;
  atomicAdd(sden + (size_t)t * HH + hh, p);
}

__global__ void k_sdinv(float* __restrict__ sden) {
  int i = blockIdx.x * 256 + threadIdx.x;
  if (i >= NN * HH) return;
  float x = sden[i];
  sden[i] = x > 0.f ? 1.0f / x : 0.f;
}

// CSR-gather message aggregation: one wave per src node, 2 dims/lane -> bf16 out
__global__ __launch_bounds__(256) void k_agg(const int* __restrict__ tgt_s,
    const int* __restrict__ rowstart,
    const float* __restrict__ escore, const float* __restrict__ sdinv,
    const ushort* __restrict__ v, ushort* __restrict__ aggmb) {
  int wave = (blockIdx.x * 256 + threadIdx.x) >> 6;
  int lane = threadIdx.x & 63;
  int rs = rowstart[wave], re = rowstart[wave + 1];
  int hh = lane >> 3;
  int d = lane * 2;
  float a0 = 0.f, a1 = 0.f;
  for (int i = rs; i < re; i++) {
    int t = tgt_s[i];
    float prob = escore[i * HH + hh] * sdinv[t * HH + hh];
    ushort2 vv = *(const ushort2*)(v + (size_t)t * DD + d);
    a0 = fmaf(prob, bf2f(vv.x), a0);
    a1 = fmaf(prob, bf2f(vv.y), a1);
  }
  ushort2 o; o.x = f2bf(a0); o.y = f2bf(a1);
  *(ushort2*)(aggmb + (size_t)wave * DD + d) = o;
}

// h += aggm @ oW + ob via swapped-operand MFMA; 32 rows/block, 8 waves, float4 RMW.
__global__ __launch_bounds__(512) void k_update_o(const ushort* __restrict__ aggmb,
    const ushort* __restrict__ oT_l, const float* __restrict__ ob_l, float* __restrict__ h) {
  int nb = blockIdx.x * 32;
  int lane = threadIdx.x & 63, w = threadIdx.x >> 6;
  int g = lane >> 4, c = lane & 15;
  BF8 a[2][4];
#pragma unroll
  for (int nt = 0; nt < 2; nt++) {
    int na = nb + nt * 16 + c; if (na >= NN) na = NN - 1;
    const ushort* ap = aggmb + (size_t)na * DD + g * 8;
#pragma unroll
    for (int kt = 0; kt < 4; kt++) a[nt][kt].u = *(const ushort8_t*)(ap + kt * 32);
  }
  int colb = w * 16;
  float4 bv = *(const float4*)(ob_l + colb + g * 4);
  f32x4_t acc0 = {bv.x, bv.y, bv.z, bv.w};
  f32x4_t acc1 = acc0;
  const ushort* wp = oT_l + (size_t)(colb + c) * DD + g * 8;
#pragma unroll
  for (int kt = 0; kt < 4; kt++) {
    BF8 b; b.u = *(const ushort8_t*)(wp + kt * 32);
    acc0 = __builtin_amdgcn_mfma_f32_16x16x32_bf16(b.b, a[0][kt].b, acc0, 0, 0, 0);
    acc1 = __builtin_amdgcn_mfma_f32_16x16x32_bf16(b.b, a[1][kt].b, acc1, 0, 0, 0);
  }
#pragma unroll
  for (int nt = 0; nt < 2; nt++) {
    int node = nb + nt * 16 + c;
    if (node < NN) {
      float* hp = h + (size_t)node * DD + colb + g * 4;
      float4 hv = *(const float4*)hp;
      f32x4_t& acc = nt ? acc1 : acc0;
      hv.x += acc[0]; hv.y += acc[1]; hv.z += acc[2]; hv.w += acc[3];
      *(float4*)hp = hv;
    }
  }
}

// fused FFN via swapped-operand MFMA: h += relu(LN2(h)@f1W+f1b)@f2W+f2b; 32 rows/block.
__global__ __launch_bounds__(512) void k_ffn(const float* __restrict__ n2s_l, const float* __restrict__ n2b_l,
    const ushort* __restrict__ f1T_l, const float* __restrict__ f1b_l,
    const ushort* __restrict__ f2T_l, const float* __restrict__ f2b_l,
    float* __restrict__ h) {
  __shared__ __align__(16) ushort xbf[32 * DD];
  __shared__ __align__(16) ushort tbf[32 * 512];
  int nb = blockIdx.x * 32;
  ln_tile_bf32(h, nb, n2s_l, n2b_l, xbf);
  __syncthreads();
  int lane = threadIdx.x & 63, w = threadIdx.x >> 6;
  int g = lane >> 4, c = lane & 15;
  int xr = (c & 7) << 4;
  char* xb = (char*)xbf;
  char* tb = (char*)tbf;
  BF8 a[2][4];
#pragma unroll
  for (int nt = 0; nt < 2; nt++)
#pragma unroll
    for (int kt = 0; kt < 4; kt++)
      a[nt][kt].u = *(ushort8_t*)(xb + (((nt * 16 + c) * 256 + kt * 64 + g * 16) ^ xr));
  // GEMM1: [32,128]@[128,512]; wave w owns col-tiles w*4 .. w*4+3
#pragma unroll
  for (int ti = 0; ti < 4; ti++) {
    int colb = (w * 4 + ti) * 16;
    float4 bv = *(const float4*)(f1b_l + colb + g * 4);
    f32x4_t acc0 = {bv.x, bv.y, bv.z, bv.w};
    f32x4_t acc1 = acc0;
    const ushort* wp = f1T_l + (size_t)(colb + c) * DD + g * 8;
#pragma unroll
    for (int kt = 0; kt < 4; kt++) {
      BF8 b; b.u = *(const ushort8_t*)(wp + kt * 32);
      acc0 = __builtin_amdgcn_mfma_f32_16x16x32_bf16(b.b, a[0][kt].b, acc0, 0, 0, 0);
      acc1 = __builtin_amdgcn_mfma_f32_16x16x32_bf16(b.b, a[1][kt].b, acc1, 0, 0, 0);
    }
    int colB = (colb + g * 4) * 2;
    ushort4 o0, o1;
    o0.x = f2bf(fmaxf(acc0[0], 0.f)); o0.y = f2bf(fmaxf(acc0[1], 0.f));
    o0.z = f2bf(fmaxf(acc0[2], 0.f)); o0.w = f2bf(fmaxf(acc0[3], 0.f));
    o1.x = f2bf(fmaxf(acc1[0], 0.f)); o1.y = f2bf(fmaxf(acc1[1], 0.f));
    o1.z = f2bf(fmaxf(acc1[2], 0.f)); o1.w = f2bf(fmaxf(acc1[3], 0.f));
    *(ushort4*)(tb + ((c * 1024 + colB) ^ ((c & 7) << 4))) = o0;
    *(ushort4*)(tb + (((16 + c) * 1024 + colB) ^ ((c & 7) << 4))) = o1;
  }
  __syncthreads();
  // GEMM2: [32,512]@[512,128]; wave w owns col-tile w
  {
    int colb = w * 16;
    float4 bv = *(const float4*)(f2b_l + colb + g * 4);
    f32x4_t acc0 = {bv.x, bv.y, bv.z, bv.w};
    f32x4_t acc1 = acc0;
    const ushort* wp = f2T_l + (size_t)(colb + c) * 512 + g * 8;
#pragma unroll
    for (int kt = 0; kt < 16; kt++) {
      BF8 b;  b.u  = *(const ushort8_t*)(wp + kt * 32);
      BF8 a0; a0.u = *(ushort8_t*)(tb + ((c * 1024 + kt * 64 + g * 16) ^ xr));
      BF8 a1; a1.u = *(ushort8_t*)(tb + (((16 + c) * 1024 + kt * 64 + g * 16) ^ xr));
      acc0 = __builtin_amdgcn_mfma_f32_16x16x32_bf16(b.b, a0.b, acc0, 0, 0, 0);
      acc1 = __builtin_amdgcn_mfma_f32_16x16x32_bf16(b.b, a1.b, acc1, 0, 0, 0);
    }
#pragma unroll
    for (int nt = 0; nt < 2; nt++) {
      int node = nb + nt * 16 + c;
      if (node < NN) {
        float* hp = h + (size_t)node * DD + colb + g * 4;
        float4 hv = *(const float4*)hp;
        f32x4_t& acc = nt ? acc1 : acc0;
        hv.x += acc[0]; hv.y += acc[1]; hv.z += acc[2]; hv.w += acc[3];
        *(float4*)hp = hv;
      }
    }
  }
}

// ---------- once-per-call setup kernels ----------
// transpose fp32 [K][C] -> bf16 [C][K], nm stacked matrices, dst stride per matrix
template <int K, int C>
__global__ void k_wt(const float* __restrict__ W, ushort* __restrict__ WT, int nm, int dstride) {
  int idx = blockIdx.x * 256 + threadIdx.x;
  if (idx >= K * C * nm) return;
  int mi = idx / (K * C), rem = idx - mi * (K * C);
  int cc = rem / K, kk2 = rem - cc * K;
  WT[(size_t)mi * dstride + cc * K + kk2] = f2bf(W[(size_t)mi * K * C + (size_t)kk2 * C + cc]);
}

__global__ void k_hist(const int* __restrict__ src, int* __restrict__ cnt) {
  int e = blockIdx.x * 256 + threadIdx.x;
  if (e < NE) atomicAdd(cnt + src[e], 1);
}

__global__ __launch_bounds__(1024) void k_scan(const int* __restrict__ cnt, int* __restrict__ rowstart) {
  __shared__ int ps[1024];
  int t = threadIdx.x;
  const int CH = 49;                 // 1024*49 = 50176 >= NN
  int base = t * CH;
  int s = 0;
  for (int i = 0; i < CH; i++) {
    int idx = base + i;
    if (idx < NN) s += cnt[idx];
  }
  ps[t] = s;
  __syncthreads();
  for (int off = 1; off < 1024; off <<= 1) {
    int vv = (t >= off) ? ps[t - off] : 0;
    __syncthreads();
    ps[t] += vv;
    __syncthreads();
  }
  int run = ps[t] - s;               // exclusive prefix
  for (int i = 0; i < CH; i++) {
    int idx = base + i;
    if (idx < NN) { rowstart[idx] = run; run += cnt[idx]; }
  }
  if (t == 1023) rowstart[NN] = ps[1023];
}

// scatter edges into src-sorted order (all per-edge arrays use sorted index)
__global__ void k_fill(const int* __restrict__ src, const int* __restrict__ tgt,
                       const int* __restrict__ rowstart,
                       int* __restrict__ cur, int* __restrict__ src_s, int* __restrict__ tgt_s) {
  int e = blockIdx.x * 256 + threadIdx.x;
  if (e >= NE) return;
  int s = src[e];
  int p = atomicAdd(cur + s, 1);
  int pos = rowstart[s] + p;
  src_s[pos] = s;
  tgt_s[pos] = tgt[e];
}

// M_l = cW2 @ bW_l  [128,8];  base_l = cb2 @ bW_l + bb_l  [8]
__global__ void k_mbias(const float* __restrict__ cW2, const float* __restrict__ cb2,
                        const float* __restrict__ bW, const float* __restrict__ bb,
                        float* __restrict__ M, float* __restrict__ base) {
  int l = blockIdx.x;
  int tid = threadIdx.x;
  const float* bWl = bW + (size_t)l * DD * HH;
  for (int idx = tid; idx < DD * HH; idx += 256) {
    int d = idx >> 3, hh = idx & 7;
    float acc = 0.f;
    for (int j = 0; j < DD; j++) acc = fmaf(cW2[d * DD + j], bWl[j * HH + hh], acc);
    M[(size_t)l * DD * HH + idx] = acc;
  }
  if (tid < HH) {
    float acc = bb[l * HH + tid];
    for (int j = 0; j < DD; j++) acc = fmaf(cb2[j], bWl[j * HH + tid], acc);
    base[l * HH + tid] = acc;
  }
}

// PWL table: bias_h(curv) = relu(curv*cW1+cb1) @ M_l + base_l is piecewise-linear
// in scalar curv with 128 breakpoints x_d = -cb1[d]/cW1[d]. Precompute sorted
// breakpoints + per-segment (slope,intercept) per head. Exact (reassociation only).
__global__ __launch_bounds__(256) void k_pwl(const float* __restrict__ cW1, const float* __restrict__ cb1,
    const float* __restrict__ Mb, const float* __restrict__ basel,
    float* __restrict__ bpg, float* __restrict__ slopeg, float* __restrict__ interg) {
  int l = blockIdx.x;
  __shared__ float c1[DD], cb[DD], x[DD], bp[DD];
  __shared__ int pos[DD];
  int tid = threadIdx.x;
  if (tid < DD) { c1[tid] = cW1[tid]; cb[tid] = cb1[tid]; }
  __syncthreads();
  if (tid < DD)
    x[tid] = (c1[tid] == 0.f) ? __builtin_inff() : (-cb[tid] / c1[tid]);
  __syncthreads();
  if (tid < DD) {
    float xv = x[tid]; int p = 0;
    for (int j = 0; j < DD; j++) {
      float xj = x[j];
      if (xj < xv || (xj == xv && j < tid)) p++;
    }
    pos[tid] = p;
    bp[p] = xv;
  }
  __syncthreads();
  if (tid < DD) bpg[l * DD + tid] = bp[tid];
  const float* M = Mb + (size_t)l * DD * HH;
  for (int idx = tid; idx < NSEG * HH; idx += 256) {
    int s = idx >> 3, hh = idx & 7;
    float sl = 0.f, in = 0.f;
    for (int d = 0; d < DD; d++) {
      bool act;
      if (c1[d] == 0.f)      act = (cb[d] > 0.f);
      else if (c1[d] > 0.f)  act = (pos[d] < s);
      else                   act = (pos[d] >= s);
      if (act) {
        float m = M[d * HH + hh];
        sl = fmaf(c1[d], m, sl);
        in = fmaf(cb[d], m, in);
      }
    }
    slopeg[(size_t)l * NSEG * HH + idx] = sl;
    interg[(size_t)l * NSEG * HH + idx] = in + basel[l * HH + hh];
  }
}

__global__ void k_bounds(const int* __restrict__ batch, int* __restrict__ gstart, int* __restrict__ gend) {
  int n = blockIdx.x * 256 + threadIdx.x;
  if (n >= NN) return;
  int b = batch[n];
  if (n == 0 || batch[n - 1] != b) gstart[b] = n;
  if (n == NN - 1 || batch[n + 1] != b) gend[b] = n + 1;
}

// parallel pool: 256 nodes/block, running sums flushed at graph boundaries
__global__ __launch_bounds__(256) void k_pool_part(const float* __restrict__ h,
    const int* __restrict__ batch, float* __restrict__ gpool) {
  int tid = threadIdx.x;
  int d = tid & 127, sub = tid >> 7;
  int n0 = blockIdx.x * 256;
  int nend = n0 + 256; if (nend > NN) nend = NN;
  float run = 0.f; int gcur = -1;
  for (int n = n0 + sub; n < nend; n += 2) {
    int g = batch[n];
    if (g != gcur) {
      if (gcur >= 0) atomicAdd(gpool + (size_t)gcur * DD + d, run);
      run = 0.f; gcur = g;
    }
    run += h[(size_t)n * DD + d];
  }
  if (gcur >= 0) atomicAdd(gpool + (size_t)gcur * DD + d, run);
}

__global__ __launch_bounds__(256) void k_head(const float* __restrict__ gpool,
    const int* __restrict__ gstart, const int* __restrict__ gend,
    const float* __restrict__ W1, const float* __restrict__ b1,
    const float* __restrict__ W2, const float* __restrict__ b2, float* __restrict__ out) {
  __shared__ float mid[NG * 64];
  int tid = threadIdx.x;
  for (int idx = tid; idx < NG * 64; idx += 256) {
    int g = idx >> 6, j = idx & 63;
    int cnt = gend[g] - gstart[g]; if (cnt < 1) cnt = 1;
    float rc = 1.0f / (float)cnt;
    float acc = 0.f;
    for (int d = 0; d < DD; d++) acc = fmaf(gpool[g * DD + d], W1[d * 64 + j], acc);
    mid[idx] = fmaxf(fmaf(acc, rc, b1[j]), 0.f);
  }
  __syncthreads();
  if (tid < NG) {
    float acc = b2[0];
    for (int j = 0; j < 64; j++) acc = fmaf(mid[tid * 64 + j], W2[j], acc);
    out[tid] = acc;
  }
}

// ---------- launch ----------
extern "C" void kernel_launch(void* const* d_in, const int* in_sizes, int n_in,
                              void* d_out, int out_size, void* d_ws, size_t ws_size,
                              hipStream_t stream) {
  const float* x      = (const float*)d_in[0];
  const int*   ei     = (const int*)d_in[1];
  const int*   batch  = (const int*)d_in[2];
  const float* node_W = (const float*)d_in[3];
  const float* node_b = (const float*)d_in[4];
  const float* cW1    = (const float*)d_in[5];
  const float* cb1    = (const float*)d_in[6];
  const float* cW2    = (const float*)d_in[7];
  const float* cb2    = (const float*)d_in[8];
  const float* qW     = (const float*)d_in[9];
  const float* qb     = (const float*)d_in[10];
  const float* kW     = (const float*)d_in[11];
  const float* kb     = (const float*)d_in[12];
  const float* vW     = (const float*)d_in[13];
  const float* vb     = (const float*)d_in[14];
  const float* oW     = (const float*)d_in[15];
  const float* ob     = (const float*)d_in[16];
  const float* bW     = (const float*)d_in[17];
  const float* bb     = (const float*)d_in[18];
  const float* f1W    = (const float*)d_in[19];
  const float* f1b    = (const float*)d_in[20];
  const float* f2W    = (const float*)d_in[21];
  const float* f2b    = (const float*)d_in[22];
  const float* n1s    = (const float*)d_in[23];
  const float* n1b    = (const float*)d_in[24];
  const float* n2s    = (const float*)d_in[25];
  const float* n2b    = (const float*)d_in[26];
  const float* outW1  = (const float*)d_in[27];
  const float* outb1  = (const float*)d_in[28];
  const float* outW2  = (const float*)d_in[29];
  const float* outb2  = (const float*)d_in[30];

  const int* src = ei;
  const int* tgt = ei + NE;

  char* wp = (char*)d_ws;
  auto alloc = [&](size_t bytes) { void* p = (void*)wp; wp += (bytes + 255) & ~(size_t)255; return p; };
  float*    h       = (float*)alloc((size_t)NN * DD * 4);
  ushort*   q       = (ushort*)alloc((size_t)NN * DD * 2);
  ushort*   kk      = (ushort*)alloc((size_t)NN * DD * 2);
  ushort*   v       = (ushort*)alloc((size_t)NN * DD * 2);
  ushort*   aggmb   = (ushort*)alloc((size_t)NN * DD * 2);
  float*    sim     = (float*)alloc((size_t)NE * 4);
  float*    dist    = (float*)alloc((size_t)NE * 4);
  float*    escore  = (float*)alloc((size_t)NE * HH * 4);
  float*    curvf   = (float*)alloc((size_t)NE * 4);
  ushort*   sege    = (ushort*)alloc((size_t)NE * 2);
  char*     zbase   = wp;                         // zeroed once per layer:
  unsigned* m_enc   = (unsigned*)alloc((size_t)NN * 4);
  float*    den     = (float*)alloc((size_t)NN * 4);
  float*    nd      = (float*)alloc((size_t)NN * 4);
  unsigned* sm_enc  = (unsigned*)alloc((size_t)NN * HH * 4);
  float*    sden    = (float*)alloc((size_t)NN * HH * 4);
  size_t    zbytes  = (size_t)(wp - zbase);
  float*    aggv    = (float*)alloc((size_t)NN * 4);
  float*    Mb      = (float*)alloc((size_t)NL * DD * HH * 4);
  float*    basel   = (float*)alloc((size_t)NL * HH * 4);
  float*    bpg     = (float*)alloc((size_t)NL * DD * 4);
  float*    slopeg  = (float*)alloc((size_t)NL * NSEG * HH * 4);
  float*    interg  = (float*)alloc((size_t)NL * NSEG * HH * 4);
  int*      rowstart= (int*)alloc((size_t)(NN + 1) * 4);
  int*      src_s   = (int*)alloc((size_t)NE * 4);
  int*      tgt_s   = (int*)alloc((size_t)NE * 4);
  int*      cnt     = (int*)alloc((size_t)NN * 4);
  int*      cur     = (int*)alloc((size_t)NN * 4);
  int*      gstart  = (int*)alloc((size_t)NG * 4);
  int*      gend    = (int*)alloc((size_t)NG * 4);
  float*    gpool   = (float*)alloc((size_t)NG * DD * 4);
  ushort*   qkvT    = (ushort*)alloc((size_t)NL * 3 * DD * DD * 2);
  ushort*   oT      = (ushort*)alloc((size_t)NL * DD * DD * 2);
  ushort*   f1T     = (ushort*)alloc((size_t)NL * DD * 512 * 2);
  ushort*   f2T     = (ushort*)alloc((size_t)NL * 512 * DD * 2);
  (void)in_sizes; (void)n_in; (void)out_size; (void)ws_size;

  // once-per-call setup
  hipMemsetAsync(cnt, 0, NN * 4, stream);
  hipMemsetAsync(cur, 0, NN * 4, stream);
  hipMemsetAsync(gstart, 0, NG * 4, stream);
  hipMemsetAsync(gend, 0, NG * 4, stream);
  hipMemsetAsync(gpool, 0, NG * DD * 4, stream);
  k_hist<<<(NE + 255) / 256, 256, 0, stream>>>(src, cnt);
  k_scan<<<1, 1024, 0, stream>>>(cnt, rowstart);
  k_fill<<<(NE + 255) / 256, 256, 0, stream>>>(src, tgt, rowstart, cur, src_s, tgt_s);
  k_mbias<<<NL, 256, 0, stream>>>(cW2, cb2, bW, bb, Mb, basel);
  k_pwl<<<NL, 256, 0, stream>>>(cW1, cb1, Mb, basel, bpg, slopeg, interg);
  k_bounds<<<(NN + 255) / 256, 256, 0, stream>>>(batch, gstart, gend);
  // bf16-transposed weights
  k_wt<DD, DD><<<(NL * DD * DD + 255) / 256, 256, 0, stream>>>(qW, qkvT,               NL, 3 * DD * DD);
  k_wt<DD, DD><<<(NL * DD * DD + 255) / 256, 256, 0, stream>>>(kW, qkvT + DD * DD,     NL, 3 * DD * DD);
  k_wt<DD, DD><<<(NL * DD * DD + 255) / 256, 256, 0, stream>>>(vW, qkvT + 2 * DD * DD, NL, 3 * DD * DD);
  k_wt<DD, DD><<<(NL * DD * DD + 255) / 256, 256, 0, stream>>>(oW, oT, NL, DD * DD);
  k_wt<DD, 512><<<(NL * DD * 512 + 255) / 256, 256, 0, stream>>>(f1W, f1T, NL, DD * 512);
  k_wt<512, DD><<<(NL * DD * 512 + 255) / 256, 256, 0, stream>>>(f2W, f2T, NL, DD * 512);
  k_node_proj<<<NN / 8, 256, 0, stream>>>(x, node_W, node_b, h);

  for (int l = 0; l < NL; l++) {
    hipMemsetAsync(zbase, 0, zbytes, stream);
    k_edge1<<<NE / 8, 256, 0, stream>>>(src_s, tgt_s, h, sim, dist, m_enc);
    k_edge2<<<(NE + 255) / 256, 256, 0, stream>>>(tgt_s, sim, dist, m_enc, den, nd);
    k_aggv<<<(NN + 255) / 256, 256, 0, stream>>>(den, nd, aggv);
    k_curv<<<(NE + 255) / 256, 256, 0, stream>>>(tgt_s, dist, aggv, bpg + l * DD, curvf, sege);
    k_ln_qkv<<<NT32, 512, 0, stream>>>(h, n1s + l * DD, n1b + l * DD,
        qkvT + (size_t)l * 3 * DD * DD,
        qb + l * DD, kb + l * DD, vb + l * DD, q, kk, v);
    k_scores<<<(NE * HH + 255) / 256, 256, 0, stream>>>(src_s, tgt_s, q, kk,
        curvf, sege, slopeg + (size_t)l * NSEG * HH, interg + (size_t)l * NSEG * HH,
        escore, sm_enc);
    k_probs<<<(NE * HH + 255) / 256, 256, 0, stream>>>(tgt_s, sm_enc, escore, sden);
    k_sdinv<<<(NN * HH + 255) / 256, 256, 0, stream>>>(sden);
    k_agg<<<NN / 4, 256, 0, stream>>>(tgt_s, rowstart, escore, sden, v, aggmb);
    k_update_o<<<NT32, 512, 0, stream>>>(aggmb, oT + (size_t)l * DD * DD, ob + l * DD, h);
    k_ffn<<<NT32, 512, 0, stream>>>(n2s + l * DD, n2b + l * DD,
        f1T + (size_t)l * DD * 512, f1b + (size_t)l * 4 * DD,
        f2T + (size_t)l * 512 * DD, f2b + l * DD, h);
  }
  k_pool_part<<<(NN + 255) / 256, 256, 0, stream>>>(h, batch, gpool);
  k_head<<<1, 256, 0, stream>>>(gpool, gstart, gend, outW1, outb1, outW2, outb2, (float*)d_out);
}

// Round 7
// 2041.801 us; speedup vs baseline: 2.1315x; 1.0108x over previous
//
#include <hip/hip_runtime.h>

#define NN 50000      // nodes
#define NE 625000     // edges
#define DD 128        // hidden dim
#define HH 8          // heads
#define DHH 16        // head dim
#define NL 4          // layers
#define FIN 64        // in channels
#define NG 64         // graphs
#define LN_EPS 1e-5f
#define NSEG 129      // PWL segments = 128 breakpoints + 1
#define NT32 1563     // ceil(NN/32)

typedef __bf16 bf16x8_t __attribute__((ext_vector_type(8)));
typedef unsigned short ushort8_t __attribute__((ext_vector_type(8)));
typedef float f32x4_t __attribute__((ext_vector_type(4)));
union BF8 { ushort8_t u; bf16x8_t b; };

// ---------- helpers ----------
__device__ __forceinline__ unsigned fenc(float f) {
  unsigned u = __float_as_uint(f);
  return (u & 0x80000000u) ? ~u : (u | 0x80000000u);   // monotonic float->uint
}
__device__ __forceinline__ float fdec(unsigned u) {
  return __uint_as_float((u & 0x80000000u) ? (u & 0x7FFFFFFFu) : ~u);
}
__device__ __forceinline__ void fma4(float4& a, float s, float4 w) {
  a.x = fmaf(s, w.x, a.x); a.y = fmaf(s, w.y, a.y);
  a.z = fmaf(s, w.z, a.z); a.w = fmaf(s, w.w, a.w);
}
__device__ __forceinline__ unsigned short f2bf(float f) {   // RNE f32->bf16
  unsigned u = __float_as_uint(f);
  unsigned r = ((u >> 16) & 1u) + 0x7FFFu;
  return (unsigned short)((u + r) >> 16);
}
__device__ __forceinline__ float bf2f(unsigned short u) {
  return __uint_as_float((unsigned)u << 16);
}

// LayerNorm 32 nodes -> swizzled bf16 LDS tile [32][128]; block = 512 threads.
__device__ __forceinline__ void ln_tile_bf32(const float* __restrict__ h, int nb,
                                             const float* __restrict__ sc,
                                             const float* __restrict__ bi,
                                             ushort* xbf) {
  int tid = threadIdx.x;
  int r = tid >> 4, l16 = tid & 15;
  int nr = nb + r; if (nr >= NN) nr = NN - 1;   // clamp: tail rows unused
  const float* hp = h + (size_t)nr * DD + l16 * 8;
  float4 a0 = *(const float4*)hp;
  float4 a1 = *(const float4*)(hp + 4);
  float sum = a0.x + a0.y + a0.z + a0.w + a1.x + a1.y + a1.z + a1.w;
  float sq  = a0.x*a0.x + a0.y*a0.y + a0.z*a0.z + a0.w*a0.w
            + a1.x*a1.x + a1.y*a1.y + a1.z*a1.z + a1.w*a1.w;
#pragma unroll
  for (int off = 8; off >= 1; off >>= 1) {
    sum += __shfl_xor(sum, off, 64);
    sq  += __shfl_xor(sq,  off, 64);
  }
  float mu   = sum * (1.0f / DD);
  float var  = sq * (1.0f / DD) - mu * mu;
  float rstd = rsqrtf(var + LN_EPS);
  int d0 = l16 * 8;
  float4 s0 = *(const float4*)(sc + d0), s1 = *(const float4*)(sc + d0 + 4);
  float4 b0 = *(const float4*)(bi + d0), b1 = *(const float4*)(bi + d0 + 4);
  ushort8_t u;
  u[0] = f2bf((a0.x - mu) * rstd * s0.x + b0.x);
  u[1] = f2bf((a0.y - mu) * rstd * s0.y + b0.y);
  u[2] = f2bf((a0.z - mu) * rstd * s0.z + b0.z);
  u[3] = f2bf((a0.w - mu) * rstd * s0.w + b0.w);
  u[4] = f2bf((a1.x - mu) * rstd * s1.x + b1.x);
  u[5] = f2bf((a1.y - mu) * rstd * s1.y + b1.y);
  u[6] = f2bf((a1.z - mu) * rstd * s1.z + b1.z);
  u[7] = f2bf((a1.w - mu) * rstd * s1.w + b1.w);
  int off = (r * 256 + l16 * 16) ^ ((r & 7) << 4);
  *(ushort8_t*)((char*)xbf + off) = u;
}

// ---------- kernels ----------
// h = x @ node_W + node_b ; 8 nodes/block (fp32 VALU — minor cost)
__global__ __launch_bounds__(256) void k_node_proj(const float* __restrict__ x,
                                                   const float* __restrict__ W,
                                                   const float* __restrict__ b,
                                                   float* __restrict__ h) {
  __shared__ float xt[8][FIN];
  int tid = threadIdx.x;
  int nb = blockIdx.x * 8;
  {
    int idx = tid * 2;
    *(float2*)&xt[idx >> 6][idx & 63] = *(const float2*)(x + (size_t)nb * FIN + idx);
  }
  __syncthreads();
  int c4 = (tid & 31) * 4;
  int r  = tid >> 5;
  float4 acc = *(const float4*)(b + c4);
  for (int k = 0; k < FIN; k += 4) {
    float4 xk = *(const float4*)&xt[r][k];
    const float* wp = W + (size_t)k * DD + c4;
    fma4(acc, xk.x, *(const float4*)wp);
    fma4(acc, xk.y, *(const float4*)(wp + DD));
    fma4(acc, xk.z, *(const float4*)(wp + 2 * DD));
    fma4(acc, xk.w, *(const float4*)(wp + 3 * DD));
  }
  *(float4*)(h + (size_t)(nb + r) * DD + c4) = acc;
}

// per sorted edge: sim (dot), dist (norm) in fp32. 32 lanes/edge.
__global__ __launch_bounds__(256) void k_edge1(const int* __restrict__ src_s, const int* __restrict__ tgt_s,
                                               const float* __restrict__ h, float* __restrict__ sim,
                                               float* __restrict__ dist, unsigned* __restrict__ m_enc) {
  int tid = threadIdx.x;
  int wave = (blockIdx.x * 256 + tid) >> 6;
  int lane = tid & 63;
  int i = wave * 2 + (lane >> 5);
  int j = lane & 31;
  int s = src_s[i], t = tgt_s[i];
  float4 a = *(const float4*)(h + (size_t)s * DD + j * 4);
  float4 b = *(const float4*)(h + (size_t)t * DD + j * 4);
  float dot = a.x*b.x + a.y*b.y + a.z*b.z + a.w*b.w;
  float dx = a.x-b.x, dy = a.y-b.y, dz = a.z-b.z, dw = a.w-b.w;
  float sq = dx*dx + dy*dy + dz*dz + dw*dw;
#pragma unroll
  for (int off = 16; off >= 1; off >>= 1) {
    dot += __shfl_xor(dot, off, 64);
    sq  += __shfl_xor(sq,  off, 64);
  }
  if (j == 0) {
    sim[i]  = dot;                  // BETA == 1.0
    dist[i] = sqrtf(sq);
    atomicMax(m_enc + t, fenc(dot));
  }
}

// denom & alpha*dist numerator per tgt
__global__ void k_edge2(const int* __restrict__ tgt_s, const float* __restrict__ sim,
                        const float* __restrict__ dist, const unsigned* __restrict__ m_enc,
                        float* __restrict__ den, float* __restrict__ nd) {
  int i = blockIdx.x * 256 + threadIdx.x;
  if (i >= NE) return;
  int t = tgt_s[i];
  float ev = expf(sim[i] - fdec(m_enc[t]));
  atomicAdd(den + t, ev);
  atomicAdd(nd + t, ev * dist[i]);
}

__global__ void k_aggv(const float* __restrict__ den, const float* __restrict__ nd,
                       float* __restrict__ aggv) {
  int n = blockIdx.x * 256 + threadIdx.x;
  if (n >= NN) return;
  float d = den[n];
  aggv[n] = d > 0.f ? nd[n] / d : 0.f;
}

// per edge: curvature + PWL segment index (binary search over 128 sorted breakpoints)
__global__ __launch_bounds__(256) void k_curv(const int* __restrict__ tgt_s,
    const float* __restrict__ dist, const float* __restrict__ aggv,
    const float* __restrict__ bp_l, float* __restrict__ curvf, ushort* __restrict__ sege) {
  __shared__ float bp[DD];
  int tid = threadIdx.x;
  if (tid < DD) bp[tid] = bp_l[tid];
  __syncthreads();
  int i = blockIdx.x * 256 + tid;
  if (i >= NE) return;
  int t = tgt_s[i];
  float curv = 1.0f - aggv[t] / fmaxf(dist[i], 1e-6f);
  int lo = 0, hi = DD;
  while (lo < hi) { int mid = (lo + hi) >> 1; if (bp[mid] < curv) lo = mid + 1; else hi = mid; }
  curvf[i] = curv;
  sege[i] = (ushort)lo;     // segment in [0,128]
}

// LN1 + QKV projection via swapped-operand MFMA -> bf16 q/k/v. 32 rows/block, 8 waves.
__global__ __launch_bounds__(512) void k_ln_qkv(const float* __restrict__ h,
    const float* __restrict__ n1s_l, const float* __restrict__ n1b_l,
    const ushort* __restrict__ qkvT_l,
    const float* __restrict__ qb_l, const float* __restrict__ kb_l, const float* __restrict__ vb_l,
    ushort* __restrict__ q, ushort* __restrict__ kk, ushort* __restrict__ v) {
  __shared__ __align__(16) ushort xbf[32 * DD];
  int nb = blockIdx.x * 32;
  ln_tile_bf32(h, nb, n1s_l, n1b_l, xbf);
  __syncthreads();
  int lane = threadIdx.x & 63;
  int w = threadIdx.x >> 6;
  int g = lane >> 4, c = lane & 15;
  int xr = (c & 7) << 4;
  char* xb = (char*)xbf;
  BF8 a[2][4];
#pragma unroll
  for (int nt = 0; nt < 2; nt++)
#pragma unroll
    for (int kt = 0; kt < 4; kt++)
      a[nt][kt].u = *(ushort8_t*)(xb + (((nt * 16 + c) * 256 + kt * 64 + g * 16) ^ xr));
#pragma unroll
  for (int ti = 0; ti < 3; ti++) {
    int t = w * 3 + ti;                // 0..23
    int m = t >> 3;                    // 0=q 1=k 2=v
    int colb = (t & 7) * 16;
    const float* bias = (m == 0 ? qb_l : (m == 1 ? kb_l : vb_l));
    float4 bv = *(const float4*)(bias + colb + g * 4);
    f32x4_t acc0 = {bv.x, bv.y, bv.z, bv.w};
    f32x4_t acc1 = acc0;
    const ushort* wp = qkvT_l + (size_t)(m * DD + colb + c) * DD + g * 8;
#pragma unroll
    for (int kt = 0; kt < 4; kt++) {
      BF8 b; b.u = *(const ushort8_t*)(wp + kt * 32);
      acc0 = __builtin_amdgcn_mfma_f32_16x16x32_bf16(b.b, a[0][kt].b, acc0, 0, 0, 0);
      acc1 = __builtin_amdgcn_mfma_f32_16x16x32_bf16(b.b, a[1][kt].b, acc1, 0, 0, 0);
    }
    ushort* out = (m == 0 ? q : (m == 1 ? kk : v));
    int n0 = nb + c;
    if (n0 < NN) {
      ushort4 o; o.x = f2bf(acc0[0]); o.y = f2bf(acc0[1]); o.z = f2bf(acc0[2]); o.w = f2bf(acc0[3]);
      *(ushort4*)(out + (size_t)n0 * DD + colb + g * 4) = o;
    }
    int n1 = nb + 16 + c;
    if (n1 < NN) {
      ushort4 o; o.x = f2bf(acc1[0]); o.y = f2bf(acc1[1]); o.z = f2bf(acc1[2]); o.w = f2bf(acc1[3]);
      *(ushort4*)(out + (size_t)n1 * DD + colb + g * 4) = o;
    }
  }
}

// per (edge, head): qk dot (bf16) + PWL bias; atomicMax over tgt (round-4 semantics)
__global__ __launch_bounds__(256) void k_scores(const int* __restrict__ src_s, const int* __restrict__ tgt_s,
    const ushort* __restrict__ q, const ushort* __restrict__ k,
    const float* __restrict__ curvf, const ushort* __restrict__ sege,
    const float* __restrict__ slope_l, const float* __restrict__ inter_l,
    float* __restrict__ escore, unsigned* __restrict__ sm_enc) {
  __shared__ float lsl[NSEG * HH], lin[NSEG * HH];
  int tid = threadIdx.x;
  for (int idx = tid; idx < NSEG * HH; idx += 256) { lsl[idx] = slope_l[idx]; lin[idx] = inter_l[idx]; }
  __syncthreads();
  int gi = blockIdx.x * 256 + tid;
  if (gi >= NE * HH) return;
  int i = gi >> 3, hh = gi & 7;
  int s = src_s[i], t = tgt_s[i];
  int seg = sege[i];
  float bias = fmaf(lsl[seg * HH + hh], curvf[i], lin[seg * HH + hh]);
  const ushort8_t* qp = (const ushort8_t*)(q + (size_t)s * DD + hh * DHH);
  const ushort8_t* kp = (const ushort8_t*)(k + (size_t)t * DD + hh * DHH);
  float dot = 0.f;
#pragma unroll
  for (int ii = 0; ii < 2; ii++) {
    ushort8_t a = qp[ii], b = kp[ii];
#pragma unroll
    for (int jj = 0; jj < 8; jj++) dot = fmaf(bf2f(a[jj]), bf2f(b[jj]), dot);
  }
  float sc = dot * 0.25f + bias;   // 1/sqrt(16)
  escore[gi] = sc;
  atomicMax(sm_enc + (size_t)t * HH + hh, fenc(sc));
}

__global__ void k_probs(const int* __restrict__ tgt_s, const unsigned* __restrict__ sm_enc,
                        float* __restrict__ escore, float* __restrict__ sden) {
  int gi = blockIdx.x * 256 + threadIdx.x;
  if (gi >= NE * HH) return;
  int i = gi >> 3, hh = gi & 7;
  int t = tgt_s[i];
  float p = expf(escore[gi] - fdec(sm_enc[(size_t)t * HH + hh]));
  escore[gi] = p;
  atomicAdd(sden + (size_t)t * HH + hh, p);
}

__global__ void k_sdinv(float* __restrict__ sden) {
  int i = blockIdx.x * 256 + threadIdx.x;
  if (i >= NN * HH) return;
  float x = sden[i];
  sden[i] = x > 0.f ? 1.0f / x : 0.f;
}

// CSR-gather message aggregation: one wave per src node, 2 dims/lane -> bf16 out
__global__ __launch_bounds__(256) void k_agg(const int* __restrict__ tgt_s,
    const int* __restrict__ rowstart,
    const float* __restrict__ escore, const float* __restrict__ sdinv,
    const ushort* __restrict__ v, ushort* __restrict__ aggmb) {
  int wave = (blockIdx.x * 256 + threadIdx.x) >> 6;
  int lane = threadIdx.x & 63;
  int rs = rowstart[wave], re = rowstart[wave + 1];
  int hh = lane >> 3;
  int d = lane * 2;
  float a0 = 0.f, a1 = 0.f;
  for (int i = rs; i < re; i++) {
    int t = tgt_s[i];
    float prob = escore[i * HH + hh] * sdinv[t * HH + hh];
    ushort2 vv = *(const ushort2*)(v + (size_t)t * DD + d);
    a0 = fmaf(prob, bf2f(vv.x), a0);
    a1 = fmaf(prob, bf2f(vv.y), a1);
  }
  ushort2 o; o.x = f2bf(a0); o.y = f2bf(a1);
  *(ushort2*)(aggmb + (size_t)wave * DD + d) = o;
}

// h += aggm @ oW + ob via swapped-operand MFMA; 32 rows/block, 8 waves, float4 RMW.
__global__ __launch_bounds__(512) void k_update_o(const ushort* __restrict__ aggmb,
    const ushort* __restrict__ oT_l, const float* __restrict__ ob_l, float* __restrict__ h) {
  int nb = blockIdx.x * 32;
  int lane = threadIdx.x & 63, w = threadIdx.x >> 6;
  int g = lane >> 4, c = lane & 15;
  BF8 a[2][4];
#pragma unroll
  for (int nt = 0; nt < 2; nt++) {
    int na = nb + nt * 16 + c; if (na >= NN) na = NN - 1;
    const ushort* ap = aggmb + (size_t)na * DD + g * 8;
#pragma unroll
    for (int kt = 0; kt < 4; kt++) a[nt][kt].u = *(const ushort8_t*)(ap + kt * 32);
  }
  int colb = w * 16;
  float4 bv = *(const float4*)(ob_l + colb + g * 4);
  f32x4_t acc0 = {bv.x, bv.y, bv.z, bv.w};
  f32x4_t acc1 = acc0;
  const ushort* wp = oT_l + (size_t)(colb + c) * DD + g * 8;
#pragma unroll
  for (int kt = 0; kt < 4; kt++) {
    BF8 b; b.u = *(const ushort8_t*)(wp + kt * 32);
    acc0 = __builtin_amdgcn_mfma_f32_16x16x32_bf16(b.b, a[0][kt].b, acc0, 0, 0, 0);
    acc1 = __builtin_amdgcn_mfma_f32_16x16x32_bf16(b.b, a[1][kt].b, acc1, 0, 0, 0);
  }
#pragma unroll
  for (int nt = 0; nt < 2; nt++) {
    int node = nb + nt * 16 + c;
    if (node < NN) {
      float* hp = h + (size_t)node * DD + colb + g * 4;
      float4 hv = *(const float4*)hp;
      f32x4_t& acc = nt ? acc1 : acc0;
      hv.x += acc[0]; hv.y += acc[1]; hv.z += acc[2]; hv.w += acc[3];
      *(float4*)hp = hv;
    }
  }
}

// fused FFN: h += relu(LN2(h)@f1W+f1b)@f2W+f2b; 32 rows/block.
__global__ __launch_bounds__(512) void k_ffn(const float* __restrict__ n2s_l, const float* __restrict__ n2b_l,
    const ushort* __restrict__ f1T_l, const float* __restrict__ f1b_l,
    const ushort* __restrict__ f2T_l, const float* __restrict__ f2b_l,
    float* __restrict__ h) {
  __shared__ __align__(16) ushort xbf[32 * DD];
  __shared__ __align__(16) ushort tbf[32 * 512];
  int nb = blockIdx.x * 32;
  ln_tile_bf32(h, nb, n2s_l, n2b_l, xbf);
  __syncthreads();
  int lane = threadIdx.x & 63, w = threadIdx.x >> 6;
  int g = lane >> 4, c = lane & 15;
  int xr = (c & 7) << 4;
  char* xb = (char*)xbf;
  char* tb = (char*)tbf;
  BF8 a[2][4];
#pragma unroll
  for (int nt = 0; nt < 2; nt++)
#pragma unroll
    for (int kt = 0; kt < 4; kt++)
      a[nt][kt].u = *(ushort8_t*)(xb + (((nt * 16 + c) * 256 + kt * 64 + g * 16) ^ xr));
  // GEMM1: [32,128]@[128,512]; wave w owns col-tiles w*4 .. w*4+3
#pragma unroll
  for (int ti = 0; ti < 4; ti++) {
    int colb = (w * 4 + ti) * 16;
    float4 bv = *(const float4*)(f1b_l + colb + g * 4);
    f32x4_t acc0 = {bv.x, bv.y, bv.z, bv.w};
    f32x4_t acc1 = acc0;
    const ushort* wp = f1T_l + (size_t)(colb + c) * DD + g * 8;
#pragma unroll
    for (int kt = 0; kt < 4; kt++) {
      BF8 b; b.u = *(const ushort8_t*)(wp + kt * 32);
      acc0 = __builtin_amdgcn_mfma_f32_16x16x32_bf16(b.b, a[0][kt].b, acc0, 0, 0, 0);
      acc1 = __builtin_amdgcn_mfma_f32_16x16x32_bf16(b.b, a[1][kt].b, acc1, 0, 0, 0);
    }
    int colB = (colb + g * 4) * 2;
    ushort4 o0, o1;
    o0.x = f2bf(fmaxf(acc0[0], 0.f)); o0.y = f2bf(fmaxf(acc0[1], 0.f));
    o0.z = f2bf(fmaxf(acc0[2], 0.f)); o0.w = f2bf(fmaxf(acc0[3], 0.f));
    o1.x = f2bf(fmaxf(acc1[0], 0.f)); o1.y = f2bf(fmaxf(acc1[1], 0.f));
    o1.z = f2bf(fmaxf(acc1[2], 0.f)); o1.w = f2bf(fmaxf(acc1[3], 0.f));
    *(ushort4*)(tb + ((c * 1024 + colB) ^ ((c & 7) << 4))) = o0;
    *(ushort4*)(tb + (((16 + c) * 1024 + colB) ^ ((c & 7) << 4))) = o1;
  }
  __syncthreads();
  // GEMM2: [32,512]@[512,128]; wave w owns col-tile w
  {
    int colb = w * 16;
    float4 bv = *(const float4*)(f2b_l + colb + g * 4);
    f32x4_t acc0 = {bv.x, bv.y, bv.z, bv.w};
    f32x4_t acc1 = acc0;
    const ushort* wp = f2T_l + (size_t)(colb + c) * 512 + g * 8;
#pragma unroll
    for (int kt = 0; kt < 16; kt++) {
      BF8 b;  b.u  = *(const ushort8_t*)(wp + kt * 32);
      BF8 a0; a0.u = *(ushort8_t*)(tb + ((c * 1024 + kt * 64 + g * 16) ^ xr));
      BF8 a1; a1.u = *(ushort8_t*)(tb + (((16 + c) * 1024 + kt * 64 + g * 16) ^ xr));
      acc0 = __builtin_amdgcn_mfma_f32_16x16x32_bf16(b.b, a0.b, acc0, 0, 0, 0);
      acc1 = __builtin_amdgcn_mfma_f32_16x16x32_bf16(b.b, a1.b, acc1, 0, 0, 0);
    }
#pragma unroll
    for (int nt = 0; nt < 2; nt++) {
      int node = nb + nt * 16 + c;
      if (node < NN) {
        float* hp = h + (size_t)node * DD + colb + g * 4;
        float4 hv = *(const float4*)hp;
        f32x4_t& acc = nt ? acc1 : acc0;
        hv.x += acc[0]; hv.y += acc[1]; hv.z += acc[2]; hv.w += acc[3];
        *(float4*)hp = hv;
      }
    }
  }
}

// ---------- once-per-call setup kernels ----------
// transpose fp32 [K][C] -> bf16 [C][K], nm stacked matrices, dst stride per matrix
template <int K, int C>
__global__ void k_wt(const float* __restrict__ W, ushort* __restrict__ WT, int nm, int dstride) {
  int idx = blockIdx.x * 256 + threadIdx.x;
  if (idx >= K * C * nm) return;
  int mi = idx / (K * C), rem = idx - mi * (K * C);
  int cc = rem / K, kk2 = rem - cc * K;
  WT[(size_t)mi * dstride + cc * K + kk2] = f2bf(W[(size_t)mi * K * C + (size_t)kk2 * C + cc]);
}

__global__ void k_hist(const int* __restrict__ src, int* __restrict__ cnt) {
  int e = blockIdx.x * 256 + threadIdx.x;
  if (e < NE) atomicAdd(cnt + src[e], 1);
}

__global__ __launch_bounds__(1024) void k_scan(const int* __restrict__ cnt, int* __restrict__ rowstart) {
  __shared__ int ps[1024];
  int t = threadIdx.x;
  const int CH = 49;                 // 1024*49 = 50176 >= NN
  int base = t * CH;
  int s = 0;
  for (int i = 0; i < CH; i++) {
    int idx = base + i;
    if (idx < NN) s += cnt[idx];
  }
  ps[t] = s;
  __syncthreads();
  for (int off = 1; off < 1024; off <<= 1) {
    int vv = (t >= off) ? ps[t - off] : 0;
    __syncthreads();
    ps[t] += vv;
    __syncthreads();
  }
  int run = ps[t] - s;               // exclusive prefix
  for (int i = 0; i < CH; i++) {
    int idx = base + i;
    if (idx < NN) { rowstart[idx] = run; run += cnt[idx]; }
  }
  if (t == 1023) rowstart[NN] = ps[1023];
}

// scatter edges into src-sorted order (all per-edge arrays use sorted index)
__global__ void k_fill(const int* __restrict__ src, const int* __restrict__ tgt,
                       const int* __restrict__ rowstart,
                       int* __restrict__ cur, int* __restrict__ src_s, int* __restrict__ tgt_s) {
  int e = blockIdx.x * 256 + threadIdx.x;
  if (e >= NE) return;
  int s = src[e];
  int p = atomicAdd(cur + s, 1);
  int pos = rowstart[s] + p;
  src_s[pos] = s;
  tgt_s[pos] = tgt[e];
}

// M_l = cW2 @ bW_l  [128,8];  base_l = cb2 @ bW_l + bb_l  [8]  (bW cached in LDS;
// identical read values & fma order as round 4 -> bit-exact)
__global__ void k_mbias(const float* __restrict__ cW2, const float* __restrict__ cb2,
                        const float* __restrict__ bW, const float* __restrict__ bb,
                        float* __restrict__ M, float* __restrict__ base) {
  int l = blockIdx.x;
  int tid = threadIdx.x;
  __shared__ float lbW[DD * HH];
  const float* bWl = bW + (size_t)l * DD * HH;
  for (int i = tid; i < DD * HH; i += 256) lbW[i] = bWl[i];
  __syncthreads();
  for (int idx = tid; idx < DD * HH; idx += 256) {
    int d = idx >> 3, hh = idx & 7;
    float acc = 0.f;
    for (int j = 0; j < DD; j++) acc = fmaf(cW2[d * DD + j], lbW[j * HH + hh], acc);
    M[(size_t)l * DD * HH + idx] = acc;
  }
  if (tid < HH) {
    float acc = bb[l * HH + tid];
    for (int j = 0; j < DD; j++) acc = fmaf(cb2[j], lbW[j * HH + tid], acc);
    base[l * HH + tid] = acc;
  }
}

// PWL table. Round-4 branch structure preserved EXACTLY (bit-exact); only change:
// M cached in LDS so the conditional loads are no longer serialized global-latency.
__global__ __launch_bounds__(256) void k_pwl(const float* __restrict__ cW1, const float* __restrict__ cb1,
    const float* __restrict__ Mb, const float* __restrict__ basel,
    float* __restrict__ bpg, float* __restrict__ slopeg, float* __restrict__ interg) {
  int l = blockIdx.x;
  __shared__ float c1[DD], cb[DD], x[DD], bp[DD], lM[DD * HH];
  __shared__ int pos[DD];
  int tid = threadIdx.x;
  if (tid < DD) { c1[tid] = cW1[tid]; cb[tid] = cb1[tid]; }
  for (int i = tid; i < DD * HH; i += 256) lM[i] = Mb[(size_t)l * DD * HH + i];
  __syncthreads();
  if (tid < DD)
    x[tid] = (c1[tid] == 0.f) ? __builtin_inff() : (-cb[tid] / c1[tid]);
  __syncthreads();
  if (tid < DD) {
    float xv = x[tid]; int p = 0;
    for (int j = 0; j < DD; j++) {
      float xj = x[j];
      if (xj < xv || (xj == xv && j < tid)) p++;
    }
    pos[tid] = p;
    bp[p] = xv;
  }
  __syncthreads();
  if (tid < DD) bpg[l * DD + tid] = bp[tid];
  for (int idx = tid; idx < NSEG * HH; idx += 256) {
    int s = idx >> 3, hh = idx & 7;
    float sl = 0.f, in = 0.f;
    for (int d = 0; d < DD; d++) {
      bool act;
      if (c1[d] == 0.f)      act = (cb[d] > 0.f);
      else if (c1[d] > 0.f)  act = (pos[d] < s);
      else                   act = (pos[d] >= s);
      if (act) {
        float m = lM[d * HH + hh];
        sl = fmaf(c1[d], m, sl);
        in = fmaf(cb[d], m, in);
      }
    }
    slopeg[(size_t)l * NSEG * HH + idx] = sl;
    interg[(size_t)l * NSEG * HH + idx] = in + basel[l * HH + hh];
  }
}

__global__ void k_bounds(const int* __restrict__ batch, int* __restrict__ gstart, int* __restrict__ gend) {
  int n = blockIdx.x * 256 + threadIdx.x;
  if (n >= NN) return;
  int b = batch[n];
  if (n == 0 || batch[n - 1] != b) gstart[b] = n;
  if (n == NN - 1 || batch[n + 1] != b) gend[b] = n + 1;
}

// parallel pool: 256 nodes/block, running sums flushed at graph boundaries
__global__ __launch_bounds__(256) void k_pool_part(const float* __restrict__ h,
    const int* __restrict__ batch, float* __restrict__ gpool) {
  int tid = threadIdx.x;
  int d = tid & 127, sub = tid >> 7;
  int n0 = blockIdx.x * 256;
  int nend = n0 + 256; if (nend > NN) nend = NN;
  float run = 0.f; int gcur = -1;
  for (int n = n0 + sub; n < nend; n += 2) {
    int g = batch[n];
    if (g != gcur) {
      if (gcur >= 0) atomicAdd(gpool + (size_t)gcur * DD + d, run);
      run = 0.f; gcur = g;
    }
    run += h[(size_t)n * DD + d];
  }
  if (gcur >= 0) atomicAdd(gpool + (size_t)gcur * DD + d, run);
}

__global__ __launch_bounds__(256) void k_head(const float* __restrict__ gpool,
    const int* __restrict__ gstart, const int* __restrict__ gend,
    const float* __restrict__ W1, const float* __restrict__ b1,
    const float* __restrict__ W2, const float* __restrict__ b2, float* __restrict__ out) {
  __shared__ float mid[NG * 64];
  int tid = threadIdx.x;
  for (int idx = tid; idx < NG * 64; idx += 256) {
    int g = idx >> 6, j = idx & 63;
    int cnt = gend[g] - gstart[g]; if (cnt < 1) cnt = 1;
    float rc = 1.0f / (float)cnt;
    float acc = 0.f;
    for (int d = 0; d < DD; d++) acc = fmaf(gpool[g * DD + d], W1[d * 64 + j], acc);
    mid[idx] = fmaxf(fmaf(acc, rc, b1[j]), 0.f);
  }
  __syncthreads();
  if (tid < NG) {
    float acc = b2[0];
    for (int j = 0; j < 64; j++) acc = fmaf(mid[tid * 64 + j], W2[j], acc);
    out[tid] = acc;
  }
}

// ---------- launch ----------
extern "C" void kernel_launch(void* const* d_in, const int* in_sizes, int n_in,
                              void* d_out, int out_size, void* d_ws, size_t ws_size,
                              hipStream_t stream) {
  const float* x      = (const float*)d_in[0];
  const int*   ei     = (const int*)d_in[1];
  const int*   batch  = (const int*)d_in[2];
  const float* node_W = (const float*)d_in[3];
  const float* node_b = (const float*)d_in[4];
  const float* cW1    = (const float*)d_in[5];
  const float* cb1    = (const float*)d_in[6];
  const float* cW2    = (const float*)d_in[7];
  const float* cb2    = (const float*)d_in[8];
  const float* qW     = (const float*)d_in[9];
  const float* qb     = (const float*)d_in[10];
  const float* kW     = (const float*)d_in[11];
  const float* kb     = (const float*)d_in[12];
  const float* vW     = (const float*)d_in[13];
  const float* vb     = (const float*)d_in[14];
  const float* oW     = (const float*)d_in[15];
  const float* ob     = (const float*)d_in[16];
  const float* bW     = (const float*)d_in[17];
  const float* bb     = (const float*)d_in[18];
  const float* f1W    = (const float*)d_in[19];
  const float* f1b    = (const float*)d_in[20];
  const float* f2W    = (const float*)d_in[21];
  const float* f2b    = (const float*)d_in[22];
  const float* n1s    = (const float*)d_in[23];
  const float* n1b    = (const float*)d_in[24];
  const float* n2s    = (const float*)d_in[25];
  const float* n2b    = (const float*)d_in[26];
  const float* outW1  = (const float*)d_in[27];
  const float* outb1  = (const float*)d_in[28];
  const float* outW2  = (const float*)d_in[29];
  const float* outb2  = (const float*)d_in[30];

  const int* src = ei;
  const int* tgt = ei + NE;

  char* wp = (char*)d_ws;
  auto alloc = [&](size_t bytes) { void* p = (void*)wp; wp += (bytes + 255) & ~(size_t)255; return p; };
  float*    h       = (float*)alloc((size_t)NN * DD * 4);
  ushort*   q       = (ushort*)alloc((size_t)NN * DD * 2);
  ushort*   kk      = (ushort*)alloc((size_t)NN * DD * 2);
  ushort*   v       = (ushort*)alloc((size_t)NN * DD * 2);
  ushort*   aggmb   = (ushort*)alloc((size_t)NN * DD * 2);
  float*    sim     = (float*)alloc((size_t)NE * 4);
  float*    dist    = (float*)alloc((size_t)NE * 4);
  float*    escore  = (float*)alloc((size_t)NE * HH * 4);
  float*    curvf   = (float*)alloc((size_t)NE * 4);
  ushort*   sege    = (ushort*)alloc((size_t)NE * 2);
  char*     zbase   = wp;                         // zeroed once per layer:
  unsigned* m_enc   = (unsigned*)alloc((size_t)NN * 4);
  float*    den     = (float*)alloc((size_t)NN * 4);
  float*    nd      = (float*)alloc((size_t)NN * 4);
  unsigned* sm_enc  = (unsigned*)alloc((size_t)NN * HH * 4);
  float*    sden    = (float*)alloc((size_t)NN * HH * 4);
  size_t    zbytes  = (size_t)(wp - zbase);
  float*    aggv    = (float*)alloc((size_t)NN * 4);
  float*    Mb      = (float*)alloc((size_t)NL * DD * HH * 4);
  float*    basel   = (float*)alloc((size_t)NL * HH * 4);
  float*    bpg     = (float*)alloc((size_t)NL * DD * 4);
  float*    slopeg  = (float*)alloc((size_t)NL * NSEG * HH * 4);
  float*    interg  = (float*)alloc((size_t)NL * NSEG * HH * 4);
  int*      rowstart= (int*)alloc((size_t)(NN + 1) * 4);
  int*      src_s   = (int*)alloc((size_t)NE * 4);
  int*      tgt_s   = (int*)alloc((size_t)NE * 4);
  int*      cnt     = (int*)alloc((size_t)NN * 4);
  int*      cur     = (int*)alloc((size_t)NN * 4);
  int*      gstart  = (int*)alloc((size_t)NG * 4);
  int*      gend    = (int*)alloc((size_t)NG * 4);
  float*    gpool   = (float*)alloc((size_t)NG * DD * 4);
  ushort*   qkvT    = (ushort*)alloc((size_t)NL * 3 * DD * DD * 2);
  ushort*   oT      = (ushort*)alloc((size_t)NL * DD * DD * 2);
  ushort*   f1T     = (ushort*)alloc((size_t)NL * DD * 512 * 2);
  ushort*   f2T     = (ushort*)alloc((size_t)NL * 512 * DD * 2);
  (void)in_sizes; (void)n_in; (void)out_size; (void)ws_size;

  // once-per-call setup
  hipMemsetAsync(cnt, 0, NN * 4, stream);
  hipMemsetAsync(cur, 0, NN * 4, stream);
  hipMemsetAsync(gstart, 0, NG * 4, stream);
  hipMemsetAsync(gend, 0, NG * 4, stream);
  hipMemsetAsync(gpool, 0, NG * DD * 4, stream);
  k_hist<<<(NE + 255) / 256, 256, 0, stream>>>(src, cnt);
  k_scan<<<1, 1024, 0, stream>>>(cnt, rowstart);
  k_fill<<<(NE + 255) / 256, 256, 0, stream>>>(src, tgt, rowstart, cur, src_s, tgt_s);
  k_mbias<<<NL, 256, 0, stream>>>(cW2, cb2, bW, bb, Mb, basel);
  k_pwl<<<NL, 256, 0, stream>>>(cW1, cb1, Mb, basel, bpg, slopeg, interg);
  k_bounds<<<(NN + 255) / 256, 256, 0, stream>>>(batch, gstart, gend);
  // bf16-transposed weights
  k_wt<DD, DD><<<(NL * DD * DD + 255) / 256, 256, 0, stream>>>(qW, qkvT,               NL, 3 * DD * DD);
  k_wt<DD, DD><<<(NL * DD * DD + 255) / 256, 256, 0, stream>>>(kW, qkvT + DD * DD,     NL, 3 * DD * DD);
  k_wt<DD, DD><<<(NL * DD * DD + 255) / 256, 256, 0, stream>>>(vW, qkvT + 2 * DD * DD, NL, 3 * DD * DD);
  k_wt<DD, DD><<<(NL * DD * DD + 255) / 256, 256, 0, stream>>>(oW, oT, NL, DD * DD);
  k_wt<DD, 512><<<(NL * DD * 512 + 255) / 256, 256, 0, stream>>>(f1W, f1T, NL, DD * 512);
  k_wt<512, DD><<<(NL * DD * 512 + 255) / 256, 256, 0, stream>>>(f2W, f2T, NL, DD * 512);
  k_node_proj<<<NN / 8, 256, 0, stream>>>(x, node_W, node_b, h);

  for (int l = 0; l < NL; l++) {
    hipMemsetAsync(zbase, 0, zbytes, stream);
    k_edge1<<<NE / 8, 256, 0, stream>>>(src_s, tgt_s, h, sim, dist, m_enc);
    k_edge2<<<(NE + 255) / 256, 256, 0, stream>>>(tgt_s, sim, dist, m_enc, den, nd);
    k_aggv<<<(NN + 255) / 256, 256, 0, stream>>>(den, nd, aggv);
    k_curv<<<(NE + 255) / 256, 256, 0, stream>>>(tgt_s, dist, aggv, bpg + l * DD, curvf, sege);
    k_ln_qkv<<<NT32, 512, 0, stream>>>(h, n1s + l * DD, n1b + l * DD,
        qkvT + (size_t)l * 3 * DD * DD,
        qb + l * DD, kb + l * DD, vb + l * DD, q, kk, v);
    k_scores<<<(NE * HH + 255) / 256, 256, 0, stream>>>(src_s, tgt_s, q, kk,
        curvf, sege, slopeg + (size_t)l * NSEG * HH, interg + (size_t)l * NSEG * HH,
        escore, sm_enc);
    k_probs<<<(NE * HH + 255) / 256, 256, 0, stream>>>(tgt_s, sm_enc, escore, sden);
    k_sdinv<<<(NN * HH + 255) / 256, 256, 0, stream>>>(sden);
    k_agg<<<NN / 4, 256, 0, stream>>>(tgt_s, rowstart, escore, sden, v, aggmb);
    k_update_o<<<NT32, 512, 0, stream>>>(aggmb, oT + (size_t)l * DD * DD, ob + l * DD, h);
    k_ffn<<<NT32, 512, 0, stream>>>(n2s + l * DD, n2b + l * DD,
        f1T + (size_t)l * DD * 512, f1b + (size_t)l * 4 * DD,
        f2T + (size_t)l * 512 * DD, f2b + l * DD, h);
  }
  k_pool_part<<<(NN + 255) / 256, 256, 0, stream>>>(h, batch, gpool);
  k_head<<<1, 256, 0, stream>>>(gpool, gstart, gend, outW1, outb1, outW2, outb2, (float*)d_out);
}

// Round 8
// 1930.268 us; speedup vs baseline: 2.2546x; 1.0578x over previous
//
#include <hip/hip_runtime.h>

#define NN 50000      // nodes
#define NE 625000     // edges
#define DD 128        // hidden dim
#define HH 8          // heads
#define DHH 16        // head dim
#define NL 4          // layers
#define FIN 64        // in channels
#define NG 64         // graphs
#define LN_EPS 1e-5f
#define NSEG 129      // PWL segments = 128 breakpoints + 1
#define NT32 1563     // ceil(NN/32)
#define NT64 782      // ceil(NN/64)
#define NBS 196       // ceil(NN/256) scan blocks

typedef __bf16 bf16x8_t __attribute__((ext_vector_type(8)));
typedef unsigned short ushort8_t __attribute__((ext_vector_type(8)));
typedef float f32x4_t __attribute__((ext_vector_type(4)));
union BF8 { ushort8_t u; bf16x8_t b; };

// ---------- helpers ----------
__device__ __forceinline__ unsigned fenc(float f) {
  unsigned u = __float_as_uint(f);
  return (u & 0x80000000u) ? ~u : (u | 0x80000000u);   // monotonic float->uint
}
__device__ __forceinline__ float fdec(unsigned u) {
  return __uint_as_float((u & 0x80000000u) ? (u & 0x7FFFFFFFu) : ~u);
}
__device__ __forceinline__ void fma4(float4& a, float s, float4 w) {
  a.x = fmaf(s, w.x, a.x); a.y = fmaf(s, w.y, a.y);
  a.z = fmaf(s, w.z, a.z); a.w = fmaf(s, w.w, a.w);
}
__device__ __forceinline__ unsigned short f2bf(float f) {   // RNE f32->bf16
  unsigned u = __float_as_uint(f);
  unsigned r = ((u >> 16) & 1u) + 0x7FFFu;
  return (unsigned short)((u + r) >> 16);
}
__device__ __forceinline__ float bf2f(unsigned short u) {
  return __uint_as_float((unsigned)u << 16);
}

// LayerNorm 32 nodes -> swizzled bf16 LDS tile [32][128]; block = 512 threads.
__device__ __forceinline__ void ln_tile_bf32(const float* __restrict__ h, int nb,
                                             const float* __restrict__ sc,
                                             const float* __restrict__ bi,
                                             ushort* xbf) {
  int tid = threadIdx.x;
  int r = tid >> 4, l16 = tid & 15;
  int nr = nb + r; if (nr >= NN) nr = NN - 1;   // clamp: tail rows unused
  const float* hp = h + (size_t)nr * DD + l16 * 8;
  float4 a0 = *(const float4*)hp;
  float4 a1 = *(const float4*)(hp + 4);
  float sum = a0.x + a0.y + a0.z + a0.w + a1.x + a1.y + a1.z + a1.w;
  float sq  = a0.x*a0.x + a0.y*a0.y + a0.z*a0.z + a0.w*a0.w
            + a1.x*a1.x + a1.y*a1.y + a1.z*a1.z + a1.w*a1.w;
#pragma unroll
  for (int off = 8; off >= 1; off >>= 1) {
    sum += __shfl_xor(sum, off, 64);
    sq  += __shfl_xor(sq,  off, 64);
  }
  float mu   = sum * (1.0f / DD);
  float var  = sq * (1.0f / DD) - mu * mu;
  float rstd = rsqrtf(var + LN_EPS);
  int d0 = l16 * 8;
  float4 s0 = *(const float4*)(sc + d0), s1 = *(const float4*)(sc + d0 + 4);
  float4 b0 = *(const float4*)(bi + d0), b1 = *(const float4*)(bi + d0 + 4);
  ushort8_t u;
  u[0] = f2bf((a0.x - mu) * rstd * s0.x + b0.x);
  u[1] = f2bf((a0.y - mu) * rstd * s0.y + b0.y);
  u[2] = f2bf((a0.z - mu) * rstd * s0.z + b0.z);
  u[3] = f2bf((a0.w - mu) * rstd * s0.w + b0.w);
  u[4] = f2bf((a1.x - mu) * rstd * s1.x + b1.x);
  u[5] = f2bf((a1.y - mu) * rstd * s1.y + b1.y);
  u[6] = f2bf((a1.z - mu) * rstd * s1.z + b1.z);
  u[7] = f2bf((a1.w - mu) * rstd * s1.w + b1.w);
  int off = (r * 256 + l16 * 16) ^ ((r & 7) << 4);
  *(ushort8_t*)((char*)xbf + off) = u;
}

// LayerNorm 64 nodes (2 passes of 32) -> swizzled bf16 LDS tile [64][128]; 512 threads.
// Same per-row arithmetic as ln_tile_bf32 -> bit-identical.
__device__ __forceinline__ void ln_tile_bf64(const float* __restrict__ h, int nb,
                                             const float* __restrict__ sc,
                                             const float* __restrict__ bi,
                                             ushort* xbf) {
  int tid = threadIdx.x;
  int l16 = tid & 15;
  int d0 = l16 * 8;
  float4 s0 = *(const float4*)(sc + d0), s1 = *(const float4*)(sc + d0 + 4);
  float4 b0 = *(const float4*)(bi + d0), b1 = *(const float4*)(bi + d0 + 4);
#pragma unroll
  for (int p = 0; p < 2; p++) {
    int r = p * 32 + (tid >> 4);
    int nr = nb + r; if (nr >= NN) nr = NN - 1;
    const float* hp = h + (size_t)nr * DD + d0;
    float4 a0 = *(const float4*)hp;
    float4 a1 = *(const float4*)(hp + 4);
    float sum = a0.x + a0.y + a0.z + a0.w + a1.x + a1.y + a1.z + a1.w;
    float sq  = a0.x*a0.x + a0.y*a0.y + a0.z*a0.z + a0.w*a0.w
              + a1.x*a1.x + a1.y*a1.y + a1.z*a1.z + a1.w*a1.w;
#pragma unroll
    for (int off = 8; off >= 1; off >>= 1) {
      sum += __shfl_xor(sum, off, 64);
      sq  += __shfl_xor(sq,  off, 64);
    }
    float mu   = sum * (1.0f / DD);
    float var  = sq * (1.0f / DD) - mu * mu;
    float rstd = rsqrtf(var + LN_EPS);
    ushort8_t u;
    u[0] = f2bf((a0.x - mu) * rstd * s0.x + b0.x);
    u[1] = f2bf((a0.y - mu) * rstd * s0.y + b0.y);
    u[2] = f2bf((a0.z - mu) * rstd * s0.z + b0.z);
    u[3] = f2bf((a0.w - mu) * rstd * s0.w + b0.w);
    u[4] = f2bf((a1.x - mu) * rstd * s1.x + b1.x);
    u[5] = f2bf((a1.y - mu) * rstd * s1.y + b1.y);
    u[6] = f2bf((a1.z - mu) * rstd * s1.z + b1.z);
    u[7] = f2bf((a1.w - mu) * rstd * s1.w + b1.w);
    int off = (r * 256 + l16 * 16) ^ ((r & 7) << 4);
    *(ushort8_t*)((char*)xbf + off) = u;
  }
}

// ---------- kernels ----------
// h = x @ node_W + node_b ; 8 nodes/block (fp32 VALU — minor cost)
__global__ __launch_bounds__(256) void k_node_proj(const float* __restrict__ x,
                                                   const float* __restrict__ W,
                                                   const float* __restrict__ b,
                                                   float* __restrict__ h) {
  __shared__ float xt[8][FIN];
  int tid = threadIdx.x;
  int nb = blockIdx.x * 8;
  {
    int idx = tid * 2;
    *(float2*)&xt[idx >> 6][idx & 63] = *(const float2*)(x + (size_t)nb * FIN + idx);
  }
  __syncthreads();
  int c4 = (tid & 31) * 4;
  int r  = tid >> 5;
  float4 acc = *(const float4*)(b + c4);
  for (int k = 0; k < FIN; k += 4) {
    float4 xk = *(const float4*)&xt[r][k];
    const float* wp = W + (size_t)k * DD + c4;
    fma4(acc, xk.x, *(const float4*)wp);
    fma4(acc, xk.y, *(const float4*)(wp + DD));
    fma4(acc, xk.z, *(const float4*)(wp + 2 * DD));
    fma4(acc, xk.w, *(const float4*)(wp + 3 * DD));
  }
  *(float4*)(h + (size_t)(nb + r) * DD + c4) = acc;
}

// per sorted edge: sim (dot), dist (norm) in fp32. 32 lanes/edge.
__global__ __launch_bounds__(256) void k_edge1(const int* __restrict__ src_s, const int* __restrict__ tgt_s,
                                               const float* __restrict__ h, float* __restrict__ sim,
                                               float* __restrict__ dist, unsigned* __restrict__ m_enc) {
  int tid = threadIdx.x;
  int wave = (blockIdx.x * 256 + tid) >> 6;
  int lane = tid & 63;
  int i = wave * 2 + (lane >> 5);
  int j = lane & 31;
  int s = src_s[i], t = tgt_s[i];
  float4 a = *(const float4*)(h + (size_t)s * DD + j * 4);
  float4 b = *(const float4*)(h + (size_t)t * DD + j * 4);
  float dot = a.x*b.x + a.y*b.y + a.z*b.z + a.w*b.w;
  float dx = a.x-b.x, dy = a.y-b.y, dz = a.z-b.z, dw = a.w-b.w;
  float sq = dx*dx + dy*dy + dz*dz + dw*dw;
#pragma unroll
  for (int off = 16; off >= 1; off >>= 1) {
    dot += __shfl_xor(dot, off, 64);
    sq  += __shfl_xor(sq,  off, 64);
  }
  if (j == 0) {
    sim[i]  = dot;                  // BETA == 1.0
    dist[i] = sqrtf(sq);
    atomicMax(m_enc + t, fenc(dot));
  }
}

// denom & alpha*dist numerator per tgt
__global__ void k_edge2(const int* __restrict__ tgt_s, const float* __restrict__ sim,
                        const float* __restrict__ dist, const unsigned* __restrict__ m_enc,
                        float* __restrict__ den, float* __restrict__ nd) {
  int i = blockIdx.x * 256 + threadIdx.x;
  if (i >= NE) return;
  int t = tgt_s[i];
  float ev = expf(sim[i] - fdec(m_enc[t]));
  atomicAdd(den + t, ev);
  atomicAdd(nd + t, ev * dist[i]);
}

__global__ void k_aggv(const float* __restrict__ den, const float* __restrict__ nd,
                       float* __restrict__ aggv) {
  int n = blockIdx.x * 256 + threadIdx.x;
  if (n >= NN) return;
  float d = den[n];
  aggv[n] = d > 0.f ? nd[n] / d : 0.f;
}

// per edge: curvature + PWL segment index (binary search over 128 sorted breakpoints)
__global__ __launch_bounds__(256) void k_curv(const int* __restrict__ tgt_s,
    const float* __restrict__ dist, const float* __restrict__ aggv,
    const float* __restrict__ bp_l, float* __restrict__ curvf, ushort* __restrict__ sege) {
  __shared__ float bp[DD];
  int tid = threadIdx.x;
  if (tid < DD) bp[tid] = bp_l[tid];
  __syncthreads();
  int i = blockIdx.x * 256 + tid;
  if (i >= NE) return;
  int t = tgt_s[i];
  float curv = 1.0f - aggv[t] / fmaxf(dist[i], 1e-6f);
  int lo = 0, hi = DD;
  while (lo < hi) { int mid = (lo + hi) >> 1; if (bp[mid] < curv) lo = mid + 1; else hi = mid; }
  curvf[i] = curv;
  sege[i] = (ushort)lo;     // segment in [0,128]
}

// LN1 + QKV projection via swapped-operand MFMA -> bf16 q/k/v. 32 rows/block, 8 waves.
__global__ __launch_bounds__(512) void k_ln_qkv(const float* __restrict__ h,
    const float* __restrict__ n1s_l, const float* __restrict__ n1b_l,
    const ushort* __restrict__ qkvT_l,
    const float* __restrict__ qb_l, const float* __restrict__ kb_l, const float* __restrict__ vb_l,
    ushort* __restrict__ q, ushort* __restrict__ kk, ushort* __restrict__ v) {
  __shared__ __align__(16) ushort xbf[32 * DD];
  int nb = blockIdx.x * 32;
  ln_tile_bf32(h, nb, n1s_l, n1b_l, xbf);
  __syncthreads();
  int lane = threadIdx.x & 63;
  int w = threadIdx.x >> 6;
  int g = lane >> 4, c = lane & 15;
  int xr = (c & 7) << 4;
  char* xb = (char*)xbf;
  BF8 a[2][4];
#pragma unroll
  for (int nt = 0; nt < 2; nt++)
#pragma unroll
    for (int kt = 0; kt < 4; kt++)
      a[nt][kt].u = *(ushort8_t*)(xb + (((nt * 16 + c) * 256 + kt * 64 + g * 16) ^ xr));
#pragma unroll
  for (int ti = 0; ti < 3; ti++) {
    int t = w * 3 + ti;                // 0..23
    int m = t >> 3;                    // 0=q 1=k 2=v
    int colb = (t & 7) * 16;
    const float* bias = (m == 0 ? qb_l : (m == 1 ? kb_l : vb_l));
    float4 bv = *(const float4*)(bias + colb + g * 4);
    f32x4_t acc0 = {bv.x, bv.y, bv.z, bv.w};
    f32x4_t acc1 = acc0;
    const ushort* wp = qkvT_l + (size_t)(m * DD + colb + c) * DD + g * 8;
#pragma unroll
    for (int kt = 0; kt < 4; kt++) {
      BF8 b; b.u = *(const ushort8_t*)(wp + kt * 32);
      acc0 = __builtin_amdgcn_mfma_f32_16x16x32_bf16(b.b, a[0][kt].b, acc0, 0, 0, 0);
      acc1 = __builtin_amdgcn_mfma_f32_16x16x32_bf16(b.b, a[1][kt].b, acc1, 0, 0, 0);
    }
    ushort* out = (m == 0 ? q : (m == 1 ? kk : v));
    int n0 = nb + c;
    if (n0 < NN) {
      ushort4 o; o.x = f2bf(acc0[0]); o.y = f2bf(acc0[1]); o.z = f2bf(acc0[2]); o.w = f2bf(acc0[3]);
      *(ushort4*)(out + (size_t)n0 * DD + colb + g * 4) = o;
    }
    int n1 = nb + 16 + c;
    if (n1 < NN) {
      ushort4 o; o.x = f2bf(acc1[0]); o.y = f2bf(acc1[1]); o.z = f2bf(acc1[2]); o.w = f2bf(acc1[3]);
      *(ushort4*)(out + (size_t)n1 * DD + colb + g * 4) = o;
    }
  }
}

// per (edge, head): qk dot (bf16) + PWL bias; atomicMax over tgt.
// NOTE: the max pass is MANDATORY — curv is unbounded (self-loop edges have
// dist==0 -> curv ~ -1e6 -> |bias| ~ 1e4), exp() overflows without it (r5/r6).
__global__ __launch_bounds__(256) void k_scores(const int* __restrict__ src_s, const int* __restrict__ tgt_s,
    const ushort* __restrict__ q, const ushort* __restrict__ k,
    const float* __restrict__ curvf, const ushort* __restrict__ sege,
    const float* __restrict__ slope_l, const float* __restrict__ inter_l,
    float* __restrict__ escore, unsigned* __restrict__ sm_enc) {
  __shared__ float lsl[NSEG * HH], lin[NSEG * HH];
  int tid = threadIdx.x;
  for (int idx = tid; idx < NSEG * HH; idx += 256) { lsl[idx] = slope_l[idx]; lin[idx] = inter_l[idx]; }
  __syncthreads();
  int gi = blockIdx.x * 256 + tid;
  if (gi >= NE * HH) return;
  int i = gi >> 3, hh = gi & 7;
  int s = src_s[i], t = tgt_s[i];
  int seg = sege[i];
  float bias = fmaf(lsl[seg * HH + hh], curvf[i], lin[seg * HH + hh]);
  const ushort8_t* qp = (const ushort8_t*)(q + (size_t)s * DD + hh * DHH);
  const ushort8_t* kp = (const ushort8_t*)(k + (size_t)t * DD + hh * DHH);
  float dot = 0.f;
#pragma unroll
  for (int ii = 0; ii < 2; ii++) {
    ushort8_t a = qp[ii], b = kp[ii];
#pragma unroll
    for (int jj = 0; jj < 8; jj++) dot = fmaf(bf2f(a[jj]), bf2f(b[jj]), dot);
  }
  float sc = dot * 0.25f + bias;   // 1/sqrt(16)
  escore[gi] = sc;
  atomicMax(sm_enc + (size_t)t * HH + hh, fenc(sc));
}

__global__ void k_probs(const int* __restrict__ tgt_s, const unsigned* __restrict__ sm_enc,
                        float* __restrict__ escore, float* __restrict__ sden) {
  int gi = blockIdx.x * 256 + threadIdx.x;
  if (gi >= NE * HH) return;
  int i = gi >> 3, hh = gi & 7;
  int t = tgt_s[i];
  float p = expf(escore[gi] - fdec(sm_enc[(size_t)t * HH + hh]));
  escore[gi] = p;
  atomicAdd(sden + (size_t)t * HH + hh, p);
}

__global__ void k_sdinv(float* __restrict__ sden) {
  int i = blockIdx.x * 256 + threadIdx.x;
  if (i >= NN * HH) return;
  float x = sden[i];
  sden[i] = x > 0.f ? 1.0f / x : 0.f;
}

// CSR-gather message aggregation: one wave per src node, 2 dims/lane -> bf16 out
__global__ __launch_bounds__(256) void k_agg(const int* __restrict__ tgt_s,
    const int* __restrict__ rowstart,
    const float* __restrict__ escore, const float* __restrict__ sdinv,
    const ushort* __restrict__ v, ushort* __restrict__ aggmb) {
  int wave = (blockIdx.x * 256 + threadIdx.x) >> 6;
  int lane = threadIdx.x & 63;
  int rs = rowstart[wave], re = rowstart[wave + 1];
  int hh = lane >> 3;
  int d = lane * 2;
  float a0 = 0.f, a1 = 0.f;
  for (int i = rs; i < re; i++) {
    int t = tgt_s[i];
    float prob = escore[i * HH + hh] * sdinv[t * HH + hh];
    ushort2 vv = *(const ushort2*)(v + (size_t)t * DD + d);
    a0 = fmaf(prob, bf2f(vv.x), a0);
    a1 = fmaf(prob, bf2f(vv.y), a1);
  }
  ushort2 o; o.x = f2bf(a0); o.y = f2bf(a1);
  *(ushort2*)(aggmb + (size_t)wave * DD + d) = o;
}

// h += aggm @ oW + ob via swapped-operand MFMA; 32 rows/block, 8 waves, float4 RMW.
__global__ __launch_bounds__(512) void k_update_o(const ushort* __restrict__ aggmb,
    const ushort* __restrict__ oT_l, const float* __restrict__ ob_l, float* __restrict__ h) {
  int nb = blockIdx.x * 32;
  int lane = threadIdx.x & 63, w = threadIdx.x >> 6;
  int g = lane >> 4, c = lane & 15;
  BF8 a[2][4];
#pragma unroll
  for (int nt = 0; nt < 2; nt++) {
    int na = nb + nt * 16 + c; if (na >= NN) na = NN - 1;
    const ushort* ap = aggmb + (size_t)na * DD + g * 8;
#pragma unroll
    for (int kt = 0; kt < 4; kt++) a[nt][kt].u = *(const ushort8_t*)(ap + kt * 32);
  }
  int colb = w * 16;
  float4 bv = *(const float4*)(ob_l + colb + g * 4);
  f32x4_t acc0 = {bv.x, bv.y, bv.z, bv.w};
  f32x4_t acc1 = acc0;
  const ushort* wp = oT_l + (size_t)(colb + c) * DD + g * 8;
#pragma unroll
  for (int kt = 0; kt < 4; kt++) {
    BF8 b; b.u = *(const ushort8_t*)(wp + kt * 32);
    acc0 = __builtin_amdgcn_mfma_f32_16x16x32_bf16(b.b, a[0][kt].b, acc0, 0, 0, 0);
    acc1 = __builtin_amdgcn_mfma_f32_16x16x32_bf16(b.b, a[1][kt].b, acc1, 0, 0, 0);
  }
#pragma unroll
  for (int nt = 0; nt < 2; nt++) {
    int node = nb + nt * 16 + c;
    if (node < NN) {
      float* hp = h + (size_t)node * DD + colb + g * 4;
      float4 hv = *(const float4*)hp;
      f32x4_t& acc = nt ? acc1 : acc0;
      hv.x += acc[0]; hv.y += acc[1]; hv.z += acc[2]; hv.w += acc[3];
      *(float4*)hp = hv;
    }
  }
}

// fused FFN, BM=64: h += relu(LN2(h)@f1W+f1b)@f2W+f2b; 64 rows/block, 8 waves.
// GEMM1 runs in two 256-col chunks through a 32KB LDS tile; per-output-element
// MFMA k-order is unchanged vs BM=32 -> bit-identical. Weight traffic halved.
__global__ __launch_bounds__(512) void k_ffn(const float* __restrict__ n2s_l, const float* __restrict__ n2b_l,
    const ushort* __restrict__ f1T_l, const float* __restrict__ f1b_l,
    const ushort* __restrict__ f2T_l, const float* __restrict__ f2b_l,
    float* __restrict__ h) {
  __shared__ __align__(16) ushort xbf[64 * DD];      // 16 KB
  __shared__ __align__(16) ushort tbf[64 * 256];     // 32 KB
  int nb = blockIdx.x * 64;
  ln_tile_bf64(h, nb, n2s_l, n2b_l, xbf);
  __syncthreads();
  int lane = threadIdx.x & 63, w = threadIdx.x >> 6;
  int g = lane >> 4, c = lane & 15;
  int xr = (c & 7) << 4;
  char* xb = (char*)xbf;
  char* tb = (char*)tbf;
  BF8 a[4][4];
#pragma unroll
  for (int nt = 0; nt < 4; nt++)
#pragma unroll
    for (int kt = 0; kt < 4; kt++)
      a[nt][kt].u = *(ushort8_t*)(xb + (((nt * 16 + c) * 256 + kt * 64 + g * 16) ^ xr));
  int colb2 = w * 16;
  float4 bv2 = *(const float4*)(f2b_l + colb2 + g * 4);
  f32x4_t o0 = {bv2.x, bv2.y, bv2.z, bv2.w};
  f32x4_t o1 = o0, o2 = o0, o3 = o0;
#pragma unroll
  for (int ch = 0; ch < 2; ch++) {
    if (ch) __syncthreads();           // tbf reuse: wait for chunk-0 reads
    // GEMM1 chunk: cols ch*256 .. ch*256+255; wave w owns col-tiles w*2, w*2+1
#pragma unroll
    for (int ti = 0; ti < 2; ti++) {
      int ctile = w * 2 + ti;          // 0..15 within chunk
      int col = ch * 256 + ctile * 16;
      float4 bv = *(const float4*)(f1b_l + col + g * 4);
      f32x4_t ac0 = {bv.x, bv.y, bv.z, bv.w};
      f32x4_t ac1 = ac0, ac2 = ac0, ac3 = ac0;
      const ushort* wp = f1T_l + (size_t)(col + c) * DD + g * 8;
#pragma unroll
      for (int kt = 0; kt < 4; kt++) {
        BF8 b; b.u = *(const ushort8_t*)(wp + kt * 32);
        ac0 = __builtin_amdgcn_mfma_f32_16x16x32_bf16(b.b, a[0][kt].b, ac0, 0, 0, 0);
        ac1 = __builtin_amdgcn_mfma_f32_16x16x32_bf16(b.b, a[1][kt].b, ac1, 0, 0, 0);
        ac2 = __builtin_amdgcn_mfma_f32_16x16x32_bf16(b.b, a[2][kt].b, ac2, 0, 0, 0);
        ac3 = __builtin_amdgcn_mfma_f32_16x16x32_bf16(b.b, a[3][kt].b, ac3, 0, 0, 0);
      }
      int colL = (ctile * 16 + g * 4) * 2;     // byte col within chunk tile
      {
        int row = c;
        ushort4 o4; o4.x = f2bf(fmaxf(ac0[0], 0.f)); o4.y = f2bf(fmaxf(ac0[1], 0.f));
        o4.z = f2bf(fmaxf(ac0[2], 0.f)); o4.w = f2bf(fmaxf(ac0[3], 0.f));
        *(ushort4*)(tb + ((row * 512 + colL) ^ ((row & 7) << 4))) = o4;
      }
      {
        int row = 16 + c;
        ushort4 o4; o4.x = f2bf(fmaxf(ac1[0], 0.f)); o4.y = f2bf(fmaxf(ac1[1], 0.f));
        o4.z = f2bf(fmaxf(ac1[2], 0.f)); o4.w = f2bf(fmaxf(ac1[3], 0.f));
        *(ushort4*)(tb + ((row * 512 + colL) ^ ((row & 7) << 4))) = o4;
      }
      {
        int row = 32 + c;
        ushort4 o4; o4.x = f2bf(fmaxf(ac2[0], 0.f)); o4.y = f2bf(fmaxf(ac2[1], 0.f));
        o4.z = f2bf(fmaxf(ac2[2], 0.f)); o4.w = f2bf(fmaxf(ac2[3], 0.f));
        *(ushort4*)(tb + ((row * 512 + colL) ^ ((row & 7) << 4))) = o4;
      }
      {
        int row = 48 + c;
        ushort4 o4; o4.x = f2bf(fmaxf(ac3[0], 0.f)); o4.y = f2bf(fmaxf(ac3[1], 0.f));
        o4.z = f2bf(fmaxf(ac3[2], 0.f)); o4.w = f2bf(fmaxf(ac3[3], 0.f));
        *(ushort4*)(tb + ((row * 512 + colL) ^ ((row & 7) << 4))) = o4;
      }
    }
    __syncthreads();
    // GEMM2 partial: this chunk's 256 k-values (k ascending -> bit-identical)
    const ushort* wp2 = f2T_l + (size_t)(colb2 + c) * 512 + ch * 256 + g * 8;
#pragma unroll
    for (int kt = 0; kt < 8; kt++) {
      BF8 b; b.u = *(const ushort8_t*)(wp2 + kt * 32);
      BF8 t0; t0.u = *(ushort8_t*)(tb + (((c) * 512 + kt * 64 + g * 16) ^ xr));
      BF8 t1; t1.u = *(ushort8_t*)(tb + (((16 + c) * 512 + kt * 64 + g * 16) ^ xr));
      BF8 t2; t2.u = *(ushort8_t*)(tb + (((32 + c) * 512 + kt * 64 + g * 16) ^ xr));
      BF8 t3; t3.u = *(ushort8_t*)(tb + (((48 + c) * 512 + kt * 64 + g * 16) ^ xr));
      o0 = __builtin_amdgcn_mfma_f32_16x16x32_bf16(b.b, t0.b, o0, 0, 0, 0);
      o1 = __builtin_amdgcn_mfma_f32_16x16x32_bf16(b.b, t1.b, o1, 0, 0, 0);
      o2 = __builtin_amdgcn_mfma_f32_16x16x32_bf16(b.b, t2.b, o2, 0, 0, 0);
      o3 = __builtin_amdgcn_mfma_f32_16x16x32_bf16(b.b, t3.b, o3, 0, 0, 0);
    }
  }
  {
    int node = nb + c;
    if (node < NN) {
      float* hp = h + (size_t)node * DD + colb2 + g * 4;
      float4 hv = *(const float4*)hp;
      hv.x += o0[0]; hv.y += o0[1]; hv.z += o0[2]; hv.w += o0[3];
      *(float4*)hp = hv;
    }
  }
  {
    int node = nb + 16 + c;
    if (node < NN) {
      float* hp = h + (size_t)node * DD + colb2 + g * 4;
      float4 hv = *(const float4*)hp;
      hv.x += o1[0]; hv.y += o1[1]; hv.z += o1[2]; hv.w += o1[3];
      *(float4*)hp = hv;
    }
  }
  {
    int node = nb + 32 + c;
    if (node < NN) {
      float* hp = h + (size_t)node * DD + colb2 + g * 4;
      float4 hv = *(const float4*)hp;
      hv.x += o2[0]; hv.y += o2[1]; hv.z += o2[2]; hv.w += o2[3];
      *(float4*)hp = hv;
    }
  }
  {
    int node = nb + 48 + c;
    if (node < NN) {
      float* hp = h + (size_t)node * DD + colb2 + g * 4;
      float4 hv = *(const float4*)hp;
      hv.x += o3[0]; hv.y += o3[1]; hv.z += o3[2]; hv.w += o3[3];
      *(float4*)hp = hv;
    }
  }
}

// ---------- once-per-call setup kernels ----------
// transpose fp32 [K][C] -> bf16 [C][K], nm stacked matrices, dst stride per matrix
template <int K, int C>
__global__ void k_wt(const float* __restrict__ W, ushort* __restrict__ WT, int nm, int dstride) {
  int idx = blockIdx.x * 256 + threadIdx.x;
  if (idx >= K * C * nm) return;
  int mi = idx / (K * C), rem = idx - mi * (K * C);
  int cc = rem / K, kk2 = rem - cc * K;
  WT[(size_t)mi * dstride + cc * K + kk2] = f2bf(W[(size_t)mi * K * C + (size_t)kk2 * C + cc]);
}

__global__ void k_hist(const int* __restrict__ src, int* __restrict__ cnt) {
  int e = blockIdx.x * 256 + threadIdx.x;
  if (e < NE) atomicAdd(cnt + src[e], 1);
}

// multi-block exclusive scan of cnt[NN] -> rowstart (3 kernels; round-7 k_scan
// was a single 1024-thread block at 93us, pure latency)
__global__ __launch_bounds__(256) void k_scan_blk(const int* __restrict__ cnt, int* __restrict__ bsum) {
  __shared__ int red[256];
  int tid = threadIdx.x;
  int idx = blockIdx.x * 256 + tid;
  red[tid] = (idx < NN) ? cnt[idx] : 0;
  __syncthreads();
  for (int off = 128; off >= 1; off >>= 1) {
    if (tid < off) red[tid] += red[tid + off];
    __syncthreads();
  }
  if (tid == 0) bsum[blockIdx.x] = red[0];
}

__global__ __launch_bounds__(256) void k_scan_top(const int* __restrict__ bsum,
                                                  int* __restrict__ boff, int* __restrict__ rowstart) {
  __shared__ int ps[256];
  int t = threadIdx.x;
  int v = (t < NBS) ? bsum[t] : 0;
  ps[t] = v;
  __syncthreads();
  for (int off = 1; off < 256; off <<= 1) {
    int x = (t >= off) ? ps[t - off] : 0;
    __syncthreads();
    ps[t] += x;
    __syncthreads();
  }
  boff[t] = ps[t] - v;                 // exclusive prefix of block sums
  if (t == 255) rowstart[NN] = ps[255];
}

__global__ __launch_bounds__(256) void k_scan_fin(const int* __restrict__ cnt,
                                                  const int* __restrict__ boff, int* __restrict__ rowstart) {
  __shared__ int ps[256];
  int t = threadIdx.x;
  int idx = blockIdx.x * 256 + t;
  int v = (idx < NN) ? cnt[idx] : 0;
  ps[t] = v;
  __syncthreads();
  for (int off = 1; off < 256; off <<= 1) {
    int x = (t >= off) ? ps[t - off] : 0;
    __syncthreads();
    ps[t] += x;
    __syncthreads();
  }
  if (idx < NN) rowstart[idx] = boff[blockIdx.x] + ps[t] - v;
}

// scatter edges into src-sorted order (all per-edge arrays use sorted index)
__global__ void k_fill(const int* __restrict__ src, const int* __restrict__ tgt,
                       const int* __restrict__ rowstart,
                       int* __restrict__ cur, int* __restrict__ src_s, int* __restrict__ tgt_s) {
  int e = blockIdx.x * 256 + threadIdx.x;
  if (e >= NE) return;
  int s = src[e];
  int p = atomicAdd(cur + s, 1);
  int pos = rowstart[s] + p;
  src_s[pos] = s;
  tgt_s[pos] = tgt[e];
}

// M_l = cW2 @ bW_l  [128,8];  base_l = cb2 @ bW_l + bb_l  [8]  (bW cached in LDS)
__global__ void k_mbias(const float* __restrict__ cW2, const float* __restrict__ cb2,
                        const float* __restrict__ bW, const float* __restrict__ bb,
                        float* __restrict__ M, float* __restrict__ base) {
  int l = blockIdx.x;
  int tid = threadIdx.x;
  __shared__ float lbW[DD * HH];
  const float* bWl = bW + (size_t)l * DD * HH;
  for (int i = tid; i < DD * HH; i += 256) lbW[i] = bWl[i];
  __syncthreads();
  for (int idx = tid; idx < DD * HH; idx += 256) {
    int d = idx >> 3, hh = idx & 7;
    float acc = 0.f;
    for (int j = 0; j < DD; j++) acc = fmaf(cW2[d * DD + j], lbW[j * HH + hh], acc);
    M[(size_t)l * DD * HH + idx] = acc;
  }
  if (tid < HH) {
    float acc = bb[l * HH + tid];
    for (int j = 0; j < DD; j++) acc = fmaf(cb2[j], lbW[j * HH + tid], acc);
    base[l * HH + tid] = acc;
  }
}

// PWL table. Round-4 branch structure preserved EXACTLY (bit-exact); M in LDS.
__global__ __launch_bounds__(256) void k_pwl(const float* __restrict__ cW1, const float* __restrict__ cb1,
    const float* __restrict__ Mb, const float* __restrict__ basel,
    float* __restrict__ bpg, float* __restrict__ slopeg, float* __restrict__ interg) {
  int l = blockIdx.x;
  __shared__ float c1[DD], cb[DD], x[DD], bp[DD], lM[DD * HH];
  __shared__ int pos[DD];
  int tid = threadIdx.x;
  if (tid < DD) { c1[tid] = cW1[tid]; cb[tid] = cb1[tid]; }
  for (int i = tid; i < DD * HH; i += 256) lM[i] = Mb[(size_t)l * DD * HH + i];
  __syncthreads();
  if (tid < DD)
    x[tid] = (c1[tid] == 0.f) ? __builtin_inff() : (-cb[tid] / c1[tid]);
  __syncthreads();
  if (tid < DD) {
    float xv = x[tid]; int p = 0;
    for (int j = 0; j < DD; j++) {
      float xj = x[j];
      if (xj < xv || (xj == xv && j < tid)) p++;
    }
    pos[tid] = p;
    bp[p] = xv;
  }
  __syncthreads();
  if (tid < DD) bpg[l * DD + tid] = bp[tid];
  for (int idx = tid; idx < NSEG * HH; idx += 256) {
    int s = idx >> 3, hh = idx & 7;
    float sl = 0.f, in = 0.f;
    for (int d = 0; d < DD; d++) {
      bool act;
      if (c1[d] == 0.f)      act = (cb[d] > 0.f);
      else if (c1[d] > 0.f)  act = (pos[d] < s);
      else                   act = (pos[d] >= s);
      if (act) {
        float m = lM[d * HH + hh];
        sl = fmaf(c1[d], m, sl);
        in = fmaf(cb[d], m, in);
      }
    }
    slopeg[(size_t)l * NSEG * HH + idx] = sl;
    interg[(size_t)l * NSEG * HH + idx] = in + basel[l * HH + hh];
  }
}

__global__ void k_bounds(const int* __restrict__ batch, int* __restrict__ gstart, int* __restrict__ gend) {
  int n = blockIdx.x * 256 + threadIdx.x;
  if (n >= NN) return;
  int b = batch[n];
  if (n == 0 || batch[n - 1] != b) gstart[b] = n;
  if (n == NN - 1 || batch[n + 1] != b) gend[b] = n + 1;
}

// parallel pool: 256 nodes/block, running sums flushed at graph boundaries
__global__ __launch_bounds__(256) void k_pool_part(const float* __restrict__ h,
    const int* __restrict__ batch, float* __restrict__ gpool) {
  int tid = threadIdx.x;
  int d = tid & 127, sub = tid >> 7;
  int n0 = blockIdx.x * 256;
  int nend = n0 + 256; if (nend > NN) nend = NN;
  float run = 0.f; int gcur = -1;
  for (int n = n0 + sub; n < nend; n += 2) {
    int g = batch[n];
    if (g != gcur) {
      if (gcur >= 0) atomicAdd(gpool + (size_t)gcur * DD + d, run);
      run = 0.f; gcur = g;
    }
    run += h[(size_t)n * DD + d];
  }
  if (gcur >= 0) atomicAdd(gpool + (size_t)gcur * DD + d, run);
}

__global__ __launch_bounds__(256) void k_head(const float* __restrict__ gpool,
    const int* __restrict__ gstart, const int* __restrict__ gend,
    const float* __restrict__ W1, const float* __restrict__ b1,
    const float* __restrict__ W2, const float* __restrict__ b2, float* __restrict__ out) {
  __shared__ float mid[NG * 64];
  int tid = threadIdx.x;
  for (int idx = tid; idx < NG * 64; idx += 256) {
    int g = idx >> 6, j = idx & 63;
    int cnt = gend[g] - gstart[g]; if (cnt < 1) cnt = 1;
    float rc = 1.0f / (float)cnt;
    float acc = 0.f;
    for (int d = 0; d < DD; d++) acc = fmaf(gpool[g * DD + d], W1[d * 64 + j], acc);
    mid[idx] = fmaxf(fmaf(acc, rc, b1[j]), 0.f);
  }
  __syncthreads();
  if (tid < NG) {
    float acc = b2[0];
    for (int j = 0; j < 64; j++) acc = fmaf(mid[tid * 64 + j], W2[j], acc);
    out[tid] = acc;
  }
}

// ---------- launch ----------
extern "C" void kernel_launch(void* const* d_in, const int* in_sizes, int n_in,
                              void* d_out, int out_size, void* d_ws, size_t ws_size,
                              hipStream_t stream) {
  const float* x      = (const float*)d_in[0];
  const int*   ei     = (const int*)d_in[1];
  const int*   batch  = (const int*)d_in[2];
  const float* node_W = (const float*)d_in[3];
  const float* node_b = (const float*)d_in[4];
  const float* cW1    = (const float*)d_in[5];
  const float* cb1    = (const float*)d_in[6];
  const float* cW2    = (const float*)d_in[7];
  const float* cb2    = (const float*)d_in[8];
  const float* qW     = (const float*)d_in[9];
  const float* qb     = (const float*)d_in[10];
  const float* kW     = (const float*)d_in[11];
  const float* kb     = (const float*)d_in[12];
  const float* vW     = (const float*)d_in[13];
  const float* vb     = (const float*)d_in[14];
  const float* oW     = (const float*)d_in[15];
  const float* ob     = (const float*)d_in[16];
  const float* bW     = (const float*)d_in[17];
  const float* bb     = (const float*)d_in[18];
  const float* f1W    = (const float*)d_in[19];
  const float* f1b    = (const float*)d_in[20];
  const float* f2W    = (const float*)d_in[21];
  const float* f2b    = (const float*)d_in[22];
  const float* n1s    = (const float*)d_in[23];
  const float* n1b    = (const float*)d_in[24];
  const float* n2s    = (const float*)d_in[25];
  const float* n2b    = (const float*)d_in[26];
  const float* outW1  = (const float*)d_in[27];
  const float* outb1  = (const float*)d_in[28];
  const float* outW2  = (const float*)d_in[29];
  const float* outb2  = (const float*)d_in[30];

  const int* src = ei;
  const int* tgt = ei + NE;

  char* wp = (char*)d_ws;
  auto alloc = [&](size_t bytes) { void* p = (void*)wp; wp += (bytes + 255) & ~(size_t)255; return p; };
  float*    h       = (float*)alloc((size_t)NN * DD * 4);
  ushort*   q       = (ushort*)alloc((size_t)NN * DD * 2);
  ushort*   kk      = (ushort*)alloc((size_t)NN * DD * 2);
  ushort*   v       = (ushort*)alloc((size_t)NN * DD * 2);
  ushort*   aggmb   = (ushort*)alloc((size_t)NN * DD * 2);
  float*    sim     = (float*)alloc((size_t)NE * 4);
  float*    dist    = (float*)alloc((size_t)NE * 4);
  float*    escore  = (float*)alloc((size_t)NE * HH * 4);
  float*    curvf   = (float*)alloc((size_t)NE * 4);
  ushort*   sege    = (ushort*)alloc((size_t)NE * 2);
  char*     zbase   = wp;                         // zeroed once per layer:
  unsigned* m_enc   = (unsigned*)alloc((size_t)NN * 4);
  float*    den     = (float*)alloc((size_t)NN * 4);
  float*    nd      = (float*)alloc((size_t)NN * 4);
  unsigned* sm_enc  = (unsigned*)alloc((size_t)NN * HH * 4);
  float*    sden    = (float*)alloc((size_t)NN * HH * 4);
  size_t    zbytes  = (size_t)(wp - zbase);
  float*    aggv    = (float*)alloc((size_t)NN * 4);
  float*    Mb      = (float*)alloc((size_t)NL * DD * HH * 4);
  float*    basel   = (float*)alloc((size_t)NL * HH * 4);
  float*    bpg     = (float*)alloc((size_t)NL * DD * 4);
  float*    slopeg  = (float*)alloc((size_t)NL * NSEG * HH * 4);
  float*    interg  = (float*)alloc((size_t)NL * NSEG * HH * 4);
  int*      rowstart= (int*)alloc((size_t)(NN + 1) * 4);
  int*      src_s   = (int*)alloc((size_t)NE * 4);
  int*      tgt_s   = (int*)alloc((size_t)NE * 4);
  int*      cnt     = (int*)alloc((size_t)NN * 4);
  int*      cur     = (int*)alloc((size_t)NN * 4);
  int*      bsum    = (int*)alloc((size_t)NBS * 4);
  int*      boff    = (int*)alloc((size_t)256 * 4);
  int*      gstart  = (int*)alloc((size_t)NG * 4);
  int*      gend    = (int*)alloc((size_t)NG * 4);
  float*    gpool   = (float*)alloc((size_t)NG * DD * 4);
  ushort*   qkvT    = (ushort*)alloc((size_t)NL * 3 * DD * DD * 2);
  ushort*   oT      = (ushort*)alloc((size_t)NL * DD * DD * 2);
  ushort*   f1T     = (ushort*)alloc((size_t)NL * DD * 512 * 2);
  ushort*   f2T     = (ushort*)alloc((size_t)NL * 512 * DD * 2);
  (void)in_sizes; (void)n_in; (void)out_size; (void)ws_size;

  // once-per-call setup
  hipMemsetAsync(cnt, 0, NN * 4, stream);
  hipMemsetAsync(cur, 0, NN * 4, stream);
  hipMemsetAsync(gstart, 0, NG * 4, stream);
  hipMemsetAsync(gend, 0, NG * 4, stream);
  hipMemsetAsync(gpool, 0, NG * DD * 4, stream);
  k_hist<<<(NE + 255) / 256, 256, 0, stream>>>(src, cnt);
  k_scan_blk<<<NBS, 256, 0, stream>>>(cnt, bsum);
  k_scan_top<<<1, 256, 0, stream>>>(bsum, boff, rowstart);
  k_scan_fin<<<NBS, 256, 0, stream>>>(cnt, boff, rowstart);
  k_fill<<<(NE + 255) / 256, 256, 0, stream>>>(src, tgt, rowstart, cur, src_s, tgt_s);
  k_mbias<<<NL, 256, 0, stream>>>(cW2, cb2, bW, bb, Mb, basel);
  k_pwl<<<NL, 256, 0, stream>>>(cW1, cb1, Mb, basel, bpg, slopeg, interg);
  k_bounds<<<(NN + 255) / 256, 256, 0, stream>>>(batch, gstart, gend);
  // bf16-transposed weights
  k_wt<DD, DD><<<(NL * DD * DD + 255) / 256, 256, 0, stream>>>(qW, qkvT,               NL, 3 * DD * DD);
  k_wt<DD, DD><<<(NL * DD * DD + 255) / 256, 256, 0, stream>>>(kW, qkvT + DD * DD,     NL, 3 * DD * DD);
  k_wt<DD, DD><<<(NL * DD * DD + 255) / 256, 256, 0, stream>>>(vW, qkvT + 2 * DD * DD, NL, 3 * DD * DD);
  k_wt<DD, DD><<<(NL * DD * DD + 255) / 256, 256, 0, stream>>>(oW, oT, NL, DD * DD);
  k_wt<DD, 512><<<(NL * DD * 512 + 255) / 256, 256, 0, stream>>>(f1W, f1T, NL, DD * 512);
  k_wt<512, DD><<<(NL * DD * 512 + 255) / 256, 256, 0, stream>>>(f2W, f2T, NL, DD * 512);
  k_node_proj<<<NN / 8, 256, 0, stream>>>(x, node_W, node_b, h);

  for (int l = 0; l < NL; l++) {
    hipMemsetAsync(zbase, 0, zbytes, stream);
    k_edge1<<<NE / 8, 256, 0, stream>>>(src_s, tgt_s, h, sim, dist, m_enc);
    k_edge2<<<(NE + 255) / 256, 256, 0, stream>>>(tgt_s, sim, dist, m_enc, den, nd);
    k_aggv<<<(NN + 255) / 256, 256, 0, stream>>>(den, nd, aggv);
    k_curv<<<(NE + 255) / 256, 256, 0, stream>>>(tgt_s, dist, aggv, bpg + l * DD, curvf, sege);
    k_ln_qkv<<<NT32, 512, 0, stream>>>(h, n1s + l * DD, n1b + l * DD,
        qkvT + (size_t)l * 3 * DD * DD,
        qb + l * DD, kb + l * DD, vb + l * DD, q, kk, v);
    k_scores<<<(NE * HH + 255) / 256, 256, 0, stream>>>(src_s, tgt_s, q, kk,
        curvf, sege, slopeg + (size_t)l * NSEG * HH, interg + (size_t)l * NSEG * HH,
        escore, sm_enc);
    k_probs<<<(NE * HH + 255) / 256, 256, 0, stream>>>(tgt_s, sm_enc, escore, sden);
    k_sdinv<<<(NN * HH + 255) / 256, 256, 0, stream>>>(sden);
    k_agg<<<NN / 4, 256, 0, stream>>>(tgt_s, rowstart, escore, sden, v, aggmb);
    k_update_o<<<NT32, 512, 0, stream>>>(aggmb, oT + (size_t)l * DD * DD, ob + l * DD, h);
    k_ffn<<<NT64, 512, 0, stream>>>(n2s + l * DD, n2b + l * DD,
        f1T + (size_t)l * DD * 512, f1b + (size_t)l * 4 * DD,
        f2T + (size_t)l * 512 * DD, f2b + l * DD, h);
  }
  k_pool_part<<<(NN + 255) / 256, 256, 0, stream>>>(h, batch, gpool);
  k_head<<<1, 256, 0, stream>>>(gpool, gstart, gend, outW1, outb1, outW2, outb2, (float*)d_out);
}

// Round 9
// 1839.164 us; speedup vs baseline: 2.3663x; 1.0495x over previous
//
#include <hip/hip_runtime.h>

#define NN 50000      // nodes
#define NE 625000     // edges
#define DD 128        // hidden dim
#define HH 8          // heads
#define DHH 16        // head dim
#define NL 4          // layers
#define FIN 64        // in channels
#define NG 64         // graphs
#define LN_EPS 1e-5f
#define NSEG 129      // PWL segments = 128 breakpoints + 1
#define NT32 1563     // ceil(NN/32)
#define NT64 782      // ceil(NN/64)
#define NBS 196       // ceil(NN/256) scan blocks

typedef __bf16 bf16x8_t __attribute__((ext_vector_type(8)));
typedef unsigned short ushort8_t __attribute__((ext_vector_type(8)));
typedef float f32x4_t __attribute__((ext_vector_type(4)));
union BF8 { ushort8_t u; bf16x8_t b; };

// ---------- helpers ----------
__device__ __forceinline__ unsigned fenc(float f) {
  unsigned u = __float_as_uint(f);
  return (u & 0x80000000u) ? ~u : (u | 0x80000000u);   // monotonic float->uint
}
__device__ __forceinline__ float fdec(unsigned u) {
  return __uint_as_float((u & 0x80000000u) ? (u & 0x7FFFFFFFu) : ~u);
}
__device__ __forceinline__ void fma4(float4& a, float s, float4 w) {
  a.x = fmaf(s, w.x, a.x); a.y = fmaf(s, w.y, a.y);
  a.z = fmaf(s, w.z, a.z); a.w = fmaf(s, w.w, a.w);
}
__device__ __forceinline__ unsigned short f2bf(float f) {   // RNE f32->bf16
  unsigned u = __float_as_uint(f);
  unsigned r = ((u >> 16) & 1u) + 0x7FFFu;
  return (unsigned short)((u + r) >> 16);
}
__device__ __forceinline__ float bf2f(unsigned short u) {
  return __uint_as_float((unsigned)u << 16);
}

// LayerNorm 32 nodes -> swizzled bf16 LDS tile [32][128]; block = 512 threads.
__device__ __forceinline__ void ln_tile_bf32(const float* __restrict__ h, int nb,
                                             const float* __restrict__ sc,
                                             const float* __restrict__ bi,
                                             ushort* xbf) {
  int tid = threadIdx.x;
  int r = tid >> 4, l16 = tid & 15;
  int nr = nb + r; if (nr >= NN) nr = NN - 1;   // clamp: tail rows unused
  const float* hp = h + (size_t)nr * DD + l16 * 8;
  float4 a0 = *(const float4*)hp;
  float4 a1 = *(const float4*)(hp + 4);
  float sum = a0.x + a0.y + a0.z + a0.w + a1.x + a1.y + a1.z + a1.w;
  float sq  = a0.x*a0.x + a0.y*a0.y + a0.z*a0.z + a0.w*a0.w
            + a1.x*a1.x + a1.y*a1.y + a1.z*a1.z + a1.w*a1.w;
#pragma unroll
  for (int off = 8; off >= 1; off >>= 1) {
    sum += __shfl_xor(sum, off, 64);
    sq  += __shfl_xor(sq,  off, 64);
  }
  float mu   = sum * (1.0f / DD);
  float var  = sq * (1.0f / DD) - mu * mu;
  float rstd = rsqrtf(var + LN_EPS);
  int d0 = l16 * 8;
  float4 s0 = *(const float4*)(sc + d0), s1 = *(const float4*)(sc + d0 + 4);
  float4 b0 = *(const float4*)(bi + d0), b1 = *(const float4*)(bi + d0 + 4);
  ushort8_t u;
  u[0] = f2bf((a0.x - mu) * rstd * s0.x + b0.x);
  u[1] = f2bf((a0.y - mu) * rstd * s0.y + b0.y);
  u[2] = f2bf((a0.z - mu) * rstd * s0.z + b0.z);
  u[3] = f2bf((a0.w - mu) * rstd * s0.w + b0.w);
  u[4] = f2bf((a1.x - mu) * rstd * s1.x + b1.x);
  u[5] = f2bf((a1.y - mu) * rstd * s1.y + b1.y);
  u[6] = f2bf((a1.z - mu) * rstd * s1.z + b1.z);
  u[7] = f2bf((a1.w - mu) * rstd * s1.w + b1.w);
  int off = (r * 256 + l16 * 16) ^ ((r & 7) << 4);
  *(ushort8_t*)((char*)xbf + off) = u;
}

// LayerNorm 64 nodes (2 passes of 32) -> swizzled bf16 LDS tile [64][128]; 512 threads.
__device__ __forceinline__ void ln_tile_bf64(const float* __restrict__ h, int nb,
                                             const float* __restrict__ sc,
                                             const float* __restrict__ bi,
                                             ushort* xbf) {
  int tid = threadIdx.x;
  int l16 = tid & 15;
  int d0 = l16 * 8;
  float4 s0 = *(const float4*)(sc + d0), s1 = *(const float4*)(sc + d0 + 4);
  float4 b0 = *(const float4*)(bi + d0), b1 = *(const float4*)(bi + d0 + 4);
#pragma unroll
  for (int p = 0; p < 2; p++) {
    int r = p * 32 + (tid >> 4);
    int nr = nb + r; if (nr >= NN) nr = NN - 1;
    const float* hp = h + (size_t)nr * DD + d0;
    float4 a0 = *(const float4*)hp;
    float4 a1 = *(const float4*)(hp + 4);
    float sum = a0.x + a0.y + a0.z + a0.w + a1.x + a1.y + a1.z + a1.w;
    float sq  = a0.x*a0.x + a0.y*a0.y + a0.z*a0.z + a0.w*a0.w
              + a1.x*a1.x + a1.y*a1.y + a1.z*a1.z + a1.w*a1.w;
#pragma unroll
    for (int off = 8; off >= 1; off >>= 1) {
      sum += __shfl_xor(sum, off, 64);
      sq  += __shfl_xor(sq,  off, 64);
    }
    float mu   = sum * (1.0f / DD);
    float var  = sq * (1.0f / DD) - mu * mu;
    float rstd = rsqrtf(var + LN_EPS);
    ushort8_t u;
    u[0] = f2bf((a0.x - mu) * rstd * s0.x + b0.x);
    u[1] = f2bf((a0.y - mu) * rstd * s0.y + b0.y);
    u[2] = f2bf((a0.z - mu) * rstd * s0.z + b0.z);
    u[3] = f2bf((a0.w - mu) * rstd * s0.w + b0.w);
    u[4] = f2bf((a1.x - mu) * rstd * s1.x + b1.x);
    u[5] = f2bf((a1.y - mu) * rstd * s1.y + b1.y);
    u[6] = f2bf((a1.z - mu) * rstd * s1.z + b1.z);
    u[7] = f2bf((a1.w - mu) * rstd * s1.w + b1.w);
    int off = (r * 256 + l16 * 16) ^ ((r & 7) << 4);
    *(ushort8_t*)((char*)xbf + off) = u;
  }
}

// ---------- kernels ----------
// h = x @ node_W + node_b ; 8 nodes/block (fp32 VALU — minor cost)
__global__ __launch_bounds__(256) void k_node_proj(const float* __restrict__ x,
                                                   const float* __restrict__ W,
                                                   const float* __restrict__ b,
                                                   float* __restrict__ h) {
  __shared__ float xt[8][FIN];
  int tid = threadIdx.x;
  int nb = blockIdx.x * 8;
  {
    int idx = tid * 2;
    *(float2*)&xt[idx >> 6][idx & 63] = *(const float2*)(x + (size_t)nb * FIN + idx);
  }
  __syncthreads();
  int c4 = (tid & 31) * 4;
  int r  = tid >> 5;
  float4 acc = *(const float4*)(b + c4);
  for (int k = 0; k < FIN; k += 4) {
    float4 xk = *(const float4*)&xt[r][k];
    const float* wp = W + (size_t)k * DD + c4;
    fma4(acc, xk.x, *(const float4*)wp);
    fma4(acc, xk.y, *(const float4*)(wp + DD));
    fma4(acc, xk.z, *(const float4*)(wp + 2 * DD));
    fma4(acc, xk.w, *(const float4*)(wp + 3 * DD));
  }
  *(float4*)(h + (size_t)(nb + r) * DD + c4) = acc;
}

// per sorted edge: sim (dot), dist (norm) in fp32. 32 lanes/edge.
__global__ __launch_bounds__(256) void k_edge1(const int* __restrict__ src_s, const int* __restrict__ tgt_s,
                                               const float* __restrict__ h, float* __restrict__ sim,
                                               float* __restrict__ dist, unsigned* __restrict__ m_enc) {
  int tid = threadIdx.x;
  int wave = (blockIdx.x * 256 + tid) >> 6;
  int lane = tid & 63;
  int i = wave * 2 + (lane >> 5);
  int j = lane & 31;
  int s = src_s[i], t = tgt_s[i];
  float4 a = *(const float4*)(h + (size_t)s * DD + j * 4);
  float4 b = *(const float4*)(h + (size_t)t * DD + j * 4);
  float dot = a.x*b.x + a.y*b.y + a.z*b.z + a.w*b.w;
  float dx = a.x-b.x, dy = a.y-b.y, dz = a.z-b.z, dw = a.w-b.w;
  float sq = dx*dx + dy*dy + dz*dz + dw*dw;
#pragma unroll
  for (int off = 16; off >= 1; off >>= 1) {
    dot += __shfl_xor(dot, off, 64);
    sq  += __shfl_xor(sq,  off, 64);
  }
  if (j == 0) {
    sim[i]  = dot;                  // BETA == 1.0
    dist[i] = sqrtf(sq);
    atomicMax(m_enc + t, fenc(dot));
  }
}

// denom & alpha*dist numerator per tgt
__global__ void k_edge2(const int* __restrict__ tgt_s, const float* __restrict__ sim,
                        const float* __restrict__ dist, const unsigned* __restrict__ m_enc,
                        float* __restrict__ den, float* __restrict__ nd) {
  int i = blockIdx.x * 256 + threadIdx.x;
  if (i >= NE) return;
  int t = tgt_s[i];
  float ev = expf(sim[i] - fdec(m_enc[t]));
  atomicAdd(den + t, ev);
  atomicAdd(nd + t, ev * dist[i]);
}

__global__ void k_aggv(const float* __restrict__ den, const float* __restrict__ nd,
                       float* __restrict__ aggv) {
  int n = blockIdx.x * 256 + threadIdx.x;
  if (n >= NN) return;
  float d = den[n];
  aggv[n] = d > 0.f ? nd[n] / d : 0.f;
}

// per edge: curvature + PWL segment index (binary search over 128 sorted breakpoints)
__global__ __launch_bounds__(256) void k_curv(const int* __restrict__ tgt_s,
    const float* __restrict__ dist, const float* __restrict__ aggv,
    const float* __restrict__ bp_g, float* __restrict__ curvf, ushort* __restrict__ sege) {
  __shared__ float bp[DD];
  int tid = threadIdx.x;
  if (tid < DD) bp[tid] = bp_g[tid];
  __syncthreads();
  int i = blockIdx.x * 256 + tid;
  if (i >= NE) return;
  int t = tgt_s[i];
  float curv = 1.0f - aggv[t] / fmaxf(dist[i], 1e-6f);
  int lo = 0, hi = DD;
  while (lo < hi) { int mid = (lo + hi) >> 1; if (bp[mid] < curv) lo = mid + 1; else hi = mid; }
  curvf[i] = curv;
  sege[i] = (ushort)lo;     // segment in [0,128]
}

// LN1 + QKV projection via swapped-operand MFMA -> bf16 q/k/v. 32 rows/block, 8 waves.
__global__ __launch_bounds__(512) void k_ln_qkv(const float* __restrict__ h,
    const float* __restrict__ n1s_l, const float* __restrict__ n1b_l,
    const ushort* __restrict__ qkvT_l,
    const float* __restrict__ qb_l, const float* __restrict__ kb_l, const float* __restrict__ vb_l,
    ushort* __restrict__ q, ushort* __restrict__ kk, ushort* __restrict__ v) {
  __shared__ __align__(16) ushort xbf[32 * DD];
  int nb = blockIdx.x * 32;
  ln_tile_bf32(h, nb, n1s_l, n1b_l, xbf);
  __syncthreads();
  int lane = threadIdx.x & 63;
  int w = threadIdx.x >> 6;
  int g = lane >> 4, c = lane & 15;
  int xr = (c & 7) << 4;
  char* xb = (char*)xbf;
  BF8 a[2][4];
#pragma unroll
  for (int nt = 0; nt < 2; nt++)
#pragma unroll
    for (int kt = 0; kt < 4; kt++)
      a[nt][kt].u = *(ushort8_t*)(xb + (((nt * 16 + c) * 256 + kt * 64 + g * 16) ^ xr));
#pragma unroll
  for (int ti = 0; ti < 3; ti++) {
    int t = w * 3 + ti;                // 0..23
    int m = t >> 3;                    // 0=q 1=k 2=v
    int colb = (t & 7) * 16;
    const float* bias = (m == 0 ? qb_l : (m == 1 ? kb_l : vb_l));
    float4 bv = *(const float4*)(bias + colb + g * 4);
    f32x4_t acc0 = {bv.x, bv.y, bv.z, bv.w};
    f32x4_t acc1 = acc0;
    const ushort* wp = qkvT_l + (size_t)(m * DD + colb + c) * DD + g * 8;
#pragma unroll
    for (int kt = 0; kt < 4; kt++) {
      BF8 b; b.u = *(const ushort8_t*)(wp + kt * 32);
      acc0 = __builtin_amdgcn_mfma_f32_16x16x32_bf16(b.b, a[0][kt].b, acc0, 0, 0, 0);
      acc1 = __builtin_amdgcn_mfma_f32_16x16x32_bf16(b.b, a[1][kt].b, acc1, 0, 0, 0);
    }
    ushort* out = (m == 0 ? q : (m == 1 ? kk : v));
    int n0 = nb + c;
    if (n0 < NN) {
      ushort4 o; o.x = f2bf(acc0[0]); o.y = f2bf(acc0[1]); o.z = f2bf(acc0[2]); o.w = f2bf(acc0[3]);
      *(ushort4*)(out + (size_t)n0 * DD + colb + g * 4) = o;
    }
    int n1 = nb + 16 + c;
    if (n1 < NN) {
      ushort4 o; o.x = f2bf(acc1[0]); o.y = f2bf(acc1[1]); o.z = f2bf(acc1[2]); o.w = f2bf(acc1[3]);
      *(ushort4*)(out + (size_t)n1 * DD + colb + g * 4) = o;
    }
  }
}

// per (edge, head): qk dot (bf16) + PWL bias; atomicMax over tgt.
// NOTE: the max pass is MANDATORY — curv is unbounded (self-loop edges have
// dist==0 -> curv ~ -1e6 -> |bias| ~ 1e4), exp() overflows without it (r5/r6).
__global__ __launch_bounds__(256) void k_scores(const int* __restrict__ src_s, const int* __restrict__ tgt_s,
    const ushort* __restrict__ q, const ushort* __restrict__ k,
    const float* __restrict__ curvf, const ushort* __restrict__ sege,
    const float* __restrict__ slope_l, const float* __restrict__ inter_l,
    float* __restrict__ escore, unsigned* __restrict__ sm_enc) {
  __shared__ float lsl[NSEG * HH], lin[NSEG * HH];
  int tid = threadIdx.x;
  for (int idx = tid; idx < NSEG * HH; idx += 256) { lsl[idx] = slope_l[idx]; lin[idx] = inter_l[idx]; }
  __syncthreads();
  int gi = blockIdx.x * 256 + tid;
  if (gi >= NE * HH) return;
  int i = gi >> 3, hh = gi & 7;
  int s = src_s[i], t = tgt_s[i];
  int seg = sege[i];
  float bias = fmaf(lsl[seg * HH + hh], curvf[i], lin[seg * HH + hh]);
  const ushort8_t* qp = (const ushort8_t*)(q + (size_t)s * DD + hh * DHH);
  const ushort8_t* kp = (const ushort8_t*)(k + (size_t)t * DD + hh * DHH);
  float dot = 0.f;
#pragma unroll
  for (int ii = 0; ii < 2; ii++) {
    ushort8_t a = qp[ii], b = kp[ii];
#pragma unroll
    for (int jj = 0; jj < 8; jj++) dot = fmaf(bf2f(a[jj]), bf2f(b[jj]), dot);
  }
  float sc = dot * 0.25f + bias;   // 1/sqrt(16)
  escore[gi] = sc;
  atomicMax(sm_enc + (size_t)t * HH + hh, fenc(sc));
}

__global__ void k_probs(const int* __restrict__ tgt_s, const unsigned* __restrict__ sm_enc,
                        float* __restrict__ escore, float* __restrict__ sden) {
  int gi = blockIdx.x * 256 + threadIdx.x;
  if (gi >= NE * HH) return;
  int i = gi >> 3, hh = gi & 7;
  int t = tgt_s[i];
  float p = expf(escore[gi] - fdec(sm_enc[(size_t)t * HH + hh]));
  escore[gi] = p;
  atomicAdd(sden + (size_t)t * HH + hh, p);
}

__global__ void k_sdinv(float* __restrict__ sden) {
  int i = blockIdx.x * 256 + threadIdx.x;
  if (i >= NN * HH) return;
  float x = sden[i];
  sden[i] = x > 0.f ? 1.0f / x : 0.f;
}

// CSR-gather message aggregation: one wave per src node, 2 dims/lane -> bf16 out
__global__ __launch_bounds__(256) void k_agg(const int* __restrict__ tgt_s,
    const int* __restrict__ rowstart,
    const float* __restrict__ escore, const float* __restrict__ sdinv,
    const ushort* __restrict__ v, ushort* __restrict__ aggmb) {
  int wave = (blockIdx.x * 256 + threadIdx.x) >> 6;
  int lane = threadIdx.x & 63;
  int rs = rowstart[wave], re = rowstart[wave + 1];
  int hh = lane >> 3;
  int d = lane * 2;
  float a0 = 0.f, a1 = 0.f;
  for (int i = rs; i < re; i++) {
    int t = tgt_s[i];
    float prob = escore[i * HH + hh] * sdinv[t * HH + hh];
    ushort2 vv = *(const ushort2*)(v + (size_t)t * DD + d);
    a0 = fmaf(prob, bf2f(vv.x), a0);
    a1 = fmaf(prob, bf2f(vv.y), a1);
  }
  ushort2 o; o.x = f2bf(a0); o.y = f2bf(a1);
  *(ushort2*)(aggmb + (size_t)wave * DD + d) = o;
}

// h += aggm @ oW + ob via swapped-operand MFMA; 32 rows/block, 8 waves, float4 RMW.
__global__ __launch_bounds__(512) void k_update_o(const ushort* __restrict__ aggmb,
    const ushort* __restrict__ oT_l, const float* __restrict__ ob_l, float* __restrict__ h) {
  int nb = blockIdx.x * 32;
  int lane = threadIdx.x & 63, w = threadIdx.x >> 6;
  int g = lane >> 4, c = lane & 15;
  BF8 a[2][4];
#pragma unroll
  for (int nt = 0; nt < 2; nt++) {
    int na = nb + nt * 16 + c; if (na >= NN) na = NN - 1;
    const ushort* ap = aggmb + (size_t)na * DD + g * 8;
#pragma unroll
    for (int kt = 0; kt < 4; kt++) a[nt][kt].u = *(const ushort8_t*)(ap + kt * 32);
  }
  int colb = w * 16;
  float4 bv = *(const float4*)(ob_l + colb + g * 4);
  f32x4_t acc0 = {bv.x, bv.y, bv.z, bv.w};
  f32x4_t acc1 = acc0;
  const ushort* wp = oT_l + (size_t)(colb + c) * DD + g * 8;
#pragma unroll
  for (int kt = 0; kt < 4; kt++) {
    BF8 b; b.u = *(const ushort8_t*)(wp + kt * 32);
    acc0 = __builtin_amdgcn_mfma_f32_16x16x32_bf16(b.b, a[0][kt].b, acc0, 0, 0, 0);
    acc1 = __builtin_amdgcn_mfma_f32_16x16x32_bf16(b.b, a[1][kt].b, acc1, 0, 0, 0);
  }
#pragma unroll
  for (int nt = 0; nt < 2; nt++) {
    int node = nb + nt * 16 + c;
    if (node < NN) {
      float* hp = h + (size_t)node * DD + colb + g * 4;
      float4 hv = *(const float4*)hp;
      f32x4_t& acc = nt ? acc1 : acc0;
      hv.x += acc[0]; hv.y += acc[1]; hv.z += acc[2]; hv.w += acc[3];
      *(float4*)hp = hv;
    }
  }
}

// fused FFN, BM=64: h += relu(LN2(h)@f1W+f1b)@f2W+f2b; 64 rows/block, 8 waves.
__global__ __launch_bounds__(512) void k_ffn(const float* __restrict__ n2s_l, const float* __restrict__ n2b_l,
    const ushort* __restrict__ f1T_l, const float* __restrict__ f1b_l,
    const ushort* __restrict__ f2T_l, const float* __restrict__ f2b_l,
    float* __restrict__ h) {
  __shared__ __align__(16) ushort xbf[64 * DD];      // 16 KB
  __shared__ __align__(16) ushort tbf[64 * 256];     // 32 KB
  int nb = blockIdx.x * 64;
  ln_tile_bf64(h, nb, n2s_l, n2b_l, xbf);
  __syncthreads();
  int lane = threadIdx.x & 63, w = threadIdx.x >> 6;
  int g = lane >> 4, c = lane & 15;
  int xr = (c & 7) << 4;
  char* xb = (char*)xbf;
  char* tb = (char*)tbf;
  BF8 a[4][4];
#pragma unroll
  for (int nt = 0; nt < 4; nt++)
#pragma unroll
    for (int kt = 0; kt < 4; kt++)
      a[nt][kt].u = *(ushort8_t*)(xb + (((nt * 16 + c) * 256 + kt * 64 + g * 16) ^ xr));
  int colb2 = w * 16;
  float4 bv2 = *(const float4*)(f2b_l + colb2 + g * 4);
  f32x4_t o0 = {bv2.x, bv2.y, bv2.z, bv2.w};
  f32x4_t o1 = o0, o2 = o0, o3 = o0;
#pragma unroll
  for (int ch = 0; ch < 2; ch++) {
    if (ch) __syncthreads();           // tbf reuse: wait for chunk-0 reads
#pragma unroll
    for (int ti = 0; ti < 2; ti++) {
      int ctile = w * 2 + ti;          // 0..15 within chunk
      int col = ch * 256 + ctile * 16;
      float4 bv = *(const float4*)(f1b_l + col + g * 4);
      f32x4_t ac0 = {bv.x, bv.y, bv.z, bv.w};
      f32x4_t ac1 = ac0, ac2 = ac0, ac3 = ac0;
      const ushort* wp = f1T_l + (size_t)(col + c) * DD + g * 8;
#pragma unroll
      for (int kt = 0; kt < 4; kt++) {
        BF8 b; b.u = *(const ushort8_t*)(wp + kt * 32);
        ac0 = __builtin_amdgcn_mfma_f32_16x16x32_bf16(b.b, a[0][kt].b, ac0, 0, 0, 0);
        ac1 = __builtin_amdgcn_mfma_f32_16x16x32_bf16(b.b, a[1][kt].b, ac1, 0, 0, 0);
        ac2 = __builtin_amdgcn_mfma_f32_16x16x32_bf16(b.b, a[2][kt].b, ac2, 0, 0, 0);
        ac3 = __builtin_amdgcn_mfma_f32_16x16x32_bf16(b.b, a[3][kt].b, ac3, 0, 0, 0);
      }
      int colL = (ctile * 16 + g * 4) * 2;     // byte col within chunk tile
      {
        int row = c;
        ushort4 o4; o4.x = f2bf(fmaxf(ac0[0], 0.f)); o4.y = f2bf(fmaxf(ac0[1], 0.f));
        o4.z = f2bf(fmaxf(ac0[2], 0.f)); o4.w = f2bf(fmaxf(ac0[3], 0.f));
        *(ushort4*)(tb + ((row * 512 + colL) ^ ((row & 7) << 4))) = o4;
      }
      {
        int row = 16 + c;
        ushort4 o4; o4.x = f2bf(fmaxf(ac1[0], 0.f)); o4.y = f2bf(fmaxf(ac1[1], 0.f));
        o4.z = f2bf(fmaxf(ac1[2], 0.f)); o4.w = f2bf(fmaxf(ac1[3], 0.f));
        *(ushort4*)(tb + ((row * 512 + colL) ^ ((row & 7) << 4))) = o4;
      }
      {
        int row = 32 + c;
        ushort4 o4; o4.x = f2bf(fmaxf(ac2[0], 0.f)); o4.y = f2bf(fmaxf(ac2[1], 0.f));
        o4.z = f2bf(fmaxf(ac2[2], 0.f)); o4.w = f2bf(fmaxf(ac2[3], 0.f));
        *(ushort4*)(tb + ((row * 512 + colL) ^ ((row & 7) << 4))) = o4;
      }
      {
        int row = 48 + c;
        ushort4 o4; o4.x = f2bf(fmaxf(ac3[0], 0.f)); o4.y = f2bf(fmaxf(ac3[1], 0.f));
        o4.z = f2bf(fmaxf(ac3[2], 0.f)); o4.w = f2bf(fmaxf(ac3[3], 0.f));
        *(ushort4*)(tb + ((row * 512 + colL) ^ ((row & 7) << 4))) = o4;
      }
    }
    __syncthreads();
    const ushort* wp2 = f2T_l + (size_t)(colb2 + c) * 512 + ch * 256 + g * 8;
#pragma unroll
    for (int kt = 0; kt < 8; kt++) {
      BF8 b; b.u = *(const ushort8_t*)(wp2 + kt * 32);
      BF8 t0; t0.u = *(ushort8_t*)(tb + (((c) * 512 + kt * 64 + g * 16) ^ xr));
      BF8 t1; t1.u = *(ushort8_t*)(tb + (((16 + c) * 512 + kt * 64 + g * 16) ^ xr));
      BF8 t2; t2.u = *(ushort8_t*)(tb + (((32 + c) * 512 + kt * 64 + g * 16) ^ xr));
      BF8 t3; t3.u = *(ushort8_t*)(tb + (((48 + c) * 512 + kt * 64 + g * 16) ^ xr));
      o0 = __builtin_amdgcn_mfma_f32_16x16x32_bf16(b.b, t0.b, o0, 0, 0, 0);
      o1 = __builtin_amdgcn_mfma_f32_16x16x32_bf16(b.b, t1.b, o1, 0, 0, 0);
      o2 = __builtin_amdgcn_mfma_f32_16x16x32_bf16(b.b, t2.b, o2, 0, 0, 0);
      o3 = __builtin_amdgcn_mfma_f32_16x16x32_bf16(b.b, t3.b, o3, 0, 0, 0);
    }
  }
  {
    int node = nb + c;
    if (node < NN) {
      float* hp = h + (size_t)node * DD + colb2 + g * 4;
      float4 hv = *(const float4*)hp;
      hv.x += o0[0]; hv.y += o0[1]; hv.z += o0[2]; hv.w += o0[3];
      *(float4*)hp = hv;
    }
  }
  {
    int node = nb + 16 + c;
    if (node < NN) {
      float* hp = h + (size_t)node * DD + colb2 + g * 4;
      float4 hv = *(const float4*)hp;
      hv.x += o1[0]; hv.y += o1[1]; hv.z += o1[2]; hv.w += o1[3];
      *(float4*)hp = hv;
    }
  }
  {
    int node = nb + 32 + c;
    if (node < NN) {
      float* hp = h + (size_t)node * DD + colb2 + g * 4;
      float4 hv = *(const float4*)hp;
      hv.x += o2[0]; hv.y += o2[1]; hv.z += o2[2]; hv.w += o2[3];
      *(float4*)hp = hv;
    }
  }
  {
    int node = nb + 48 + c;
    if (node < NN) {
      float* hp = h + (size_t)node * DD + colb2 + g * 4;
      float4 hv = *(const float4*)hp;
      hv.x += o3[0]; hv.y += o3[1]; hv.z += o3[2]; hv.w += o3[3];
      *(float4*)hp = hv;
    }
  }
}

// ---------- once-per-call setup kernels ----------
// transpose fp32 [K][C] -> bf16 [C][K], nm stacked matrices, dst stride per matrix
template <int K, int C>
__global__ void k_wt(const float* __restrict__ W, ushort* __restrict__ WT, int nm, int dstride) {
  int idx = blockIdx.x * 256 + threadIdx.x;
  if (idx >= K * C * nm) return;
  int mi = idx / (K * C), rem = idx - mi * (K * C);
  int cc = rem / K, kk2 = rem - cc * K;
  WT[(size_t)mi * dstride + cc * K + kk2] = f2bf(W[(size_t)mi * K * C + (size_t)kk2 * C + cc]);
}

__global__ void k_hist(const int* __restrict__ src, int* __restrict__ cnt) {
  int e = blockIdx.x * 256 + threadIdx.x;
  if (e < NE) atomicAdd(cnt + src[e], 1);
}

// multi-block exclusive scan of cnt[NN] -> rowstart
__global__ __launch_bounds__(256) void k_scan_blk(const int* __restrict__ cnt, int* __restrict__ bsum) {
  __shared__ int red[256];
  int tid = threadIdx.x;
  int idx = blockIdx.x * 256 + tid;
  red[tid] = (idx < NN) ? cnt[idx] : 0;
  __syncthreads();
  for (int off = 128; off >= 1; off >>= 1) {
    if (tid < off) red[tid] += red[tid + off];
    __syncthreads();
  }
  if (tid == 0) bsum[blockIdx.x] = red[0];
}

__global__ __launch_bounds__(256) void k_scan_top(const int* __restrict__ bsum,
                                                  int* __restrict__ boff, int* __restrict__ rowstart) {
  __shared__ int ps[256];
  int t = threadIdx.x;
  int v = (t < NBS) ? bsum[t] : 0;
  ps[t] = v;
  __syncthreads();
  for (int off = 1; off < 256; off <<= 1) {
    int x = (t >= off) ? ps[t - off] : 0;
    __syncthreads();
    ps[t] += x;
    __syncthreads();
  }
  boff[t] = ps[t] - v;                 // exclusive prefix of block sums
  if (t == 255) rowstart[NN] = ps[255];
}

__global__ __launch_bounds__(256) void k_scan_fin(const int* __restrict__ cnt,
                                                  const int* __restrict__ boff, int* __restrict__ rowstart) {
  __shared__ int ps[256];
  int t = threadIdx.x;
  int idx = blockIdx.x * 256 + t;
  int v = (idx < NN) ? cnt[idx] : 0;
  ps[t] = v;
  __syncthreads();
  for (int off = 1; off < 256; off <<= 1) {
    int x = (t >= off) ? ps[t - off] : 0;
    __syncthreads();
    ps[t] += x;
    __syncthreads();
  }
  if (idx < NN) rowstart[idx] = boff[blockIdx.x] + ps[t] - v;
}

// scatter edges into src-sorted order (all per-edge arrays use sorted index)
__global__ void k_fill(const int* __restrict__ src, const int* __restrict__ tgt,
                       const int* __restrict__ rowstart,
                       int* __restrict__ cur, int* __restrict__ src_s, int* __restrict__ tgt_s) {
  int e = blockIdx.x * 256 + threadIdx.x;
  if (e >= NE) return;
  int s = src[e];
  int p = atomicAdd(cur + s, 1);
  int pos = rowstart[s] + p;
  src_s[pos] = s;
  tgt_s[pos] = tgt[e];
}

// M[l][d][hh] = Sum_k cW2[d][k]*bW[l][k][hh]. Wave-parallel: one block per (l,d),
// 8 lanes/head x 16 k's + shfl tree (round-8's 4-block serial version was ~latency
// bound like k_pwl). base: computed by d==0 blocks.
__global__ __launch_bounds__(64) void k_mbias_par(const float* __restrict__ cW2, const float* __restrict__ cb2,
                                                  const float* __restrict__ bW, const float* __restrict__ bb,
                                                  float* __restrict__ M, float* __restrict__ base) {
  int bid = blockIdx.x;
  int l = bid >> 7, d = bid & 127;
  int lane = threadIdx.x;
  int hh = lane >> 3, j0 = lane & 7;
  const float* bWl = bW + (size_t)l * DD * HH;
  float acc = 0.f;
#pragma unroll
  for (int t = 0; t < 16; t++) {
    int k = j0 + t * 8;
    acc = fmaf(cW2[d * DD + k], bWl[k * HH + hh], acc);
  }
#pragma unroll
  for (int off = 1; off <= 4; off <<= 1) acc += __shfl_xor(acc, off, 64);
  if (j0 == 0) M[(size_t)l * DD * HH + d * HH + hh] = acc;
  if (d == 0) {
    float bacc = 0.f;
#pragma unroll
    for (int t = 0; t < 16; t++) {
      int k = j0 + t * 8;
      bacc = fmaf(cb2[k], bWl[k * HH + hh], bacc);
    }
#pragma unroll
    for (int off = 1; off <= 4; off <<= 1) bacc += __shfl_xor(bacc, off, 64);
    if (j0 == 0) base[l * HH + hh] = bacc + bb[l * HH + hh];
  }
}

// sorted breakpoints + ranks — cW1/cb1 are layer-INDEPENDENT, computed once.
// pos/bp arithmetic identical to round 4 (bit-exact segment boundaries).
__global__ __launch_bounds__(128) void k_bp(const float* __restrict__ cW1, const float* __restrict__ cb1,
                                            float* __restrict__ bpg, int* __restrict__ posg) {
  __shared__ float x[DD], bp[DD];
  int tid = threadIdx.x;
  float c1v = cW1[tid], cbv = cb1[tid];
  x[tid] = (c1v == 0.f) ? __builtin_inff() : (-cbv / c1v);
  __syncthreads();
  float xv = x[tid]; int p = 0;
  for (int j = 0; j < DD; j++) {
    float xj = x[j];
    if (xj < xv || (xj == xv && j < tid)) p++;
  }
  bp[p] = xv;
  posg[tid] = p;
  __syncthreads();
  bpg[tid] = bp[tid];
}

// PWL table, wave-parallel: one block per (l, segment); 8 lanes/head x 16 d's
// + shfl tree. act-select is exact (m=0 contributes nothing); reassociation of
// the d-sum perturbs table ~1e-7 rel (analyzed safe through softmax).
__global__ __launch_bounds__(64) void k_pwl_tab(const float* __restrict__ cW1, const float* __restrict__ cb1,
    const int* __restrict__ posg, const float* __restrict__ Mb, const float* __restrict__ basel,
    float* __restrict__ slopeg, float* __restrict__ interg) {
  int bid = blockIdx.x;
  int l = bid / NSEG, s = bid - l * NSEG;
  int lane = threadIdx.x;
  int hh = lane >> 3, j0 = lane & 7;
  const float* M = Mb + (size_t)l * DD * HH;
  float sl = 0.f, in = 0.f;
#pragma unroll
  for (int t = 0; t < 16; t++) {
    int d = j0 + t * 8;
    float cv = cW1[d], cbv = cb1[d];
    int p = posg[d];
    bool act = (cv == 0.f) ? (cbv > 0.f) : ((cv > 0.f) ? (p < s) : (p >= s));
    float m = act ? M[d * HH + hh] : 0.f;
    sl = fmaf(cv, m, sl);
    in = fmaf(cbv, m, in);
  }
#pragma unroll
  for (int off = 1; off <= 4; off <<= 1) {
    sl += __shfl_xor(sl, off, 64);
    in += __shfl_xor(in, off, 64);
  }
  if (j0 == 0) {
    size_t o = (size_t)l * NSEG * HH + s * HH + hh;
    slopeg[o] = sl;
    interg[o] = in + basel[l * HH + hh];
  }
}

__global__ void k_bounds(const int* __restrict__ batch, int* __restrict__ gstart, int* __restrict__ gend) {
  int n = blockIdx.x * 256 + threadIdx.x;
  if (n >= NN) return;
  int b = batch[n];
  if (n == 0 || batch[n - 1] != b) gstart[b] = n;
  if (n == NN - 1 || batch[n + 1] != b) gend[b] = n + 1;
}

// parallel pool: 256 nodes/block, running sums flushed at graph boundaries
__global__ __launch_bounds__(256) void k_pool_part(const float* __restrict__ h,
    const int* __restrict__ batch, float* __restrict__ gpool) {
  int tid = threadIdx.x;
  int d = tid & 127, sub = tid >> 7;
  int n0 = blockIdx.x * 256;
  int nend = n0 + 256; if (nend > NN) nend = NN;
  float run = 0.f; int gcur = -1;
  for (int n = n0 + sub; n < nend; n += 2) {
    int g = batch[n];
    if (g != gcur) {
      if (gcur >= 0) atomicAdd(gpool + (size_t)gcur * DD + d, run);
      run = 0.f; gcur = g;
    }
    run += h[(size_t)n * DD + d];
  }
  if (gcur >= 0) atomicAdd(gpool + (size_t)gcur * DD + d, run);
}

__global__ __launch_bounds__(256) void k_head(const float* __restrict__ gpool,
    const int* __restrict__ gstart, const int* __restrict__ gend,
    const float* __restrict__ W1, const float* __restrict__ b1,
    const float* __restrict__ W2, const float* __restrict__ b2, float* __restrict__ out) {
  __shared__ float mid[NG * 64];
  int tid = threadIdx.x;
  for (int idx = tid; idx < NG * 64; idx += 256) {
    int g = idx >> 6, j = idx & 63;
    int cnt = gend[g] - gstart[g]; if (cnt < 1) cnt = 1;
    float rc = 1.0f / (float)cnt;
    float acc = 0.f;
    for (int d = 0; d < DD; d++) acc = fmaf(gpool[g * DD + d], W1[d * 64 + j], acc);
    mid[idx] = fmaxf(fmaf(acc, rc, b1[j]), 0.f);
  }
  __syncthreads();
  if (tid < NG) {
    float acc = b2[0];
    for (int j = 0; j < 64; j++) acc = fmaf(mid[tid * 64 + j], W2[j], acc);
    out[tid] = acc;
  }
}

// ---------- launch ----------
extern "C" void kernel_launch(void* const* d_in, const int* in_sizes, int n_in,
                              void* d_out, int out_size, void* d_ws, size_t ws_size,
                              hipStream_t stream) {
  const float* x      = (const float*)d_in[0];
  const int*   ei     = (const int*)d_in[1];
  const int*   batch  = (const int*)d_in[2];
  const float* node_W = (const float*)d_in[3];
  const float* node_b = (const float*)d_in[4];
  const float* cW1    = (const float*)d_in[5];
  const float* cb1    = (const float*)d_in[6];
  const float* cW2    = (const float*)d_in[7];
  const float* cb2    = (const float*)d_in[8];
  const float* qW     = (const float*)d_in[9];
  const float* qb     = (const float*)d_in[10];
  const float* kW     = (const float*)d_in[11];
  const float* kb     = (const float*)d_in[12];
  const float* vW     = (const float*)d_in[13];
  const float* vb     = (const float*)d_in[14];
  const float* oW     = (const float*)d_in[15];
  const float* ob     = (const float*)d_in[16];
  const float* bW     = (const float*)d_in[17];
  const float* bb     = (const float*)d_in[18];
  const float* f1W    = (const float*)d_in[19];
  const float* f1b    = (const float*)d_in[20];
  const float* f2W    = (const float*)d_in[21];
  const float* f2b    = (const float*)d_in[22];
  const float* n1s    = (const float*)d_in[23];
  const float* n1b    = (const float*)d_in[24];
  const float* n2s    = (const float*)d_in[25];
  const float* n2b    = (const float*)d_in[26];
  const float* outW1  = (const float*)d_in[27];
  const float* outb1  = (const float*)d_in[28];
  const float* outW2  = (const float*)d_in[29];
  const float* outb2  = (const float*)d_in[30];

  const int* src = ei;
  const int* tgt = ei + NE;

  char* wp = (char*)d_ws;
  auto alloc = [&](size_t bytes) { void* p = (void*)wp; wp += (bytes + 255) & ~(size_t)255; return p; };
  float*    h       = (float*)alloc((size_t)NN * DD * 4);
  ushort*   q       = (ushort*)alloc((size_t)NN * DD * 2);
  ushort*   kk      = (ushort*)alloc((size_t)NN * DD * 2);
  ushort*   v       = (ushort*)alloc((size_t)NN * DD * 2);
  ushort*   aggmb   = (ushort*)alloc((size_t)NN * DD * 2);
  float*    sim     = (float*)alloc((size_t)NE * 4);
  float*    dist    = (float*)alloc((size_t)NE * 4);
  float*    escore  = (float*)alloc((size_t)NE * HH * 4);
  float*    curvf   = (float*)alloc((size_t)NE * 4);
  ushort*   sege    = (ushort*)alloc((size_t)NE * 2);
  char*     zbase   = wp;                         // zeroed once per layer:
  unsigned* m_enc   = (unsigned*)alloc((size_t)NN * 4);
  float*    den     = (float*)alloc((size_t)NN * 4);
  float*    nd      = (float*)alloc((size_t)NN * 4);
  unsigned* sm_enc  = (unsigned*)alloc((size_t)NN * HH * 4);
  float*    sden    = (float*)alloc((size_t)NN * HH * 4);
  size_t    zbytes  = (size_t)(wp - zbase);
  float*    aggv    = (float*)alloc((size_t)NN * 4);
  float*    Mb      = (float*)alloc((size_t)NL * DD * HH * 4);
  float*    basel   = (float*)alloc((size_t)NL * HH * 4);
  float*    bpg     = (float*)alloc((size_t)DD * 4);
  int*      posg    = (int*)alloc((size_t)DD * 4);
  float*    slopeg  = (float*)alloc((size_t)NL * NSEG * HH * 4);
  float*    interg  = (float*)alloc((size_t)NL * NSEG * HH * 4);
  int*      rowstart= (int*)alloc((size_t)(NN + 1) * 4);
  int*      src_s   = (int*)alloc((size_t)NE * 4);
  int*      tgt_s   = (int*)alloc((size_t)NE * 4);
  int*      cnt     = (int*)alloc((size_t)NN * 4);
  int*      cur     = (int*)alloc((size_t)NN * 4);
  int*      bsum    = (int*)alloc((size_t)NBS * 4);
  int*      boff    = (int*)alloc((size_t)256 * 4);
  int*      gstart  = (int*)alloc((size_t)NG * 4);
  int*      gend    = (int*)alloc((size_t)NG * 4);
  float*    gpool   = (float*)alloc((size_t)NG * DD * 4);
  ushort*   qkvT    = (ushort*)alloc((size_t)NL * 3 * DD * DD * 2);
  ushort*   oT      = (ushort*)alloc((size_t)NL * DD * DD * 2);
  ushort*   f1T     = (ushort*)alloc((size_t)NL * DD * 512 * 2);
  ushort*   f2T     = (ushort*)alloc((size_t)NL * 512 * DD * 2);
  (void)in_sizes; (void)n_in; (void)out_size; (void)ws_size;

  // once-per-call setup
  hipMemsetAsync(cnt, 0, NN * 4, stream);
  hipMemsetAsync(cur, 0, NN * 4, stream);
  hipMemsetAsync(gstart, 0, NG * 4, stream);
  hipMemsetAsync(gend, 0, NG * 4, stream);
  hipMemsetAsync(gpool, 0, NG * DD * 4, stream);
  k_hist<<<(NE + 255) / 256, 256, 0, stream>>>(src, cnt);
  k_scan_blk<<<NBS, 256, 0, stream>>>(cnt, bsum);
  k_scan_top<<<1, 256, 0, stream>>>(bsum, boff, rowstart);
  k_scan_fin<<<NBS, 256, 0, stream>>>(cnt, boff, rowstart);
  k_fill<<<(NE + 255) / 256, 256, 0, stream>>>(src, tgt, rowstart, cur, src_s, tgt_s);
  k_mbias_par<<<NL * DD, 64, 0, stream>>>(cW2, cb2, bW, bb, Mb, basel);
  k_bp<<<1, 128, 0, stream>>>(cW1, cb1, bpg, posg);
  k_pwl_tab<<<NL * NSEG, 64, 0, stream>>>(cW1, cb1, posg, Mb, basel, slopeg, interg);
  k_bounds<<<(NN + 255) / 256, 256, 0, stream>>>(batch, gstart, gend);
  // bf16-transposed weights
  k_wt<DD, DD><<<(NL * DD * DD + 255) / 256, 256, 0, stream>>>(qW, qkvT,               NL, 3 * DD * DD);
  k_wt<DD, DD><<<(NL * DD * DD + 255) / 256, 256, 0, stream>>>(kW, qkvT + DD * DD,     NL, 3 * DD * DD);
  k_wt<DD, DD><<<(NL * DD * DD + 255) / 256, 256, 0, stream>>>(vW, qkvT + 2 * DD * DD, NL, 3 * DD * DD);
  k_wt<DD, DD><<<(NL * DD * DD + 255) / 256, 256, 0, stream>>>(oW, oT, NL, DD * DD);
  k_wt<DD, 512><<<(NL * DD * 512 + 255) / 256, 256, 0, stream>>>(f1W, f1T, NL, DD * 512);
  k_wt<512, DD><<<(NL * DD * 512 + 255) / 256, 256, 0, stream>>>(f2W, f2T, NL, DD * 512);
  k_node_proj<<<NN / 8, 256, 0, stream>>>(x, node_W, node_b, h);

  for (int l = 0; l < NL; l++) {
    hipMemsetAsync(zbase, 0, zbytes, stream);
    k_edge1<<<NE / 8, 256, 0, stream>>>(src_s, tgt_s, h, sim, dist, m_enc);
    k_edge2<<<(NE + 255) / 256, 256, 0, stream>>>(tgt_s, sim, dist, m_enc, den, nd);
    k_aggv<<<(NN + 255) / 256, 256, 0, stream>>>(den, nd, aggv);
    k_curv<<<(NE + 255) / 256, 256, 0, stream>>>(tgt_s, dist, aggv, bpg, curvf, sege);
    k_ln_qkv<<<NT32, 512, 0, stream>>>(h, n1s + l * DD, n1b + l * DD,
        qkvT + (size_t)l * 3 * DD * DD,
        qb + l * DD, kb + l * DD, vb + l * DD, q, kk, v);
    k_scores<<<(NE * HH + 255) / 256, 256, 0, stream>>>(src_s, tgt_s, q, kk,
        curvf, sege, slopeg + (size_t)l * NSEG * HH, interg + (size_t)l * NSEG * HH,
        escore, sm_enc);
    k_probs<<<(NE * HH + 255) / 256, 256, 0, stream>>>(tgt_s, sm_enc, escore, sden);
    k_sdinv<<<(NN * HH + 255) / 256, 256, 0, stream>>>(sden);
    k_agg<<<NN / 4, 256, 0, stream>>>(tgt_s, rowstart, escore, sden, v, aggmb);
    k_update_o<<<NT32, 512, 0, stream>>>(aggmb, oT + (size_t)l * DD * DD, ob + l * DD, h);
    k_ffn<<<NT64, 512, 0, stream>>>(n2s + l * DD, n2b + l * DD,
        f1T + (size_t)l * DD * 512, f1b + (size_t)l * 4 * DD,
        f2T + (size_t)l * 512 * DD, f2b + l * DD, h);
  }
  k_pool_part<<<(NN + 255) / 256, 256, 0, stream>>>(h, batch, gpool);
  k_head<<<1, 256, 0, stream>>>(gpool, gstart, gend, outW1, outb1, outW2, outb2, (float*)d_out);
}

// Round 10
// 1708.089 us; speedup vs baseline: 2.5479x; 1.0767x over previous
//
#include <hip/hip_runtime.h>

#define NN 50000      // nodes
#define NE 625000     // edges
#define DD 128        // hidden dim
#define HH 8          // heads
#define DHH 16        // head dim
#define NL 4          // layers
#define FIN 64        // in channels
#define NG 64         // graphs
#define LN_EPS 1e-5f
#define NSEG 129      // PWL segments = 128 breakpoints + 1
#define NT32 1563     // ceil(NN/32)
#define NT64 782      // ceil(NN/64)
#define NBS 196       // ceil(NN/256) scan blocks

typedef __bf16 bf16x8_t __attribute__((ext_vector_type(8)));
typedef unsigned short ushort8_t __attribute__((ext_vector_type(8)));
typedef float f32x4_t __attribute__((ext_vector_type(4)));
union BF8 { ushort8_t u; bf16x8_t b; };

// ---------- helpers ----------
__device__ __forceinline__ unsigned fenc(float f) {
  unsigned u = __float_as_uint(f);
  return (u & 0x80000000u) ? ~u : (u | 0x80000000u);   // monotonic float->uint
}
__device__ __forceinline__ float fdec(unsigned u) {
  return __uint_as_float((u & 0x80000000u) ? (u & 0x7FFFFFFFu) : ~u);
}
__device__ __forceinline__ void fma4(float4& a, float s, float4 w) {
  a.x = fmaf(s, w.x, a.x); a.y = fmaf(s, w.y, a.y);
  a.z = fmaf(s, w.z, a.z); a.w = fmaf(s, w.w, a.w);
}
__device__ __forceinline__ unsigned short f2bf(float f) {   // RNE f32->bf16
  unsigned u = __float_as_uint(f);
  unsigned r = ((u >> 16) & 1u) + 0x7FFFu;
  return (unsigned short)((u + r) >> 16);
}
__device__ __forceinline__ float bf2f(unsigned short u) {
  return __uint_as_float((unsigned)u << 16);
}

// LayerNorm 32 nodes -> swizzled bf16 LDS tile [32][128]; block = 512 threads.
__device__ __forceinline__ void ln_tile_bf32(const float* __restrict__ h, int nb,
                                             const float* __restrict__ sc,
                                             const float* __restrict__ bi,
                                             ushort* xbf) {
  int tid = threadIdx.x;
  int r = tid >> 4, l16 = tid & 15;
  int nr = nb + r; if (nr >= NN) nr = NN - 1;   // clamp: tail rows unused
  const float* hp = h + (size_t)nr * DD + l16 * 8;
  float4 a0 = *(const float4*)hp;
  float4 a1 = *(const float4*)(hp + 4);
  float sum = a0.x + a0.y + a0.z + a0.w + a1.x + a1.y + a1.z + a1.w;
  float sq  = a0.x*a0.x + a0.y*a0.y + a0.z*a0.z + a0.w*a0.w
            + a1.x*a1.x + a1.y*a1.y + a1.z*a1.z + a1.w*a1.w;
#pragma unroll
  for (int off = 8; off >= 1; off >>= 1) {
    sum += __shfl_xor(sum, off, 64);
    sq  += __shfl_xor(sq,  off, 64);
  }
  float mu   = sum * (1.0f / DD);
  float var  = sq * (1.0f / DD) - mu * mu;
  float rstd = rsqrtf(var + LN_EPS);
  int d0 = l16 * 8;
  float4 s0 = *(const float4*)(sc + d0), s1 = *(const float4*)(sc + d0 + 4);
  float4 b0 = *(const float4*)(bi + d0), b1 = *(const float4*)(bi + d0 + 4);
  ushort8_t u;
  u[0] = f2bf((a0.x - mu) * rstd * s0.x + b0.x);
  u[1] = f2bf((a0.y - mu) * rstd * s0.y + b0.y);
  u[2] = f2bf((a0.z - mu) * rstd * s0.z + b0.z);
  u[3] = f2bf((a0.w - mu) * rstd * s0.w + b0.w);
  u[4] = f2bf((a1.x - mu) * rstd * s1.x + b1.x);
  u[5] = f2bf((a1.y - mu) * rstd * s1.y + b1.y);
  u[6] = f2bf((a1.z - mu) * rstd * s1.z + b1.z);
  u[7] = f2bf((a1.w - mu) * rstd * s1.w + b1.w);
  int off = (r * 256 + l16 * 16) ^ ((r & 7) << 4);
  *(ushort8_t*)((char*)xbf + off) = u;
}

// LayerNorm 64 nodes (2 passes of 32) -> swizzled bf16 LDS tile [64][128]; 512 threads.
__device__ __forceinline__ void ln_tile_bf64(const float* __restrict__ h, int nb,
                                             const float* __restrict__ sc,
                                             const float* __restrict__ bi,
                                             ushort* xbf) {
  int tid = threadIdx.x;
  int l16 = tid & 15;
  int d0 = l16 * 8;
  float4 s0 = *(const float4*)(sc + d0), s1 = *(const float4*)(sc + d0 + 4);
  float4 b0 = *(const float4*)(bi + d0), b1 = *(const float4*)(bi + d0 + 4);
#pragma unroll
  for (int p = 0; p < 2; p++) {
    int r = p * 32 + (tid >> 4);
    int nr = nb + r; if (nr >= NN) nr = NN - 1;
    const float* hp = h + (size_t)nr * DD + d0;
    float4 a0 = *(const float4*)hp;
    float4 a1 = *(const float4*)(hp + 4);
    float sum = a0.x + a0.y + a0.z + a0.w + a1.x + a1.y + a1.z + a1.w;
    float sq  = a0.x*a0.x + a0.y*a0.y + a0.z*a0.z + a0.w*a0.w
              + a1.x*a1.x + a1.y*a1.y + a1.z*a1.z + a1.w*a1.w;
#pragma unroll
    for (int off = 8; off >= 1; off >>= 1) {
      sum += __shfl_xor(sum, off, 64);
      sq  += __shfl_xor(sq,  off, 64);
    }
    float mu   = sum * (1.0f / DD);
    float var  = sq * (1.0f / DD) - mu * mu;
    float rstd = rsqrtf(var + LN_EPS);
    ushort8_t u;
    u[0] = f2bf((a0.x - mu) * rstd * s0.x + b0.x);
    u[1] = f2bf((a0.y - mu) * rstd * s0.y + b0.y);
    u[2] = f2bf((a0.z - mu) * rstd * s0.z + b0.z);
    u[3] = f2bf((a0.w - mu) * rstd * s0.w + b0.w);
    u[4] = f2bf((a1.x - mu) * rstd * s1.x + b1.x);
    u[5] = f2bf((a1.y - mu) * rstd * s1.y + b1.y);
    u[6] = f2bf((a1.z - mu) * rstd * s1.z + b1.z);
    u[7] = f2bf((a1.w - mu) * rstd * s1.w + b1.w);
    int off = (r * 256 + l16 * 16) ^ ((r & 7) << 4);
    *(ushort8_t*)((char*)xbf + off) = u;
  }
}

// ---------- kernels ----------
// h = x @ node_W + node_b ; 8 nodes/block (fp32 VALU — minor cost)
__global__ __launch_bounds__(256) void k_node_proj(const float* __restrict__ x,
                                                   const float* __restrict__ W,
                                                   const float* __restrict__ b,
                                                   float* __restrict__ h) {
  __shared__ float xt[8][FIN];
  int tid = threadIdx.x;
  int nb = blockIdx.x * 8;
  {
    int idx = tid * 2;
    *(float2*)&xt[idx >> 6][idx & 63] = *(const float2*)(x + (size_t)nb * FIN + idx);
  }
  __syncthreads();
  int c4 = (tid & 31) * 4;
  int r  = tid >> 5;
  float4 acc = *(const float4*)(b + c4);
  for (int k = 0; k < FIN; k += 4) {
    float4 xk = *(const float4*)&xt[r][k];
    const float* wp = W + (size_t)k * DD + c4;
    fma4(acc, xk.x, *(const float4*)wp);
    fma4(acc, xk.y, *(const float4*)(wp + DD));
    fma4(acc, xk.z, *(const float4*)(wp + 2 * DD));
    fma4(acc, xk.w, *(const float4*)(wp + 3 * DD));
  }
  *(float4*)(h + (size_t)(nb + r) * DD + c4) = acc;
}

// per sorted edge: sim (dot), dist (norm) in fp32. 32 lanes/edge.
__global__ __launch_bounds__(256) void k_edge1(const int* __restrict__ src_s, const int* __restrict__ tgt_s,
                                               const float* __restrict__ h, float* __restrict__ sim,
                                               float* __restrict__ dist, unsigned* __restrict__ m_enc) {
  int tid = threadIdx.x;
  int wave = (blockIdx.x * 256 + tid) >> 6;
  int lane = tid & 63;
  int i = wave * 2 + (lane >> 5);
  int j = lane & 31;
  int s = src_s[i], t = tgt_s[i];
  float4 a = *(const float4*)(h + (size_t)s * DD + j * 4);
  float4 b = *(const float4*)(h + (size_t)t * DD + j * 4);
  float dot = a.x*b.x + a.y*b.y + a.z*b.z + a.w*b.w;
  float dx = a.x-b.x, dy = a.y-b.y, dz = a.z-b.z, dw = a.w-b.w;
  float sq = dx*dx + dy*dy + dz*dz + dw*dw;
#pragma unroll
  for (int off = 16; off >= 1; off >>= 1) {
    dot += __shfl_xor(dot, off, 64);
    sq  += __shfl_xor(sq,  off, 64);
  }
  if (j == 0) {
    sim[i]  = dot;                  // BETA == 1.0
    dist[i] = sqrtf(sq);
    atomicMax(m_enc + t, fenc(dot));
  }
}

// denom & alpha*dist numerator per tgt
__global__ void k_edge2(const int* __restrict__ tgt_s, const float* __restrict__ sim,
                        const float* __restrict__ dist, const unsigned* __restrict__ m_enc,
                        float* __restrict__ den, float* __restrict__ nd) {
  int i = blockIdx.x * 256 + threadIdx.x;
  if (i >= NE) return;
  int t = tgt_s[i];
  float ev = expf(sim[i] - fdec(m_enc[t]));
  atomicAdd(den + t, ev);
  atomicAdd(nd + t, ev * dist[i]);
}

__global__ void k_aggv(const float* __restrict__ den, const float* __restrict__ nd,
                       float* __restrict__ aggv) {
  int n = blockIdx.x * 256 + threadIdx.x;
  if (n >= NN) return;
  float d = den[n];
  aggv[n] = d > 0.f ? nd[n] / d : 0.f;
}

// per edge: curvature + PWL segment index (binary search over 128 sorted breakpoints)
__global__ __launch_bounds__(256) void k_curv(const int* __restrict__ tgt_s,
    const float* __restrict__ dist, const float* __restrict__ aggv,
    const float* __restrict__ bp_g, float* __restrict__ curvf, ushort* __restrict__ sege) {
  __shared__ float bp[DD];
  int tid = threadIdx.x;
  if (tid < DD) bp[tid] = bp_g[tid];
  __syncthreads();
  int i = blockIdx.x * 256 + tid;
  if (i >= NE) return;
  int t = tgt_s[i];
  float curv = 1.0f - aggv[t] / fmaxf(dist[i], 1e-6f);
  int lo = 0, hi = DD;
  while (lo < hi) { int mid = (lo + hi) >> 1; if (bp[mid] < curv) lo = mid + 1; else hi = mid; }
  curvf[i] = curv;
  sege[i] = (ushort)lo;     // segment in [0,128]
}

// LN1 + QKV projection via swapped-operand MFMA -> bf16 q/k/v. 32 rows/block, 8 waves.
__global__ __launch_bounds__(512) void k_ln_qkv(const float* __restrict__ h,
    const float* __restrict__ n1s_l, const float* __restrict__ n1b_l,
    const ushort* __restrict__ qkvT_l,
    const float* __restrict__ qb_l, const float* __restrict__ kb_l, const float* __restrict__ vb_l,
    ushort* __restrict__ q, ushort* __restrict__ kk, ushort* __restrict__ v) {
  __shared__ __align__(16) ushort xbf[32 * DD];
  int nb = blockIdx.x * 32;
  ln_tile_bf32(h, nb, n1s_l, n1b_l, xbf);
  __syncthreads();
  int lane = threadIdx.x & 63;
  int w = threadIdx.x >> 6;
  int g = lane >> 4, c = lane & 15;
  int xr = (c & 7) << 4;
  char* xb = (char*)xbf;
  BF8 a[2][4];
#pragma unroll
  for (int nt = 0; nt < 2; nt++)
#pragma unroll
    for (int kt = 0; kt < 4; kt++)
      a[nt][kt].u = *(ushort8_t*)(xb + (((nt * 16 + c) * 256 + kt * 64 + g * 16) ^ xr));
#pragma unroll
  for (int ti = 0; ti < 3; ti++) {
    int t = w * 3 + ti;                // 0..23
    int m = t >> 3;                    // 0=q 1=k 2=v
    int colb = (t & 7) * 16;
    const float* bias = (m == 0 ? qb_l : (m == 1 ? kb_l : vb_l));
    float4 bv = *(const float4*)(bias + colb + g * 4);
    f32x4_t acc0 = {bv.x, bv.y, bv.z, bv.w};
    f32x4_t acc1 = acc0;
    const ushort* wp = qkvT_l + (size_t)(m * DD + colb + c) * DD + g * 8;
#pragma unroll
    for (int kt = 0; kt < 4; kt++) {
      BF8 b; b.u = *(const ushort8_t*)(wp + kt * 32);
      acc0 = __builtin_amdgcn_mfma_f32_16x16x32_bf16(b.b, a[0][kt].b, acc0, 0, 0, 0);
      acc1 = __builtin_amdgcn_mfma_f32_16x16x32_bf16(b.b, a[1][kt].b, acc1, 0, 0, 0);
    }
    ushort* out = (m == 0 ? q : (m == 1 ? kk : v));
    int n0 = nb + c;
    if (n0 < NN) {
      ushort4 o; o.x = f2bf(acc0[0]); o.y = f2bf(acc0[1]); o.z = f2bf(acc0[2]); o.w = f2bf(acc0[3]);
      *(ushort4*)(out + (size_t)n0 * DD + colb + g * 4) = o;
    }
    int n1 = nb + 16 + c;
    if (n1 < NN) {
      ushort4 o; o.x = f2bf(acc1[0]); o.y = f2bf(acc1[1]); o.z = f2bf(acc1[2]); o.w = f2bf(acc1[3]);
      *(ushort4*)(out + (size_t)n1 * DD + colb + g * 4) = o;
    }
  }
}

// per (edge, head): qk dot (bf16) + PWL bias; atomicMax over tgt.
// NOTE: the max pass is MANDATORY — curv is unbounded (self-loop edges have
// dist==0 -> curv ~ -1e6 -> |bias| ~ 1e4), exp() overflows without it (r5/r6).
__global__ __launch_bounds__(256) void k_scores(const int* __restrict__ src_s, const int* __restrict__ tgt_s,
    const ushort* __restrict__ q, const ushort* __restrict__ k,
    const float* __restrict__ curvf, const ushort* __restrict__ sege,
    const float* __restrict__ slope_l, const float* __restrict__ inter_l,
    float* __restrict__ escore, unsigned* __restrict__ sm_enc) {
  __shared__ float lsl[NSEG * HH], lin[NSEG * HH];
  int tid = threadIdx.x;
  for (int idx = tid; idx < NSEG * HH; idx += 256) { lsl[idx] = slope_l[idx]; lin[idx] = inter_l[idx]; }
  __syncthreads();
  int gi = blockIdx.x * 256 + tid;
  if (gi >= NE * HH) return;
  int i = gi >> 3, hh = gi & 7;
  int s = src_s[i], t = tgt_s[i];
  int seg = sege[i];
  float bias = fmaf(lsl[seg * HH + hh], curvf[i], lin[seg * HH + hh]);
  const ushort8_t* qp = (const ushort8_t*)(q + (size_t)s * DD + hh * DHH);
  const ushort8_t* kp = (const ushort8_t*)(k + (size_t)t * DD + hh * DHH);
  float dot = 0.f;
#pragma unroll
  for (int ii = 0; ii < 2; ii++) {
    ushort8_t a = qp[ii], b = kp[ii];
#pragma unroll
    for (int jj = 0; jj < 8; jj++) dot = fmaf(bf2f(a[jj]), bf2f(b[jj]), dot);
  }
  float sc = dot * 0.25f + bias;   // 1/sqrt(16)
  escore[gi] = sc;
  atomicMax(sm_enc + (size_t)t * HH + hh, fenc(sc));
}

__global__ void k_probs(const int* __restrict__ tgt_s, const unsigned* __restrict__ sm_enc,
                        float* __restrict__ escore, float* __restrict__ sden) {
  int gi = blockIdx.x * 256 + threadIdx.x;
  if (gi >= NE * HH) return;
  int i = gi >> 3, hh = gi & 7;
  int t = tgt_s[i];
  float p = expf(escore[gi] - fdec(sm_enc[(size_t)t * HH + hh]));
  escore[gi] = p;
  atomicAdd(sden + (size_t)t * HH + hh, p);
}

__global__ void k_sdinv(float* __restrict__ sden) {
  int i = blockIdx.x * 256 + threadIdx.x;
  if (i >= NN * HH) return;
  float x = sden[i];
  sden[i] = x > 0.f ? 1.0f / x : 0.f;
}

// CSR-gather message aggregation: one wave per src node, 2 dims/lane -> bf16 out.
// 4-deep software-pipelined unroll: all gathers issued before use; fma order is
// ascending-i (identical to serial loop) -> bit-identical result. Round-9 profile:
// latency-bound (VALU 24%, HBM 20%) on the serial tgt->v dependent chain.
__global__ __launch_bounds__(256) void k_agg(const int* __restrict__ tgt_s,
    const int* __restrict__ rowstart,
    const float* __restrict__ escore, const float* __restrict__ sdinv,
    const ushort* __restrict__ v, ushort* __restrict__ aggmb) {
  int wave = (blockIdx.x * 256 + threadIdx.x) >> 6;
  int lane = threadIdx.x & 63;
  int rs = rowstart[wave], re = rowstart[wave + 1];
  int hh = lane >> 3;
  int d = lane * 2;
  float a0 = 0.f, a1 = 0.f;
  int i = rs;
  for (; i + 4 <= re; i += 4) {
    int t0 = tgt_s[i], t1 = tgt_s[i + 1], t2 = tgt_s[i + 2], t3 = tgt_s[i + 3];
    float e0 = escore[(i    ) * HH + hh];
    float e1 = escore[(i + 1) * HH + hh];
    float e2 = escore[(i + 2) * HH + hh];
    float e3 = escore[(i + 3) * HH + hh];
    float s0 = sdinv[t0 * HH + hh], s1 = sdinv[t1 * HH + hh];
    float s2 = sdinv[t2 * HH + hh], s3 = sdinv[t3 * HH + hh];
    ushort2 v0 = *(const ushort2*)(v + (size_t)t0 * DD + d);
    ushort2 v1 = *(const ushort2*)(v + (size_t)t1 * DD + d);
    ushort2 v2 = *(const ushort2*)(v + (size_t)t2 * DD + d);
    ushort2 v3 = *(const ushort2*)(v + (size_t)t3 * DD + d);
    float p0 = e0 * s0, p1 = e1 * s1, p2 = e2 * s2, p3 = e3 * s3;
    a0 = fmaf(p0, bf2f(v0.x), a0); a1 = fmaf(p0, bf2f(v0.y), a1);
    a0 = fmaf(p1, bf2f(v1.x), a0); a1 = fmaf(p1, bf2f(v1.y), a1);
    a0 = fmaf(p2, bf2f(v2.x), a0); a1 = fmaf(p2, bf2f(v2.y), a1);
    a0 = fmaf(p3, bf2f(v3.x), a0); a1 = fmaf(p3, bf2f(v3.y), a1);
  }
  for (; i < re; i++) {
    int t = tgt_s[i];
    float prob = escore[i * HH + hh] * sdinv[t * HH + hh];
    ushort2 vv = *(const ushort2*)(v + (size_t)t * DD + d);
    a0 = fmaf(prob, bf2f(vv.x), a0);
    a1 = fmaf(prob, bf2f(vv.y), a1);
  }
  ushort2 o; o.x = f2bf(a0); o.y = f2bf(a1);
  *(ushort2*)(aggmb + (size_t)wave * DD + d) = o;
}

// h += aggm @ oW + ob via swapped-operand MFMA; 32 rows/block, 8 waves, float4 RMW.
__global__ __launch_bounds__(512) void k_update_o(const ushort* __restrict__ aggmb,
    const ushort* __restrict__ oT_l, const float* __restrict__ ob_l, float* __restrict__ h) {
  int nb = blockIdx.x * 32;
  int lane = threadIdx.x & 63, w = threadIdx.x >> 6;
  int g = lane >> 4, c = lane & 15;
  BF8 a[2][4];
#pragma unroll
  for (int nt = 0; nt < 2; nt++) {
    int na = nb + nt * 16 + c; if (na >= NN) na = NN - 1;
    const ushort* ap = aggmb + (size_t)na * DD + g * 8;
#pragma unroll
    for (int kt = 0; kt < 4; kt++) a[nt][kt].u = *(const ushort8_t*)(ap + kt * 32);
  }
  int colb = w * 16;
  float4 bv = *(const float4*)(ob_l + colb + g * 4);
  f32x4_t acc0 = {bv.x, bv.y, bv.z, bv.w};
  f32x4_t acc1 = acc0;
  const ushort* wp = oT_l + (size_t)(colb + c) * DD + g * 8;
#pragma unroll
  for (int kt = 0; kt < 4; kt++) {
    BF8 b; b.u = *(const ushort8_t*)(wp + kt * 32);
    acc0 = __builtin_amdgcn_mfma_f32_16x16x32_bf16(b.b, a[0][kt].b, acc0, 0, 0, 0);
    acc1 = __builtin_amdgcn_mfma_f32_16x16x32_bf16(b.b, a[1][kt].b, acc1, 0, 0, 0);
  }
#pragma unroll
  for (int nt = 0; nt < 2; nt++) {
    int node = nb + nt * 16 + c;
    if (node < NN) {
      float* hp = h + (size_t)node * DD + colb + g * 4;
      float4 hv = *(const float4*)hp;
      f32x4_t& acc = nt ? acc1 : acc0;
      hv.x += acc[0]; hv.y += acc[1]; hv.z += acc[2]; hv.w += acc[3];
      *(float4*)hp = hv;
    }
  }
}

// fused FFN, BM=64: h += relu(LN2(h)@f1W+f1b)@f2W+f2b; 64 rows/block, 8 waves.
__global__ __launch_bounds__(512) void k_ffn(const float* __restrict__ n2s_l, const float* __restrict__ n2b_l,
    const ushort* __restrict__ f1T_l, const float* __restrict__ f1b_l,
    const ushort* __restrict__ f2T_l, const float* __restrict__ f2b_l,
    float* __restrict__ h) {
  __shared__ __align__(16) ushort xbf[64 * DD];      // 16 KB
  __shared__ __align__(16) ushort tbf[64 * 256];     // 32 KB
  int nb = blockIdx.x * 64;
  ln_tile_bf64(h, nb, n2s_l, n2b_l, xbf);
  __syncthreads();
  int lane = threadIdx.x & 63, w = threadIdx.x >> 6;
  int g = lane >> 4, c = lane & 15;
  int xr = (c & 7) << 4;
  char* xb = (char*)xbf;
  char* tb = (char*)tbf;
  BF8 a[4][4];
#pragma unroll
  for (int nt = 0; nt < 4; nt++)
#pragma unroll
    for (int kt = 0; kt < 4; kt++)
      a[nt][kt].u = *(ushort8_t*)(xb + (((nt * 16 + c) * 256 + kt * 64 + g * 16) ^ xr));
  int colb2 = w * 16;
  float4 bv2 = *(const float4*)(f2b_l + colb2 + g * 4);
  f32x4_t o0 = {bv2.x, bv2.y, bv2.z, bv2.w};
  f32x4_t o1 = o0, o2 = o0, o3 = o0;
#pragma unroll
  for (int ch = 0; ch < 2; ch++) {
    if (ch) __syncthreads();           // tbf reuse: wait for chunk-0 reads
#pragma unroll
    for (int ti = 0; ti < 2; ti++) {
      int ctile = w * 2 + ti;          // 0..15 within chunk
      int col = ch * 256 + ctile * 16;
      float4 bv = *(const float4*)(f1b_l + col + g * 4);
      f32x4_t ac0 = {bv.x, bv.y, bv.z, bv.w};
      f32x4_t ac1 = ac0, ac2 = ac0, ac3 = ac0;
      const ushort* wp = f1T_l + (size_t)(col + c) * DD + g * 8;
#pragma unroll
      for (int kt = 0; kt < 4; kt++) {
        BF8 b; b.u = *(const ushort8_t*)(wp + kt * 32);
        ac0 = __builtin_amdgcn_mfma_f32_16x16x32_bf16(b.b, a[0][kt].b, ac0, 0, 0, 0);
        ac1 = __builtin_amdgcn_mfma_f32_16x16x32_bf16(b.b, a[1][kt].b, ac1, 0, 0, 0);
        ac2 = __builtin_amdgcn_mfma_f32_16x16x32_bf16(b.b, a[2][kt].b, ac2, 0, 0, 0);
        ac3 = __builtin_amdgcn_mfma_f32_16x16x32_bf16(b.b, a[3][kt].b, ac3, 0, 0, 0);
      }
      int colL = (ctile * 16 + g * 4) * 2;     // byte col within chunk tile
      {
        int row = c;
        ushort4 o4; o4.x = f2bf(fmaxf(ac0[0], 0.f)); o4.y = f2bf(fmaxf(ac0[1], 0.f));
        o4.z = f2bf(fmaxf(ac0[2], 0.f)); o4.w = f2bf(fmaxf(ac0[3], 0.f));
        *(ushort4*)(tb + ((row * 512 + colL) ^ ((row & 7) << 4))) = o4;
      }
      {
        int row = 16 + c;
        ushort4 o4; o4.x = f2bf(fmaxf(ac1[0], 0.f)); o4.y = f2bf(fmaxf(ac1[1], 0.f));
        o4.z = f2bf(fmaxf(ac1[2], 0.f)); o4.w = f2bf(fmaxf(ac1[3], 0.f));
        *(ushort4*)(tb + ((row * 512 + colL) ^ ((row & 7) << 4))) = o4;
      }
      {
        int row = 32 + c;
        ushort4 o4; o4.x = f2bf(fmaxf(ac2[0], 0.f)); o4.y = f2bf(fmaxf(ac2[1], 0.f));
        o4.z = f2bf(fmaxf(ac2[2], 0.f)); o4.w = f2bf(fmaxf(ac2[3], 0.f));
        *(ushort4*)(tb + ((row * 512 + colL) ^ ((row & 7) << 4))) = o4;
      }
      {
        int row = 48 + c;
        ushort4 o4; o4.x = f2bf(fmaxf(ac3[0], 0.f)); o4.y = f2bf(fmaxf(ac3[1], 0.f));
        o4.z = f2bf(fmaxf(ac3[2], 0.f)); o4.w = f2bf(fmaxf(ac3[3], 0.f));
        *(ushort4*)(tb + ((row * 512 + colL) ^ ((row & 7) << 4))) = o4;
      }
    }
    __syncthreads();
    const ushort* wp2 = f2T_l + (size_t)(colb2 + c) * 512 + ch * 256 + g * 8;
#pragma unroll
    for (int kt = 0; kt < 8; kt++) {
      BF8 b; b.u = *(const ushort8_t*)(wp2 + kt * 32);
      BF8 t0; t0.u = *(ushort8_t*)(tb + (((c) * 512 + kt * 64 + g * 16) ^ xr));
      BF8 t1; t1.u = *(ushort8_t*)(tb + (((16 + c) * 512 + kt * 64 + g * 16) ^ xr));
      BF8 t2; t2.u = *(ushort8_t*)(tb + (((32 + c) * 512 + kt * 64 + g * 16) ^ xr));
      BF8 t3; t3.u = *(ushort8_t*)(tb + (((48 + c) * 512 + kt * 64 + g * 16) ^ xr));
      o0 = __builtin_amdgcn_mfma_f32_16x16x32_bf16(b.b, t0.b, o0, 0, 0, 0);
      o1 = __builtin_amdgcn_mfma_f32_16x16x32_bf16(b.b, t1.b, o1, 0, 0, 0);
      o2 = __builtin_amdgcn_mfma_f32_16x16x32_bf16(b.b, t2.b, o2, 0, 0, 0);
      o3 = __builtin_amdgcn_mfma_f32_16x16x32_bf16(b.b, t3.b, o3, 0, 0, 0);
    }
  }
  {
    int node = nb + c;
    if (node < NN) {
      float* hp = h + (size_t)node * DD + colb2 + g * 4;
      float4 hv = *(const float4*)hp;
      hv.x += o0[0]; hv.y += o0[1]; hv.z += o0[2]; hv.w += o0[3];
      *(float4*)hp = hv;
    }
  }
  {
    int node = nb + 16 + c;
    if (node < NN) {
      float* hp = h + (size_t)node * DD + colb2 + g * 4;
      float4 hv = *(const float4*)hp;
      hv.x += o1[0]; hv.y += o1[1]; hv.z += o1[2]; hv.w += o1[3];
      *(float4*)hp = hv;
    }
  }
  {
    int node = nb + 32 + c;
    if (node < NN) {
      float* hp = h + (size_t)node * DD + colb2 + g * 4;
      float4 hv = *(const float4*)hp;
      hv.x += o2[0]; hv.y += o2[1]; hv.z += o2[2]; hv.w += o2[3];
      *(float4*)hp = hv;
    }
  }
  {
    int node = nb + 48 + c;
    if (node < NN) {
      float* hp = h + (size_t)node * DD + colb2 + g * 4;
      float4 hv = *(const float4*)hp;
      hv.x += o3[0]; hv.y += o3[1]; hv.z += o3[2]; hv.w += o3[3];
      *(float4*)hp = hv;
    }
  }
}

// ---------- once-per-call setup kernels ----------
// transpose fp32 [K][C] -> bf16 [C][K], nm stacked matrices, dst stride per matrix
template <int K, int C>
__global__ void k_wt(const float* __restrict__ W, ushort* __restrict__ WT, int nm, int dstride) {
  int idx = blockIdx.x * 256 + threadIdx.x;
  if (idx >= K * C * nm) return;
  int mi = idx / (K * C), rem = idx - mi * (K * C);
  int cc = rem / K, kk2 = rem - cc * K;
  WT[(size_t)mi * dstride + cc * K + kk2] = f2bf(W[(size_t)mi * K * C + (size_t)kk2 * C + cc]);
}

__global__ void k_hist(const int* __restrict__ src, int* __restrict__ cnt) {
  int e = blockIdx.x * 256 + threadIdx.x;
  if (e < NE) atomicAdd(cnt + src[e], 1);
}

// multi-block exclusive scan of cnt[NN] -> rowstart
__global__ __launch_bounds__(256) void k_scan_blk(const int* __restrict__ cnt, int* __restrict__ bsum) {
  __shared__ int red[256];
  int tid = threadIdx.x;
  int idx = blockIdx.x * 256 + tid;
  red[tid] = (idx < NN) ? cnt[idx] : 0;
  __syncthreads();
  for (int off = 128; off >= 1; off >>= 1) {
    if (tid < off) red[tid] += red[tid + off];
    __syncthreads();
  }
  if (tid == 0) bsum[blockIdx.x] = red[0];
}

__global__ __launch_bounds__(256) void k_scan_top(const int* __restrict__ bsum,
                                                  int* __restrict__ boff, int* __restrict__ rowstart) {
  __shared__ int ps[256];
  int t = threadIdx.x;
  int v = (t < NBS) ? bsum[t] : 0;
  ps[t] = v;
  __syncthreads();
  for (int off = 1; off < 256; off <<= 1) {
    int x = (t >= off) ? ps[t - off] : 0;
    __syncthreads();
    ps[t] += x;
    __syncthreads();
  }
  boff[t] = ps[t] - v;                 // exclusive prefix of block sums
  if (t == 255) rowstart[NN] = ps[255];
}

__global__ __launch_bounds__(256) void k_scan_fin(const int* __restrict__ cnt,
                                                  const int* __restrict__ boff, int* __restrict__ rowstart) {
  __shared__ int ps[256];
  int t = threadIdx.x;
  int idx = blockIdx.x * 256 + t;
  int v = (idx < NN) ? cnt[idx] : 0;
  ps[t] = v;
  __syncthreads();
  for (int off = 1; off < 256; off <<= 1) {
    int x = (t >= off) ? ps[t - off] : 0;
    __syncthreads();
    ps[t] += x;
    __syncthreads();
  }
  if (idx < NN) rowstart[idx] = boff[blockIdx.x] + ps[t] - v;
}

// scatter edges into src-sorted order (all per-edge arrays use sorted index)
__global__ void k_fill(const int* __restrict__ src, const int* __restrict__ tgt,
                       const int* __restrict__ rowstart,
                       int* __restrict__ cur, int* __restrict__ src_s, int* __restrict__ tgt_s) {
  int e = blockIdx.x * 256 + threadIdx.x;
  if (e >= NE) return;
  int s = src[e];
  int p = atomicAdd(cur + s, 1);
  int pos = rowstart[s] + p;
  src_s[pos] = s;
  tgt_s[pos] = tgt[e];
}

// M[l][d][hh] = Sum_k cW2[d][k]*bW[l][k][hh]. Wave-parallel: one block per (l,d).
__global__ __launch_bounds__(64) void k_mbias_par(const float* __restrict__ cW2, const float* __restrict__ cb2,
                                                  const float* __restrict__ bW, const float* __restrict__ bb,
                                                  float* __restrict__ M, float* __restrict__ base) {
  int bid = blockIdx.x;
  int l = bid >> 7, d = bid & 127;
  int lane = threadIdx.x;
  int hh = lane >> 3, j0 = lane & 7;
  const float* bWl = bW + (size_t)l * DD * HH;
  float acc = 0.f;
#pragma unroll
  for (int t = 0; t < 16; t++) {
    int k = j0 + t * 8;
    acc = fmaf(cW2[d * DD + k], bWl[k * HH + hh], acc);
  }
#pragma unroll
  for (int off = 1; off <= 4; off <<= 1) acc += __shfl_xor(acc, off, 64);
  if (j0 == 0) M[(size_t)l * DD * HH + d * HH + hh] = acc;
  if (d == 0) {
    float bacc = 0.f;
#pragma unroll
    for (int t = 0; t < 16; t++) {
      int k = j0 + t * 8;
      bacc = fmaf(cb2[k], bWl[k * HH + hh], bacc);
    }
#pragma unroll
    for (int off = 1; off <= 4; off <<= 1) bacc += __shfl_xor(bacc, off, 64);
    if (j0 == 0) base[l * HH + hh] = bacc + bb[l * HH + hh];
  }
}

// sorted breakpoints + ranks — cW1/cb1 are layer-INDEPENDENT, computed once.
__global__ __launch_bounds__(128) void k_bp(const float* __restrict__ cW1, const float* __restrict__ cb1,
                                            float* __restrict__ bpg, int* __restrict__ posg) {
  __shared__ float x[DD], bp[DD];
  int tid = threadIdx.x;
  float c1v = cW1[tid], cbv = cb1[tid];
  x[tid] = (c1v == 0.f) ? __builtin_inff() : (-cbv / c1v);
  __syncthreads();
  float xv = x[tid]; int p = 0;
  for (int j = 0; j < DD; j++) {
    float xj = x[j];
    if (xj < xv || (xj == xv && j < tid)) p++;
  }
  bp[p] = xv;
  posg[tid] = p;
  __syncthreads();
  bpg[tid] = bp[tid];
}

// PWL table, wave-parallel: one block per (l, segment).
__global__ __launch_bounds__(64) void k_pwl_tab(const float* __restrict__ cW1, const float* __restrict__ cb1,
    const int* __restrict__ posg, const float* __restrict__ Mb, const float* __restrict__ basel,
    float* __restrict__ slopeg, float* __restrict__ interg) {
  int bid = blockIdx.x;
  int l = bid / NSEG, s = bid - l * NSEG;
  int lane = threadIdx.x;
  int hh = lane >> 3, j0 = lane & 7;
  const float* M = Mb + (size_t)l * DD * HH;
  float sl = 0.f, in = 0.f;
#pragma unroll
  for (int t = 0; t < 16; t++) {
    int d = j0 + t * 8;
    float cv = cW1[d], cbv = cb1[d];
    int p = posg[d];
    bool act = (cv == 0.f) ? (cbv > 0.f) : ((cv > 0.f) ? (p < s) : (p >= s));
    float m = act ? M[d * HH + hh] : 0.f;
    sl = fmaf(cv, m, sl);
    in = fmaf(cbv, m, in);
  }
#pragma unroll
  for (int off = 1; off <= 4; off <<= 1) {
    sl += __shfl_xor(sl, off, 64);
    in += __shfl_xor(in, off, 64);
  }
  if (j0 == 0) {
    size_t o = (size_t)l * NSEG * HH + s * HH + hh;
    slopeg[o] = sl;
    interg[o] = in + basel[l * HH + hh];
  }
}

__global__ void k_bounds(const int* __restrict__ batch, int* __restrict__ gstart, int* __restrict__ gend) {
  int n = blockIdx.x * 256 + threadIdx.x;
  if (n >= NN) return;
  int b = batch[n];
  if (n == 0 || batch[n - 1] != b) gstart[b] = n;
  if (n == NN - 1 || batch[n + 1] != b) gend[b] = n + 1;
}

// parallel pool: 256 nodes/block, running sums flushed at graph boundaries
__global__ __launch_bounds__(256) void k_pool_part(const float* __restrict__ h,
    const int* __restrict__ batch, float* __restrict__ gpool) {
  int tid = threadIdx.x;
  int d = tid & 127, sub = tid >> 7;
  int n0 = blockIdx.x * 256;
  int nend = n0 + 256; if (nend > NN) nend = NN;
  float run = 0.f; int gcur = -1;
  for (int n = n0 + sub; n < nend; n += 2) {
    int g = batch[n];
    if (g != gcur) {
      if (gcur >= 0) atomicAdd(gpool + (size_t)gcur * DD + d, run);
      run = 0.f; gcur = g;
    }
    run += h[(size_t)n * DD + d];
  }
  if (gcur >= 0) atomicAdd(gpool + (size_t)gcur * DD + d, run);
}

__global__ __launch_bounds__(256) void k_head(const float* __restrict__ gpool,
    const int* __restrict__ gstart, const int* __restrict__ gend,
    const float* __restrict__ W1, const float* __restrict__ b1,
    const float* __restrict__ W2, const float* __restrict__ b2, float* __restrict__ out) {
  __shared__ float mid[NG * 64];
  int tid = threadIdx.x;
  for (int idx = tid; idx < NG * 64; idx += 256) {
    int g = idx >> 6, j = idx & 63;
    int cnt = gend[g] - gstart[g]; if (cnt < 1) cnt = 1;
    float rc = 1.0f / (float)cnt;
    float acc = 0.f;
    for (int d = 0; d < DD; d++) acc = fmaf(gpool[g * DD + d], W1[d * 64 + j], acc);
    mid[idx] = fmaxf(fmaf(acc, rc, b1[j]), 0.f);
  }
  __syncthreads();
  if (tid < NG) {
    float acc = b2[0];
    for (int j = 0; j < 64; j++) acc = fmaf(mid[tid * 64 + j], W2[j], acc);
    out[tid] = acc;
  }
}

// ---------- launch ----------
extern "C" void kernel_launch(void* const* d_in, const int* in_sizes, int n_in,
                              void* d_out, int out_size, void* d_ws, size_t ws_size,
                              hipStream_t stream) {
  const float* x      = (const float*)d_in[0];
  const int*   ei     = (const int*)d_in[1];
  const int*   batch  = (const int*)d_in[2];
  const float* node_W = (const float*)d_in[3];
  const float* node_b = (const float*)d_in[4];
  const float* cW1    = (const float*)d_in[5];
  const float* cb1    = (const float*)d_in[6];
  const float* cW2    = (const float*)d_in[7];
  const float* cb2    = (const float*)d_in[8];
  const float* qW     = (const float*)d_in[9];
  const float* qb     = (const float*)d_in[10];
  const float* kW     = (const float*)d_in[11];
  const float* kb     = (const float*)d_in[12];
  const float* vW     = (const float*)d_in[13];
  const float* vb     = (const float*)d_in[14];
  const float* oW     = (const float*)d_in[15];
  const float* ob     = (const float*)d_in[16];
  const float* bW     = (const float*)d_in[17];
  const float* bb     = (const float*)d_in[18];
  const float* f1W    = (const float*)d_in[19];
  const float* f1b    = (const float*)d_in[20];
  const float* f2W    = (const float*)d_in[21];
  const float* f2b    = (const float*)d_in[22];
  const float* n1s    = (const float*)d_in[23];
  const float* n1b    = (const float*)d_in[24];
  const float* n2s    = (const float*)d_in[25];
  const float* n2b    = (const float*)d_in[26];
  const float* outW1  = (const float*)d_in[27];
  const float* outb1  = (const float*)d_in[28];
  const float* outW2  = (const float*)d_in[29];
  const float* outb2  = (const float*)d_in[30];

  const int* src = ei;
  const int* tgt = ei + NE;

  char* wp = (char*)d_ws;
  auto alloc = [&](size_t bytes) { void* p = (void*)wp; wp += (bytes + 255) & ~(size_t)255; return p; };
  float*    h       = (float*)alloc((size_t)NN * DD * 4);
  ushort*   q       = (ushort*)alloc((size_t)NN * DD * 2);
  ushort*   kk      = (ushort*)alloc((size_t)NN * DD * 2);
  ushort*   v       = (ushort*)alloc((size_t)NN * DD * 2);
  ushort*   aggmb   = (ushort*)alloc((size_t)NN * DD * 2);
  float*    sim     = (float*)alloc((size_t)NE * 4);
  float*    dist    = (float*)alloc((size_t)NE * 4);
  float*    escore  = (float*)alloc((size_t)NE * HH * 4);
  float*    curvf   = (float*)alloc((size_t)NE * 4);
  ushort*   sege    = (ushort*)alloc((size_t)NE * 2);
  char*     zbase   = wp;                         // zeroed once per layer:
  unsigned* m_enc   = (unsigned*)alloc((size_t)NN * 4);
  float*    den     = (float*)alloc((size_t)NN * 4);
  float*    nd      = (float*)alloc((size_t)NN * 4);
  unsigned* sm_enc  = (unsigned*)alloc((size_t)NN * HH * 4);
  float*    sden    = (float*)alloc((size_t)NN * HH * 4);
  size_t    zbytes  = (size_t)(wp - zbase);
  float*    aggv    = (float*)alloc((size_t)NN * 4);
  float*    Mb      = (float*)alloc((size_t)NL * DD * HH * 4);
  float*    basel   = (float*)alloc((size_t)NL * HH * 4);
  float*    bpg     = (float*)alloc((size_t)DD * 4);
  int*      posg    = (int*)alloc((size_t)DD * 4);
  float*    slopeg  = (float*)alloc((size_t)NL * NSEG * HH * 4);
  float*    interg  = (float*)alloc((size_t)NL * NSEG * HH * 4);
  int*      rowstart= (int*)alloc((size_t)(NN + 1) * 4);
  int*      src_s   = (int*)alloc((size_t)NE * 4);
  int*      tgt_s   = (int*)alloc((size_t)NE * 4);
  int*      cnt     = (int*)alloc((size_t)NN * 4);
  int*      cur     = (int*)alloc((size_t)NN * 4);
  int*      bsum    = (int*)alloc((size_t)NBS * 4);
  int*      boff    = (int*)alloc((size_t)256 * 4);
  int*      gstart  = (int*)alloc((size_t)NG * 4);
  int*      gend    = (int*)alloc((size_t)NG * 4);
  float*    gpool   = (float*)alloc((size_t)NG * DD * 4);
  ushort*   qkvT    = (ushort*)alloc((size_t)NL * 3 * DD * DD * 2);
  ushort*   oT      = (ushort*)alloc((size_t)NL * DD * DD * 2);
  ushort*   f1T     = (ushort*)alloc((size_t)NL * DD * 512 * 2);
  ushort*   f2T     = (ushort*)alloc((size_t)NL * 512 * DD * 2);
  (void)in_sizes; (void)n_in; (void)out_size; (void)ws_size;

  // once-per-call setup
  hipMemsetAsync(cnt, 0, NN * 4, stream);
  hipMemsetAsync(cur, 0, NN * 4, stream);
  hipMemsetAsync(gstart, 0, NG * 4, stream);
  hipMemsetAsync(gend, 0, NG * 4, stream);
  hipMemsetAsync(gpool, 0, NG * DD * 4, stream);
  k_hist<<<(NE + 255) / 256, 256, 0, stream>>>(src, cnt);
  k_scan_blk<<<NBS, 256, 0, stream>>>(cnt, bsum);
  k_scan_top<<<1, 256, 0, stream>>>(bsum, boff, rowstart);
  k_scan_fin<<<NBS, 256, 0, stream>>>(cnt, boff, rowstart);
  k_fill<<<(NE + 255) / 256, 256, 0, stream>>>(src, tgt, rowstart, cur, src_s, tgt_s);
  k_mbias_par<<<NL * DD, 64, 0, stream>>>(cW2, cb2, bW, bb, Mb, basel);
  k_bp<<<1, 128, 0, stream>>>(cW1, cb1, bpg, posg);
  k_pwl_tab<<<NL * NSEG, 64, 0, stream>>>(cW1, cb1, posg, Mb, basel, slopeg, interg);
  k_bounds<<<(NN + 255) / 256, 256, 0, stream>>>(batch, gstart, gend);
  // bf16-transposed weights
  k_wt<DD, DD><<<(NL * DD * DD + 255) / 256, 256, 0, stream>>>(qW, qkvT,               NL, 3 * DD * DD);
  k_wt<DD, DD><<<(NL * DD * DD + 255) / 256, 256, 0, stream>>>(kW, qkvT + DD * DD,     NL, 3 * DD * DD);
  k_wt<DD, DD><<<(NL * DD * DD + 255) / 256, 256, 0, stream>>>(vW, qkvT + 2 * DD * DD, NL, 3 * DD * DD);
  k_wt<DD, DD><<<(NL * DD * DD + 255) / 256, 256, 0, stream>>>(oW, oT, NL, DD * DD);
  k_wt<DD, 512><<<(NL * DD * 512 + 255) / 256, 256, 0, stream>>>(f1W, f1T, NL, DD * 512);
  k_wt<512, DD><<<(NL * DD * 512 + 255) / 256, 256, 0, stream>>>(f2W, f2T, NL, DD * 512);
  k_node_proj<<<NN / 8, 256, 0, stream>>>(x, node_W, node_b, h);

  for (int l = 0; l < NL; l++) {
    hipMemsetAsync(zbase, 0, zbytes, stream);
    k_edge1<<<NE / 8, 256, 0, stream>>>(src_s, tgt_s, h, sim, dist, m_enc);
    k_edge2<<<(NE + 255) / 256, 256, 0, stream>>>(tgt_s, sim, dist, m_enc, den, nd);
    k_aggv<<<(NN + 255) / 256, 256, 0, stream>>>(den, nd, aggv);
    k_curv<<<(NE + 255) / 256, 256, 0, stream>>>(tgt_s, dist, aggv, bpg, curvf, sege);
    k_ln_qkv<<<NT32, 512, 0, stream>>>(h, n1s + l * DD, n1b + l * DD,
        qkvT + (size_t)l * 3 * DD * DD,
        qb + l * DD, kb + l * DD, vb + l * DD, q, kk, v);
    k_scores<<<(NE * HH + 255) / 256, 256, 0, stream>>>(src_s, tgt_s, q, kk,
        curvf, sege, slopeg + (size_t)l * NSEG * HH, interg + (size_t)l * NSEG * HH,
        escore, sm_enc);
    k_probs<<<(NE * HH + 255) / 256, 256, 0, stream>>>(tgt_s, sm_enc, escore, sden);
    k_sdinv<<<(NN * HH + 255) / 256, 256, 0, stream>>>(sden);
    k_agg<<<NN / 4, 256, 0, stream>>>(tgt_s, rowstart, escore, sden, v, aggmb);
    k_update_o<<<NT32, 512, 0, stream>>>(aggmb, oT + (size_t)l * DD * DD, ob + l * DD, h);
    k_ffn<<<NT64, 512, 0, stream>>>(n2s + l * DD, n2b + l * DD,
        f1T + (size_t)l * DD * 512, f1b + (size_t)l * 4 * DD,
        f2T + (size_t)l * 512 * DD, f2b + l * DD, h);
  }
  k_pool_part<<<(NN + 255) / 256, 256, 0, stream>>>(h, batch, gpool);
  k_head<<<1, 256, 0, stream>>>(gpool, gstart, gend, outW1, outb1, outW2, outb2, (float*)d_out);
}

// Round 11
// 1664.236 us; speedup vs baseline: 2.6151x; 1.0264x over previous
//
#include <hip/hip_runtime.h>

#define NN 50000      // nodes
#define NE 625000     // edges
#define DD 128        // hidden dim
#define HH 8          // heads
#define DHH 16        // head dim
#define NL 4          // layers
#define FIN 64        // in channels
#define NG 64         // graphs
#define LN_EPS 1e-5f
#define NSEG 129      // PWL segments = 128 breakpoints + 1
#define NT32 1563     // ceil(NN/32)
#define NT64 782      // ceil(NN/64)
#define NBS 196       // ceil(NN/256) scan blocks

typedef __bf16 bf16x8_t __attribute__((ext_vector_type(8)));
typedef unsigned short ushort8_t __attribute__((ext_vector_type(8)));
typedef float f32x4_t __attribute__((ext_vector_type(4)));
union BF8 { ushort8_t u; bf16x8_t b; };

// ---------- helpers ----------
__device__ __forceinline__ unsigned fenc(float f) {
  unsigned u = __float_as_uint(f);
  return (u & 0x80000000u) ? ~u : (u | 0x80000000u);   // monotonic float->uint
}
__device__ __forceinline__ float fdec(unsigned u) {
  return __uint_as_float((u & 0x80000000u) ? (u & 0x7FFFFFFFu) : ~u);
}
__device__ __forceinline__ void fma4(float4& a, float s, float4 w) {
  a.x = fmaf(s, w.x, a.x); a.y = fmaf(s, w.y, a.y);
  a.z = fmaf(s, w.z, a.z); a.w = fmaf(s, w.w, a.w);
}
__device__ __forceinline__ unsigned short f2bf(float f) {   // RNE f32->bf16
  unsigned u = __float_as_uint(f);
  unsigned r = ((u >> 16) & 1u) + 0x7FFFu;
  return (unsigned short)((u + r) >> 16);
}
__device__ __forceinline__ float bf2f(unsigned short u) {
  return __uint_as_float((unsigned)u << 16);
}

// LayerNorm 32 nodes -> swizzled bf16 LDS tile [32][128]; block = 512 threads.
__device__ __forceinline__ void ln_tile_bf32(const float* __restrict__ h, int nb,
                                             const float* __restrict__ sc,
                                             const float* __restrict__ bi,
                                             ushort* xbf) {
  int tid = threadIdx.x;
  int r = tid >> 4, l16 = tid & 15;
  int nr = nb + r; if (nr >= NN) nr = NN - 1;   // clamp: tail rows unused
  const float* hp = h + (size_t)nr * DD + l16 * 8;
  float4 a0 = *(const float4*)hp;
  float4 a1 = *(const float4*)(hp + 4);
  float sum = a0.x + a0.y + a0.z + a0.w + a1.x + a1.y + a1.z + a1.w;
  float sq  = a0.x*a0.x + a0.y*a0.y + a0.z*a0.z + a0.w*a0.w
            + a1.x*a1.x + a1.y*a1.y + a1.z*a1.z + a1.w*a1.w;
#pragma unroll
  for (int off = 8; off >= 1; off >>= 1) {
    sum += __shfl_xor(sum, off, 64);
    sq  += __shfl_xor(sq,  off, 64);
  }
  float mu   = sum * (1.0f / DD);
  float var  = sq * (1.0f / DD) - mu * mu;
  float rstd = rsqrtf(var + LN_EPS);
  int d0 = l16 * 8;
  float4 s0 = *(const float4*)(sc + d0), s1 = *(const float4*)(sc + d0 + 4);
  float4 b0 = *(const float4*)(bi + d0), b1 = *(const float4*)(bi + d0 + 4);
  ushort8_t u;
  u[0] = f2bf((a0.x - mu) * rstd * s0.x + b0.x);
  u[1] = f2bf((a0.y - mu) * rstd * s0.y + b0.y);
  u[2] = f2bf((a0.z - mu) * rstd * s0.z + b0.z);
  u[3] = f2bf((a0.w - mu) * rstd * s0.w + b0.w);
  u[4] = f2bf((a1.x - mu) * rstd * s1.x + b1.x);
  u[5] = f2bf((a1.y - mu) * rstd * s1.y + b1.y);
  u[6] = f2bf((a1.z - mu) * rstd * s1.z + b1.z);
  u[7] = f2bf((a1.w - mu) * rstd * s1.w + b1.w);
  int off = (r * 256 + l16 * 16) ^ ((r & 7) << 4);
  *(ushort8_t*)((char*)xbf + off) = u;
}

// LayerNorm 64 nodes (2 passes of 32) -> swizzled bf16 LDS tile [64][128]; 512 threads.
__device__ __forceinline__ void ln_tile_bf64(const float* __restrict__ h, int nb,
                                             const float* __restrict__ sc,
                                             const float* __restrict__ bi,
                                             ushort* xbf) {
  int tid = threadIdx.x;
  int l16 = tid & 15;
  int d0 = l16 * 8;
  float4 s0 = *(const float4*)(sc + d0), s1 = *(const float4*)(sc + d0 + 4);
  float4 b0 = *(const float4*)(bi + d0), b1 = *(const float4*)(bi + d0 + 4);
#pragma unroll
  for (int p = 0; p < 2; p++) {
    int r = p * 32 + (tid >> 4);
    int nr = nb + r; if (nr >= NN) nr = NN - 1;
    const float* hp = h + (size_t)nr * DD + d0;
    float4 a0 = *(const float4*)hp;
    float4 a1 = *(const float4*)(hp + 4);
    float sum = a0.x + a0.y + a0.z + a0.w + a1.x + a1.y + a1.z + a1.w;
    float sq  = a0.x*a0.x + a0.y*a0.y + a0.z*a0.z + a0.w*a0.w
              + a1.x*a1.x + a1.y*a1.y + a1.z*a1.z + a1.w*a1.w;
#pragma unroll
    for (int off = 8; off >= 1; off >>= 1) {
      sum += __shfl_xor(sum, off, 64);
      sq  += __shfl_xor(sq,  off, 64);
    }
    float mu   = sum * (1.0f / DD);
    float var  = sq * (1.0f / DD) - mu * mu;
    float rstd = rsqrtf(var + LN_EPS);
    ushort8_t u;
    u[0] = f2bf((a0.x - mu) * rstd * s0.x + b0.x);
    u[1] = f2bf((a0.y - mu) * rstd * s0.y + b0.y);
    u[2] = f2bf((a0.z - mu) * rstd * s0.z + b0.z);
    u[3] = f2bf((a0.w - mu) * rstd * s0.w + b0.w);
    u[4] = f2bf((a1.x - mu) * rstd * s1.x + b1.x);
    u[5] = f2bf((a1.y - mu) * rstd * s1.y + b1.y);
    u[6] = f2bf((a1.z - mu) * rstd * s1.z + b1.z);
    u[7] = f2bf((a1.w - mu) * rstd * s1.w + b1.w);
    int off = (r * 256 + l16 * 16) ^ ((r & 7) << 4);
    *(ushort8_t*)((char*)xbf + off) = u;
  }
}

// ---------- kernels ----------
// h = x @ node_W + node_b ; 8 nodes/block (fp32 VALU — minor cost)
__global__ __launch_bounds__(256) void k_node_proj(const float* __restrict__ x,
                                                   const float* __restrict__ W,
                                                   const float* __restrict__ b,
                                                   float* __restrict__ h) {
  __shared__ float xt[8][FIN];
  int tid = threadIdx.x;
  int nb = blockIdx.x * 8;
  {
    int idx = tid * 2;
    *(float2*)&xt[idx >> 6][idx & 63] = *(const float2*)(x + (size_t)nb * FIN + idx);
  }
  __syncthreads();
  int c4 = (tid & 31) * 4;
  int r  = tid >> 5;
  float4 acc = *(const float4*)(b + c4);
  for (int k = 0; k < FIN; k += 4) {
    float4 xk = *(const float4*)&xt[r][k];
    const float* wp = W + (size_t)k * DD + c4;
    fma4(acc, xk.x, *(const float4*)wp);
    fma4(acc, xk.y, *(const float4*)(wp + DD));
    fma4(acc, xk.z, *(const float4*)(wp + 2 * DD));
    fma4(acc, xk.w, *(const float4*)(wp + 3 * DD));
  }
  *(float4*)(h + (size_t)(nb + r) * DD + c4) = acc;
}

// per sorted edge: sim (dot), dist (norm) in fp32. 16 lanes/edge, 32B/lane/row —
// halves the shuffle-reduce depth vs 32-lane version (round-10: VALUBusy 60%,
// reduce tree was ~60% of per-edge VALU ops). fp32 reassoc only (~1e-6 rel).
__global__ __launch_bounds__(256) void k_edge1(const int* __restrict__ src_s, const int* __restrict__ tgt_s,
                                               const float* __restrict__ h, float* __restrict__ sim,
                                               float* __restrict__ dist, unsigned* __restrict__ m_enc) {
  int gid = blockIdx.x * 256 + threadIdx.x;
  int e = gid >> 4;
  if (e >= NE) return;
  int j = gid & 15;
  int s = src_s[e], t = tgt_s[e];
  const float4* ap = (const float4*)(h + (size_t)s * DD + j * 8);
  const float4* bp = (const float4*)(h + (size_t)t * DD + j * 8);
  float4 a0 = ap[0], a1 = ap[1];
  float4 b0 = bp[0], b1 = bp[1];
  float dot = 0.f, sq = 0.f;
  dot = fmaf(a0.x, b0.x, dot); dot = fmaf(a0.y, b0.y, dot);
  dot = fmaf(a0.z, b0.z, dot); dot = fmaf(a0.w, b0.w, dot);
  dot = fmaf(a1.x, b1.x, dot); dot = fmaf(a1.y, b1.y, dot);
  dot = fmaf(a1.z, b1.z, dot); dot = fmaf(a1.w, b1.w, dot);
  float d0 = a0.x - b0.x, d1 = a0.y - b0.y, d2 = a0.z - b0.z, d3 = a0.w - b0.w;
  float d4 = a1.x - b1.x, d5 = a1.y - b1.y, d6 = a1.z - b1.z, d7 = a1.w - b1.w;
  sq = fmaf(d0, d0, sq); sq = fmaf(d1, d1, sq); sq = fmaf(d2, d2, sq); sq = fmaf(d3, d3, sq);
  sq = fmaf(d4, d4, sq); sq = fmaf(d5, d5, sq); sq = fmaf(d6, d6, sq); sq = fmaf(d7, d7, sq);
#pragma unroll
  for (int off = 8; off >= 1; off >>= 1) {
    dot += __shfl_xor(dot, off, 64);
    sq  += __shfl_xor(sq,  off, 64);
  }
  if (j == 0) {
    sim[e]  = dot;                  // BETA == 1.0
    dist[e] = sqrtf(sq);
    atomicMax(m_enc + t, fenc(dot));
  }
}

// denom & alpha*dist numerator per tgt
__global__ void k_edge2(const int* __restrict__ tgt_s, const float* __restrict__ sim,
                        const float* __restrict__ dist, const unsigned* __restrict__ m_enc,
                        float* __restrict__ den, float* __restrict__ nd) {
  int i = blockIdx.x * 256 + threadIdx.x;
  if (i >= NE) return;
  int t = tgt_s[i];
  float ev = expf(sim[i] - fdec(m_enc[t]));
  atomicAdd(den + t, ev);
  atomicAdd(nd + t, ev * dist[i]);
}

__global__ void k_aggv(const float* __restrict__ den, const float* __restrict__ nd,
                       float* __restrict__ aggv) {
  int n = blockIdx.x * 256 + threadIdx.x;
  if (n >= NN) return;
  float d = den[n];
  aggv[n] = d > 0.f ? nd[n] / d : 0.f;
}

// LN1 + QKV projection via swapped-operand MFMA -> bf16 q/k/v. 32 rows/block, 8 waves.
__global__ __launch_bounds__(512) void k_ln_qkv(const float* __restrict__ h,
    const float* __restrict__ n1s_l, const float* __restrict__ n1b_l,
    const ushort* __restrict__ qkvT_l,
    const float* __restrict__ qb_l, const float* __restrict__ kb_l, const float* __restrict__ vb_l,
    ushort* __restrict__ q, ushort* __restrict__ kk, ushort* __restrict__ v) {
  __shared__ __align__(16) ushort xbf[32 * DD];
  int nb = blockIdx.x * 32;
  ln_tile_bf32(h, nb, n1s_l, n1b_l, xbf);
  __syncthreads();
  int lane = threadIdx.x & 63;
  int w = threadIdx.x >> 6;
  int g = lane >> 4, c = lane & 15;
  int xr = (c & 7) << 4;
  char* xb = (char*)xbf;
  BF8 a[2][4];
#pragma unroll
  for (int nt = 0; nt < 2; nt++)
#pragma unroll
    for (int kt = 0; kt < 4; kt++)
      a[nt][kt].u = *(ushort8_t*)(xb + (((nt * 16 + c) * 256 + kt * 64 + g * 16) ^ xr));
#pragma unroll
  for (int ti = 0; ti < 3; ti++) {
    int t = w * 3 + ti;                // 0..23
    int m = t >> 3;                    // 0=q 1=k 2=v
    int colb = (t & 7) * 16;
    const float* bias = (m == 0 ? qb_l : (m == 1 ? kb_l : vb_l));
    float4 bv = *(const float4*)(bias + colb + g * 4);
    f32x4_t acc0 = {bv.x, bv.y, bv.z, bv.w};
    f32x4_t acc1 = acc0;
    const ushort* wp = qkvT_l + (size_t)(m * DD + colb + c) * DD + g * 8;
#pragma unroll
    for (int kt = 0; kt < 4; kt++) {
      BF8 b; b.u = *(const ushort8_t*)(wp + kt * 32);
      acc0 = __builtin_amdgcn_mfma_f32_16x16x32_bf16(b.b, a[0][kt].b, acc0, 0, 0, 0);
      acc1 = __builtin_amdgcn_mfma_f32_16x16x32_bf16(b.b, a[1][kt].b, acc1, 0, 0, 0);
    }
    ushort* out = (m == 0 ? q : (m == 1 ? kk : v));
    int n0 = nb + c;
    if (n0 < NN) {
      ushort4 o; o.x = f2bf(acc0[0]); o.y = f2bf(acc0[1]); o.z = f2bf(acc0[2]); o.w = f2bf(acc0[3]);
      *(ushort4*)(out + (size_t)n0 * DD + colb + g * 4) = o;
    }
    int n1 = nb + 16 + c;
    if (n1 < NN) {
      ushort4 o; o.x = f2bf(acc1[0]); o.y = f2bf(acc1[1]); o.z = f2bf(acc1[2]); o.w = f2bf(acc1[3]);
      *(ushort4*)(out + (size_t)n1 * DD + colb + g * 4) = o;
    }
  }
}

// per (edge, head): curv + PWL segment staged in LDS by first 32 threads (was the
// separate k_curv kernel — identical binary search, bit-exact), then qk dot (bf16)
// + PWL bias; atomicMax over tgt. Max pass MANDATORY (r5/r6: self-loop dist==0
// -> curv ~ -1e6 -> |bias| ~ 1e4 -> exp overflow without it).
__global__ __launch_bounds__(256) void k_scores(const int* __restrict__ src_s, const int* __restrict__ tgt_s,
    const ushort* __restrict__ q, const ushort* __restrict__ k,
    const float* __restrict__ dist, const float* __restrict__ aggv,
    const float* __restrict__ bp_g,
    const float* __restrict__ slope_l, const float* __restrict__ inter_l,
    float* __restrict__ escore, unsigned* __restrict__ sm_enc) {
  __shared__ float lsl[NSEG * HH], lin[NSEG * HH], bp[DD];
  __shared__ float lcurv[32];
  __shared__ int   lseg[32];
  int tid = threadIdx.x;
  for (int idx = tid; idx < NSEG * HH; idx += 256) { lsl[idx] = slope_l[idx]; lin[idx] = inter_l[idx]; }
  if (tid < DD) bp[tid] = bp_g[tid];
  __syncthreads();
  int eb = blockIdx.x * 32;
  if (tid < 32) {
    int e = eb + tid;
    if (e < NE) {
      int t = tgt_s[e];
      float curv = 1.0f - aggv[t] / fmaxf(dist[e], 1e-6f);
      int lo = 0, hi = DD;
      while (lo < hi) { int mid = (lo + hi) >> 1; if (bp[mid] < curv) lo = mid + 1; else hi = mid; }
      lcurv[tid] = curv;
      lseg[tid] = lo;
    }
  }
  __syncthreads();
  int gi = blockIdx.x * 256 + tid;
  if (gi >= NE * HH) return;
  int i = gi >> 3, hh = gi & 7;
  int s = src_s[i], t = tgt_s[i];
  int li = tid >> 3;
  float curv = lcurv[li];
  int seg = lseg[li];
  float bias = fmaf(lsl[seg * HH + hh], curv, lin[seg * HH + hh]);
  const ushort8_t* qp = (const ushort8_t*)(q + (size_t)s * DD + hh * DHH);
  const ushort8_t* kp = (const ushort8_t*)(k + (size_t)t * DD + hh * DHH);
  float dot = 0.f;
#pragma unroll
  for (int ii = 0; ii < 2; ii++) {
    ushort8_t a = qp[ii], b = kp[ii];
#pragma unroll
    for (int jj = 0; jj < 8; jj++) dot = fmaf(bf2f(a[jj]), bf2f(b[jj]), dot);
  }
  float sc = dot * 0.25f + bias;   // 1/sqrt(16)
  escore[gi] = sc;
  atomicMax(sm_enc + (size_t)t * HH + hh, fenc(sc));
}

__global__ void k_probs(const int* __restrict__ tgt_s, const unsigned* __restrict__ sm_enc,
                        float* __restrict__ escore, float* __restrict__ sden) {
  int gi = blockIdx.x * 256 + threadIdx.x;
  if (gi >= NE * HH) return;
  int i = gi >> 3, hh = gi & 7;
  int t = tgt_s[i];
  float p = expf(escore[gi] - fdec(sm_enc[(size_t)t * HH + hh]));
  escore[gi] = p;
  atomicAdd(sden + (size_t)t * HH + hh, p);
}

__global__ void k_sdinv(float* __restrict__ sden) {
  int i = blockIdx.x * 256 + threadIdx.x;
  if (i >= NN * HH) return;
  float x = sden[i];
  sden[i] = x > 0.f ? 1.0f / x : 0.f;
}

// CSR-gather message aggregation: one wave per src node, 2 dims/lane -> bf16 out.
// 4-deep software-pipelined unroll (round-10 win); fma order ascending-i.
__global__ __launch_bounds__(256) void k_agg(const int* __restrict__ tgt_s,
    const int* __restrict__ rowstart,
    const float* __restrict__ escore, const float* __restrict__ sdinv,
    const ushort* __restrict__ v, ushort* __restrict__ aggmb) {
  int wave = (blockIdx.x * 256 + threadIdx.x) >> 6;
  int lane = threadIdx.x & 63;
  int rs = rowstart[wave], re = rowstart[wave + 1];
  int hh = lane >> 3;
  int d = lane * 2;
  float a0 = 0.f, a1 = 0.f;
  int i = rs;
  for (; i + 4 <= re; i += 4) {
    int t0 = tgt_s[i], t1 = tgt_s[i + 1], t2 = tgt_s[i + 2], t3 = tgt_s[i + 3];
    float e0 = escore[(i    ) * HH + hh];
    float e1 = escore[(i + 1) * HH + hh];
    float e2 = escore[(i + 2) * HH + hh];
    float e3 = escore[(i + 3) * HH + hh];
    float s0 = sdinv[t0 * HH + hh], s1 = sdinv[t1 * HH + hh];
    float s2 = sdinv[t2 * HH + hh], s3 = sdinv[t3 * HH + hh];
    ushort2 v0 = *(const ushort2*)(v + (size_t)t0 * DD + d);
    ushort2 v1 = *(const ushort2*)(v + (size_t)t1 * DD + d);
    ushort2 v2 = *(const ushort2*)(v + (size_t)t2 * DD + d);
    ushort2 v3 = *(const ushort2*)(v + (size_t)t3 * DD + d);
    float p0 = e0 * s0, p1 = e1 * s1, p2 = e2 * s2, p3 = e3 * s3;
    a0 = fmaf(p0, bf2f(v0.x), a0); a1 = fmaf(p0, bf2f(v0.y), a1);
    a0 = fmaf(p1, bf2f(v1.x), a0); a1 = fmaf(p1, bf2f(v1.y), a1);
    a0 = fmaf(p2, bf2f(v2.x), a0); a1 = fmaf(p2, bf2f(v2.y), a1);
    a0 = fmaf(p3, bf2f(v3.x), a0); a1 = fmaf(p3, bf2f(v3.y), a1);
  }
  for (; i < re; i++) {
    int t = tgt_s[i];
    float prob = escore[i * HH + hh] * sdinv[t * HH + hh];
    ushort2 vv = *(const ushort2*)(v + (size_t)t * DD + d);
    a0 = fmaf(prob, bf2f(vv.x), a0);
    a1 = fmaf(prob, bf2f(vv.y), a1);
  }
  ushort2 o; o.x = f2bf(a0); o.y = f2bf(a1);
  *(ushort2*)(aggmb + (size_t)wave * DD + d) = o;
}

// h += aggm @ oW + ob via swapped-operand MFMA; 32 rows/block, 8 waves, float4 RMW.
__global__ __launch_bounds__(512) void k_update_o(const ushort* __restrict__ aggmb,
    const ushort* __restrict__ oT_l, const float* __restrict__ ob_l, float* __restrict__ h) {
  int nb = blockIdx.x * 32;
  int lane = threadIdx.x & 63, w = threadIdx.x >> 6;
  int g = lane >> 4, c = lane & 15;
  BF8 a[2][4];
#pragma unroll
  for (int nt = 0; nt < 2; nt++) {
    int na = nb + nt * 16 + c; if (na >= NN) na = NN - 1;
    const ushort* ap = aggmb + (size_t)na * DD + g * 8;
#pragma unroll
    for (int kt = 0; kt < 4; kt++) a[nt][kt].u = *(const ushort8_t*)(ap + kt * 32);
  }
  int colb = w * 16;
  float4 bv = *(const float4*)(ob_l + colb + g * 4);
  f32x4_t acc0 = {bv.x, bv.y, bv.z, bv.w};
  f32x4_t acc1 = acc0;
  const ushort* wp = oT_l + (size_t)(colb + c) * DD + g * 8;
#pragma unroll
  for (int kt = 0; kt < 4; kt++) {
    BF8 b; b.u = *(const ushort8_t*)(wp + kt * 32);
    acc0 = __builtin_amdgcn_mfma_f32_16x16x32_bf16(b.b, a[0][kt].b, acc0, 0, 0, 0);
    acc1 = __builtin_amdgcn_mfma_f32_16x16x32_bf16(b.b, a[1][kt].b, acc1, 0, 0, 0);
  }
#pragma unroll
  for (int nt = 0; nt < 2; nt++) {
    int node = nb + nt * 16 + c;
    if (node < NN) {
      float* hp = h + (size_t)node * DD + colb + g * 4;
      float4 hv = *(const float4*)hp;
      f32x4_t& acc = nt ? acc1 : acc0;
      hv.x += acc[0]; hv.y += acc[1]; hv.z += acc[2]; hv.w += acc[3];
      *(float4*)hp = hv;
    }
  }
}

// fused FFN, BM=64: h += relu(LN2(h)@f1W+f1b)@f2W+f2b; 64 rows/block, 8 waves.
__global__ __launch_bounds__(512) void k_ffn(const float* __restrict__ n2s_l, const float* __restrict__ n2b_l,
    const ushort* __restrict__ f1T_l, const float* __restrict__ f1b_l,
    const ushort* __restrict__ f2T_l, const float* __restrict__ f2b_l,
    float* __restrict__ h) {
  __shared__ __align__(16) ushort xbf[64 * DD];      // 16 KB
  __shared__ __align__(16) ushort tbf[64 * 256];     // 32 KB
  int nb = blockIdx.x * 64;
  ln_tile_bf64(h, nb, n2s_l, n2b_l, xbf);
  __syncthreads();
  int lane = threadIdx.x & 63, w = threadIdx.x >> 6;
  int g = lane >> 4, c = lane & 15;
  int xr = (c & 7) << 4;
  char* xb = (char*)xbf;
  char* tb = (char*)tbf;
  BF8 a[4][4];
#pragma unroll
  for (int nt = 0; nt < 4; nt++)
#pragma unroll
    for (int kt = 0; kt < 4; kt++)
      a[nt][kt].u = *(ushort8_t*)(xb + (((nt * 16 + c) * 256 + kt * 64 + g * 16) ^ xr));
  int colb2 = w * 16;
  float4 bv2 = *(const float4*)(f2b_l + colb2 + g * 4);
  f32x4_t o0 = {bv2.x, bv2.y, bv2.z, bv2.w};
  f32x4_t o1 = o0, o2 = o0, o3 = o0;
#pragma unroll
  for (int ch = 0; ch < 2; ch++) {
    if (ch) __syncthreads();           // tbf reuse: wait for chunk-0 reads
#pragma unroll
    for (int ti = 0; ti < 2; ti++) {
      int ctile = w * 2 + ti;          // 0..15 within chunk
      int col = ch * 256 + ctile * 16;
      float4 bv = *(const float4*)(f1b_l + col + g * 4);
      f32x4_t ac0 = {bv.x, bv.y, bv.z, bv.w};
      f32x4_t ac1 = ac0, ac2 = ac0, ac3 = ac0;
      const ushort* wp = f1T_l + (size_t)(col + c) * DD + g * 8;
#pragma unroll
      for (int kt = 0; kt < 4; kt++) {
        BF8 b; b.u = *(const ushort8_t*)(wp + kt * 32);
        ac0 = __builtin_amdgcn_mfma_f32_16x16x32_bf16(b.b, a[0][kt].b, ac0, 0, 0, 0);
        ac1 = __builtin_amdgcn_mfma_f32_16x16x32_bf16(b.b, a[1][kt].b, ac1, 0, 0, 0);
        ac2 = __builtin_amdgcn_mfma_f32_16x16x32_bf16(b.b, a[2][kt].b, ac2, 0, 0, 0);
        ac3 = __builtin_amdgcn_mfma_f32_16x16x32_bf16(b.b, a[3][kt].b, ac3, 0, 0, 0);
      }
      int colL = (ctile * 16 + g * 4) * 2;     // byte col within chunk tile
      {
        int row = c;
        ushort4 o4; o4.x = f2bf(fmaxf(ac0[0], 0.f)); o4.y = f2bf(fmaxf(ac0[1], 0.f));
        o4.z = f2bf(fmaxf(ac0[2], 0.f)); o4.w = f2bf(fmaxf(ac0[3], 0.f));
        *(ushort4*)(tb + ((row * 512 + colL) ^ ((row & 7) << 4))) = o4;
      }
      {
        int row = 16 + c;
        ushort4 o4; o4.x = f2bf(fmaxf(ac1[0], 0.f)); o4.y = f2bf(fmaxf(ac1[1], 0.f));
        o4.z = f2bf(fmaxf(ac1[2], 0.f)); o4.w = f2bf(fmaxf(ac1[3], 0.f));
        *(ushort4*)(tb + ((row * 512 + colL) ^ ((row & 7) << 4))) = o4;
      }
      {
        int row = 32 + c;
        ushort4 o4; o4.x = f2bf(fmaxf(ac2[0], 0.f)); o4.y = f2bf(fmaxf(ac2[1], 0.f));
        o4.z = f2bf(fmaxf(ac2[2], 0.f)); o4.w = f2bf(fmaxf(ac2[3], 0.f));
        *(ushort4*)(tb + ((row * 512 + colL) ^ ((row & 7) << 4))) = o4;
      }
      {
        int row = 48 + c;
        ushort4 o4; o4.x = f2bf(fmaxf(ac3[0], 0.f)); o4.y = f2bf(fmaxf(ac3[1], 0.f));
        o4.z = f2bf(fmaxf(ac3[2], 0.f)); o4.w = f2bf(fmaxf(ac3[3], 0.f));
        *(ushort4*)(tb + ((row * 512 + colL) ^ ((row & 7) << 4))) = o4;
      }
    }
    __syncthreads();
    const ushort* wp2 = f2T_l + (size_t)(colb2 + c) * 512 + ch * 256 + g * 8;
#pragma unroll
    for (int kt = 0; kt < 8; kt++) {
      BF8 b; b.u = *(const ushort8_t*)(wp2 + kt * 32);
      BF8 t0; t0.u = *(ushort8_t*)(tb + (((c) * 512 + kt * 64 + g * 16) ^ xr));
      BF8 t1; t1.u = *(ushort8_t*)(tb + (((16 + c) * 512 + kt * 64 + g * 16) ^ xr));
      BF8 t2; t2.u = *(ushort8_t*)(tb + (((32 + c) * 512 + kt * 64 + g * 16) ^ xr));
      BF8 t3; t3.u = *(ushort8_t*)(tb + (((48 + c) * 512 + kt * 64 + g * 16) ^ xr));
      o0 = __builtin_amdgcn_mfma_f32_16x16x32_bf16(b.b, t0.b, o0, 0, 0, 0);
      o1 = __builtin_amdgcn_mfma_f32_16x16x32_bf16(b.b, t1.b, o1, 0, 0, 0);
      o2 = __builtin_amdgcn_mfma_f32_16x16x32_bf16(b.b, t2.b, o2, 0, 0, 0);
      o3 = __builtin_amdgcn_mfma_f32_16x16x32_bf16(b.b, t3.b, o3, 0, 0, 0);
    }
  }
  {
    int node = nb + c;
    if (node < NN) {
      float* hp = h + (size_t)node * DD + colb2 + g * 4;
      float4 hv = *(const float4*)hp;
      hv.x += o0[0]; hv.y += o0[1]; hv.z += o0[2]; hv.w += o0[3];
      *(float4*)hp = hv;
    }
  }
  {
    int node = nb + 16 + c;
    if (node < NN) {
      float* hp = h + (size_t)node * DD + colb2 + g * 4;
      float4 hv = *(const float4*)hp;
      hv.x += o1[0]; hv.y += o1[1]; hv.z += o1[2]; hv.w += o1[3];
      *(float4*)hp = hv;
    }
  }
  {
    int node = nb + 32 + c;
    if (node < NN) {
      float* hp = h + (size_t)node * DD + colb2 + g * 4;
      float4 hv = *(const float4*)hp;
      hv.x += o2[0]; hv.y += o2[1]; hv.z += o2[2]; hv.w += o2[3];
      *(float4*)hp = hv;
    }
  }
  {
    int node = nb + 48 + c;
    if (node < NN) {
      float* hp = h + (size_t)node * DD + colb2 + g * 4;
      float4 hv = *(const float4*)hp;
      hv.x += o3[0]; hv.y += o3[1]; hv.z += o3[2]; hv.w += o3[3];
      *(float4*)hp = hv;
    }
  }
}

// ---------- once-per-call setup kernels ----------
// transpose fp32 [K][C] -> bf16 [C][K], nm stacked matrices, dst stride per matrix
template <int K, int C>
__global__ void k_wt(const float* __restrict__ W, ushort* __restrict__ WT, int nm, int dstride) {
  int idx = blockIdx.x * 256 + threadIdx.x;
  if (idx >= K * C * nm) return;
  int mi = idx / (K * C), rem = idx - mi * (K * C);
  int cc = rem / K, kk2 = rem - cc * K;
  WT[(size_t)mi * dstride + cc * K + kk2] = f2bf(W[(size_t)mi * K * C + (size_t)kk2 * C + cc]);
}

__global__ void k_hist(const int* __restrict__ src, int* __restrict__ cnt) {
  int e = blockIdx.x * 256 + threadIdx.x;
  if (e < NE) atomicAdd(cnt + src[e], 1);
}

// multi-block exclusive scan of cnt[NN] -> rowstart
__global__ __launch_bounds__(256) void k_scan_blk(const int* __restrict__ cnt, int* __restrict__ bsum) {
  __shared__ int red[256];
  int tid = threadIdx.x;
  int idx = blockIdx.x * 256 + tid;
  red[tid] = (idx < NN) ? cnt[idx] : 0;
  __syncthreads();
  for (int off = 128; off >= 1; off >>= 1) {
    if (tid < off) red[tid] += red[tid + off];
    __syncthreads();
  }
  if (tid == 0) bsum[blockIdx.x] = red[0];
}

__global__ __launch_bounds__(256) void k_scan_top(const int* __restrict__ bsum,
                                                  int* __restrict__ boff, int* __restrict__ rowstart) {
  __shared__ int ps[256];
  int t = threadIdx.x;
  int v = (t < NBS) ? bsum[t] : 0;
  ps[t] = v;
  __syncthreads();
  for (int off = 1; off < 256; off <<= 1) {
    int x = (t >= off) ? ps[t - off] : 0;
    __syncthreads();
    ps[t] += x;
    __syncthreads();
  }
  boff[t] = ps[t] - v;                 // exclusive prefix of block sums
  if (t == 255) rowstart[NN] = ps[255];
}

__global__ __launch_bounds__(256) void k_scan_fin(const int* __restrict__ cnt,
                                                  const int* __restrict__ boff, int* __restrict__ rowstart) {
  __shared__ int ps[256];
  int t = threadIdx.x;
  int idx = blockIdx.x * 256 + t;
  int v = (idx < NN) ? cnt[idx] : 0;
  ps[t] = v;
  __syncthreads();
  for (int off = 1; off < 256; off <<= 1) {
    int x = (t >= off) ? ps[t - off] : 0;
    __syncthreads();
    ps[t] += x;
    __syncthreads();
  }
  if (idx < NN) rowstart[idx] = boff[blockIdx.x] + ps[t] - v;
}

// scatter edges into src-sorted order (all per-edge arrays use sorted index)
__global__ void k_fill(const int* __restrict__ src, const int* __restrict__ tgt,
                       const int* __restrict__ rowstart,
                       int* __restrict__ cur, int* __restrict__ src_s, int* __restrict__ tgt_s) {
  int e = blockIdx.x * 256 + threadIdx.x;
  if (e >= NE) return;
  int s = src[e];
  int p = atomicAdd(cur + s, 1);
  int pos = rowstart[s] + p;
  src_s[pos] = s;
  tgt_s[pos] = tgt[e];
}

// M[l][d][hh] = Sum_k cW2[d][k]*bW[l][k][hh]. Wave-parallel: one block per (l,d).
__global__ __launch_bounds__(64) void k_mbias_par(const float* __restrict__ cW2, const float* __restrict__ cb2,
                                                  const float* __restrict__ bW, const float* __restrict__ bb,
                                                  float* __restrict__ M, float* __restrict__ base) {
  int bid = blockIdx.x;
  int l = bid >> 7, d = bid & 127;
  int lane = threadIdx.x;
  int hh = lane >> 3, j0 = lane & 7;
  const float* bWl = bW + (size_t)l * DD * HH;
  float acc = 0.f;
#pragma unroll
  for (int t = 0; t < 16; t++) {
    int k = j0 + t * 8;
    acc = fmaf(cW2[d * DD + k], bWl[k * HH + hh], acc);
  }
#pragma unroll
  for (int off = 1; off <= 4; off <<= 1) acc += __shfl_xor(acc, off, 64);
  if (j0 == 0) M[(size_t)l * DD * HH + d * HH + hh] = acc;
  if (d == 0) {
    float bacc = 0.f;
#pragma unroll
    for (int t = 0; t < 16; t++) {
      int k = j0 + t * 8;
      bacc = fmaf(cb2[k], bWl[k * HH + hh], bacc);
    }
#pragma unroll
    for (int off = 1; off <= 4; off <<= 1) bacc += __shfl_xor(bacc, off, 64);
    if (j0 == 0) base[l * HH + hh] = bacc + bb[l * HH + hh];
  }
}

// sorted breakpoints + ranks — cW1/cb1 are layer-INDEPENDENT, computed once.
__global__ __launch_bounds__(128) void k_bp(const float* __restrict__ cW1, const float* __restrict__ cb1,
                                            float* __restrict__ bpg, int* __restrict__ posg) {
  __shared__ float x[DD], bp[DD];
  int tid = threadIdx.x;
  float c1v = cW1[tid], cbv = cb1[tid];
  x[tid] = (c1v == 0.f) ? __builtin_inff() : (-cbv / c1v);
  __syncthreads();
  float xv = x[tid]; int p = 0;
  for (int j = 0; j < DD; j++) {
    float xj = x[j];
    if (xj < xv || (xj == xv && j < tid)) p++;
  }
  bp[p] = xv;
  posg[tid] = p;
  __syncthreads();
  bpg[tid] = bp[tid];
}

// PWL table, wave-parallel: one block per (l, segment).
__global__ __launch_bounds__(64) void k_pwl_tab(const float* __restrict__ cW1, const float* __restrict__ cb1,
    const int* __restrict__ posg, const float* __restrict__ Mb, const float* __restrict__ basel,
    float* __restrict__ slopeg, float* __restrict__ interg) {
  int bid = blockIdx.x;
  int l = bid / NSEG, s = bid - l * NSEG;
  int lane = threadIdx.x;
  int hh = lane >> 3, j0 = lane & 7;
  const float* M = Mb + (size_t)l * DD * HH;
  float sl = 0.f, in = 0.f;
#pragma unroll
  for (int t = 0; t < 16; t++) {
    int d = j0 + t * 8;
    float cv = cW1[d], cbv = cb1[d];
    int p = posg[d];
    bool act = (cv == 0.f) ? (cbv > 0.f) : ((cv > 0.f) ? (p < s) : (p >= s));
    float m = act ? M[d * HH + hh] : 0.f;
    sl = fmaf(cv, m, sl);
    in = fmaf(cbv, m, in);
  }
#pragma unroll
  for (int off = 1; off <= 4; off <<= 1) {
    sl += __shfl_xor(sl, off, 64);
    in += __shfl_xor(in, off, 64);
  }
  if (j0 == 0) {
    size_t o = (size_t)l * NSEG * HH + s * HH + hh;
    slopeg[o] = sl;
    interg[o] = in + basel[l * HH + hh];
  }
}

__global__ void k_bounds(const int* __restrict__ batch, int* __restrict__ gstart, int* __restrict__ gend) {
  int n = blockIdx.x * 256 + threadIdx.x;
  if (n >= NN) return;
  int b = batch[n];
  if (n == 0 || batch[n - 1] != b) gstart[b] = n;
  if (n == NN - 1 || batch[n + 1] != b) gend[b] = n + 1;
}

// parallel pool: 256 nodes/block, running sums flushed at graph boundaries
__global__ __launch_bounds__(256) void k_pool_part(const float* __restrict__ h,
    const int* __restrict__ batch, float* __restrict__ gpool) {
  int tid = threadIdx.x;
  int d = tid & 127, sub = tid >> 7;
  int n0 = blockIdx.x * 256;
  int nend = n0 + 256; if (nend > NN) nend = NN;
  float run = 0.f; int gcur = -1;
  for (int n = n0 + sub; n < nend; n += 2) {
    int g = batch[n];
    if (g != gcur) {
      if (gcur >= 0) atomicAdd(gpool + (size_t)gcur * DD + d, run);
      run = 0.f; gcur = g;
    }
    run += h[(size_t)n * DD + d];
  }
  if (gcur >= 0) atomicAdd(gpool + (size_t)gcur * DD + d, run);
}

__global__ __launch_bounds__(256) void k_head(const float* __restrict__ gpool,
    const int* __restrict__ gstart, const int* __restrict__ gend,
    const float* __restrict__ W1, const float* __restrict__ b1,
    const float* __restrict__ W2, const float* __restrict__ b2, float* __restrict__ out) {
  __shared__ float mid[NG * 64];
  int tid = threadIdx.x;
  for (int idx = tid; idx < NG * 64; idx += 256) {
    int g = idx >> 6, j = idx & 63;
    int cnt = gend[g] - gstart[g]; if (cnt < 1) cnt = 1;
    float rc = 1.0f / (float)cnt;
    float acc = 0.f;
    for (int d = 0; d < DD; d++) acc = fmaf(gpool[g * DD + d], W1[d * 64 + j], acc);
    mid[idx] = fmaxf(fmaf(acc, rc, b1[j]), 0.f);
  }
  __syncthreads();
  if (tid < NG) {
    float acc = b2[0];
    for (int j = 0; j < 64; j++) acc = fmaf(mid[tid * 64 + j], W2[j], acc);
    out[tid] = acc;
  }
}

// ---------- launch ----------
extern "C" void kernel_launch(void* const* d_in, const int* in_sizes, int n_in,
                              void* d_out, int out_size, void* d_ws, size_t ws_size,
                              hipStream_t stream) {
  const float* x      = (const float*)d_in[0];
  const int*   ei     = (const int*)d_in[1];
  const int*   batch  = (const int*)d_in[2];
  const float* node_W = (const float*)d_in[3];
  const float* node_b = (const float*)d_in[4];
  const float* cW1    = (const float*)d_in[5];
  const float* cb1    = (const float*)d_in[6];
  const float* cW2    = (const float*)d_in[7];
  const float* cb2    = (const float*)d_in[8];
  const float* qW     = (const float*)d_in[9];
  const float* qb     = (const float*)d_in[10];
  const float* kW     = (const float*)d_in[11];
  const float* kb     = (const float*)d_in[12];
  const float* vW     = (const float*)d_in[13];
  const float* vb     = (const float*)d_in[14];
  const float* oW     = (const float*)d_in[15];
  const float* ob     = (const float*)d_in[16];
  const float* bW     = (const float*)d_in[17];
  const float* bb     = (const float*)d_in[18];
  const float* f1W    = (const float*)d_in[19];
  const float* f1b    = (const float*)d_in[20];
  const float* f2W    = (const float*)d_in[21];
  const float* f2b    = (const float*)d_in[22];
  const float* n1s    = (const float*)d_in[23];
  const float* n1b    = (const float*)d_in[24];
  const float* n2s    = (const float*)d_in[25];
  const float* n2b    = (const float*)d_in[26];
  const float* outW1  = (const float*)d_in[27];
  const float* outb1  = (const float*)d_in[28];
  const float* outW2  = (const float*)d_in[29];
  const float* outb2  = (const float*)d_in[30];

  const int* src = ei;
  const int* tgt = ei + NE;

  char* wp = (char*)d_ws;
  auto alloc = [&](size_t bytes) { void* p = (void*)wp; wp += (bytes + 255) & ~(size_t)255; return p; };
  float*    h       = (float*)alloc((size_t)NN * DD * 4);
  ushort*   q       = (ushort*)alloc((size_t)NN * DD * 2);
  ushort*   kk      = (ushort*)alloc((size_t)NN * DD * 2);
  ushort*   v       = (ushort*)alloc((size_t)NN * DD * 2);
  ushort*   aggmb   = (ushort*)alloc((size_t)NN * DD * 2);
  float*    sim     = (float*)alloc((size_t)NE * 4);
  float*    dist    = (float*)alloc((size_t)NE * 4);
  float*    escore  = (float*)alloc((size_t)NE * HH * 4);
  char*     zbase   = wp;                         // zeroed once per layer:
  unsigned* m_enc   = (unsigned*)alloc((size_t)NN * 4);
  float*    den     = (float*)alloc((size_t)NN * 4);
  float*    nd      = (float*)alloc((size_t)NN * 4);
  unsigned* sm_enc  = (unsigned*)alloc((size_t)NN * HH * 4);
  float*    sden    = (float*)alloc((size_t)NN * HH * 4);
  size_t    zbytes  = (size_t)(wp - zbase);
  float*    aggv    = (float*)alloc((size_t)NN * 4);
  float*    Mb      = (float*)alloc((size_t)NL * DD * HH * 4);
  float*    basel   = (float*)alloc((size_t)NL * HH * 4);
  float*    bpg     = (float*)alloc((size_t)DD * 4);
  int*      posg    = (int*)alloc((size_t)DD * 4);
  float*    slopeg  = (float*)alloc((size_t)NL * NSEG * HH * 4);
  float*    interg  = (float*)alloc((size_t)NL * NSEG * HH * 4);
  int*      rowstart= (int*)alloc((size_t)(NN + 1) * 4);
  int*      src_s   = (int*)alloc((size_t)NE * 4);
  int*      tgt_s   = (int*)alloc((size_t)NE * 4);
  int*      cnt     = (int*)alloc((size_t)NN * 4);
  int*      cur     = (int*)alloc((size_t)NN * 4);
  int*      bsum    = (int*)alloc((size_t)NBS * 4);
  int*      boff    = (int*)alloc((size_t)256 * 4);
  int*      gstart  = (int*)alloc((size_t)NG * 4);
  int*      gend    = (int*)alloc((size_t)NG * 4);
  float*    gpool   = (float*)alloc((size_t)NG * DD * 4);
  ushort*   qkvT    = (ushort*)alloc((size_t)NL * 3 * DD * DD * 2);
  ushort*   oT      = (ushort*)alloc((size_t)NL * DD * DD * 2);
  ushort*   f1T     = (ushort*)alloc((size_t)NL * DD * 512 * 2);
  ushort*   f2T     = (ushort*)alloc((size_t)NL * 512 * DD * 2);
  (void)in_sizes; (void)n_in; (void)out_size; (void)ws_size;

  // once-per-call setup
  hipMemsetAsync(cnt, 0, NN * 4, stream);
  hipMemsetAsync(cur, 0, NN * 4, stream);
  hipMemsetAsync(gstart, 0, NG * 4, stream);
  hipMemsetAsync(gend, 0, NG * 4, stream);
  hipMemsetAsync(gpool, 0, NG * DD * 4, stream);
  k_hist<<<(NE + 255) / 256, 256, 0, stream>>>(src, cnt);
  k_scan_blk<<<NBS, 256, 0, stream>>>(cnt, bsum);
  k_scan_top<<<1, 256, 0, stream>>>(bsum, boff, rowstart);
  k_scan_fin<<<NBS, 256, 0, stream>>>(cnt, boff, rowstart);
  k_fill<<<(NE + 255) / 256, 256, 0, stream>>>(src, tgt, rowstart, cur, src_s, tgt_s);
  k_mbias_par<<<NL * DD, 64, 0, stream>>>(cW2, cb2, bW, bb, Mb, basel);
  k_bp<<<1, 128, 0, stream>>>(cW1, cb1, bpg, posg);
  k_pwl_tab<<<NL * NSEG, 64, 0, stream>>>(cW1, cb1, posg, Mb, basel, slopeg, interg);
  k_bounds<<<(NN + 255) / 256, 256, 0, stream>>>(batch, gstart, gend);
  // bf16-transposed weights
  k_wt<DD, DD><<<(NL * DD * DD + 255) / 256, 256, 0, stream>>>(qW, qkvT,               NL, 3 * DD * DD);
  k_wt<DD, DD><<<(NL * DD * DD + 255) / 256, 256, 0, stream>>>(kW, qkvT + DD * DD,     NL, 3 * DD * DD);
  k_wt<DD, DD><<<(NL * DD * DD + 255) / 256, 256, 0, stream>>>(vW, qkvT + 2 * DD * DD, NL, 3 * DD * DD);
  k_wt<DD, DD><<<(NL * DD * DD + 255) / 256, 256, 0, stream>>>(oW, oT, NL, DD * DD);
  k_wt<DD, 512><<<(NL * DD * 512 + 255) / 256, 256, 0, stream>>>(f1W, f1T, NL, DD * 512);
  k_wt<512, DD><<<(NL * DD * 512 + 255) / 256, 256, 0, stream>>>(f2W, f2T, NL, DD * 512);
  k_node_proj<<<NN / 8, 256, 0, stream>>>(x, node_W, node_b, h);

  for (int l = 0; l < NL; l++) {
    hipMemsetAsync(zbase, 0, zbytes, stream);
    k_edge1<<<(NE * 16 + 255) / 256, 256, 0, stream>>>(src_s, tgt_s, h, sim, dist, m_enc);
    k_edge2<<<(NE + 255) / 256, 256, 0, stream>>>(tgt_s, sim, dist, m_enc, den, nd);
    k_aggv<<<(NN + 255) / 256, 256, 0, stream>>>(den, nd, aggv);
    k_ln_qkv<<<NT32, 512, 0, stream>>>(h, n1s + l * DD, n1b + l * DD,
        qkvT + (size_t)l * 3 * DD * DD,
        qb + l * DD, kb + l * DD, vb + l * DD, q, kk, v);
    k_scores<<<(NE * HH + 255) / 256, 256, 0, stream>>>(src_s, tgt_s, q, kk,
        dist, aggv, bpg,
        slopeg + (size_t)l * NSEG * HH, interg + (size_t)l * NSEG * HH,
        escore, sm_enc);
    k_probs<<<(NE * HH + 255) / 256, 256, 0, stream>>>(tgt_s, sm_enc, escore, sden);
    k_sdinv<<<(NN * HH + 255) / 256, 256, 0, stream>>>(sden);
    k_agg<<<NN / 4, 256, 0, stream>>>(tgt_s, rowstart, escore, sden, v, aggmb);
    k_update_o<<<NT32, 512, 0, stream>>>(aggmb, oT + (size_t)l * DD * DD, ob + l * DD, h);
    k_ffn<<<NT64, 512, 0, stream>>>(n2s + l * DD, n2b + l * DD,
        f1T + (size_t)l * DD * 512, f1b + (size_t)l * 4 * DD,
        f2T + (size_t)l * 512 * DD, f2b + l * DD, h);
  }
  k_pool_part<<<(NN + 255) / 256, 256, 0, stream>>>(h, batch, gpool);
  k_head<<<1, 256, 0, stream>>>(gpool, gstart, gend, outW1, outb1, outW2, outb2, (float*)d_out);
}

// Round 12
// 1449.906 us; speedup vs baseline: 3.0016x; 1.1478x over previous
//
#include <hip/hip_runtime.h>

#define NN 50000      // nodes
#define NE 625000     // edges
#define DD 128        // hidden dim
#define HH 8          // heads
#define DHH 16        // head dim
#define NL 4          // layers
#define FIN 64        // in channels
#define NG 64         // graphs
#define LN_EPS 1e-5f
#define NSEG 129      // PWL segments = 128 breakpoints + 1
#define NT32 1563     // ceil(NN/32)
#define NT64 782      // ceil(NN/64)
#define NBS 196       // ceil(NN/256) scan blocks

typedef __bf16 bf16x8_t __attribute__((ext_vector_type(8)));
typedef unsigned short ushort8_t __attribute__((ext_vector_type(8)));
typedef float f32x4_t __attribute__((ext_vector_type(4)));
union BF8 { ushort8_t u; bf16x8_t b; };

// ---------- helpers ----------
__device__ __forceinline__ void fma4(float4& a, float s, float4 w) {
  a.x = fmaf(s, w.x, a.x); a.y = fmaf(s, w.y, a.y);
  a.z = fmaf(s, w.z, a.z); a.w = fmaf(s, w.w, a.w);
}
__device__ __forceinline__ unsigned short f2bf(float f) {   // RNE f32->bf16
  unsigned u = __float_as_uint(f);
  unsigned r = ((u >> 16) & 1u) + 0x7FFFu;
  return (unsigned short)((u + r) >> 16);
}
__device__ __forceinline__ float bf2f(unsigned short u) {
  return __uint_as_float((unsigned)u << 16);
}

// LayerNorm 32 nodes -> swizzled bf16 LDS tile [32][128]; block = 512 threads.
__device__ __forceinline__ void ln_tile_bf32(const float* __restrict__ h, int nb,
                                             const float* __restrict__ sc,
                                             const float* __restrict__ bi,
                                             ushort* xbf) {
  int tid = threadIdx.x;
  int r = tid >> 4, l16 = tid & 15;
  int nr = nb + r; if (nr >= NN) nr = NN - 1;   // clamp: tail rows unused
  const float* hp = h + (size_t)nr * DD + l16 * 8;
  float4 a0 = *(const float4*)hp;
  float4 a1 = *(const float4*)(hp + 4);
  float sum = a0.x + a0.y + a0.z + a0.w + a1.x + a1.y + a1.z + a1.w;
  float sq  = a0.x*a0.x + a0.y*a0.y + a0.z*a0.z + a0.w*a0.w
            + a1.x*a1.x + a1.y*a1.y + a1.z*a1.z + a1.w*a1.w;
#pragma unroll
  for (int off = 8; off >= 1; off >>= 1) {
    sum += __shfl_xor(sum, off, 64);
    sq  += __shfl_xor(sq,  off, 64);
  }
  float mu   = sum * (1.0f / DD);
  float var  = sq * (1.0f / DD) - mu * mu;
  float rstd = rsqrtf(var + LN_EPS);
  int d0 = l16 * 8;
  float4 s0 = *(const float4*)(sc + d0), s1 = *(const float4*)(sc + d0 + 4);
  float4 b0 = *(const float4*)(bi + d0), b1 = *(const float4*)(bi + d0 + 4);
  ushort8_t u;
  u[0] = f2bf((a0.x - mu) * rstd * s0.x + b0.x);
  u[1] = f2bf((a0.y - mu) * rstd * s0.y + b0.y);
  u[2] = f2bf((a0.z - mu) * rstd * s0.z + b0.z);
  u[3] = f2bf((a0.w - mu) * rstd * s0.w + b0.w);
  u[4] = f2bf((a1.x - mu) * rstd * s1.x + b1.x);
  u[5] = f2bf((a1.y - mu) * rstd * s1.y + b1.y);
  u[6] = f2bf((a1.z - mu) * rstd * s1.z + b1.z);
  u[7] = f2bf((a1.w - mu) * rstd * s1.w + b1.w);
  int off = (r * 256 + l16 * 16) ^ ((r & 7) << 4);
  *(ushort8_t*)((char*)xbf + off) = u;
}

// LayerNorm 64 nodes (2 passes of 32) -> swizzled bf16 LDS tile [64][128]; 512 threads.
__device__ __forceinline__ void ln_tile_bf64(const float* __restrict__ h, int nb,
                                             const float* __restrict__ sc,
                                             const float* __restrict__ bi,
                                             ushort* xbf) {
  int tid = threadIdx.x;
  int l16 = tid & 15;
  int d0 = l16 * 8;
  float4 s0 = *(const float4*)(sc + d0), s1 = *(const float4*)(sc + d0 + 4);
  float4 b0 = *(const float4*)(bi + d0), b1 = *(const float4*)(bi + d0 + 4);
#pragma unroll
  for (int p = 0; p < 2; p++) {
    int r = p * 32 + (tid >> 4);
    int nr = nb + r; if (nr >= NN) nr = NN - 1;
    const float* hp = h + (size_t)nr * DD + d0;
    float4 a0 = *(const float4*)hp;
    float4 a1 = *(const float4*)(hp + 4);
    float sum = a0.x + a0.y + a0.z + a0.w + a1.x + a1.y + a1.z + a1.w;
    float sq  = a0.x*a0.x + a0.y*a0.y + a0.z*a0.z + a0.w*a0.w
              + a1.x*a1.x + a1.y*a1.y + a1.z*a1.z + a1.w*a1.w;
#pragma unroll
    for (int off = 8; off >= 1; off >>= 1) {
      sum += __shfl_xor(sum, off, 64);
      sq  += __shfl_xor(sq,  off, 64);
    }
    float mu   = sum * (1.0f / DD);
    float var  = sq * (1.0f / DD) - mu * mu;
    float rstd = rsqrtf(var + LN_EPS);
    ushort8_t u;
    u[0] = f2bf((a0.x - mu) * rstd * s0.x + b0.x);
    u[1] = f2bf((a0.y - mu) * rstd * s0.y + b0.y);
    u[2] = f2bf((a0.z - mu) * rstd * s0.z + b0.z);
    u[3] = f2bf((a0.w - mu) * rstd * s0.w + b0.w);
    u[4] = f2bf((a1.x - mu) * rstd * s1.x + b1.x);
    u[5] = f2bf((a1.y - mu) * rstd * s1.y + b1.y);
    u[6] = f2bf((a1.z - mu) * rstd * s1.z + b1.z);
    u[7] = f2bf((a1.w - mu) * rstd * s1.w + b1.w);
    int off = (r * 256 + l16 * 16) ^ ((r & 7) << 4);
    *(ushort8_t*)((char*)xbf + off) = u;
  }
}

// ---------- kernels ----------
// h = x @ node_W + node_b ; 8 nodes/block (fp32 VALU — minor cost)
__global__ __launch_bounds__(256) void k_node_proj(const float* __restrict__ x,
                                                   const float* __restrict__ W,
                                                   const float* __restrict__ b,
                                                   float* __restrict__ h) {
  __shared__ float xt[8][FIN];
  int tid = threadIdx.x;
  int nb = blockIdx.x * 8;
  {
    int idx = tid * 2;
    *(float2*)&xt[idx >> 6][idx & 63] = *(const float2*)(x + (size_t)nb * FIN + idx);
  }
  __syncthreads();
  int c4 = (tid & 31) * 4;
  int r  = tid >> 5;
  float4 acc = *(const float4*)(b + c4);
  for (int k = 0; k < FIN; k += 4) {
    float4 xk = *(const float4*)&xt[r][k];
    const float* wp = W + (size_t)k * DD + c4;
    fma4(acc, xk.x, *(const float4*)wp);
    fma4(acc, xk.y, *(const float4*)(wp + DD));
    fma4(acc, xk.z, *(const float4*)(wp + 2 * DD));
    fma4(acc, xk.w, *(const float4*)(wp + 3 * DD));
  }
  *(float4*)(h + (size_t)(nb + r) * DD + c4) = acc;
}

// per sorted edge: sim (dot), dist (norm) in fp32. 16 lanes/edge. NO atomics
// (max now computed in k_curva via tgt-CSR — round 11: edge2 was atomic-bound).
__global__ __launch_bounds__(256) void k_edge1(const int* __restrict__ src_s, const int* __restrict__ tgt_s,
                                               const float* __restrict__ h, float* __restrict__ sim,
                                               float* __restrict__ dist) {
  int gid = blockIdx.x * 256 + threadIdx.x;
  int e = gid >> 4;
  if (e >= NE) return;
  int j = gid & 15;
  int s = src_s[e], t = tgt_s[e];
  const float4* ap = (const float4*)(h + (size_t)s * DD + j * 8);
  const float4* bp = (const float4*)(h + (size_t)t * DD + j * 8);
  float4 a0 = ap[0], a1 = ap[1];
  float4 b0 = bp[0], b1 = bp[1];
  float dot = 0.f, sq = 0.f;
  dot = fmaf(a0.x, b0.x, dot); dot = fmaf(a0.y, b0.y, dot);
  dot = fmaf(a0.z, b0.z, dot); dot = fmaf(a0.w, b0.w, dot);
  dot = fmaf(a1.x, b1.x, dot); dot = fmaf(a1.y, b1.y, dot);
  dot = fmaf(a1.z, b1.z, dot); dot = fmaf(a1.w, b1.w, dot);
  float d0 = a0.x - b0.x, d1 = a0.y - b0.y, d2 = a0.z - b0.z, d3 = a0.w - b0.w;
  float d4 = a1.x - b1.x, d5 = a1.y - b1.y, d6 = a1.z - b1.z, d7 = a1.w - b1.w;
  sq = fmaf(d0, d0, sq); sq = fmaf(d1, d1, sq); sq = fmaf(d2, d2, sq); sq = fmaf(d3, d3, sq);
  sq = fmaf(d4, d4, sq); sq = fmaf(d5, d5, sq); sq = fmaf(d6, d6, sq); sq = fmaf(d7, d7, sq);
#pragma unroll
  for (int off = 8; off >= 1; off >>= 1) {
    dot += __shfl_xor(dot, off, 64);
    sq  += __shfl_xor(sq,  off, 64);
  }
  if (j == 0) {
    sim[e]  = dot;                  // BETA == 1.0
    dist[e] = sqrtf(sq);
  }
}

// curvature aggregate per tgt node via tgt-CSR gather (no atomics): 8 lanes/node,
// tree-max (exact) then exp-sum -> aggv = seg_sum(alpha*dist) directly.
__global__ __launch_bounds__(256) void k_curva(const int* __restrict__ rowstart_t,
    const int* __restrict__ eid_t, const float* __restrict__ sim,
    const float* __restrict__ dist, float* __restrict__ aggv) {
  int node = blockIdx.x * 32 + (threadIdx.x >> 3);
  if (node >= NN) return;
  int j = threadIdx.x & 7;
  int rs = rowstart_t[node], re = rowstart_t[node + 1];
  float m = -3.4e38f;
  for (int i = rs + j; i < re; i += 8) m = fmaxf(m, sim[eid_t[i]]);
#pragma unroll
  for (int off = 1; off <= 4; off <<= 1) m = fmaxf(m, __shfl_xor(m, off, 64));
  float den = 0.f, nd = 0.f;
  for (int i = rs + j; i < re; i += 8) {
    int e = eid_t[i];
    float ev = expf(sim[e] - m);
    den += ev;
    nd = fmaf(ev, dist[e], nd);
  }
#pragma unroll
  for (int off = 1; off <= 4; off <<= 1) {
    den += __shfl_xor(den, off, 64);
    nd  += __shfl_xor(nd,  off, 64);
  }
  if (j == 0) aggv[node] = den > 0.f ? nd / den : 0.f;
}

// LN1 + QKV projection via swapped-operand MFMA -> bf16 q/k/v. 32 rows/block, 8 waves.
__global__ __launch_bounds__(512) void k_ln_qkv(const float* __restrict__ h,
    const float* __restrict__ n1s_l, const float* __restrict__ n1b_l,
    const ushort* __restrict__ qkvT_l,
    const float* __restrict__ qb_l, const float* __restrict__ kb_l, const float* __restrict__ vb_l,
    ushort* __restrict__ q, ushort* __restrict__ kk, ushort* __restrict__ v) {
  __shared__ __align__(16) ushort xbf[32 * DD];
  int nb = blockIdx.x * 32;
  ln_tile_bf32(h, nb, n1s_l, n1b_l, xbf);
  __syncthreads();
  int lane = threadIdx.x & 63;
  int w = threadIdx.x >> 6;
  int g = lane >> 4, c = lane & 15;
  int xr = (c & 7) << 4;
  char* xb = (char*)xbf;
  BF8 a[2][4];
#pragma unroll
  for (int nt = 0; nt < 2; nt++)
#pragma unroll
    for (int kt = 0; kt < 4; kt++)
      a[nt][kt].u = *(ushort8_t*)(xb + (((nt * 16 + c) * 256 + kt * 64 + g * 16) ^ xr));
#pragma unroll
  for (int ti = 0; ti < 3; ti++) {
    int t = w * 3 + ti;                // 0..23
    int m = t >> 3;                    // 0=q 1=k 2=v
    int colb = (t & 7) * 16;
    const float* bias = (m == 0 ? qb_l : (m == 1 ? kb_l : vb_l));
    float4 bv = *(const float4*)(bias + colb + g * 4);
    f32x4_t acc0 = {bv.x, bv.y, bv.z, bv.w};
    f32x4_t acc1 = acc0;
    const ushort* wp = qkvT_l + (size_t)(m * DD + colb + c) * DD + g * 8;
#pragma unroll
    for (int kt = 0; kt < 4; kt++) {
      BF8 b; b.u = *(const ushort8_t*)(wp + kt * 32);
      acc0 = __builtin_amdgcn_mfma_f32_16x16x32_bf16(b.b, a[0][kt].b, acc0, 0, 0, 0);
      acc1 = __builtin_amdgcn_mfma_f32_16x16x32_bf16(b.b, a[1][kt].b, acc1, 0, 0, 0);
    }
    ushort* out = (m == 0 ? q : (m == 1 ? kk : v));
    int n0 = nb + c;
    if (n0 < NN) {
      ushort4 o; o.x = f2bf(acc0[0]); o.y = f2bf(acc0[1]); o.z = f2bf(acc0[2]); o.w = f2bf(acc0[3]);
      *(ushort4*)(out + (size_t)n0 * DD + colb + g * 4) = o;
    }
    int n1 = nb + 16 + c;
    if (n1 < NN) {
      ushort4 o; o.x = f2bf(acc1[0]); o.y = f2bf(acc1[1]); o.z = f2bf(acc1[2]); o.w = f2bf(acc1[3]);
      *(ushort4*)(out + (size_t)n1 * DD + colb + g * 4) = o;
    }
  }
}

// per (edge, head): curv + PWL segment staged in LDS by first 32 threads, then
// qk dot (bf16) + PWL bias -> RAW score (softmax handled by k_softmax_t; the
// max subtraction stays MANDATORY — r5/r6: self-loop dist==0 -> |bias| ~ 1e4).
__global__ __launch_bounds__(256) void k_scores(const int* __restrict__ src_s, const int* __restrict__ tgt_s,
    const ushort* __restrict__ q, const ushort* __restrict__ k,
    const float* __restrict__ dist, const float* __restrict__ aggv,
    const float* __restrict__ bp_g,
    const float* __restrict__ slope_l, const float* __restrict__ inter_l,
    float* __restrict__ escore) {
  __shared__ float lsl[NSEG * HH], lin[NSEG * HH], bp[DD];
  __shared__ float lcurv[32];
  __shared__ int   lseg[32];
  int tid = threadIdx.x;
  for (int idx = tid; idx < NSEG * HH; idx += 256) { lsl[idx] = slope_l[idx]; lin[idx] = inter_l[idx]; }
  if (tid < DD) bp[tid] = bp_g[tid];
  __syncthreads();
  int eb = blockIdx.x * 32;
  if (tid < 32) {
    int e = eb + tid;
    if (e < NE) {
      int t = tgt_s[e];
      float curv = 1.0f - aggv[t] / fmaxf(dist[e], 1e-6f);
      int lo = 0, hi = DD;
      while (lo < hi) { int mid = (lo + hi) >> 1; if (bp[mid] < curv) lo = mid + 1; else hi = mid; }
      lcurv[tid] = curv;
      lseg[tid] = lo;
    }
  }
  __syncthreads();
  int gi = blockIdx.x * 256 + tid;
  if (gi >= NE * HH) return;
  int i = gi >> 3, hh = gi & 7;
  int s = src_s[i], t = tgt_s[i];
  int li = tid >> 3;
  float curv = lcurv[li];
  int seg = lseg[li];
  float bias = fmaf(lsl[seg * HH + hh], curv, lin[seg * HH + hh]);
  const ushort8_t* qp = (const ushort8_t*)(q + (size_t)s * DD + hh * DHH);
  const ushort8_t* kp = (const ushort8_t*)(k + (size_t)t * DD + hh * DHH);
  float dot = 0.f;
#pragma unroll
  for (int ii = 0; ii < 2; ii++) {
    ushort8_t a = qp[ii], b = kp[ii];
#pragma unroll
    for (int jj = 0; jj < 8; jj++) dot = fmaf(bf2f(a[jj]), bf2f(b[jj]), dot);
  }
  escore[gi] = dot * 0.25f + bias;   // 1/sqrt(16)
  (void)t;
}

// attention softmax per (tgt node, head) via tgt-CSR gather (no atomics):
// 8 lanes = 8 heads per node; max pass (exact), then exp + in-place rewrite
// escore->p + sum; sdinv written directly. 4-deep pipelined gathers.
__global__ __launch_bounds__(256) void k_softmax_t(const int* __restrict__ rowstart_t,
    const int* __restrict__ eid_t, float* __restrict__ escore, float* __restrict__ sdinv) {
  int node = blockIdx.x * 32 + (threadIdx.x >> 3);
  if (node >= NN) return;
  int hh = threadIdx.x & 7;
  int rs = rowstart_t[node], re = rowstart_t[node + 1];
  float m = -3.4e38f;
  int i = rs;
  for (; i + 4 <= re; i += 4) {
    int e0 = eid_t[i], e1 = eid_t[i + 1], e2 = eid_t[i + 2], e3 = eid_t[i + 3];
    float s0 = escore[e0 * HH + hh];
    float s1 = escore[e1 * HH + hh];
    float s2 = escore[e2 * HH + hh];
    float s3 = escore[e3 * HH + hh];
    m = fmaxf(m, s0); m = fmaxf(m, s1); m = fmaxf(m, s2); m = fmaxf(m, s3);
  }
  for (; i < re; i++) m = fmaxf(m, escore[eid_t[i] * HH + hh]);
  float sum = 0.f;
  i = rs;
  for (; i + 4 <= re; i += 4) {
    int e0 = eid_t[i], e1 = eid_t[i + 1], e2 = eid_t[i + 2], e3 = eid_t[i + 3];
    float p0 = expf(escore[e0 * HH + hh] - m);
    float p1 = expf(escore[e1 * HH + hh] - m);
    float p2 = expf(escore[e2 * HH + hh] - m);
    float p3 = expf(escore[e3 * HH + hh] - m);
    escore[e0 * HH + hh] = p0; escore[e1 * HH + hh] = p1;
    escore[e2 * HH + hh] = p2; escore[e3 * HH + hh] = p3;
    sum += p0; sum += p1; sum += p2; sum += p3;
  }
  for (; i < re; i++) {
    int e = eid_t[i];
    float p = expf(escore[e * HH + hh] - m);
    escore[e * HH + hh] = p;
    sum += p;
  }
  sdinv[node * HH + hh] = sum > 0.f ? 1.0f / sum : 0.f;
}

// CSR-gather message aggregation: one wave per src node, 2 dims/lane -> bf16 out.
// 4-deep software-pipelined unroll (round-10 win); fma order ascending-i.
__global__ __launch_bounds__(256) void k_agg(const int* __restrict__ tgt_s,
    const int* __restrict__ rowstart,
    const float* __restrict__ escore, const float* __restrict__ sdinv,
    const ushort* __restrict__ v, ushort* __restrict__ aggmb) {
  int wave = (blockIdx.x * 256 + threadIdx.x) >> 6;
  int lane = threadIdx.x & 63;
  int rs = rowstart[wave], re = rowstart[wave + 1];
  int hh = lane >> 3;
  int d = lane * 2;
  float a0 = 0.f, a1 = 0.f;
  int i = rs;
  for (; i + 4 <= re; i += 4) {
    int t0 = tgt_s[i], t1 = tgt_s[i + 1], t2 = tgt_s[i + 2], t3 = tgt_s[i + 3];
    float e0 = escore[(i    ) * HH + hh];
    float e1 = escore[(i + 1) * HH + hh];
    float e2 = escore[(i + 2) * HH + hh];
    float e3 = escore[(i + 3) * HH + hh];
    float s0 = sdinv[t0 * HH + hh], s1 = sdinv[t1 * HH + hh];
    float s2 = sdinv[t2 * HH + hh], s3 = sdinv[t3 * HH + hh];
    ushort2 v0 = *(const ushort2*)(v + (size_t)t0 * DD + d);
    ushort2 v1 = *(const ushort2*)(v + (size_t)t1 * DD + d);
    ushort2 v2 = *(const ushort2*)(v + (size_t)t2 * DD + d);
    ushort2 v3 = *(const ushort2*)(v + (size_t)t3 * DD + d);
    float p0 = e0 * s0, p1 = e1 * s1, p2 = e2 * s2, p3 = e3 * s3;
    a0 = fmaf(p0, bf2f(v0.x), a0); a1 = fmaf(p0, bf2f(v0.y), a1);
    a0 = fmaf(p1, bf2f(v1.x), a0); a1 = fmaf(p1, bf2f(v1.y), a1);
    a0 = fmaf(p2, bf2f(v2.x), a0); a1 = fmaf(p2, bf2f(v2.y), a1);
    a0 = fmaf(p3, bf2f(v3.x), a0); a1 = fmaf(p3, bf2f(v3.y), a1);
  }
  for (; i < re; i++) {
    int t = tgt_s[i];
    float prob = escore[i * HH + hh] * sdinv[t * HH + hh];
    ushort2 vv = *(const ushort2*)(v + (size_t)t * DD + d);
    a0 = fmaf(prob, bf2f(vv.x), a0);
    a1 = fmaf(prob, bf2f(vv.y), a1);
  }
  ushort2 o; o.x = f2bf(a0); o.y = f2bf(a1);
  *(ushort2*)(aggmb + (size_t)wave * DD + d) = o;
}

// h += aggm @ oW + ob via swapped-operand MFMA; 32 rows/block, 8 waves, float4 RMW.
__global__ __launch_bounds__(512) void k_update_o(const ushort* __restrict__ aggmb,
    const ushort* __restrict__ oT_l, const float* __restrict__ ob_l, float* __restrict__ h) {
  int nb = blockIdx.x * 32;
  int lane = threadIdx.x & 63, w = threadIdx.x >> 6;
  int g = lane >> 4, c = lane & 15;
  BF8 a[2][4];
#pragma unroll
  for (int nt = 0; nt < 2; nt++) {
    int na = nb + nt * 16 + c; if (na >= NN) na = NN - 1;
    const ushort* ap = aggmb + (size_t)na * DD + g * 8;
#pragma unroll
    for (int kt = 0; kt < 4; kt++) a[nt][kt].u = *(const ushort8_t*)(ap + kt * 32);
  }
  int colb = w * 16;
  float4 bv = *(const float4*)(ob_l + colb + g * 4);
  f32x4_t acc0 = {bv.x, bv.y, bv.z, bv.w};
  f32x4_t acc1 = acc0;
  const ushort* wp = oT_l + (size_t)(colb + c) * DD + g * 8;
#pragma unroll
  for (int kt = 0; kt < 4; kt++) {
    BF8 b; b.u = *(const ushort8_t*)(wp + kt * 32);
    acc0 = __builtin_amdgcn_mfma_f32_16x16x32_bf16(b.b, a[0][kt].b, acc0, 0, 0, 0);
    acc1 = __builtin_amdgcn_mfma_f32_16x16x32_bf16(b.b, a[1][kt].b, acc1, 0, 0, 0);
  }
#pragma unroll
  for (int nt = 0; nt < 2; nt++) {
    int node = nb + nt * 16 + c;
    if (node < NN) {
      float* hp = h + (size_t)node * DD + colb + g * 4;
      float4 hv = *(const float4*)hp;
      f32x4_t& acc = nt ? acc1 : acc0;
      hv.x += acc[0]; hv.y += acc[1]; hv.z += acc[2]; hv.w += acc[3];
      *(float4*)hp = hv;
    }
  }
}

// fused FFN, BM=64: h += relu(LN2(h)@f1W+f1b)@f2W+f2b; 64 rows/block, 8 waves.
__global__ __launch_bounds__(512) void k_ffn(const float* __restrict__ n2s_l, const float* __restrict__ n2b_l,
    const ushort* __restrict__ f1T_l, const float* __restrict__ f1b_l,
    const ushort* __restrict__ f2T_l, const float* __restrict__ f2b_l,
    float* __restrict__ h) {
  __shared__ __align__(16) ushort xbf[64 * DD];      // 16 KB
  __shared__ __align__(16) ushort tbf[64 * 256];     // 32 KB
  int nb = blockIdx.x * 64;
  ln_tile_bf64(h, nb, n2s_l, n2b_l, xbf);
  __syncthreads();
  int lane = threadIdx.x & 63, w = threadIdx.x >> 6;
  int g = lane >> 4, c = lane & 15;
  int xr = (c & 7) << 4;
  char* xb = (char*)xbf;
  char* tb = (char*)tbf;
  BF8 a[4][4];
#pragma unroll
  for (int nt = 0; nt < 4; nt++)
#pragma unroll
    for (int kt = 0; kt < 4; kt++)
      a[nt][kt].u = *(ushort8_t*)(xb + (((nt * 16 + c) * 256 + kt * 64 + g * 16) ^ xr));
  int colb2 = w * 16;
  float4 bv2 = *(const float4*)(f2b_l + colb2 + g * 4);
  f32x4_t o0 = {bv2.x, bv2.y, bv2.z, bv2.w};
  f32x4_t o1 = o0, o2 = o0, o3 = o0;
#pragma unroll
  for (int ch = 0; ch < 2; ch++) {
    if (ch) __syncthreads();           // tbf reuse: wait for chunk-0 reads
#pragma unroll
    for (int ti = 0; ti < 2; ti++) {
      int ctile = w * 2 + ti;          // 0..15 within chunk
      int col = ch * 256 + ctile * 16;
      float4 bv = *(const float4*)(f1b_l + col + g * 4);
      f32x4_t ac0 = {bv.x, bv.y, bv.z, bv.w};
      f32x4_t ac1 = ac0, ac2 = ac0, ac3 = ac0;
      const ushort* wp = f1T_l + (size_t)(col + c) * DD + g * 8;
#pragma unroll
      for (int kt = 0; kt < 4; kt++) {
        BF8 b; b.u = *(const ushort8_t*)(wp + kt * 32);
        ac0 = __builtin_amdgcn_mfma_f32_16x16x32_bf16(b.b, a[0][kt].b, ac0, 0, 0, 0);
        ac1 = __builtin_amdgcn_mfma_f32_16x16x32_bf16(b.b, a[1][kt].b, ac1, 0, 0, 0);
        ac2 = __builtin_amdgcn_mfma_f32_16x16x32_bf16(b.b, a[2][kt].b, ac2, 0, 0, 0);
        ac3 = __builtin_amdgcn_mfma_f32_16x16x32_bf16(b.b, a[3][kt].b, ac3, 0, 0, 0);
      }
      int colL = (ctile * 16 + g * 4) * 2;     // byte col within chunk tile
      {
        int row = c;
        ushort4 o4; o4.x = f2bf(fmaxf(ac0[0], 0.f)); o4.y = f2bf(fmaxf(ac0[1], 0.f));
        o4.z = f2bf(fmaxf(ac0[2], 0.f)); o4.w = f2bf(fmaxf(ac0[3], 0.f));
        *(ushort4*)(tb + ((row * 512 + colL) ^ ((row & 7) << 4))) = o4;
      }
      {
        int row = 16 + c;
        ushort4 o4; o4.x = f2bf(fmaxf(ac1[0], 0.f)); o4.y = f2bf(fmaxf(ac1[1], 0.f));
        o4.z = f2bf(fmaxf(ac1[2], 0.f)); o4.w = f2bf(fmaxf(ac1[3], 0.f));
        *(ushort4*)(tb + ((row * 512 + colL) ^ ((row & 7) << 4))) = o4;
      }
      {
        int row = 32 + c;
        ushort4 o4; o4.x = f2bf(fmaxf(ac2[0], 0.f)); o4.y = f2bf(fmaxf(ac2[1], 0.f));
        o4.z = f2bf(fmaxf(ac2[2], 0.f)); o4.w = f2bf(fmaxf(ac2[3], 0.f));
        *(ushort4*)(tb + ((row * 512 + colL) ^ ((row & 7) << 4))) = o4;
      }
      {
        int row = 48 + c;
        ushort4 o4; o4.x = f2bf(fmaxf(ac3[0], 0.f)); o4.y = f2bf(fmaxf(ac3[1], 0.f));
        o4.z = f2bf(fmaxf(ac3[2], 0.f)); o4.w = f2bf(fmaxf(ac3[3], 0.f));
        *(ushort4*)(tb + ((row * 512 + colL) ^ ((row & 7) << 4))) = o4;
      }
    }
    __syncthreads();
    const ushort* wp2 = f2T_l + (size_t)(colb2 + c) * 512 + ch * 256 + g * 8;
#pragma unroll
    for (int kt = 0; kt < 8; kt++) {
      BF8 b; b.u = *(const ushort8_t*)(wp2 + kt * 32);
      BF8 t0; t0.u = *(ushort8_t*)(tb + (((c) * 512 + kt * 64 + g * 16) ^ xr));
      BF8 t1; t1.u = *(ushort8_t*)(tb + (((16 + c) * 512 + kt * 64 + g * 16) ^ xr));
      BF8 t2; t2.u = *(ushort8_t*)(tb + (((32 + c) * 512 + kt * 64 + g * 16) ^ xr));
      BF8 t3; t3.u = *(ushort8_t*)(tb + (((48 + c) * 512 + kt * 64 + g * 16) ^ xr));
      o0 = __builtin_amdgcn_mfma_f32_16x16x32_bf16(b.b, t0.b, o0, 0, 0, 0);
      o1 = __builtin_amdgcn_mfma_f32_16x16x32_bf16(b.b, t1.b, o1, 0, 0, 0);
      o2 = __builtin_amdgcn_mfma_f32_16x16x32_bf16(b.b, t2.b, o2, 0, 0, 0);
      o3 = __builtin_amdgcn_mfma_f32_16x16x32_bf16(b.b, t3.b, o3, 0, 0, 0);
    }
  }
  {
    int node = nb + c;
    if (node < NN) {
      float* hp = h + (size_t)node * DD + colb2 + g * 4;
      float4 hv = *(const float4*)hp;
      hv.x += o0[0]; hv.y += o0[1]; hv.z += o0[2]; hv.w += o0[3];
      *(float4*)hp = hv;
    }
  }
  {
    int node = nb + 16 + c;
    if (node < NN) {
      float* hp = h + (size_t)node * DD + colb2 + g * 4;
      float4 hv = *(const float4*)hp;
      hv.x += o1[0]; hv.y += o1[1]; hv.z += o1[2]; hv.w += o1[3];
      *(float4*)hp = hv;
    }
  }
  {
    int node = nb + 32 + c;
    if (node < NN) {
      float* hp = h + (size_t)node * DD + colb2 + g * 4;
      float4 hv = *(const float4*)hp;
      hv.x += o2[0]; hv.y += o2[1]; hv.z += o2[2]; hv.w += o2[3];
      *(float4*)hp = hv;
    }
  }
  {
    int node = nb + 48 + c;
    if (node < NN) {
      float* hp = h + (size_t)node * DD + colb2 + g * 4;
      float4 hv = *(const float4*)hp;
      hv.x += o3[0]; hv.y += o3[1]; hv.z += o3[2]; hv.w += o3[3];
      *(float4*)hp = hv;
    }
  }
}

// ---------- once-per-call setup kernels ----------
// transpose fp32 [K][C] -> bf16 [C][K], nm stacked matrices, dst stride per matrix
template <int K, int C>
__global__ void k_wt(const float* __restrict__ W, ushort* __restrict__ WT, int nm, int dstride) {
  int idx = blockIdx.x * 256 + threadIdx.x;
  if (idx >= K * C * nm) return;
  int mi = idx / (K * C), rem = idx - mi * (K * C);
  int cc = rem / K, kk2 = rem - cc * K;
  WT[(size_t)mi * dstride + cc * K + kk2] = f2bf(W[(size_t)mi * K * C + (size_t)kk2 * C + cc]);
}

__global__ void k_hist(const int* __restrict__ idxs, int* __restrict__ cnt) {
  int e = blockIdx.x * 256 + threadIdx.x;
  if (e < NE) atomicAdd(cnt + idxs[e], 1);
}

// multi-block exclusive scan of cnt[NN] -> rowstart
__global__ __launch_bounds__(256) void k_scan_blk(const int* __restrict__ cnt, int* __restrict__ bsum) {
  __shared__ int red[256];
  int tid = threadIdx.x;
  int idx = blockIdx.x * 256 + tid;
  red[tid] = (idx < NN) ? cnt[idx] : 0;
  __syncthreads();
  for (int off = 128; off >= 1; off >>= 1) {
    if (tid < off) red[tid] += red[tid + off];
    __syncthreads();
  }
  if (tid == 0) bsum[blockIdx.x] = red[0];
}

__global__ __launch_bounds__(256) void k_scan_top(const int* __restrict__ bsum,
                                                  int* __restrict__ boff, int* __restrict__ rowstart) {
  __shared__ int ps[256];
  int t = threadIdx.x;
  int v = (t < NBS) ? bsum[t] : 0;
  ps[t] = v;
  __syncthreads();
  for (int off = 1; off < 256; off <<= 1) {
    int x = (t >= off) ? ps[t - off] : 0;
    __syncthreads();
    ps[t] += x;
    __syncthreads();
  }
  boff[t] = ps[t] - v;                 // exclusive prefix of block sums
  if (t == 255) rowstart[NN] = ps[255];
}

__global__ __launch_bounds__(256) void k_scan_fin(const int* __restrict__ cnt,
                                                  const int* __restrict__ boff, int* __restrict__ rowstart) {
  __shared__ int ps[256];
  int t = threadIdx.x;
  int idx = blockIdx.x * 256 + t;
  int v = (idx < NN) ? cnt[idx] : 0;
  ps[t] = v;
  __syncthreads();
  for (int off = 1; off < 256; off <<= 1) {
    int x = (t >= off) ? ps[t - off] : 0;
    __syncthreads();
    ps[t] += x;
    __syncthreads();
  }
  if (idx < NN) rowstart[idx] = boff[blockIdx.x] + ps[t] - v;
}

// scatter edges into src-sorted order (all per-edge arrays use sorted index)
__global__ void k_fill(const int* __restrict__ src, const int* __restrict__ tgt,
                       const int* __restrict__ rowstart,
                       int* __restrict__ cur, int* __restrict__ src_s, int* __restrict__ tgt_s) {
  int e = blockIdx.x * 256 + threadIdx.x;
  if (e >= NE) return;
  int s = src[e];
  int p = atomicAdd(cur + s, 1);
  int pos = rowstart[s] + p;
  src_s[pos] = s;
  tgt_s[pos] = tgt[e];
}

// tgt-CSR: list of src-sorted edge ids per tgt node
__global__ void k_fill_t(const int* __restrict__ tgt_s, const int* __restrict__ rowstart_t,
                         int* __restrict__ cur_t, int* __restrict__ eid_t) {
  int i = blockIdx.x * 256 + threadIdx.x;
  if (i >= NE) return;
  int t = tgt_s[i];
  int p = atomicAdd(cur_t + t, 1);
  eid_t[rowstart_t[t] + p] = i;
}

// M[l][d][hh] = Sum_k cW2[d][k]*bW[l][k][hh]. Wave-parallel: one block per (l,d).
__global__ __launch_bounds__(64) void k_mbias_par(const float* __restrict__ cW2, const float* __restrict__ cb2,
                                                  const float* __restrict__ bW, const float* __restrict__ bb,
                                                  float* __restrict__ M, float* __restrict__ base) {
  int bid = blockIdx.x;
  int l = bid >> 7, d = bid & 127;
  int lane = threadIdx.x;
  int hh = lane >> 3, j0 = lane & 7;
  const float* bWl = bW + (size_t)l * DD * HH;
  float acc = 0.f;
#pragma unroll
  for (int t = 0; t < 16; t++) {
    int k = j0 + t * 8;
    acc = fmaf(cW2[d * DD + k], bWl[k * HH + hh], acc);
  }
#pragma unroll
  for (int off = 1; off <= 4; off <<= 1) acc += __shfl_xor(acc, off, 64);
  if (j0 == 0) M[(size_t)l * DD * HH + d * HH + hh] = acc;
  if (d == 0) {
    float bacc = 0.f;
#pragma unroll
    for (int t = 0; t < 16; t++) {
      int k = j0 + t * 8;
      bacc = fmaf(cb2[k], bWl[k * HH + hh], bacc);
    }
#pragma unroll
    for (int off = 1; off <= 4; off <<= 1) bacc += __shfl_xor(bacc, off, 64);
    if (j0 == 0) base[l * HH + hh] = bacc + bb[l * HH + hh];
  }
}

// sorted breakpoints + ranks — cW1/cb1 are layer-INDEPENDENT, computed once.
__global__ __launch_bounds__(128) void k_bp(const float* __restrict__ cW1, const float* __restrict__ cb1,
                                            float* __restrict__ bpg, int* __restrict__ posg) {
  __shared__ float x[DD], bp[DD];
  int tid = threadIdx.x;
  float c1v = cW1[tid], cbv = cb1[tid];
  x[tid] = (c1v == 0.f) ? __builtin_inff() : (-cbv / c1v);
  __syncthreads();
  float xv = x[tid]; int p = 0;
  for (int j = 0; j < DD; j++) {
    float xj = x[j];
    if (xj < xv || (xj == xv && j < tid)) p++;
  }
  bp[p] = xv;
  posg[tid] = p;
  __syncthreads();
  bpg[tid] = bp[tid];
}

// PWL table, wave-parallel: one block per (l, segment).
__global__ __launch_bounds__(64) void k_pwl_tab(const float* __restrict__ cW1, const float* __restrict__ cb1,
    const int* __restrict__ posg, const float* __restrict__ Mb, const float* __restrict__ basel,
    float* __restrict__ slopeg, float* __restrict__ interg) {
  int bid = blockIdx.x;
  int l = bid / NSEG, s = bid - l * NSEG;
  int lane = threadIdx.x;
  int hh = lane >> 3, j0 = lane & 7;
  const float* M = Mb + (size_t)l * DD * HH;
  float sl = 0.f, in = 0.f;
#pragma unroll
  for (int t = 0; t < 16; t++) {
    int d = j0 + t * 8;
    float cv = cW1[d], cbv = cb1[d];
    int p = posg[d];
    bool act = (cv == 0.f) ? (cbv > 0.f) : ((cv > 0.f) ? (p < s) : (p >= s));
    float m = act ? M[d * HH + hh] : 0.f;
    sl = fmaf(cv, m, sl);
    in = fmaf(cbv, m, in);
  }
#pragma unroll
  for (int off = 1; off <= 4; off <<= 1) {
    sl += __shfl_xor(sl, off, 64);
    in += __shfl_xor(in, off, 64);
  }
  if (j0 == 0) {
    size_t o = (size_t)l * NSEG * HH + s * HH + hh;
    slopeg[o] = sl;
    interg[o] = in + basel[l * HH + hh];
  }
}

__global__ void k_bounds(const int* __restrict__ batch, int* __restrict__ gstart, int* __restrict__ gend) {
  int n = blockIdx.x * 256 + threadIdx.x;
  if (n >= NN) return;
  int b = batch[n];
  if (n == 0 || batch[n - 1] != b) gstart[b] = n;
  if (n == NN - 1 || batch[n + 1] != b) gend[b] = n + 1;
}

// parallel pool: 256 nodes/block, running sums flushed at graph boundaries
__global__ __launch_bounds__(256) void k_pool_part(const float* __restrict__ h,
    const int* __restrict__ batch, float* __restrict__ gpool) {
  int tid = threadIdx.x;
  int d = tid & 127, sub = tid >> 7;
  int n0 = blockIdx.x * 256;
  int nend = n0 + 256; if (nend > NN) nend = NN;
  float run = 0.f; int gcur = -1;
  for (int n = n0 + sub; n < nend; n += 2) {
    int g = batch[n];
    if (g != gcur) {
      if (gcur >= 0) atomicAdd(gpool + (size_t)gcur * DD + d, run);
      run = 0.f; gcur = g;
    }
    run += h[(size_t)n * DD + d];
  }
  if (gcur >= 0) atomicAdd(gpool + (size_t)gcur * DD + d, run);
}

__global__ __launch_bounds__(256) void k_head(const float* __restrict__ gpool,
    const int* __restrict__ gstart, const int* __restrict__ gend,
    const float* __restrict__ W1, const float* __restrict__ b1,
    const float* __restrict__ W2, const float* __restrict__ b2, float* __restrict__ out) {
  __shared__ float mid[NG * 64];
  int tid = threadIdx.x;
  for (int idx = tid; idx < NG * 64; idx += 256) {
    int g = idx >> 6, j = idx & 63;
    int cnt = gend[g] - gstart[g]; if (cnt < 1) cnt = 1;
    float rc = 1.0f / (float)cnt;
    float acc = 0.f;
    for (int d = 0; d < DD; d++) acc = fmaf(gpool[g * DD + d], W1[d * 64 + j], acc);
    mid[idx] = fmaxf(fmaf(acc, rc, b1[j]), 0.f);
  }
  __syncthreads();
  if (tid < NG) {
    float acc = b2[0];
    for (int j = 0; j < 64; j++) acc = fmaf(mid[tid * 64 + j], W2[j], acc);
    out[tid] = acc;
  }
}

// ---------- launch ----------
extern "C" void kernel_launch(void* const* d_in, const int* in_sizes, int n_in,
                              void* d_out, int out_size, void* d_ws, size_t ws_size,
                              hipStream_t stream) {
  const float* x      = (const float*)d_in[0];
  const int*   ei     = (const int*)d_in[1];
  const int*   batch  = (const int*)d_in[2];
  const float* node_W = (const float*)d_in[3];
  const float* node_b = (const float*)d_in[4];
  const float* cW1    = (const float*)d_in[5];
  const float* cb1    = (const float*)d_in[6];
  const float* cW2    = (const float*)d_in[7];
  const float* cb2    = (const float*)d_in[8];
  const float* qW     = (const float*)d_in[9];
  const float* qb     = (const float*)d_in[10];
  const float* kW     = (const float*)d_in[11];
  const float* kb     = (const float*)d_in[12];
  const float* vW     = (const float*)d_in[13];
  const float* vb     = (const float*)d_in[14];
  const float* oW     = (const float*)d_in[15];
  const float* ob     = (const float*)d_in[16];
  const float* bW     = (const float*)d_in[17];
  const float* bb     = (const float*)d_in[18];
  const float* f1W    = (const float*)d_in[19];
  const float* f1b    = (const float*)d_in[20];
  const float* f2W    = (const float*)d_in[21];
  const float* f2b    = (const float*)d_in[22];
  const float* n1s    = (const float*)d_in[23];
  const float* n1b    = (const float*)d_in[24];
  const float* n2s    = (const float*)d_in[25];
  const float* n2b    = (const float*)d_in[26];
  const float* outW1  = (const float*)d_in[27];
  const float* outb1  = (const float*)d_in[28];
  const float* outW2  = (const float*)d_in[29];
  const float* outb2  = (const float*)d_in[30];

  const int* src = ei;
  const int* tgt = ei + NE;

  char* wp = (char*)d_ws;
  auto alloc = [&](size_t bytes) { void* p = (void*)wp; wp += (bytes + 255) & ~(size_t)255; return p; };
  float*    h       = (float*)alloc((size_t)NN * DD * 4);
  ushort*   q       = (ushort*)alloc((size_t)NN * DD * 2);
  ushort*   kk      = (ushort*)alloc((size_t)NN * DD * 2);
  ushort*   v       = (ushort*)alloc((size_t)NN * DD * 2);
  ushort*   aggmb   = (ushort*)alloc((size_t)NN * DD * 2);
  float*    sim     = (float*)alloc((size_t)NE * 4);
  float*    dist    = (float*)alloc((size_t)NE * 4);
  float*    escore  = (float*)alloc((size_t)NE * HH * 4);
  float*    sdinv   = (float*)alloc((size_t)NN * HH * 4);
  float*    aggv    = (float*)alloc((size_t)NN * 4);
  float*    Mb      = (float*)alloc((size_t)NL * DD * HH * 4);
  float*    basel   = (float*)alloc((size_t)NL * HH * 4);
  float*    bpg     = (float*)alloc((size_t)DD * 4);
  int*      posg    = (int*)alloc((size_t)DD * 4);
  float*    slopeg  = (float*)alloc((size_t)NL * NSEG * HH * 4);
  float*    interg  = (float*)alloc((size_t)NL * NSEG * HH * 4);
  int*      rowstart= (int*)alloc((size_t)(NN + 1) * 4);
  int*      rowstart_t = (int*)alloc((size_t)(NN + 1) * 4);
  int*      eid_t   = (int*)alloc((size_t)NE * 4);
  int*      src_s   = (int*)alloc((size_t)NE * 4);
  int*      tgt_s   = (int*)alloc((size_t)NE * 4);
  int*      cnt     = (int*)alloc((size_t)NN * 4);
  int*      cur     = (int*)alloc((size_t)NN * 4);
  int*      cnt_t   = (int*)alloc((size_t)NN * 4);
  int*      cur_t   = (int*)alloc((size_t)NN * 4);
  int*      bsum    = (int*)alloc((size_t)NBS * 4);
  int*      boff    = (int*)alloc((size_t)256 * 4);
  int*      gstart  = (int*)alloc((size_t)NG * 4);
  int*      gend    = (int*)alloc((size_t)NG * 4);
  float*    gpool   = (float*)alloc((size_t)NG * DD * 4);
  ushort*   qkvT    = (ushort*)alloc((size_t)NL * 3 * DD * DD * 2);
  ushort*   oT      = (ushort*)alloc((size_t)NL * DD * DD * 2);
  ushort*   f1T     = (ushort*)alloc((size_t)NL * DD * 512 * 2);
  ushort*   f2T     = (ushort*)alloc((size_t)NL * 512 * DD * 2);
  (void)in_sizes; (void)n_in; (void)out_size; (void)ws_size;

  // once-per-call setup
  hipMemsetAsync(cnt, 0, NN * 4, stream);
  hipMemsetAsync(cur, 0, NN * 4, stream);
  hipMemsetAsync(cnt_t, 0, NN * 4, stream);
  hipMemsetAsync(cur_t, 0, NN * 4, stream);
  hipMemsetAsync(gstart, 0, NG * 4, stream);
  hipMemsetAsync(gend, 0, NG * 4, stream);
  hipMemsetAsync(gpool, 0, NG * DD * 4, stream);
  // src-CSR (edge sort) and tgt-CSR (incoming-edge lists)
  k_hist<<<(NE + 255) / 256, 256, 0, stream>>>(src, cnt);
  k_scan_blk<<<NBS, 256, 0, stream>>>(cnt, bsum);
  k_scan_top<<<1, 256, 0, stream>>>(bsum, boff, rowstart);
  k_scan_fin<<<NBS, 256, 0, stream>>>(cnt, boff, rowstart);
  k_fill<<<(NE + 255) / 256, 256, 0, stream>>>(src, tgt, rowstart, cur, src_s, tgt_s);
  k_hist<<<(NE + 255) / 256, 256, 0, stream>>>(tgt, cnt_t);
  k_scan_blk<<<NBS, 256, 0, stream>>>(cnt_t, bsum);
  k_scan_top<<<1, 256, 0, stream>>>(bsum, boff, rowstart_t);
  k_scan_fin<<<NBS, 256, 0, stream>>>(cnt_t, boff, rowstart_t);
  k_fill_t<<<(NE + 255) / 256, 256, 0, stream>>>(tgt_s, rowstart_t, cur_t, eid_t);
  k_mbias_par<<<NL * DD, 64, 0, stream>>>(cW2, cb2, bW, bb, Mb, basel);
  k_bp<<<1, 128, 0, stream>>>(cW1, cb1, bpg, posg);
  k_pwl_tab<<<NL * NSEG, 64, 0, stream>>>(cW1, cb1, posg, Mb, basel, slopeg, interg);
  k_bounds<<<(NN + 255) / 256, 256, 0, stream>>>(batch, gstart, gend);
  // bf16-transposed weights
  k_wt<DD, DD><<<(NL * DD * DD + 255) / 256, 256, 0, stream>>>(qW, qkvT,               NL, 3 * DD * DD);
  k_wt<DD, DD><<<(NL * DD * DD + 255) / 256, 256, 0, stream>>>(kW, qkvT + DD * DD,     NL, 3 * DD * DD);
  k_wt<DD, DD><<<(NL * DD * DD + 255) / 256, 256, 0, stream>>>(vW, qkvT + 2 * DD * DD, NL, 3 * DD * DD);
  k_wt<DD, DD><<<(NL * DD * DD + 255) / 256, 256, 0, stream>>>(oW, oT, NL, DD * DD);
  k_wt<DD, 512><<<(NL * DD * 512 + 255) / 256, 256, 0, stream>>>(f1W, f1T, NL, DD * 512);
  k_wt<512, DD><<<(NL * DD * 512 + 255) / 256, 256, 0, stream>>>(f2W, f2T, NL, DD * 512);
  k_node_proj<<<NN / 8, 256, 0, stream>>>(x, node_W, node_b, h);

  for (int l = 0; l < NL; l++) {
    k_edge1<<<(NE * 16 + 255) / 256, 256, 0, stream>>>(src_s, tgt_s, h, sim, dist);
    k_curva<<<NT32, 256, 0, stream>>>(rowstart_t, eid_t, sim, dist, aggv);
    k_ln_qkv<<<NT32, 512, 0, stream>>>(h, n1s + l * DD, n1b + l * DD,
        qkvT + (size_t)l * 3 * DD * DD,
        qb + l * DD, kb + l * DD, vb + l * DD, q, kk, v);
    k_scores<<<(NE * HH + 255) / 256, 256, 0, stream>>>(src_s, tgt_s, q, kk,
        dist, aggv, bpg,
        slopeg + (size_t)l * NSEG * HH, interg + (size_t)l * NSEG * HH,
        escore);
    k_softmax_t<<<NT32, 256, 0, stream>>>(rowstart_t, eid_t, escore, sdinv);
    k_agg<<<NN / 4, 256, 0, stream>>>(tgt_s, rowstart, escore, sdinv, v, aggmb);
    k_update_o<<<NT32, 512, 0, stream>>>(aggmb, oT + (size_t)l * DD * DD, ob + l * DD, h);
    k_ffn<<<NT64, 512, 0, stream>>>(n2s + l * DD, n2b + l * DD,
        f1T + (size_t)l * DD * 512, f1b + (size_t)l * 4 * DD,
        f2T + (size_t)l * 512 * DD, f2b + l * DD, h);
  }
  k_pool_part<<<(NN + 255) / 256, 256, 0, stream>>>(h, batch, gpool);
  k_head<<<1, 256, 0, stream>>>(gpool, gstart, gend, outW1, outb1, outW2, outb2, (float*)d_out);
}

// Round 13
// 1407.313 us; speedup vs baseline: 3.0925x; 1.0303x over previous
//
#include <hip/hip_runtime.h>

#define NN 50000      // nodes
#define NE 625000     // edges
#define DD 128        // hidden dim
#define HH 8          // heads
#define DHH 16        // head dim
#define NL 4          // layers
#define FIN 64        // in channels
#define NG 64         // graphs
#define LN_EPS 1e-5f
#define NSEG 129      // PWL segments = 128 breakpoints + 1
#define NT32 1563     // ceil(NN/32)
#define NT64 782      // ceil(NN/64)
#define NBS 196       // ceil(NN/256) scan blocks

typedef __bf16 bf16x8_t __attribute__((ext_vector_type(8)));
typedef unsigned short ushort8_t __attribute__((ext_vector_type(8)));
typedef float f32x4_t __attribute__((ext_vector_type(4)));
union BF8 { ushort8_t u; bf16x8_t b; };

// ---------- helpers ----------
__device__ __forceinline__ void fma4(float4& a, float s, float4 w) {
  a.x = fmaf(s, w.x, a.x); a.y = fmaf(s, w.y, a.y);
  a.z = fmaf(s, w.z, a.z); a.w = fmaf(s, w.w, a.w);
}
__device__ __forceinline__ unsigned short f2bf(float f) {   // RNE f32->bf16
  unsigned u = __float_as_uint(f);
  unsigned r = ((u >> 16) & 1u) + 0x7FFFu;
  return (unsigned short)((u + r) >> 16);
}
__device__ __forceinline__ float bf2f(unsigned short u) {
  return __uint_as_float((unsigned)u << 16);
}

// LayerNorm 32 nodes -> swizzled bf16 LDS tile [32][128]; block = 512 threads.
__device__ __forceinline__ void ln_tile_bf32(const float* __restrict__ h, int nb,
                                             const float* __restrict__ sc,
                                             const float* __restrict__ bi,
                                             ushort* xbf) {
  int tid = threadIdx.x;
  int r = tid >> 4, l16 = tid & 15;
  int nr = nb + r; if (nr >= NN) nr = NN - 1;   // clamp: tail rows unused
  const float* hp = h + (size_t)nr * DD + l16 * 8;
  float4 a0 = *(const float4*)hp;
  float4 a1 = *(const float4*)(hp + 4);
  float sum = a0.x + a0.y + a0.z + a0.w + a1.x + a1.y + a1.z + a1.w;
  float sq  = a0.x*a0.x + a0.y*a0.y + a0.z*a0.z + a0.w*a0.w
            + a1.x*a1.x + a1.y*a1.y + a1.z*a1.z + a1.w*a1.w;
#pragma unroll
  for (int off = 8; off >= 1; off >>= 1) {
    sum += __shfl_xor(sum, off, 64);
    sq  += __shfl_xor(sq,  off, 64);
  }
  float mu   = sum * (1.0f / DD);
  float var  = sq * (1.0f / DD) - mu * mu;
  float rstd = rsqrtf(var + LN_EPS);
  int d0 = l16 * 8;
  float4 s0 = *(const float4*)(sc + d0), s1 = *(const float4*)(sc + d0 + 4);
  float4 b0 = *(const float4*)(bi + d0), b1 = *(const float4*)(bi + d0 + 4);
  ushort8_t u;
  u[0] = f2bf((a0.x - mu) * rstd * s0.x + b0.x);
  u[1] = f2bf((a0.y - mu) * rstd * s0.y + b0.y);
  u[2] = f2bf((a0.z - mu) * rstd * s0.z + b0.z);
  u[3] = f2bf((a0.w - mu) * rstd * s0.w + b0.w);
  u[4] = f2bf((a1.x - mu) * rstd * s1.x + b1.x);
  u[5] = f2bf((a1.y - mu) * rstd * s1.y + b1.y);
  u[6] = f2bf((a1.z - mu) * rstd * s1.z + b1.z);
  u[7] = f2bf((a1.w - mu) * rstd * s1.w + b1.w);
  int off = (r * 256 + l16 * 16) ^ ((r & 7) << 4);
  *(ushort8_t*)((char*)xbf + off) = u;
}

// LayerNorm 64 nodes (2 passes of 32) -> swizzled bf16 LDS tile [64][128]; 512 threads.
__device__ __forceinline__ void ln_tile_bf64(const float* __restrict__ h, int nb,
                                             const float* __restrict__ sc,
                                             const float* __restrict__ bi,
                                             ushort* xbf) {
  int tid = threadIdx.x;
  int l16 = tid & 15;
  int d0 = l16 * 8;
  float4 s0 = *(const float4*)(sc + d0), s1 = *(const float4*)(sc + d0 + 4);
  float4 b0 = *(const float4*)(bi + d0), b1 = *(const float4*)(bi + d0 + 4);
#pragma unroll
  for (int p = 0; p < 2; p++) {
    int r = p * 32 + (tid >> 4);
    int nr = nb + r; if (nr >= NN) nr = NN - 1;
    const float* hp = h + (size_t)nr * DD + d0;
    float4 a0 = *(const float4*)hp;
    float4 a1 = *(const float4*)(hp + 4);
    float sum = a0.x + a0.y + a0.z + a0.w + a1.x + a1.y + a1.z + a1.w;
    float sq  = a0.x*a0.x + a0.y*a0.y + a0.z*a0.z + a0.w*a0.w
              + a1.x*a1.x + a1.y*a1.y + a1.z*a1.z + a1.w*a1.w;
#pragma unroll
    for (int off = 8; off >= 1; off >>= 1) {
      sum += __shfl_xor(sum, off, 64);
      sq  += __shfl_xor(sq,  off, 64);
    }
    float mu   = sum * (1.0f / DD);
    float var  = sq * (1.0f / DD) - mu * mu;
    float rstd = rsqrtf(var + LN_EPS);
    ushort8_t u;
    u[0] = f2bf((a0.x - mu) * rstd * s0.x + b0.x);
    u[1] = f2bf((a0.y - mu) * rstd * s0.y + b0.y);
    u[2] = f2bf((a0.z - mu) * rstd * s0.z + b0.z);
    u[3] = f2bf((a0.w - mu) * rstd * s0.w + b0.w);
    u[4] = f2bf((a1.x - mu) * rstd * s1.x + b1.x);
    u[5] = f2bf((a1.y - mu) * rstd * s1.y + b1.y);
    u[6] = f2bf((a1.z - mu) * rstd * s1.z + b1.z);
    u[7] = f2bf((a1.w - mu) * rstd * s1.w + b1.w);
    int off = (r * 256 + l16 * 16) ^ ((r & 7) << 4);
    *(ushort8_t*)((char*)xbf + off) = u;
  }
}

// ---------- kernels ----------
// h = x @ node_W + node_b ; 32 nodes/block, W staged in LDS (round-12 profile:
// 56us latency-bound on serialized L2 W-loads at 11% VALU). Same ascending-k
// fma chain per output -> bit-identical.
__global__ __launch_bounds__(256) void k_node_proj(const float* __restrict__ x,
                                                   const float* __restrict__ W,
                                                   const float* __restrict__ b,
                                                   float* __restrict__ h) {
  __shared__ float Wl[FIN * DD];    // 32 KB
  __shared__ float xt[32][FIN];     // 8 KB
  int tid = threadIdx.x;
  int nb = blockIdx.x * 32;
  for (int i = tid * 4; i < FIN * DD; i += 1024)
    *(float4*)&Wl[i] = *(const float4*)(W + i);
  for (int i = tid * 4; i < 32 * FIN; i += 1024) {
    int row = i >> 6, cc = i & 63;
    int node = nb + row; if (node >= NN) node = NN - 1;
    *(float4*)&xt[row][cc] = *(const float4*)(x + (size_t)node * FIN + cc);
  }
  __syncthreads();
  int c4 = (tid & 31) * 4;
  int r0 = (tid >> 5) * 4;
  float4 bv = *(const float4*)(b + c4);
  float4 a0 = bv, a1 = bv, a2 = bv, a3 = bv;
  for (int k = 0; k < FIN; k++) {
    float4 wv = *(const float4*)&Wl[k * DD + c4];
    fma4(a0, xt[r0][k], wv);
    fma4(a1, xt[r0 + 1][k], wv);
    fma4(a2, xt[r0 + 2][k], wv);
    fma4(a3, xt[r0 + 3][k], wv);
  }
  int n0 = nb + r0;
  if (n0 < NN)     *(float4*)(h + (size_t)n0 * DD + c4) = a0;
  if (n0 + 1 < NN) *(float4*)(h + (size_t)(n0 + 1) * DD + c4) = a1;
  if (n0 + 2 < NN) *(float4*)(h + (size_t)(n0 + 2) * DD + c4) = a2;
  if (n0 + 3 < NN) *(float4*)(h + (size_t)(n0 + 3) * DD + c4) = a3;
}

// per sorted edge: sim (dot), dist (norm) in fp32. 16 lanes/edge. No atomics.
__global__ __launch_bounds__(256) void k_edge1(const int* __restrict__ src_s, const int* __restrict__ tgt_s,
                                               const float* __restrict__ h, float* __restrict__ sim,
                                               float* __restrict__ dist) {
  int gid = blockIdx.x * 256 + threadIdx.x;
  int e = gid >> 4;
  if (e >= NE) return;
  int j = gid & 15;
  int s = src_s[e], t = tgt_s[e];
  const float4* ap = (const float4*)(h + (size_t)s * DD + j * 8);
  const float4* bp = (const float4*)(h + (size_t)t * DD + j * 8);
  float4 a0 = ap[0], a1 = ap[1];
  float4 b0 = bp[0], b1 = bp[1];
  float dot = 0.f, sq = 0.f;
  dot = fmaf(a0.x, b0.x, dot); dot = fmaf(a0.y, b0.y, dot);
  dot = fmaf(a0.z, b0.z, dot); dot = fmaf(a0.w, b0.w, dot);
  dot = fmaf(a1.x, b1.x, dot); dot = fmaf(a1.y, b1.y, dot);
  dot = fmaf(a1.z, b1.z, dot); dot = fmaf(a1.w, b1.w, dot);
  float d0 = a0.x - b0.x, d1 = a0.y - b0.y, d2 = a0.z - b0.z, d3 = a0.w - b0.w;
  float d4 = a1.x - b1.x, d5 = a1.y - b1.y, d6 = a1.z - b1.z, d7 = a1.w - b1.w;
  sq = fmaf(d0, d0, sq); sq = fmaf(d1, d1, sq); sq = fmaf(d2, d2, sq); sq = fmaf(d3, d3, sq);
  sq = fmaf(d4, d4, sq); sq = fmaf(d5, d5, sq); sq = fmaf(d6, d6, sq); sq = fmaf(d7, d7, sq);
#pragma unroll
  for (int off = 8; off >= 1; off >>= 1) {
    dot += __shfl_xor(dot, off, 64);
    sq  += __shfl_xor(sq,  off, 64);
  }
  if (j == 0) {
    sim[e]  = dot;                  // BETA == 1.0
    dist[e] = sqrtf(sq);
  }
}

// curvature aggregate per tgt node via tgt-CSR gather (no atomics): 8 lanes/node,
// tree-max (exact) then exp-sum -> aggv = seg_sum(alpha*dist) directly.
__global__ __launch_bounds__(256) void k_curva(const int* __restrict__ rowstart_t,
    const int* __restrict__ eid_t, const float* __restrict__ sim,
    const float* __restrict__ dist, float* __restrict__ aggv) {
  int node = blockIdx.x * 32 + (threadIdx.x >> 3);
  if (node >= NN) return;
  int j = threadIdx.x & 7;
  int rs = rowstart_t[node], re = rowstart_t[node + 1];
  float m = -3.4e38f;
  for (int i = rs + j; i < re; i += 8) m = fmaxf(m, sim[eid_t[i]]);
#pragma unroll
  for (int off = 1; off <= 4; off <<= 1) m = fmaxf(m, __shfl_xor(m, off, 64));
  float den = 0.f, nd = 0.f;
  for (int i = rs + j; i < re; i += 8) {
    int e = eid_t[i];
    float ev = expf(sim[e] - m);
    den += ev;
    nd = fmaf(ev, dist[e], nd);
  }
#pragma unroll
  for (int off = 1; off <= 4; off <<= 1) {
    den += __shfl_xor(den, off, 64);
    nd  += __shfl_xor(nd,  off, 64);
  }
  if (j == 0) aggv[node] = den > 0.f ? nd / den : 0.f;
}

// LN1 + QKV projection via swapped-operand MFMA -> bf16 q/k/v. 32 rows/block, 8 waves.
__global__ __launch_bounds__(512) void k_ln_qkv(const float* __restrict__ h,
    const float* __restrict__ n1s_l, const float* __restrict__ n1b_l,
    const ushort* __restrict__ qkvT_l,
    const float* __restrict__ qb_l, const float* __restrict__ kb_l, const float* __restrict__ vb_l,
    ushort* __restrict__ q, ushort* __restrict__ kk, ushort* __restrict__ v) {
  __shared__ __align__(16) ushort xbf[32 * DD];
  int nb = blockIdx.x * 32;
  ln_tile_bf32(h, nb, n1s_l, n1b_l, xbf);
  __syncthreads();
  int lane = threadIdx.x & 63;
  int w = threadIdx.x >> 6;
  int g = lane >> 4, c = lane & 15;
  int xr = (c & 7) << 4;
  char* xb = (char*)xbf;
  BF8 a[2][4];
#pragma unroll
  for (int nt = 0; nt < 2; nt++)
#pragma unroll
    for (int kt = 0; kt < 4; kt++)
      a[nt][kt].u = *(ushort8_t*)(xb + (((nt * 16 + c) * 256 + kt * 64 + g * 16) ^ xr));
#pragma unroll
  for (int ti = 0; ti < 3; ti++) {
    int t = w * 3 + ti;                // 0..23
    int m = t >> 3;                    // 0=q 1=k 2=v
    int colb = (t & 7) * 16;
    const float* bias = (m == 0 ? qb_l : (m == 1 ? kb_l : vb_l));
    float4 bv = *(const float4*)(bias + colb + g * 4);
    f32x4_t acc0 = {bv.x, bv.y, bv.z, bv.w};
    f32x4_t acc1 = acc0;
    const ushort* wp = qkvT_l + (size_t)(m * DD + colb + c) * DD + g * 8;
#pragma unroll
    for (int kt = 0; kt < 4; kt++) {
      BF8 b; b.u = *(const ushort8_t*)(wp + kt * 32);
      acc0 = __builtin_amdgcn_mfma_f32_16x16x32_bf16(b.b, a[0][kt].b, acc0, 0, 0, 0);
      acc1 = __builtin_amdgcn_mfma_f32_16x16x32_bf16(b.b, a[1][kt].b, acc1, 0, 0, 0);
    }
    ushort* out = (m == 0 ? q : (m == 1 ? kk : v));
    int n0 = nb + c;
    if (n0 < NN) {
      ushort4 o; o.x = f2bf(acc0[0]); o.y = f2bf(acc0[1]); o.z = f2bf(acc0[2]); o.w = f2bf(acc0[3]);
      *(ushort4*)(out + (size_t)n0 * DD + colb + g * 4) = o;
    }
    int n1 = nb + 16 + c;
    if (n1 < NN) {
      ushort4 o; o.x = f2bf(acc1[0]); o.y = f2bf(acc1[1]); o.z = f2bf(acc1[2]); o.w = f2bf(acc1[3]);
      *(ushort4*)(out + (size_t)n1 * DD + colb + g * 4) = o;
    }
  }
}

// per (edge, head): curv + PWL segment staged in LDS by first 32 threads, then
// qk dot (bf16) + PWL bias -> RAW score (softmax handled by k_softmax_t; the
// max subtraction stays MANDATORY — r5/r6: self-loop dist==0 -> |bias| ~ 1e4).
__global__ __launch_bounds__(256) void k_scores(const int* __restrict__ src_s, const int* __restrict__ tgt_s,
    const ushort* __restrict__ q, const ushort* __restrict__ k,
    const float* __restrict__ dist, const float* __restrict__ aggv,
    const float* __restrict__ bp_g,
    const float* __restrict__ slope_l, const float* __restrict__ inter_l,
    float* __restrict__ escore) {
  __shared__ float lsl[NSEG * HH], lin[NSEG * HH], bp[DD];
  __shared__ float lcurv[32];
  __shared__ int   lseg[32];
  int tid = threadIdx.x;
  for (int idx = tid; idx < NSEG * HH; idx += 256) { lsl[idx] = slope_l[idx]; lin[idx] = inter_l[idx]; }
  if (tid < DD) bp[tid] = bp_g[tid];
  __syncthreads();
  int eb = blockIdx.x * 32;
  if (tid < 32) {
    int e = eb + tid;
    if (e < NE) {
      int t = tgt_s[e];
      float curv = 1.0f - aggv[t] / fmaxf(dist[e], 1e-6f);
      int lo = 0, hi = DD;
      while (lo < hi) { int mid = (lo + hi) >> 1; if (bp[mid] < curv) lo = mid + 1; else hi = mid; }
      lcurv[tid] = curv;
      lseg[tid] = lo;
    }
  }
  __syncthreads();
  int gi = blockIdx.x * 256 + tid;
  if (gi >= NE * HH) return;
  int i = gi >> 3, hh = gi & 7;
  int s = src_s[i], t = tgt_s[i];
  int li = tid >> 3;
  float curv = lcurv[li];
  int seg = lseg[li];
  float bias = fmaf(lsl[seg * HH + hh], curv, lin[seg * HH + hh]);
  const ushort8_t* qp = (const ushort8_t*)(q + (size_t)s * DD + hh * DHH);
  const ushort8_t* kp = (const ushort8_t*)(k + (size_t)t * DD + hh * DHH);
  float dot = 0.f;
#pragma unroll
  for (int ii = 0; ii < 2; ii++) {
    ushort8_t a = qp[ii], b = kp[ii];
#pragma unroll
    for (int jj = 0; jj < 8; jj++) dot = fmaf(bf2f(a[jj]), bf2f(b[jj]), dot);
  }
  escore[gi] = dot * 0.25f + bias;   // 1/sqrt(16)
  (void)t;
}

// attention softmax stats per (tgt node, head) via tgt-CSR gather, READ-ONLY:
// max pass + sum pass (same value/order as r12 -> p bits identical when k_agg
// recomputes exp). Outputs packed (m, 1/sum). No 20MB escore rewrite.
__global__ __launch_bounds__(256) void k_softmax_t(const int* __restrict__ rowstart_t,
    const int* __restrict__ eid_t, const float* __restrict__ escore, float2* __restrict__ msd) {
  int node = blockIdx.x * 32 + (threadIdx.x >> 3);
  if (node >= NN) return;
  int hh = threadIdx.x & 7;
  int rs = rowstart_t[node], re = rowstart_t[node + 1];
  float m = -3.4e38f;
  int i = rs;
  for (; i + 4 <= re; i += 4) {
    int e0 = eid_t[i], e1 = eid_t[i + 1], e2 = eid_t[i + 2], e3 = eid_t[i + 3];
    float s0 = escore[e0 * HH + hh];
    float s1 = escore[e1 * HH + hh];
    float s2 = escore[e2 * HH + hh];
    float s3 = escore[e3 * HH + hh];
    m = fmaxf(m, s0); m = fmaxf(m, s1); m = fmaxf(m, s2); m = fmaxf(m, s3);
  }
  for (; i < re; i++) m = fmaxf(m, escore[eid_t[i] * HH + hh]);
  float sum = 0.f;
  i = rs;
  for (; i + 4 <= re; i += 4) {
    int e0 = eid_t[i], e1 = eid_t[i + 1], e2 = eid_t[i + 2], e3 = eid_t[i + 3];
    float p0 = expf(escore[e0 * HH + hh] - m);
    float p1 = expf(escore[e1 * HH + hh] - m);
    float p2 = expf(escore[e2 * HH + hh] - m);
    float p3 = expf(escore[e3 * HH + hh] - m);
    sum += p0; sum += p1; sum += p2; sum += p3;
  }
  for (; i < re; i++) sum += expf(escore[eid_t[i] * HH + hh] - m);
  float2 o; o.x = m; o.y = sum > 0.f ? 1.0f / sum : 0.f;
  msd[(size_t)node * HH + hh] = o;
}

// CSR-gather message aggregation: one wave per src node, 2 dims/lane -> bf16 out.
// 4-deep software-pipelined; p recomputed inline from raw score + (m, inv) —
// identical bits to the r12 stored-p path.
__global__ __launch_bounds__(256) void k_agg(const int* __restrict__ tgt_s,
    const int* __restrict__ rowstart,
    const float* __restrict__ escore, const float2* __restrict__ msd,
    const ushort* __restrict__ v, ushort* __restrict__ aggmb) {
  int wave = (blockIdx.x * 256 + threadIdx.x) >> 6;
  int lane = threadIdx.x & 63;
  int rs = rowstart[wave], re = rowstart[wave + 1];
  int hh = lane >> 3;
  int d = lane * 2;
  float a0 = 0.f, a1 = 0.f;
  int i = rs;
  for (; i + 4 <= re; i += 4) {
    int t0 = tgt_s[i], t1 = tgt_s[i + 1], t2 = tgt_s[i + 2], t3 = tgt_s[i + 3];
    float e0 = escore[(i    ) * HH + hh];
    float e1 = escore[(i + 1) * HH + hh];
    float e2 = escore[(i + 2) * HH + hh];
    float e3 = escore[(i + 3) * HH + hh];
    float2 m0 = msd[(size_t)t0 * HH + hh], m1 = msd[(size_t)t1 * HH + hh];
    float2 m2 = msd[(size_t)t2 * HH + hh], m3 = msd[(size_t)t3 * HH + hh];
    ushort2 v0 = *(const ushort2*)(v + (size_t)t0 * DD + d);
    ushort2 v1 = *(const ushort2*)(v + (size_t)t1 * DD + d);
    ushort2 v2 = *(const ushort2*)(v + (size_t)t2 * DD + d);
    ushort2 v3 = *(const ushort2*)(v + (size_t)t3 * DD + d);
    float p0 = expf(e0 - m0.x) * m0.y;
    float p1 = expf(e1 - m1.x) * m1.y;
    float p2 = expf(e2 - m2.x) * m2.y;
    float p3 = expf(e3 - m3.x) * m3.y;
    a0 = fmaf(p0, bf2f(v0.x), a0); a1 = fmaf(p0, bf2f(v0.y), a1);
    a0 = fmaf(p1, bf2f(v1.x), a0); a1 = fmaf(p1, bf2f(v1.y), a1);
    a0 = fmaf(p2, bf2f(v2.x), a0); a1 = fmaf(p2, bf2f(v2.y), a1);
    a0 = fmaf(p3, bf2f(v3.x), a0); a1 = fmaf(p3, bf2f(v3.y), a1);
  }
  for (; i < re; i++) {
    int t = tgt_s[i];
    float2 md = msd[(size_t)t * HH + hh];
    float prob = expf(escore[i * HH + hh] - md.x) * md.y;
    ushort2 vv = *(const ushort2*)(v + (size_t)t * DD + d);
    a0 = fmaf(prob, bf2f(vv.x), a0);
    a1 = fmaf(prob, bf2f(vv.y), a1);
  }
  ushort2 o; o.x = f2bf(a0); o.y = f2bf(a1);
  *(ushort2*)(aggmb + (size_t)wave * DD + d) = o;
}

// h += aggm @ oW + ob via swapped-operand MFMA; 32 rows/block, 8 waves, float4 RMW.
__global__ __launch_bounds__(512) void k_update_o(const ushort* __restrict__ aggmb,
    const ushort* __restrict__ oT_l, const float* __restrict__ ob_l, float* __restrict__ h) {
  int nb = blockIdx.x * 32;
  int lane = threadIdx.x & 63, w = threadIdx.x >> 6;
  int g = lane >> 4, c = lane & 15;
  BF8 a[2][4];
#pragma unroll
  for (int nt = 0; nt < 2; nt++) {
    int na = nb + nt * 16 + c; if (na >= NN) na = NN - 1;
    const ushort* ap = aggmb + (size_t)na * DD + g * 8;
#pragma unroll
    for (int kt = 0; kt < 4; kt++) a[nt][kt].u = *(const ushort8_t*)(ap + kt * 32);
  }
  int colb = w * 16;
  float4 bv = *(const float4*)(ob_l + colb + g * 4);
  f32x4_t acc0 = {bv.x, bv.y, bv.z, bv.w};
  f32x4_t acc1 = acc0;
  const ushort* wp = oT_l + (size_t)(colb + c) * DD + g * 8;
#pragma unroll
  for (int kt = 0; kt < 4; kt++) {
    BF8 b; b.u = *(const ushort8_t*)(wp + kt * 32);
    acc0 = __builtin_amdgcn_mfma_f32_16x16x32_bf16(b.b, a[0][kt].b, acc0, 0, 0, 0);
    acc1 = __builtin_amdgcn_mfma_f32_16x16x32_bf16(b.b, a[1][kt].b, acc1, 0, 0, 0);
  }
#pragma unroll
  for (int nt = 0; nt < 2; nt++) {
    int node = nb + nt * 16 + c;
    if (node < NN) {
      float* hp = h + (size_t)node * DD + colb + g * 4;
      float4 hv = *(const float4*)hp;
      f32x4_t& acc = nt ? acc1 : acc0;
      hv.x += acc[0]; hv.y += acc[1]; hv.z += acc[2]; hv.w += acc[3];
      *(float4*)hp = hv;
    }
  }
}

// fused FFN, BM=64: h += relu(LN2(h)@f1W+f1b)@f2W+f2b; 64 rows/block, 8 waves.
__global__ __launch_bounds__(512) void k_ffn(const float* __restrict__ n2s_l, const float* __restrict__ n2b_l,
    const ushort* __restrict__ f1T_l, const float* __restrict__ f1b_l,
    const ushort* __restrict__ f2T_l, const float* __restrict__ f2b_l,
    float* __restrict__ h) {
  __shared__ __align__(16) ushort xbf[64 * DD];      // 16 KB
  __shared__ __align__(16) ushort tbf[64 * 256];     // 32 KB
  int nb = blockIdx.x * 64;
  ln_tile_bf64(h, nb, n2s_l, n2b_l, xbf);
  __syncthreads();
  int lane = threadIdx.x & 63, w = threadIdx.x >> 6;
  int g = lane >> 4, c = lane & 15;
  int xr = (c & 7) << 4;
  char* xb = (char*)xbf;
  char* tb = (char*)tbf;
  BF8 a[4][4];
#pragma unroll
  for (int nt = 0; nt < 4; nt++)
#pragma unroll
    for (int kt = 0; kt < 4; kt++)
      a[nt][kt].u = *(ushort8_t*)(xb + (((nt * 16 + c) * 256 + kt * 64 + g * 16) ^ xr));
  int colb2 = w * 16;
  float4 bv2 = *(const float4*)(f2b_l + colb2 + g * 4);
  f32x4_t o0 = {bv2.x, bv2.y, bv2.z, bv2.w};
  f32x4_t o1 = o0, o2 = o0, o3 = o0;
#pragma unroll
  for (int ch = 0; ch < 2; ch++) {
    if (ch) __syncthreads();           // tbf reuse: wait for chunk-0 reads
#pragma unroll
    for (int ti = 0; ti < 2; ti++) {
      int ctile = w * 2 + ti;          // 0..15 within chunk
      int col = ch * 256 + ctile * 16;
      float4 bv = *(const float4*)(f1b_l + col + g * 4);
      f32x4_t ac0 = {bv.x, bv.y, bv.z, bv.w};
      f32x4_t ac1 = ac0, ac2 = ac0, ac3 = ac0;
      const ushort* wp = f1T_l + (size_t)(col + c) * DD + g * 8;
#pragma unroll
      for (int kt = 0; kt < 4; kt++) {
        BF8 b; b.u = *(const ushort8_t*)(wp + kt * 32);
        ac0 = __builtin_amdgcn_mfma_f32_16x16x32_bf16(b.b, a[0][kt].b, ac0, 0, 0, 0);
        ac1 = __builtin_amdgcn_mfma_f32_16x16x32_bf16(b.b, a[1][kt].b, ac1, 0, 0, 0);
        ac2 = __builtin_amdgcn_mfma_f32_16x16x32_bf16(b.b, a[2][kt].b, ac2, 0, 0, 0);
        ac3 = __builtin_amdgcn_mfma_f32_16x16x32_bf16(b.b, a[3][kt].b, ac3, 0, 0, 0);
      }
      int colL = (ctile * 16 + g * 4) * 2;     // byte col within chunk tile
      {
        int row = c;
        ushort4 o4; o4.x = f2bf(fmaxf(ac0[0], 0.f)); o4.y = f2bf(fmaxf(ac0[1], 0.f));
        o4.z = f2bf(fmaxf(ac0[2], 0.f)); o4.w = f2bf(fmaxf(ac0[3], 0.f));
        *(ushort4*)(tb + ((row * 512 + colL) ^ ((row & 7) << 4))) = o4;
      }
      {
        int row = 16 + c;
        ushort4 o4; o4.x = f2bf(fmaxf(ac1[0], 0.f)); o4.y = f2bf(fmaxf(ac1[1], 0.f));
        o4.z = f2bf(fmaxf(ac1[2], 0.f)); o4.w = f2bf(fmaxf(ac1[3], 0.f));
        *(ushort4*)(tb + ((row * 512 + colL) ^ ((row & 7) << 4))) = o4;
      }
      {
        int row = 32 + c;
        ushort4 o4; o4.x = f2bf(fmaxf(ac2[0], 0.f)); o4.y = f2bf(fmaxf(ac2[1], 0.f));
        o4.z = f2bf(fmaxf(ac2[2], 0.f)); o4.w = f2bf(fmaxf(ac2[3], 0.f));
        *(ushort4*)(tb + ((row * 512 + colL) ^ ((row & 7) << 4))) = o4;
      }
      {
        int row = 48 + c;
        ushort4 o4; o4.x = f2bf(fmaxf(ac3[0], 0.f)); o4.y = f2bf(fmaxf(ac3[1], 0.f));
        o4.z = f2bf(fmaxf(ac3[2], 0.f)); o4.w = f2bf(fmaxf(ac3[3], 0.f));
        *(ushort4*)(tb + ((row * 512 + colL) ^ ((row & 7) << 4))) = o4;
      }
    }
    __syncthreads();
    const ushort* wp2 = f2T_l + (size_t)(colb2 + c) * 512 + ch * 256 + g * 8;
#pragma unroll
    for (int kt = 0; kt < 8; kt++) {
      BF8 b; b.u = *(const ushort8_t*)(wp2 + kt * 32);
      BF8 t0; t0.u = *(ushort8_t*)(tb + (((c) * 512 + kt * 64 + g * 16) ^ xr));
      BF8 t1; t1.u = *(ushort8_t*)(tb + (((16 + c) * 512 + kt * 64 + g * 16) ^ xr));
      BF8 t2; t2.u = *(ushort8_t*)(tb + (((32 + c) * 512 + kt * 64 + g * 16) ^ xr));
      BF8 t3; t3.u = *(ushort8_t*)(tb + (((48 + c) * 512 + kt * 64 + g * 16) ^ xr));
      o0 = __builtin_amdgcn_mfma_f32_16x16x32_bf16(b.b, t0.b, o0, 0, 0, 0);
      o1 = __builtin_amdgcn_mfma_f32_16x16x32_bf16(b.b, t1.b, o1, 0, 0, 0);
      o2 = __builtin_amdgcn_mfma_f32_16x16x32_bf16(b.b, t2.b, o2, 0, 0, 0);
      o3 = __builtin_amdgcn_mfma_f32_16x16x32_bf16(b.b, t3.b, o3, 0, 0, 0);
    }
  }
  {
    int node = nb + c;
    if (node < NN) {
      float* hp = h + (size_t)node * DD + colb2 + g * 4;
      float4 hv = *(const float4*)hp;
      hv.x += o0[0]; hv.y += o0[1]; hv.z += o0[2]; hv.w += o0[3];
      *(float4*)hp = hv;
    }
  }
  {
    int node = nb + 16 + c;
    if (node < NN) {
      float* hp = h + (size_t)node * DD + colb2 + g * 4;
      float4 hv = *(const float4*)hp;
      hv.x += o1[0]; hv.y += o1[1]; hv.z += o1[2]; hv.w += o1[3];
      *(float4*)hp = hv;
    }
  }
  {
    int node = nb + 32 + c;
    if (node < NN) {
      float* hp = h + (size_t)node * DD + colb2 + g * 4;
      float4 hv = *(const float4*)hp;
      hv.x += o2[0]; hv.y += o2[1]; hv.z += o2[2]; hv.w += o2[3];
      *(float4*)hp = hv;
    }
  }
  {
    int node = nb + 48 + c;
    if (node < NN) {
      float* hp = h + (size_t)node * DD + colb2 + g * 4;
      float4 hv = *(const float4*)hp;
      hv.x += o3[0]; hv.y += o3[1]; hv.z += o3[2]; hv.w += o3[3];
      *(float4*)hp = hv;
    }
  }
}

// ---------- once-per-call setup kernels ----------
// transpose fp32 [K][C] -> bf16 [C][K], nm stacked matrices, dst stride per matrix
template <int K, int C>
__global__ void k_wt(const float* __restrict__ W, ushort* __restrict__ WT, int nm, int dstride) {
  int idx = blockIdx.x * 256 + threadIdx.x;
  if (idx >= K * C * nm) return;
  int mi = idx / (K * C), rem = idx - mi * (K * C);
  int cc = rem / K, kk2 = rem - cc * K;
  WT[(size_t)mi * dstride + cc * K + kk2] = f2bf(W[(size_t)mi * K * C + (size_t)kk2 * C + cc]);
}

__global__ void k_hist(const int* __restrict__ idxs, int* __restrict__ cnt) {
  int e = blockIdx.x * 256 + threadIdx.x;
  if (e < NE) atomicAdd(cnt + idxs[e], 1);
}

// multi-block exclusive scan of cnt[NN] -> rowstart
__global__ __launch_bounds__(256) void k_scan_blk(const int* __restrict__ cnt, int* __restrict__ bsum) {
  __shared__ int red[256];
  int tid = threadIdx.x;
  int idx = blockIdx.x * 256 + tid;
  red[tid] = (idx < NN) ? cnt[idx] : 0;
  __syncthreads();
  for (int off = 128; off >= 1; off >>= 1) {
    if (tid < off) red[tid] += red[tid + off];
    __syncthreads();
  }
  if (tid == 0) bsum[blockIdx.x] = red[0];
}

__global__ __launch_bounds__(256) void k_scan_top(const int* __restrict__ bsum,
                                                  int* __restrict__ boff, int* __restrict__ rowstart) {
  __shared__ int ps[256];
  int t = threadIdx.x;
  int v = (t < NBS) ? bsum[t] : 0;
  ps[t] = v;
  __syncthreads();
  for (int off = 1; off < 256; off <<= 1) {
    int x = (t >= off) ? ps[t - off] : 0;
    __syncthreads();
    ps[t] += x;
    __syncthreads();
  }
  boff[t] = ps[t] - v;                 // exclusive prefix of block sums
  if (t == 255) rowstart[NN] = ps[255];
}

__global__ __launch_bounds__(256) void k_scan_fin(const int* __restrict__ cnt,
                                                  const int* __restrict__ boff, int* __restrict__ rowstart) {
  __shared__ int ps[256];
  int t = threadIdx.x;
  int idx = blockIdx.x * 256 + t;
  int v = (idx < NN) ? cnt[idx] : 0;
  ps[t] = v;
  __syncthreads();
  for (int off = 1; off < 256; off <<= 1) {
    int x = (t >= off) ? ps[t - off] : 0;
    __syncthreads();
    ps[t] += x;
    __syncthreads();
  }
  if (idx < NN) rowstart[idx] = boff[blockIdx.x] + ps[t] - v;
}

// scatter edges into src-sorted order (all per-edge arrays use sorted index)
__global__ void k_fill(const int* __restrict__ src, const int* __restrict__ tgt,
                       const int* __restrict__ rowstart,
                       int* __restrict__ cur, int* __restrict__ src_s, int* __restrict__ tgt_s) {
  int e = blockIdx.x * 256 + threadIdx.x;
  if (e >= NE) return;
  int s = src[e];
  int p = atomicAdd(cur + s, 1);
  int pos = rowstart[s] + p;
  src_s[pos] = s;
  tgt_s[pos] = tgt[e];
}

// tgt-CSR: list of src-sorted edge ids per tgt node
__global__ void k_fill_t(const int* __restrict__ tgt_s, const int* __restrict__ rowstart_t,
                         int* __restrict__ cur_t, int* __restrict__ eid_t) {
  int i = blockIdx.x * 256 + threadIdx.x;
  if (i >= NE) return;
  int t = tgt_s[i];
  int p = atomicAdd(cur_t + t, 1);
  eid_t[rowstart_t[t] + p] = i;
}

// M[l][d][hh] = Sum_k cW2[d][k]*bW[l][k][hh]. Wave-parallel: one block per (l,d).
__global__ __launch_bounds__(64) void k_mbias_par(const float* __restrict__ cW2, const float* __restrict__ cb2,
                                                  const float* __restrict__ bW, const float* __restrict__ bb,
                                                  float* __restrict__ M, float* __restrict__ base) {
  int bid = blockIdx.x;
  int l = bid >> 7, d = bid & 127;
  int lane = threadIdx.x;
  int hh = lane >> 3, j0 = lane & 7;
  const float* bWl = bW + (size_t)l * DD * HH;
  float acc = 0.f;
#pragma unroll
  for (int t = 0; t < 16; t++) {
    int k = j0 + t * 8;
    acc = fmaf(cW2[d * DD + k], bWl[k * HH + hh], acc);
  }
#pragma unroll
  for (int off = 1; off <= 4; off <<= 1) acc += __shfl_xor(acc, off, 64);
  if (j0 == 0) M[(size_t)l * DD * HH + d * HH + hh] = acc;
  if (d == 0) {
    float bacc = 0.f;
#pragma unroll
    for (int t = 0; t < 16; t++) {
      int k = j0 + t * 8;
      bacc = fmaf(cb2[k], bWl[k * HH + hh], bacc);
    }
#pragma unroll
    for (int off = 1; off <= 4; off <<= 1) bacc += __shfl_xor(bacc, off, 64);
    if (j0 == 0) base[l * HH + hh] = bacc + bb[l * HH + hh];
  }
}

// sorted breakpoints + ranks — cW1/cb1 are layer-INDEPENDENT, computed once.
__global__ __launch_bounds__(128) void k_bp(const float* __restrict__ cW1, const float* __restrict__ cb1,
                                            float* __restrict__ bpg, int* __restrict__ posg) {
  __shared__ float x[DD], bp[DD];
  int tid = threadIdx.x;
  float c1v = cW1[tid], cbv = cb1[tid];
  x[tid] = (c1v == 0.f) ? __builtin_inff() : (-cbv / c1v);
  __syncthreads();
  float xv = x[tid]; int p = 0;
  for (int j = 0; j < DD; j++) {
    float xj = x[j];
    if (xj < xv || (xj == xv && j < tid)) p++;
  }
  bp[p] = xv;
  posg[tid] = p;
  __syncthreads();
  bpg[tid] = bp[tid];
}

// PWL table, wave-parallel: one block per (l, segment).
__global__ __launch_bounds__(64) void k_pwl_tab(const float* __restrict__ cW1, const float* __restrict__ cb1,
    const int* __restrict__ posg, const float* __restrict__ Mb, const float* __restrict__ basel,
    float* __restrict__ slopeg, float* __restrict__ interg) {
  int bid = blockIdx.x;
  int l = bid / NSEG, s = bid - l * NSEG;
  int lane = threadIdx.x;
  int hh = lane >> 3, j0 = lane & 7;
  const float* M = Mb + (size_t)l * DD * HH;
  float sl = 0.f, in = 0.f;
#pragma unroll
  for (int t = 0; t < 16; t++) {
    int d = j0 + t * 8;
    float cv = cW1[d], cbv = cb1[d];
    int p = posg[d];
    bool act = (cv == 0.f) ? (cbv > 0.f) : ((cv > 0.f) ? (p < s) : (p >= s));
    float m = act ? M[d * HH + hh] : 0.f;
    sl = fmaf(cv, m, sl);
    in = fmaf(cbv, m, in);
  }
#pragma unroll
  for (int off = 1; off <= 4; off <<= 1) {
    sl += __shfl_xor(sl, off, 64);
    in += __shfl_xor(in, off, 64);
  }
  if (j0 == 0) {
    size_t o = (size_t)l * NSEG * HH + s * HH + hh;
    slopeg[o] = sl;
    interg[o] = in + basel[l * HH + hh];
  }
}

__global__ void k_bounds(const int* __restrict__ batch, int* __restrict__ gstart, int* __restrict__ gend) {
  int n = blockIdx.x * 256 + threadIdx.x;
  if (n >= NN) return;
  int b = batch[n];
  if (n == 0 || batch[n - 1] != b) gstart[b] = n;
  if (n == NN - 1 || batch[n + 1] != b) gend[b] = n + 1;
}

// parallel pool: 256 nodes/block, running sums flushed at graph boundaries
__global__ __launch_bounds__(256) void k_pool_part(const float* __restrict__ h,
    const int* __restrict__ batch, float* __restrict__ gpool) {
  int tid = threadIdx.x;
  int d = tid & 127, sub = tid >> 7;
  int n0 = blockIdx.x * 256;
  int nend = n0 + 256; if (nend > NN) nend = NN;
  float run = 0.f; int gcur = -1;
  for (int n = n0 + sub; n < nend; n += 2) {
    int g = batch[n];
    if (g != gcur) {
      if (gcur >= 0) atomicAdd(gpool + (size_t)gcur * DD + d, run);
      run = 0.f; gcur = g;
    }
    run += h[(size_t)n * DD + d];
  }
  if (gcur >= 0) atomicAdd(gpool + (size_t)gcur * DD + d, run);
}

__global__ __launch_bounds__(256) void k_head(const float* __restrict__ gpool,
    const int* __restrict__ gstart, const int* __restrict__ gend,
    const float* __restrict__ W1, const float* __restrict__ b1,
    const float* __restrict__ W2, const float* __restrict__ b2, float* __restrict__ out) {
  __shared__ float mid[NG * 64];
  int tid = threadIdx.x;
  for (int idx = tid; idx < NG * 64; idx += 256) {
    int g = idx >> 6, j = idx & 63;
    int cnt = gend[g] - gstart[g]; if (cnt < 1) cnt = 1;
    float rc = 1.0f / (float)cnt;
    float acc = 0.f;
    for (int d = 0; d < DD; d++) acc = fmaf(gpool[g * DD + d], W1[d * 64 + j], acc);
    mid[idx] = fmaxf(fmaf(acc, rc, b1[j]), 0.f);
  }
  __syncthreads();
  if (tid < NG) {
    float acc = b2[0];
    for (int j = 0; j < 64; j++) acc = fmaf(mid[tid * 64 + j], W2[j], acc);
    out[tid] = acc;
  }
}

// ---------- launch ----------
extern "C" void kernel_launch(void* const* d_in, const int* in_sizes, int n_in,
                              void* d_out, int out_size, void* d_ws, size_t ws_size,
                              hipStream_t stream) {
  const float* x      = (const float*)d_in[0];
  const int*   ei     = (const int*)d_in[1];
  const int*   batch  = (const int*)d_in[2];
  const float* node_W = (const float*)d_in[3];
  const float* node_b = (const float*)d_in[4];
  const float* cW1    = (const float*)d_in[5];
  const float* cb1    = (const float*)d_in[6];
  const float* cW2    = (const float*)d_in[7];
  const float* cb2    = (const float*)d_in[8];
  const float* qW     = (const float*)d_in[9];
  const float* qb     = (const float*)d_in[10];
  const float* kW     = (const float*)d_in[11];
  const float* kb     = (const float*)d_in[12];
  const float* vW     = (const float*)d_in[13];
  const float* vb     = (const float*)d_in[14];
  const float* oW     = (const float*)d_in[15];
  const float* ob     = (const float*)d_in[16];
  const float* bW     = (const float*)d_in[17];
  const float* bb     = (const float*)d_in[18];
  const float* f1W    = (const float*)d_in[19];
  const float* f1b    = (const float*)d_in[20];
  const float* f2W    = (const float*)d_in[21];
  const float* f2b    = (const float*)d_in[22];
  const float* n1s    = (const float*)d_in[23];
  const float* n1b    = (const float*)d_in[24];
  const float* n2s    = (const float*)d_in[25];
  const float* n2b    = (const float*)d_in[26];
  const float* outW1  = (const float*)d_in[27];
  const float* outb1  = (const float*)d_in[28];
  const float* outW2  = (const float*)d_in[29];
  const float* outb2  = (const float*)d_in[30];

  const int* src = ei;
  const int* tgt = ei + NE;

  char* wp = (char*)d_ws;
  auto alloc = [&](size_t bytes) { void* p = (void*)wp; wp += (bytes + 255) & ~(size_t)255; return p; };
  float*    h       = (float*)alloc((size_t)NN * DD * 4);
  ushort*   q       = (ushort*)alloc((size_t)NN * DD * 2);
  ushort*   kk      = (ushort*)alloc((size_t)NN * DD * 2);
  ushort*   v       = (ushort*)alloc((size_t)NN * DD * 2);
  ushort*   aggmb   = (ushort*)alloc((size_t)NN * DD * 2);
  float*    sim     = (float*)alloc((size_t)NE * 4);
  float*    dist    = (float*)alloc((size_t)NE * 4);
  float*    escore  = (float*)alloc((size_t)NE * HH * 4);
  float2*   msd     = (float2*)alloc((size_t)NN * HH * 8);
  float*    aggv    = (float*)alloc((size_t)NN * 4);
  float*    Mb      = (float*)alloc((size_t)NL * DD * HH * 4);
  float*    basel   = (float*)alloc((size_t)NL * HH * 4);
  float*    bpg     = (float*)alloc((size_t)DD * 4);
  int*      posg    = (int*)alloc((size_t)DD * 4);
  float*    slopeg  = (float*)alloc((size_t)NL * NSEG * HH * 4);
  float*    interg  = (float*)alloc((size_t)NL * NSEG * HH * 4);
  int*      rowstart= (int*)alloc((size_t)(NN + 1) * 4);
  int*      rowstart_t = (int*)alloc((size_t)(NN + 1) * 4);
  int*      eid_t   = (int*)alloc((size_t)NE * 4);
  int*      src_s   = (int*)alloc((size_t)NE * 4);
  int*      tgt_s   = (int*)alloc((size_t)NE * 4);
  int*      cnt     = (int*)alloc((size_t)NN * 4);
  int*      cur     = (int*)alloc((size_t)NN * 4);
  int*      cnt_t   = (int*)alloc((size_t)NN * 4);
  int*      cur_t   = (int*)alloc((size_t)NN * 4);
  int*      bsum    = (int*)alloc((size_t)NBS * 4);
  int*      boff    = (int*)alloc((size_t)256 * 4);
  int*      gstart  = (int*)alloc((size_t)NG * 4);
  int*      gend    = (int*)alloc((size_t)NG * 4);
  float*    gpool   = (float*)alloc((size_t)NG * DD * 4);
  ushort*   qkvT    = (ushort*)alloc((size_t)NL * 3 * DD * DD * 2);
  ushort*   oT      = (ushort*)alloc((size_t)NL * DD * DD * 2);
  ushort*   f1T     = (ushort*)alloc((size_t)NL * DD * 512 * 2);
  ushort*   f2T     = (ushort*)alloc((size_t)NL * 512 * DD * 2);
  (void)in_sizes; (void)n_in; (void)out_size; (void)ws_size;

  // once-per-call setup
  hipMemsetAsync(cnt, 0, NN * 4, stream);
  hipMemsetAsync(cur, 0, NN * 4, stream);
  hipMemsetAsync(cnt_t, 0, NN * 4, stream);
  hipMemsetAsync(cur_t, 0, NN * 4, stream);
  hipMemsetAsync(gstart, 0, NG * 4, stream);
  hipMemsetAsync(gend, 0, NG * 4, stream);
  hipMemsetAsync(gpool, 0, NG * DD * 4, stream);
  // src-CSR (edge sort) and tgt-CSR (incoming-edge lists)
  k_hist<<<(NE + 255) / 256, 256, 0, stream>>>(src, cnt);
  k_scan_blk<<<NBS, 256, 0, stream>>>(cnt, bsum);
  k_scan_top<<<1, 256, 0, stream>>>(bsum, boff, rowstart);
  k_scan_fin<<<NBS, 256, 0, stream>>>(cnt, boff, rowstart);
  k_fill<<<(NE + 255) / 256, 256, 0, stream>>>(src, tgt, rowstart, cur, src_s, tgt_s);
  k_hist<<<(NE + 255) / 256, 256, 0, stream>>>(tgt, cnt_t);
  k_scan_blk<<<NBS, 256, 0, stream>>>(cnt_t, bsum);
  k_scan_top<<<1, 256, 0, stream>>>(bsum, boff, rowstart_t);
  k_scan_fin<<<NBS, 256, 0, stream>>>(cnt_t, boff, rowstart_t);
  k_fill_t<<<(NE + 255) / 256, 256, 0, stream>>>(tgt_s, rowstart_t, cur_t, eid_t);
  k_mbias_par<<<NL * DD, 64, 0, stream>>>(cW2, cb2, bW, bb, Mb, basel);
  k_bp<<<1, 128, 0, stream>>>(cW1, cb1, bpg, posg);
  k_pwl_tab<<<NL * NSEG, 64, 0, stream>>>(cW1, cb1, posg, Mb, basel, slopeg, interg);
  k_bounds<<<(NN + 255) / 256, 256, 0, stream>>>(batch, gstart, gend);
  // bf16-transposed weights
  k_wt<DD, DD><<<(NL * DD * DD + 255) / 256, 256, 0, stream>>>(qW, qkvT,               NL, 3 * DD * DD);
  k_wt<DD, DD><<<(NL * DD * DD + 255) / 256, 256, 0, stream>>>(kW, qkvT + DD * DD,     NL, 3 * DD * DD);
  k_wt<DD, DD><<<(NL * DD * DD + 255) / 256, 256, 0, stream>>>(vW, qkvT + 2 * DD * DD, NL, 3 * DD * DD);
  k_wt<DD, DD><<<(NL * DD * DD + 255) / 256, 256, 0, stream>>>(oW, oT, NL, DD * DD);
  k_wt<DD, 512><<<(NL * DD * 512 + 255) / 256, 256, 0, stream>>>(f1W, f1T, NL, DD * 512);
  k_wt<512, DD><<<(NL * DD * 512 + 255) / 256, 256, 0, stream>>>(f2W, f2T, NL, DD * 512);
  k_node_proj<<<NT32, 256, 0, stream>>>(x, node_W, node_b, h);

  for (int l = 0; l < NL; l++) {
    k_edge1<<<(NE * 16 + 255) / 256, 256, 0, stream>>>(src_s, tgt_s, h, sim, dist);
    k_curva<<<NT32, 256, 0, stream>>>(rowstart_t, eid_t, sim, dist, aggv);
    k_ln_qkv<<<NT32, 512, 0, stream>>>(h, n1s + l * DD, n1b + l * DD,
        qkvT + (size_t)l * 3 * DD * DD,
        qb + l * DD, kb + l * DD, vb + l * DD, q, kk, v);
    k_scores<<<(NE * HH + 255) / 256, 256, 0, stream>>>(src_s, tgt_s, q, kk,
        dist, aggv, bpg,
        slopeg + (size_t)l * NSEG * HH, interg + (size_t)l * NSEG * HH,
        escore);
    k_softmax_t<<<NT32, 256, 0, stream>>>(rowstart_t, eid_t, escore, msd);
    k_agg<<<NN / 4, 256, 0, stream>>>(tgt_s, rowstart, escore, msd, v, aggmb);
    k_update_o<<<NT32, 512, 0, stream>>>(aggmb, oT + (size_t)l * DD * DD, ob + l * DD, h);
    k_ffn<<<NT64, 512, 0, stream>>>(n2s + l * DD, n2b + l * DD,
        f1T + (size_t)l * DD * 512, f1b + (size_t)l * 4 * DD,
        f2T + (size_t)l * 512 * DD, f2b + l * DD, h);
  }
  k_pool_part<<<(NN + 255) / 256, 256, 0, stream>>>(h, batch, gpool);
  k_head<<<1, 256, 0, stream>>>(gpool, gstart, gend, outW1, outb1, outW2, outb2, (float*)d_out);
}

// Round 14
// 1372.091 us; speedup vs baseline: 3.1718x; 1.0257x over previous
//
#include <hip/hip_runtime.h>

#define NN 50000      // nodes
#define NE 625000     // edges
#define DD 128        // hidden dim
#define HH 8          // heads
#define DHH 16        // head dim
#define NL 4          // layers
#define FIN 64        // in channels
#define NG 64         // graphs
#define LN_EPS 1e-5f
#define NSEG 129      // PWL segments = 128 breakpoints + 1
#define NT32 1563     // ceil(NN/32)
#define NT64 782      // ceil(NN/64)
#define NBS 196       // ceil(NN/256) scan blocks
#define HLP 132       // hL padded row stride (floats): +4 breaks bank conflicts

typedef __bf16 bf16x8_t __attribute__((ext_vector_type(8)));
typedef unsigned short ushort8_t __attribute__((ext_vector_type(8)));
typedef float f32x4_t __attribute__((ext_vector_type(4)));
union BF8 { ushort8_t u; bf16x8_t b; };

// ---------- helpers ----------
__device__ __forceinline__ void fma4(float4& a, float s, float4 w) {
  a.x = fmaf(s, w.x, a.x); a.y = fmaf(s, w.y, a.y);
  a.z = fmaf(s, w.z, a.z); a.w = fmaf(s, w.w, a.w);
}
__device__ __forceinline__ unsigned short f2bf(float f) {   // RNE f32->bf16
  unsigned u = __float_as_uint(f);
  unsigned r = ((u >> 16) & 1u) + 0x7FFFu;
  return (unsigned short)((u + r) >> 16);
}
__device__ __forceinline__ float bf2f(unsigned short u) {
  return __uint_as_float((unsigned)u << 16);
}

// LayerNorm 32 nodes -> swizzled bf16 LDS tile [32][128]; block = 512 threads.
__device__ __forceinline__ void ln_tile_bf32(const float* __restrict__ h, int nb,
                                             const float* __restrict__ sc,
                                             const float* __restrict__ bi,
                                             ushort* xbf) {
  int tid = threadIdx.x;
  int r = tid >> 4, l16 = tid & 15;
  int nr = nb + r; if (nr >= NN) nr = NN - 1;   // clamp: tail rows unused
  const float* hp = h + (size_t)nr * DD + l16 * 8;
  float4 a0 = *(const float4*)hp;
  float4 a1 = *(const float4*)(hp + 4);
  float sum = a0.x + a0.y + a0.z + a0.w + a1.x + a1.y + a1.z + a1.w;
  float sq  = a0.x*a0.x + a0.y*a0.y + a0.z*a0.z + a0.w*a0.w
            + a1.x*a1.x + a1.y*a1.y + a1.z*a1.z + a1.w*a1.w;
#pragma unroll
  for (int off = 8; off >= 1; off >>= 1) {
    sum += __shfl_xor(sum, off, 64);
    sq  += __shfl_xor(sq,  off, 64);
  }
  float mu   = sum * (1.0f / DD);
  float var  = sq * (1.0f / DD) - mu * mu;
  float rstd = rsqrtf(var + LN_EPS);
  int d0 = l16 * 8;
  float4 s0 = *(const float4*)(sc + d0), s1 = *(const float4*)(sc + d0 + 4);
  float4 b0 = *(const float4*)(bi + d0), b1 = *(const float4*)(bi + d0 + 4);
  ushort8_t u;
  u[0] = f2bf((a0.x - mu) * rstd * s0.x + b0.x);
  u[1] = f2bf((a0.y - mu) * rstd * s0.y + b0.y);
  u[2] = f2bf((a0.z - mu) * rstd * s0.z + b0.z);
  u[3] = f2bf((a0.w - mu) * rstd * s0.w + b0.w);
  u[4] = f2bf((a1.x - mu) * rstd * s1.x + b1.x);
  u[5] = f2bf((a1.y - mu) * rstd * s1.y + b1.y);
  u[6] = f2bf((a1.z - mu) * rstd * s1.z + b1.z);
  u[7] = f2bf((a1.w - mu) * rstd * s1.w + b1.w);
  int off = (r * 256 + l16 * 16) ^ ((r & 7) << 4);
  *(ushort8_t*)((char*)xbf + off) = u;
}

// ---------- kernels ----------
// h = x @ node_W + node_b ; 32 nodes/block, W staged in LDS.
__global__ __launch_bounds__(256) void k_node_proj(const float* __restrict__ x,
                                                   const float* __restrict__ W,
                                                   const float* __restrict__ b,
                                                   float* __restrict__ h) {
  __shared__ float Wl[FIN * DD];    // 32 KB
  __shared__ float xt[32][FIN];     // 8 KB
  int tid = threadIdx.x;
  int nb = blockIdx.x * 32;
  for (int i = tid * 4; i < FIN * DD; i += 1024)
    *(float4*)&Wl[i] = *(const float4*)(W + i);
  for (int i = tid * 4; i < 32 * FIN; i += 1024) {
    int row = i >> 6, cc = i & 63;
    int node = nb + row; if (node >= NN) node = NN - 1;
    *(float4*)&xt[row][cc] = *(const float4*)(x + (size_t)node * FIN + cc);
  }
  __syncthreads();
  int c4 = (tid & 31) * 4;
  int r0 = (tid >> 5) * 4;
  float4 bv = *(const float4*)(b + c4);
  float4 a0 = bv, a1 = bv, a2 = bv, a3 = bv;
  for (int k = 0; k < FIN; k++) {
    float4 wv = *(const float4*)&Wl[k * DD + c4];
    fma4(a0, xt[r0][k], wv);
    fma4(a1, xt[r0 + 1][k], wv);
    fma4(a2, xt[r0 + 2][k], wv);
    fma4(a3, xt[r0 + 3][k], wv);
  }
  int n0 = nb + r0;
  if (n0 < NN)     *(float4*)(h + (size_t)n0 * DD + c4) = a0;
  if (n0 + 1 < NN) *(float4*)(h + (size_t)(n0 + 1) * DD + c4) = a1;
  if (n0 + 2 < NN) *(float4*)(h + (size_t)(n0 + 2) * DD + c4) = a2;
  if (n0 + 3 < NN) *(float4*)(h + (size_t)(n0 + 3) * DD + c4) = a3;
}

// per sorted edge: sim (dot), dist (norm) in fp32. 16 lanes/edge. No atomics.
__global__ __launch_bounds__(256) void k_edge1(const int* __restrict__ src_s, const int* __restrict__ tgt_s,
                                               const float* __restrict__ h, float* __restrict__ sim,
                                               float* __restrict__ dist) {
  int gid = blockIdx.x * 256 + threadIdx.x;
  int e = gid >> 4;
  if (e >= NE) return;
  int j = gid & 15;
  int s = src_s[e], t = tgt_s[e];
  const float4* ap = (const float4*)(h + (size_t)s * DD + j * 8);
  const float4* bp = (const float4*)(h + (size_t)t * DD + j * 8);
  float4 a0 = ap[0], a1 = ap[1];
  float4 b0 = bp[0], b1 = bp[1];
  float dot = 0.f, sq = 0.f;
  dot = fmaf(a0.x, b0.x, dot); dot = fmaf(a0.y, b0.y, dot);
  dot = fmaf(a0.z, b0.z, dot); dot = fmaf(a0.w, b0.w, dot);
  dot = fmaf(a1.x, b1.x, dot); dot = fmaf(a1.y, b1.y, dot);
  dot = fmaf(a1.z, b1.z, dot); dot = fmaf(a1.w, b1.w, dot);
  float d0 = a0.x - b0.x, d1 = a0.y - b0.y, d2 = a0.z - b0.z, d3 = a0.w - b0.w;
  float d4 = a1.x - b1.x, d5 = a1.y - b1.y, d6 = a1.z - b1.z, d7 = a1.w - b1.w;
  sq = fmaf(d0, d0, sq); sq = fmaf(d1, d1, sq); sq = fmaf(d2, d2, sq); sq = fmaf(d3, d3, sq);
  sq = fmaf(d4, d4, sq); sq = fmaf(d5, d5, sq); sq = fmaf(d6, d6, sq); sq = fmaf(d7, d7, sq);
#pragma unroll
  for (int off = 8; off >= 1; off >>= 1) {
    dot += __shfl_xor(dot, off, 64);
    sq  += __shfl_xor(sq,  off, 64);
  }
  if (j == 0) {
    sim[e]  = dot;                  // BETA == 1.0
    dist[e] = sqrtf(sq);
  }
}

// curvature aggregate per tgt node via tgt-CSR gather (no atomics): 8 lanes/node.
__global__ __launch_bounds__(256) void k_curva(const int* __restrict__ rowstart_t,
    const int* __restrict__ eid_t, const float* __restrict__ sim,
    const float* __restrict__ dist, float* __restrict__ aggv) {
  int node = blockIdx.x * 32 + (threadIdx.x >> 3);
  if (node >= NN) return;
  int j = threadIdx.x & 7;
  int rs = rowstart_t[node], re = rowstart_t[node + 1];
  float m = -3.4e38f;
  for (int i = rs + j; i < re; i += 8) m = fmaxf(m, sim[eid_t[i]]);
#pragma unroll
  for (int off = 1; off <= 4; off <<= 1) m = fmaxf(m, __shfl_xor(m, off, 64));
  float den = 0.f, nd = 0.f;
  for (int i = rs + j; i < re; i += 8) {
    int e = eid_t[i];
    float ev = expf(sim[e] - m);
    den += ev;
    nd = fmaf(ev, dist[e], nd);
  }
#pragma unroll
  for (int off = 1; off <= 4; off <<= 1) {
    den += __shfl_xor(den, off, 64);
    nd  += __shfl_xor(nd,  off, 64);
  }
  if (j == 0) aggv[node] = den > 0.f ? nd / den : 0.f;
}

// LN1 + QKV projection via swapped-operand MFMA -> bf16 q/k/v. 32 rows/block, 8 waves.
__global__ __launch_bounds__(512) void k_ln_qkv(const float* __restrict__ h,
    const float* __restrict__ n1s_l, const float* __restrict__ n1b_l,
    const ushort* __restrict__ qkvT_l,
    const float* __restrict__ qb_l, const float* __restrict__ kb_l, const float* __restrict__ vb_l,
    ushort* __restrict__ q, ushort* __restrict__ kk, ushort* __restrict__ v) {
  __shared__ __align__(16) ushort xbf[32 * DD];
  int nb = blockIdx.x * 32;
  ln_tile_bf32(h, nb, n1s_l, n1b_l, xbf);
  __syncthreads();
  int lane = threadIdx.x & 63;
  int w = threadIdx.x >> 6;
  int g = lane >> 4, c = lane & 15;
  int xr = (c & 7) << 4;
  char* xb = (char*)xbf;
  BF8 a[2][4];
#pragma unroll
  for (int nt = 0; nt < 2; nt++)
#pragma unroll
    for (int kt = 0; kt < 4; kt++)
      a[nt][kt].u = *(ushort8_t*)(xb + (((nt * 16 + c) * 256 + kt * 64 + g * 16) ^ xr));
#pragma unroll
  for (int ti = 0; ti < 3; ti++) {
    int t = w * 3 + ti;                // 0..23
    int m = t >> 3;                    // 0=q 1=k 2=v
    int colb = (t & 7) * 16;
    const float* bias = (m == 0 ? qb_l : (m == 1 ? kb_l : vb_l));
    float4 bv = *(const float4*)(bias + colb + g * 4);
    f32x4_t acc0 = {bv.x, bv.y, bv.z, bv.w};
    f32x4_t acc1 = acc0;
    const ushort* wp = qkvT_l + (size_t)(m * DD + colb + c) * DD + g * 8;
#pragma unroll
    for (int kt = 0; kt < 4; kt++) {
      BF8 b; b.u = *(const ushort8_t*)(wp + kt * 32);
      acc0 = __builtin_amdgcn_mfma_f32_16x16x32_bf16(b.b, a[0][kt].b, acc0, 0, 0, 0);
      acc1 = __builtin_amdgcn_mfma_f32_16x16x32_bf16(b.b, a[1][kt].b, acc1, 0, 0, 0);
    }
    ushort* out = (m == 0 ? q : (m == 1 ? kk : v));
    int n0 = nb + c;
    if (n0 < NN) {
      ushort4 o; o.x = f2bf(acc0[0]); o.y = f2bf(acc0[1]); o.z = f2bf(acc0[2]); o.w = f2bf(acc0[3]);
      *(ushort4*)(out + (size_t)n0 * DD + colb + g * 4) = o;
    }
    int n1 = nb + 16 + c;
    if (n1 < NN) {
      ushort4 o; o.x = f2bf(acc1[0]); o.y = f2bf(acc1[1]); o.z = f2bf(acc1[2]); o.w = f2bf(acc1[3]);
      *(ushort4*)(out + (size_t)n1 * DD + colb + g * 4) = o;
    }
  }
}

// per (edge, head): curv + PWL segment staged in LDS by first 32 threads, then
// qk dot (bf16) + PWL bias -> RAW score (softmax handled by k_softmax_t; the
// max subtraction stays MANDATORY — r5/r6: self-loop dist==0 -> |bias| ~ 1e4).
__global__ __launch_bounds__(256) void k_scores(const int* __restrict__ src_s, const int* __restrict__ tgt_s,
    const ushort* __restrict__ q, const ushort* __restrict__ k,
    const float* __restrict__ dist, const float* __restrict__ aggv,
    const float* __restrict__ bp_g,
    const float* __restrict__ slope_l, const float* __restrict__ inter_l,
    float* __restrict__ escore) {
  __shared__ float lsl[NSEG * HH], lin[NSEG * HH], bp[DD];
  __shared__ float lcurv[32];
  __shared__ int   lseg[32];
  int tid = threadIdx.x;
  for (int idx = tid; idx < NSEG * HH; idx += 256) { lsl[idx] = slope_l[idx]; lin[idx] = inter_l[idx]; }
  if (tid < DD) bp[tid] = bp_g[tid];
  __syncthreads();
  int eb = blockIdx.x * 32;
  if (tid < 32) {
    int e = eb + tid;
    if (e < NE) {
      int t = tgt_s[e];
      float curv = 1.0f - aggv[t] / fmaxf(dist[e], 1e-6f);
      int lo = 0, hi = DD;
      while (lo < hi) { int mid = (lo + hi) >> 1; if (bp[mid] < curv) lo = mid + 1; else hi = mid; }
      lcurv[tid] = curv;
      lseg[tid] = lo;
    }
  }
  __syncthreads();
  int gi = blockIdx.x * 256 + tid;
  if (gi >= NE * HH) return;
  int i = gi >> 3, hh = gi & 7;
  int s = src_s[i], t = tgt_s[i];
  int li = tid >> 3;
  float curv = lcurv[li];
  int seg = lseg[li];
  float bias = fmaf(lsl[seg * HH + hh], curv, lin[seg * HH + hh]);
  const ushort8_t* qp = (const ushort8_t*)(q + (size_t)s * DD + hh * DHH);
  const ushort8_t* kp = (const ushort8_t*)(k + (size_t)t * DD + hh * DHH);
  float dot = 0.f;
#pragma unroll
  for (int ii = 0; ii < 2; ii++) {
    ushort8_t a = qp[ii], b = kp[ii];
#pragma unroll
    for (int jj = 0; jj < 8; jj++) dot = fmaf(bf2f(a[jj]), bf2f(b[jj]), dot);
  }
  escore[gi] = dot * 0.25f + bias;   // 1/sqrt(16)
  (void)t;
}

// attention softmax stats per (tgt node, head), READ-ONLY -> packed (m, 1/sum).
__global__ __launch_bounds__(256) void k_softmax_t(const int* __restrict__ rowstart_t,
    const int* __restrict__ eid_t, const float* __restrict__ escore, float2* __restrict__ msd) {
  int node = blockIdx.x * 32 + (threadIdx.x >> 3);
  if (node >= NN) return;
  int hh = threadIdx.x & 7;
  int rs = rowstart_t[node], re = rowstart_t[node + 1];
  float m = -3.4e38f;
  int i = rs;
  for (; i + 4 <= re; i += 4) {
    int e0 = eid_t[i], e1 = eid_t[i + 1], e2 = eid_t[i + 2], e3 = eid_t[i + 3];
    float s0 = escore[e0 * HH + hh];
    float s1 = escore[e1 * HH + hh];
    float s2 = escore[e2 * HH + hh];
    float s3 = escore[e3 * HH + hh];
    m = fmaxf(m, s0); m = fmaxf(m, s1); m = fmaxf(m, s2); m = fmaxf(m, s3);
  }
  for (; i < re; i++) m = fmaxf(m, escore[eid_t[i] * HH + hh]);
  float sum = 0.f;
  i = rs;
  for (; i + 4 <= re; i += 4) {
    int e0 = eid_t[i], e1 = eid_t[i + 1], e2 = eid_t[i + 2], e3 = eid_t[i + 3];
    float p0 = expf(escore[e0 * HH + hh] - m);
    float p1 = expf(escore[e1 * HH + hh] - m);
    float p2 = expf(escore[e2 * HH + hh] - m);
    float p3 = expf(escore[e3 * HH + hh] - m);
    sum += p0; sum += p1; sum += p2; sum += p3;
  }
  for (; i < re; i++) sum += expf(escore[eid_t[i] * HH + hh] - m);
  float2 o; o.x = m; o.y = sum > 0.f ? 1.0f / sum : 0.f;
  msd[(size_t)node * HH + hh] = o;
}

// CSR-gather message aggregation: one wave per src node, 2 dims/lane -> bf16 out.
__global__ __launch_bounds__(256) void k_agg(const int* __restrict__ tgt_s,
    const int* __restrict__ rowstart,
    const float* __restrict__ escore, const float2* __restrict__ msd,
    const ushort* __restrict__ v, ushort* __restrict__ aggmb) {
  int wave = (blockIdx.x * 256 + threadIdx.x) >> 6;
  int lane = threadIdx.x & 63;
  int rs = rowstart[wave], re = rowstart[wave + 1];
  int hh = lane >> 3;
  int d = lane * 2;
  float a0 = 0.f, a1 = 0.f;
  int i = rs;
  for (; i + 4 <= re; i += 4) {
    int t0 = tgt_s[i], t1 = tgt_s[i + 1], t2 = tgt_s[i + 2], t3 = tgt_s[i + 3];
    float e0 = escore[(i    ) * HH + hh];
    float e1 = escore[(i + 1) * HH + hh];
    float e2 = escore[(i + 2) * HH + hh];
    float e3 = escore[(i + 3) * HH + hh];
    float2 m0 = msd[(size_t)t0 * HH + hh], m1 = msd[(size_t)t1 * HH + hh];
    float2 m2 = msd[(size_t)t2 * HH + hh], m3 = msd[(size_t)t3 * HH + hh];
    ushort2 v0 = *(const ushort2*)(v + (size_t)t0 * DD + d);
    ushort2 v1 = *(const ushort2*)(v + (size_t)t1 * DD + d);
    ushort2 v2 = *(const ushort2*)(v + (size_t)t2 * DD + d);
    ushort2 v3 = *(const ushort2*)(v + (size_t)t3 * DD + d);
    float p0 = expf(e0 - m0.x) * m0.y;
    float p1 = expf(e1 - m1.x) * m1.y;
    float p2 = expf(e2 - m2.x) * m2.y;
    float p3 = expf(e3 - m3.x) * m3.y;
    a0 = fmaf(p0, bf2f(v0.x), a0); a1 = fmaf(p0, bf2f(v0.y), a1);
    a0 = fmaf(p1, bf2f(v1.x), a0); a1 = fmaf(p1, bf2f(v1.y), a1);
    a0 = fmaf(p2, bf2f(v2.x), a0); a1 = fmaf(p2, bf2f(v2.y), a1);
    a0 = fmaf(p3, bf2f(v3.x), a0); a1 = fmaf(p3, bf2f(v3.y), a1);
  }
  for (; i < re; i++) {
    int t = tgt_s[i];
    float2 md = msd[(size_t)t * HH + hh];
    float prob = expf(escore[i * HH + hh] - md.x) * md.y;
    ushort2 vv = *(const ushort2*)(v + (size_t)t * DD + d);
    a0 = fmaf(prob, bf2f(vv.x), a0);
    a1 = fmaf(prob, bf2f(vv.y), a1);
  }
  ushort2 o; o.x = f2bf(a0); o.y = f2bf(a1);
  *(ushort2*)(aggmb + (size_t)wave * DD + d) = o;
}

// FUSED: h' = h + aggm@oW + ob (in LDS hL) -> LN2 -> FFN -> h = h' + FFN out.
// Deletes the separate k_update_o pass and its full h RMW (round-13 top kernels).
// All per-element arithmetic sequences identical to r13 -> bit-exact.
__global__ __launch_bounds__(512) void k_attn_ffn(const ushort* __restrict__ aggmb,
    const ushort* __restrict__ oT_l, const float* __restrict__ ob_l,
    const float* __restrict__ n2s_l, const float* __restrict__ n2b_l,
    const ushort* __restrict__ f1T_l, const float* __restrict__ f1b_l,
    const ushort* __restrict__ f2T_l, const float* __restrict__ f2b_l,
    float* __restrict__ h) {
  __shared__ float hL[64 * HLP];                      // 33 KB (pad +4: no col-write conflicts)
  __shared__ __align__(16) char ubuf[64 * 256 * 2];   // 32 KB union: xbf then tbf
  ushort* xbf = (ushort*)ubuf;
  char* xb = ubuf;
  char* tb = ubuf;
  int nb = blockIdx.x * 64;
  int tid = threadIdx.x;
  int lane = tid & 63, w = tid >> 6;
  int g = lane >> 4, c = lane & 15;
  int colb = w * 16;
  int xr = (c & 7) << 4;
  // ---- Stage 1: O-projection + residual -> hL (same MFMA/add order as r13 k_update_o)
  {
    float4 obv = *(const float4*)(ob_l + colb + g * 4);
    const ushort* wp = oT_l + (size_t)(colb + c) * DD + g * 8;
    BF8 b0, b1, b2, b3;
    b0.u = *(const ushort8_t*)(wp);
    b1.u = *(const ushort8_t*)(wp + 32);
    b2.u = *(const ushort8_t*)(wp + 64);
    b3.u = *(const ushort8_t*)(wp + 96);
#pragma unroll
    for (int nt = 0; nt < 4; nt++) {
      int node = nb + nt * 16 + c;
      int na = node < NN ? node : NN - 1;
      const ushort* ap = aggmb + (size_t)na * DD + g * 8;
      BF8 a0, a1, a2, a3;
      a0.u = *(const ushort8_t*)(ap);
      a1.u = *(const ushort8_t*)(ap + 32);
      a2.u = *(const ushort8_t*)(ap + 64);
      a3.u = *(const ushort8_t*)(ap + 96);
      f32x4_t acc = {obv.x, obv.y, obv.z, obv.w};
      acc = __builtin_amdgcn_mfma_f32_16x16x32_bf16(b0.b, a0.b, acc, 0, 0, 0);
      acc = __builtin_amdgcn_mfma_f32_16x16x32_bf16(b1.b, a1.b, acc, 0, 0, 0);
      acc = __builtin_amdgcn_mfma_f32_16x16x32_bf16(b2.b, a2.b, acc, 0, 0, 0);
      acc = __builtin_amdgcn_mfma_f32_16x16x32_bf16(b3.b, a3.b, acc, 0, 0, 0);
      float4 hv = *(const float4*)(h + (size_t)na * DD + colb + g * 4);
      hv.x += acc[0]; hv.y += acc[1]; hv.z += acc[2]; hv.w += acc[3];
      *(float4*)&hL[(nt * 16 + c) * HLP + colb + g * 4] = hv;
    }
  }
  __syncthreads();
  // ---- Stage 2: LN2 from hL -> xbf (same arithmetic as r13 ln_tile_bf64)
  {
    int l16 = tid & 15;
    int d0 = l16 * 8;
    float4 s0 = *(const float4*)(n2s_l + d0), s1 = *(const float4*)(n2s_l + d0 + 4);
    float4 bb0 = *(const float4*)(n2b_l + d0), bb1 = *(const float4*)(n2b_l + d0 + 4);
#pragma unroll
    for (int p = 0; p < 2; p++) {
      int r = p * 32 + (tid >> 4);
      const float* hp = &hL[r * HLP + d0];
      float4 a0 = *(const float4*)hp;
      float4 a1 = *(const float4*)(hp + 4);
      float sum = a0.x + a0.y + a0.z + a0.w + a1.x + a1.y + a1.z + a1.w;
      float sq  = a0.x*a0.x + a0.y*a0.y + a0.z*a0.z + a0.w*a0.w
                + a1.x*a1.x + a1.y*a1.y + a1.z*a1.z + a1.w*a1.w;
#pragma unroll
      for (int off = 8; off >= 1; off >>= 1) {
        sum += __shfl_xor(sum, off, 64);
        sq  += __shfl_xor(sq,  off, 64);
      }
      float mu   = sum * (1.0f / DD);
      float var  = sq * (1.0f / DD) - mu * mu;
      float rstd = rsqrtf(var + LN_EPS);
      ushort8_t u;
      u[0] = f2bf((a0.x - mu) * rstd * s0.x + bb0.x);
      u[1] = f2bf((a0.y - mu) * rstd * s0.y + bb0.y);
      u[2] = f2bf((a0.z - mu) * rstd * s0.z + bb0.z);
      u[3] = f2bf((a0.w - mu) * rstd * s0.w + bb0.w);
      u[4] = f2bf((a1.x - mu) * rstd * s1.x + bb1.x);
      u[5] = f2bf((a1.y - mu) * rstd * s1.y + bb1.y);
      u[6] = f2bf((a1.z - mu) * rstd * s1.z + bb1.z);
      u[7] = f2bf((a1.w - mu) * rstd * s1.w + bb1.w);
      int off = (r * 256 + l16 * 16) ^ ((r & 7) << 4);
      *(ushort8_t*)(xb + off) = u;
    }
  }
  __syncthreads();
  // A-frags from xbf (registers)
  BF8 a[4][4];
#pragma unroll
  for (int nt = 0; nt < 4; nt++)
#pragma unroll
    for (int kt = 0; kt < 4; kt++)
      a[nt][kt].u = *(ushort8_t*)(xb + (((nt * 16 + c) * 256 + kt * 64 + g * 16) ^ xr));
  __syncthreads();   // xbf dead; ubuf becomes tbf
  // ---- Stage 3: FFN (identical structure to r13 k_ffn, 2 chunks of 256)
  float4 bv2 = *(const float4*)(f2b_l + colb + g * 4);
  f32x4_t o0 = {bv2.x, bv2.y, bv2.z, bv2.w};
  f32x4_t o1 = o0, o2 = o0, o3 = o0;
#pragma unroll
  for (int ch = 0; ch < 2; ch++) {
    if (ch) __syncthreads();           // tbf reuse: wait for chunk-0 reads
#pragma unroll
    for (int ti = 0; ti < 2; ti++) {
      int ctile = w * 2 + ti;          // 0..15 within chunk
      int col = ch * 256 + ctile * 16;
      float4 bv = *(const float4*)(f1b_l + col + g * 4);
      f32x4_t ac0 = {bv.x, bv.y, bv.z, bv.w};
      f32x4_t ac1 = ac0, ac2 = ac0, ac3 = ac0;
      const ushort* wp = f1T_l + (size_t)(col + c) * DD + g * 8;
#pragma unroll
      for (int kt = 0; kt < 4; kt++) {
        BF8 b; b.u = *(const ushort8_t*)(wp + kt * 32);
        ac0 = __builtin_amdgcn_mfma_f32_16x16x32_bf16(b.b, a[0][kt].b, ac0, 0, 0, 0);
        ac1 = __builtin_amdgcn_mfma_f32_16x16x32_bf16(b.b, a[1][kt].b, ac1, 0, 0, 0);
        ac2 = __builtin_amdgcn_mfma_f32_16x16x32_bf16(b.b, a[2][kt].b, ac2, 0, 0, 0);
        ac3 = __builtin_amdgcn_mfma_f32_16x16x32_bf16(b.b, a[3][kt].b, ac3, 0, 0, 0);
      }
      int colL = (ctile * 16 + g * 4) * 2;     // byte col within chunk tile
      {
        int row = c;
        ushort4 o4; o4.x = f2bf(fmaxf(ac0[0], 0.f)); o4.y = f2bf(fmaxf(ac0[1], 0.f));
        o4.z = f2bf(fmaxf(ac0[2], 0.f)); o4.w = f2bf(fmaxf(ac0[3], 0.f));
        *(ushort4*)(tb + ((row * 512 + colL) ^ ((row & 7) << 4))) = o4;
      }
      {
        int row = 16 + c;
        ushort4 o4; o4.x = f2bf(fmaxf(ac1[0], 0.f)); o4.y = f2bf(fmaxf(ac1[1], 0.f));
        o4.z = f2bf(fmaxf(ac1[2], 0.f)); o4.w = f2bf(fmaxf(ac1[3], 0.f));
        *(ushort4*)(tb + ((row * 512 + colL) ^ ((row & 7) << 4))) = o4;
      }
      {
        int row = 32 + c;
        ushort4 o4; o4.x = f2bf(fmaxf(ac2[0], 0.f)); o4.y = f2bf(fmaxf(ac2[1], 0.f));
        o4.z = f2bf(fmaxf(ac2[2], 0.f)); o4.w = f2bf(fmaxf(ac2[3], 0.f));
        *(ushort4*)(tb + ((row * 512 + colL) ^ ((row & 7) << 4))) = o4;
      }
      {
        int row = 48 + c;
        ushort4 o4; o4.x = f2bf(fmaxf(ac3[0], 0.f)); o4.y = f2bf(fmaxf(ac3[1], 0.f));
        o4.z = f2bf(fmaxf(ac3[2], 0.f)); o4.w = f2bf(fmaxf(ac3[3], 0.f));
        *(ushort4*)(tb + ((row * 512 + colL) ^ ((row & 7) << 4))) = o4;
      }
    }
    __syncthreads();
    const ushort* wp2 = f2T_l + (size_t)(colb + c) * 512 + ch * 256 + g * 8;
#pragma unroll
    for (int kt = 0; kt < 8; kt++) {
      BF8 b; b.u = *(const ushort8_t*)(wp2 + kt * 32);
      BF8 t0; t0.u = *(ushort8_t*)(tb + (((c) * 512 + kt * 64 + g * 16) ^ xr));
      BF8 t1; t1.u = *(ushort8_t*)(tb + (((16 + c) * 512 + kt * 64 + g * 16) ^ xr));
      BF8 t2; t2.u = *(ushort8_t*)(tb + (((32 + c) * 512 + kt * 64 + g * 16) ^ xr));
      BF8 t3; t3.u = *(ushort8_t*)(tb + (((48 + c) * 512 + kt * 64 + g * 16) ^ xr));
      o0 = __builtin_amdgcn_mfma_f32_16x16x32_bf16(b.b, t0.b, o0, 0, 0, 0);
      o1 = __builtin_amdgcn_mfma_f32_16x16x32_bf16(b.b, t1.b, o1, 0, 0, 0);
      o2 = __builtin_amdgcn_mfma_f32_16x16x32_bf16(b.b, t2.b, o2, 0, 0, 0);
      o3 = __builtin_amdgcn_mfma_f32_16x16x32_bf16(b.b, t3.b, o3, 0, 0, 0);
    }
  }
  // ---- Stage 4: final residual from hL -> global h
  {
    int node = nb + c;
    if (node < NN) {
      const float* lp = &hL[c * HLP + colb + g * 4];
      float4 hv = *(const float4*)lp;
      hv.x += o0[0]; hv.y += o0[1]; hv.z += o0[2]; hv.w += o0[3];
      *(float4*)(h + (size_t)node * DD + colb + g * 4) = hv;
    }
  }
  {
    int node = nb + 16 + c;
    if (node < NN) {
      const float* lp = &hL[(16 + c) * HLP + colb + g * 4];
      float4 hv = *(const float4*)lp;
      hv.x += o1[0]; hv.y += o1[1]; hv.z += o1[2]; hv.w += o1[3];
      *(float4*)(h + (size_t)node * DD + colb + g * 4) = hv;
    }
  }
  {
    int node = nb + 32 + c;
    if (node < NN) {
      const float* lp = &hL[(32 + c) * HLP + colb + g * 4];
      float4 hv = *(const float4*)lp;
      hv.x += o2[0]; hv.y += o2[1]; hv.z += o2[2]; hv.w += o2[3];
      *(float4*)(h + (size_t)node * DD + colb + g * 4) = hv;
    }
  }
  {
    int node = nb + 48 + c;
    if (node < NN) {
      const float* lp = &hL[(48 + c) * HLP + colb + g * 4];
      float4 hv = *(const float4*)lp;
      hv.x += o3[0]; hv.y += o3[1]; hv.z += o3[2]; hv.w += o3[3];
      *(float4*)(h + (size_t)node * DD + colb + g * 4) = hv;
    }
  }
}

// ---------- once-per-call setup kernels ----------
// transpose fp32 [K][C] -> bf16 [C][K], nm stacked matrices, dst stride per matrix
template <int K, int C>
__global__ void k_wt(const float* __restrict__ W, ushort* __restrict__ WT, int nm, int dstride) {
  int idx = blockIdx.x * 256 + threadIdx.x;
  if (idx >= K * C * nm) return;
  int mi = idx / (K * C), rem = idx - mi * (K * C);
  int cc = rem / K, kk2 = rem - cc * K;
  WT[(size_t)mi * dstride + cc * K + kk2] = f2bf(W[(size_t)mi * K * C + (size_t)kk2 * C + cc]);
}

__global__ void k_hist(const int* __restrict__ idxs, int* __restrict__ cnt) {
  int e = blockIdx.x * 256 + threadIdx.x;
  if (e < NE) atomicAdd(cnt + idxs[e], 1);
}

// multi-block exclusive scan of cnt[NN] -> rowstart
__global__ __launch_bounds__(256) void k_scan_blk(const int* __restrict__ cnt, int* __restrict__ bsum) {
  __shared__ int red[256];
  int tid = threadIdx.x;
  int idx = blockIdx.x * 256 + tid;
  red[tid] = (idx < NN) ? cnt[idx] : 0;
  __syncthreads();
  for (int off = 128; off >= 1; off >>= 1) {
    if (tid < off) red[tid] += red[tid + off];
    __syncthreads();
  }
  if (tid == 0) bsum[blockIdx.x] = red[0];
}

__global__ __launch_bounds__(256) void k_scan_top(const int* __restrict__ bsum,
                                                  int* __restrict__ boff, int* __restrict__ rowstart) {
  __shared__ int ps[256];
  int t = threadIdx.x;
  int v = (t < NBS) ? bsum[t] : 0;
  ps[t] = v;
  __syncthreads();
  for (int off = 1; off < 256; off <<= 1) {
    int x = (t >= off) ? ps[t - off] : 0;
    __syncthreads();
    ps[t] += x;
    __syncthreads();
  }
  boff[t] = ps[t] - v;                 // exclusive prefix of block sums
  if (t == 255) rowstart[NN] = ps[255];
}

__global__ __launch_bounds__(256) void k_scan_fin(const int* __restrict__ cnt,
                                                  const int* __restrict__ boff, int* __restrict__ rowstart) {
  __shared__ int ps[256];
  int t = threadIdx.x;
  int idx = blockIdx.x * 256 + t;
  int v = (idx < NN) ? cnt[idx] : 0;
  ps[t] = v;
  __syncthreads();
  for (int off = 1; off < 256; off <<= 1) {
    int x = (t >= off) ? ps[t - off] : 0;
    __syncthreads();
    ps[t] += x;
    __syncthreads();
  }
  if (idx < NN) rowstart[idx] = boff[blockIdx.x] + ps[t] - v;
}

// scatter edges into src-sorted order (all per-edge arrays use sorted index)
__global__ void k_fill(const int* __restrict__ src, const int* __restrict__ tgt,
                       const int* __restrict__ rowstart,
                       int* __restrict__ cur, int* __restrict__ src_s, int* __restrict__ tgt_s) {
  int e = blockIdx.x * 256 + threadIdx.x;
  if (e >= NE) return;
  int s = src[e];
  int p = atomicAdd(cur + s, 1);
  int pos = rowstart[s] + p;
  src_s[pos] = s;
  tgt_s[pos] = tgt[e];
}

// tgt-CSR: list of src-sorted edge ids per tgt node
__global__ void k_fill_t(const int* __restrict__ tgt_s, const int* __restrict__ rowstart_t,
                         int* __restrict__ cur_t, int* __restrict__ eid_t) {
  int i = blockIdx.x * 256 + threadIdx.x;
  if (i >= NE) return;
  int t = tgt_s[i];
  int p = atomicAdd(cur_t + t, 1);
  eid_t[rowstart_t[t] + p] = i;
}

// M[l][d][hh] = Sum_k cW2[d][k]*bW[l][k][hh]. Wave-parallel: one block per (l,d).
__global__ __launch_bounds__(64) void k_mbias_par(const float* __restrict__ cW2, const float* __restrict__ cb2,
                                                  const float* __restrict__ bW, const float* __restrict__ bb,
                                                  float* __restrict__ M, float* __restrict__ base) {
  int bid = blockIdx.x;
  int l = bid >> 7, d = bid & 127;
  int lane = threadIdx.x;
  int hh = lane >> 3, j0 = lane & 7;
  const float* bWl = bW + (size_t)l * DD * HH;
  float acc = 0.f;
#pragma unroll
  for (int t = 0; t < 16; t++) {
    int k = j0 + t * 8;
    acc = fmaf(cW2[d * DD + k], bWl[k * HH + hh], acc);
  }
#pragma unroll
  for (int off = 1; off <= 4; off <<= 1) acc += __shfl_xor(acc, off, 64);
  if (j0 == 0) M[(size_t)l * DD * HH + d * HH + hh] = acc;
  if (d == 0) {
    float bacc = 0.f;
#pragma unroll
    for (int t = 0; t < 16; t++) {
      int k = j0 + t * 8;
      bacc = fmaf(cb2[k], bWl[k * HH + hh], bacc);
    }
#pragma unroll
    for (int off = 1; off <= 4; off <<= 1) bacc += __shfl_xor(bacc, off, 64);
    if (j0 == 0) base[l * HH + hh] = bacc + bb[l * HH + hh];
  }
}

// sorted breakpoints + ranks — cW1/cb1 are layer-INDEPENDENT, computed once.
__global__ __launch_bounds__(128) void k_bp(const float* __restrict__ cW1, const float* __restrict__ cb1,
                                            float* __restrict__ bpg, int* __restrict__ posg) {
  __shared__ float x[DD], bp[DD];
  int tid = threadIdx.x;
  float c1v = cW1[tid], cbv = cb1[tid];
  x[tid] = (c1v == 0.f) ? __builtin_inff() : (-cbv / c1v);
  __syncthreads();
  float xv = x[tid]; int p = 0;
  for (int j = 0; j < DD; j++) {
    float xj = x[j];
    if (xj < xv || (xj == xv && j < tid)) p++;
  }
  bp[p] = xv;
  posg[tid] = p;
  __syncthreads();
  bpg[tid] = bp[tid];
}

// PWL table, wave-parallel: one block per (l, segment).
__global__ __launch_bounds__(64) void k_pwl_tab(const float* __restrict__ cW1, const float* __restrict__ cb1,
    const int* __restrict__ posg, const float* __restrict__ Mb, const float* __restrict__ basel,
    float* __restrict__ slopeg, float* __restrict__ interg) {
  int bid = blockIdx.x;
  int l = bid / NSEG, s = bid - l * NSEG;
  int lane = threadIdx.x;
  int hh = lane >> 3, j0 = lane & 7;
  const float* M = Mb + (size_t)l * DD * HH;
  float sl = 0.f, in = 0.f;
#pragma unroll
  for (int t = 0; t < 16; t++) {
    int d = j0 + t * 8;
    float cv = cW1[d], cbv = cb1[d];
    int p = posg[d];
    bool act = (cv == 0.f) ? (cbv > 0.f) : ((cv > 0.f) ? (p < s) : (p >= s));
    float m = act ? M[d * HH + hh] : 0.f;
    sl = fmaf(cv, m, sl);
    in = fmaf(cbv, m, in);
  }
#pragma unroll
  for (int off = 1; off <= 4; off <<= 1) {
    sl += __shfl_xor(sl, off, 64);
    in += __shfl_xor(in, off, 64);
  }
  if (j0 == 0) {
    size_t o = (size_t)l * NSEG * HH + s * HH + hh;
    slopeg[o] = sl;
    interg[o] = in + basel[l * HH + hh];
  }
}

__global__ void k_bounds(const int* __restrict__ batch, int* __restrict__ gstart, int* __restrict__ gend) {
  int n = blockIdx.x * 256 + threadIdx.x;
  if (n >= NN) return;
  int b = batch[n];
  if (n == 0 || batch[n - 1] != b) gstart[b] = n;
  if (n == NN - 1 || batch[n + 1] != b) gend[b] = n + 1;
}

// parallel pool: 256 nodes/block, running sums flushed at graph boundaries
__global__ __launch_bounds__(256) void k_pool_part(const float* __restrict__ h,
    const int* __restrict__ batch, float* __restrict__ gpool) {
  int tid = threadIdx.x;
  int d = tid & 127, sub = tid >> 7;
  int n0 = blockIdx.x * 256;
  int nend = n0 + 256; if (nend > NN) nend = NN;
  float run = 0.f; int gcur = -1;
  for (int n = n0 + sub; n < nend; n += 2) {
    int g = batch[n];
    if (g != gcur) {
      if (gcur >= 0) atomicAdd(gpool + (size_t)gcur * DD + d, run);
      run = 0.f; gcur = g;
    }
    run += h[(size_t)n * DD + d];
  }
  if (gcur >= 0) atomicAdd(gpool + (size_t)gcur * DD + d, run);
}

__global__ __launch_bounds__(256) void k_head(const float* __restrict__ gpool,
    const int* __restrict__ gstart, const int* __restrict__ gend,
    const float* __restrict__ W1, const float* __restrict__ b1,
    const float* __restrict__ W2, const float* __restrict__ b2, float* __restrict__ out) {
  __shared__ float mid[NG * 64];
  int tid = threadIdx.x;
  for (int idx = tid; idx < NG * 64; idx += 256) {
    int g = idx >> 6, j = idx & 63;
    int cnt = gend[g] - gstart[g]; if (cnt < 1) cnt = 1;
    float rc = 1.0f / (float)cnt;
    float acc = 0.f;
    for (int d = 0; d < DD; d++) acc = fmaf(gpool[g * DD + d], W1[d * 64 + j], acc);
    mid[idx] = fmaxf(fmaf(acc, rc, b1[j]), 0.f);
  }
  __syncthreads();
  if (tid < NG) {
    float acc = b2[0];
    for (int j = 0; j < 64; j++) acc = fmaf(mid[tid * 64 + j], W2[j], acc);
    out[tid] = acc;
  }
}

// ---------- launch ----------
extern "C" void kernel_launch(void* const* d_in, const int* in_sizes, int n_in,
                              void* d_out, int out_size, void* d_ws, size_t ws_size,
                              hipStream_t stream) {
  const float* x      = (const float*)d_in[0];
  const int*   ei     = (const int*)d_in[1];
  const int*   batch  = (const int*)d_in[2];
  const float* node_W = (const float*)d_in[3];
  const float* node_b = (const float*)d_in[4];
  const float* cW1    = (const float*)d_in[5];
  const float* cb1    = (const float*)d_in[6];
  const float* cW2    = (const float*)d_in[7];
  const float* cb2    = (const float*)d_in[8];
  const float* qW     = (const float*)d_in[9];
  const float* qb     = (const float*)d_in[10];
  const float* kW     = (const float*)d_in[11];
  const float* kb     = (const float*)d_in[12];
  const float* vW     = (const float*)d_in[13];
  const float* vb     = (const float*)d_in[14];
  const float* oW     = (const float*)d_in[15];
  const float* ob     = (const float*)d_in[16];
  const float* bW     = (const float*)d_in[17];
  const float* bb     = (const float*)d_in[18];
  const float* f1W    = (const float*)d_in[19];
  const float* f1b    = (const float*)d_in[20];
  const float* f2W    = (const float*)d_in[21];
  const float* f2b    = (const float*)d_in[22];
  const float* n1s    = (const float*)d_in[23];
  const float* n1b    = (const float*)d_in[24];
  const float* n2s    = (const float*)d_in[25];
  const float* n2b    = (const float*)d_in[26];
  const float* outW1  = (const float*)d_in[27];
  const float* outb1  = (const float*)d_in[28];
  const float* outW2  = (const float*)d_in[29];
  const float* outb2  = (const float*)d_in[30];

  const int* src = ei;
  const int* tgt = ei + NE;

  char* wp = (char*)d_ws;
  auto alloc = [&](size_t bytes) { void* p = (void*)wp; wp += (bytes + 255) & ~(size_t)255; return p; };
  float*    h       = (float*)alloc((size_t)NN * DD * 4);
  ushort*   q       = (ushort*)alloc((size_t)NN * DD * 2);
  ushort*   kk      = (ushort*)alloc((size_t)NN * DD * 2);
  ushort*   v       = (ushort*)alloc((size_t)NN * DD * 2);
  ushort*   aggmb   = (ushort*)alloc((size_t)NN * DD * 2);
  float*    sim     = (float*)alloc((size_t)NE * 4);
  float*    dist    = (float*)alloc((size_t)NE * 4);
  float*    escore  = (float*)alloc((size_t)NE * HH * 4);
  float2*   msd     = (float2*)alloc((size_t)NN * HH * 8);
  float*    aggv    = (float*)alloc((size_t)NN * 4);
  float*    Mb      = (float*)alloc((size_t)NL * DD * HH * 4);
  float*    basel   = (float*)alloc((size_t)NL * HH * 4);
  float*    bpg     = (float*)alloc((size_t)DD * 4);
  int*      posg    = (int*)alloc((size_t)DD * 4);
  float*    slopeg  = (float*)alloc((size_t)NL * NSEG * HH * 4);
  float*    interg  = (float*)alloc((size_t)NL * NSEG * HH * 4);
  int*      rowstart= (int*)alloc((size_t)(NN + 1) * 4);
  int*      rowstart_t = (int*)alloc((size_t)(NN + 1) * 4);
  int*      eid_t   = (int*)alloc((size_t)NE * 4);
  int*      src_s   = (int*)alloc((size_t)NE * 4);
  int*      tgt_s   = (int*)alloc((size_t)NE * 4);
  int*      cnt     = (int*)alloc((size_t)NN * 4);
  int*      cur     = (int*)alloc((size_t)NN * 4);
  int*      cnt_t   = (int*)alloc((size_t)NN * 4);
  int*      cur_t   = (int*)alloc((size_t)NN * 4);
  int*      bsum    = (int*)alloc((size_t)NBS * 4);
  int*      boff    = (int*)alloc((size_t)256 * 4);
  int*      gstart  = (int*)alloc((size_t)NG * 4);
  int*      gend    = (int*)alloc((size_t)NG * 4);
  float*    gpool   = (float*)alloc((size_t)NG * DD * 4);
  ushort*   qkvT    = (ushort*)alloc((size_t)NL * 3 * DD * DD * 2);
  ushort*   oT      = (ushort*)alloc((size_t)NL * DD * DD * 2);
  ushort*   f1T     = (ushort*)alloc((size_t)NL * DD * 512 * 2);
  ushort*   f2T     = (ushort*)alloc((size_t)NL * 512 * DD * 2);
  (void)in_sizes; (void)n_in; (void)out_size; (void)ws_size;

  // once-per-call setup
  hipMemsetAsync(cnt, 0, NN * 4, stream);
  hipMemsetAsync(cur, 0, NN * 4, stream);
  hipMemsetAsync(cnt_t, 0, NN * 4, stream);
  hipMemsetAsync(cur_t, 0, NN * 4, stream);
  hipMemsetAsync(gstart, 0, NG * 4, stream);
  hipMemsetAsync(gend, 0, NG * 4, stream);
  hipMemsetAsync(gpool, 0, NG * DD * 4, stream);
  // src-CSR (edge sort) and tgt-CSR (incoming-edge lists)
  k_hist<<<(NE + 255) / 256, 256, 0, stream>>>(src, cnt);
  k_scan_blk<<<NBS, 256, 0, stream>>>(cnt, bsum);
  k_scan_top<<<1, 256, 0, stream>>>(bsum, boff, rowstart);
  k_scan_fin<<<NBS, 256, 0, stream>>>(cnt, boff, rowstart);
  k_fill<<<(NE + 255) / 256, 256, 0, stream>>>(src, tgt, rowstart, cur, src_s, tgt_s);
  k_hist<<<(NE + 255) / 256, 256, 0, stream>>>(tgt, cnt_t);
  k_scan_blk<<<NBS, 256, 0, stream>>>(cnt_t, bsum);
  k_scan_top<<<1, 256, 0, stream>>>(bsum, boff, rowstart_t);
  k_scan_fin<<<NBS, 256, 0, stream>>>(cnt_t, boff, rowstart_t);
  k_fill_t<<<(NE + 255) / 256, 256, 0, stream>>>(tgt_s, rowstart_t, cur_t, eid_t);
  k_mbias_par<<<NL * DD, 64, 0, stream>>>(cW2, cb2, bW, bb, Mb, basel);
  k_bp<<<1, 128, 0, stream>>>(cW1, cb1, bpg, posg);
  k_pwl_tab<<<NL * NSEG, 64, 0, stream>>>(cW1, cb1, posg, Mb, basel, slopeg, interg);
  k_bounds<<<(NN + 255) / 256, 256, 0, stream>>>(batch, gstart, gend);
  // bf16-transposed weights
  k_wt<DD, DD><<<(NL * DD * DD + 255) / 256, 256, 0, stream>>>(qW, qkvT,               NL, 3 * DD * DD);
  k_wt<DD, DD><<<(NL * DD * DD + 255) / 256, 256, 0, stream>>>(kW, qkvT + DD * DD,     NL, 3 * DD * DD);
  k_wt<DD, DD><<<(NL * DD * DD + 255) / 256, 256, 0, stream>>>(vW, qkvT + 2 * DD * DD, NL, 3 * DD * DD);
  k_wt<DD, DD><<<(NL * DD * DD + 255) / 256, 256, 0, stream>>>(oW, oT, NL, DD * DD);
  k_wt<DD, 512><<<(NL * DD * 512 + 255) / 256, 256, 0, stream>>>(f1W, f1T, NL, DD * 512);
  k_wt<512, DD><<<(NL * DD * 512 + 255) / 256, 256, 0, stream>>>(f2W, f2T, NL, DD * 512);
  k_node_proj<<<NT32, 256, 0, stream>>>(x, node_W, node_b, h);

  for (int l = 0; l < NL; l++) {
    k_edge1<<<(NE * 16 + 255) / 256, 256, 0, stream>>>(src_s, tgt_s, h, sim, dist);
    k_curva<<<NT32, 256, 0, stream>>>(rowstart_t, eid_t, sim, dist, aggv);
    k_ln_qkv<<<NT32, 512, 0, stream>>>(h, n1s + l * DD, n1b + l * DD,
        qkvT + (size_t)l * 3 * DD * DD,
        qb + l * DD, kb + l * DD, vb + l * DD, q, kk, v);
    k_scores<<<(NE * HH + 255) / 256, 256, 0, stream>>>(src_s, tgt_s, q, kk,
        dist, aggv, bpg,
        slopeg + (size_t)l * NSEG * HH, interg + (size_t)l * NSEG * HH,
        escore);
    k_softmax_t<<<NT32, 256, 0, stream>>>(rowstart_t, eid_t, escore, msd);
    k_agg<<<NN / 4, 256, 0, stream>>>(tgt_s, rowstart, escore, msd, v, aggmb);
    k_attn_ffn<<<NT64, 512, 0, stream>>>(aggmb, oT + (size_t)l * DD * DD, ob + l * DD,
        n2s + l * DD, n2b + l * DD,
        f1T + (size_t)l * DD * 512, f1b + (size_t)l * 4 * DD,
        f2T + (size_t)l * 512 * DD, f2b + l * DD, h);
  }
  k_pool_part<<<(NN + 255) / 256, 256, 0, stream>>>(h, batch, gpool);
  k_head<<<1, 256, 0, stream>>>(gpool, gstart, gend, outW1, outb1, outW2, outb2, (float*)d_out);
}